// Round 1
// baseline (7965.611 us; speedup 1.0000x reference)
//
#include <hip/hip_runtime.h>
#include <cstdint>
#include <cstddef>

#define DEV __device__ __forceinline__

DEV float gelu_f(float x){ return 0.5f*x*(1.0f + erff(x*0.7071067811865476f)); }
DEV float softplus_f(float x){ return fmaxf(x,0.f) + log1pf(expf(-fabsf(x))); }

// ---------------------------------------------------------------------------
// Generic 3x3 conv, pad=1, 31x31 spatial. MODE 0: src is [item][CIN][31][31].
// MODE 1: src is vis_stem [64][1024][1024], window gathered around pos[item].
// Block: 256 threads, one (item, OCT-out-channel-tile).
// ---------------------------------------------------------------------------
template<int CIN, int OCT, int MODE, bool FGELU>
__global__ __launch_bounds__(256,2) void conv3x3_k(
    const float* __restrict__ src, const float* __restrict__ pos,
    const float* __restrict__ W, const float* __restrict__ Bv,
    float* __restrict__ out)
{
  const int item = blockIdx.x;
  const int oc0  = blockIdx.y * OCT;
  const int COUT = gridDim.y * OCT;
  const int t = threadIdx.x;

  __shared__ float tile[33*33];
  __shared__ float wl[CIN*9*OCT];

  // stage weights: wl[(ic*9+k)*OCT + oc] = W[oc0+oc][ic][k]
  for (int i = t; i < CIN*9*OCT; i += 256) {
    int oc = i / (CIN*9);
    int rk = i % (CIN*9);
    wl[rk*OCT + oc] = W[(size_t)(oc0+oc)*CIN*9 + rk];
  }

  int pp[4], py[4], px[4];
#pragma unroll
  for (int j=0;j<4;++j){ pp[j]=t+256*j; int pc=min(pp[j],960); py[j]=pc/31; px[j]=pc%31; }

  float acc[OCT][4];
#pragma unroll
  for (int o=0;o<OCT;++o)
#pragma unroll
    for (int j=0;j<4;++j) acc[o][j]=0.f;

  int cx=0, cy=0;
  if (MODE==1){ cx=(int)rintf(pos[item*2+0]); cy=(int)rintf(pos[item*2+1]); }
  const float* sb = (MODE==1) ? src : src + (size_t)item*CIN*961;

  for (int ic=0; ic<CIN; ++ic) {
    __syncthreads();
    for (int i=t; i<1089; i+=256) {
      int yy = i/33 - 1, xx = i%33 - 1;
      float v = 0.f;
      if ((unsigned)yy < 31u && (unsigned)xx < 31u) {
        if (MODE==1) {
          int gy = min(max(cy-15+yy,0),1023);
          int gx = min(max(cx-15+xx,0),1023);
          v = src[((size_t)ic<<20) + (gy<<10) + gx];
        } else {
          v = sb[ic*961 + yy*31 + xx];
        }
      }
      tile[i] = v;
    }
    __syncthreads();

    float tv[4][9];
#pragma unroll
    for (int j=0;j<4;++j)
#pragma unroll
      for (int dy=0;dy<3;++dy)
#pragma unroll
        for (int dx=0;dx<3;++dx)
          tv[j][dy*3+dx] = tile[(py[j]+dy)*33 + px[j]+dx];

    const float* wic = &wl[ic*9*OCT];
#pragma unroll
    for (int k=0;k<9;++k) {
#pragma unroll
      for (int og=0; og<OCT/4; ++og) {
        const float4 w4 = *reinterpret_cast<const float4*>(&wic[k*OCT + og*4]);
#pragma unroll
        for (int j=0;j<4;++j) {
          acc[og*4+0][j] = fmaf(tv[j][k], w4.x, acc[og*4+0][j]);
          acc[og*4+1][j] = fmaf(tv[j][k], w4.y, acc[og*4+1][j]);
          acc[og*4+2][j] = fmaf(tv[j][k], w4.z, acc[og*4+2][j]);
          acc[og*4+3][j] = fmaf(tv[j][k], w4.w, acc[og*4+3][j]);
        }
      }
    }
  }

#pragma unroll
  for (int o=0;o<OCT;++o) {
    float bv = Bv[oc0+o];
#pragma unroll
    for (int j=0;j<4;++j) {
      if (pp[j] < 961) {
        float v = acc[o][j] + bv;
        if (FGELU) v = gelu_f(v);
        out[((size_t)item*COUT + oc0+o)*961 + pp[j]] = v;
      }
    }
  }
}

// ---------------------------------------------------------------------------
// bottleneck window extraction: bwin[il][c][y][x], chunk of items
// ---------------------------------------------------------------------------
__global__ void extbwin_k(const float* __restrict__ bott, const float* __restrict__ spv,
                          float* __restrict__ bwin, int total)
{
  for (int idx = blockIdx.x*blockDim.x + threadIdx.x; idx < total; idx += gridDim.x*blockDim.x) {
    int il = idx / (256*121);
    int rem = idx % (256*121);
    int c = rem / 121;
    int p = rem % 121;
    int y = p/11, x = p%11;
    float pxf = fminf(fmaxf(spv[il*2+0]*0.25f, 0.f), 255.f);
    float pyf = fminf(fmaxf(spv[il*2+1]*0.25f, 0.f), 255.f);
    int cx = (int)rintf(pxf), cy = (int)rintf(pyf);
    int gy = min(max(cy + y - 5, 0), 255);
    int gx = min(max(cx + x - 5, 0), 255);
    bwin[idx] = bott[((size_t)c<<16) + (gy<<8) + gx];
  }
}

// ---------------------------------------------------------------------------
// depthwise 7x7, pad=3, zero-padded on the 11x11 window. thread = channel.
// output NHWC: dwout[(n*121+p)][256]
// ---------------------------------------------------------------------------
__global__ __launch_bounds__(256) void dw7x7_k(
    const float* __restrict__ bwin, const float* __restrict__ w,
    const float* __restrict__ b, float* __restrict__ dwout)
{
  int n = blockIdx.x, y = blockIdx.y, c = threadIdx.x;
  const float* pl = bwin + ((size_t)n*256 + c)*121;
  const float* wc = w + c*49;
  float bias = b[c];
  for (int x=0; x<11; ++x) {
    float a = bias;
#pragma unroll
    for (int dy=0; dy<7; ++dy) {
      int yy = y + dy - 3;
      if (yy < 0 || yy >= 11) continue;
#pragma unroll
      for (int dx=0; dx<7; ++dx) {
        int xx = x + dx - 3;
        if (xx < 0 || xx >= 11) continue;
        a = fmaf(pl[yy*11+xx], wc[dy*7+dx], a);
      }
    }
    dwout[((size_t)n*121 + y*11 + x)*256 + c] = a;
  }
}

// ---------------------------------------------------------------------------
// Fused ConvNeXt MLP: LN -> pw1(256->1024) -> gelu -> pw2(1024->256) -> *gamma
// -> residual into bwin (in place). Block: 32 rows, 256 threads.
// ---------------------------------------------------------------------------
__global__ __launch_bounds__(256,2) void cnx_mlp_k(
    const float* __restrict__ xin,
    const float* __restrict__ lnw, const float* __restrict__ lnb,
    const float* __restrict__ W1, const float* __restrict__ B1,
    const float* __restrict__ W2, const float* __restrict__ B2,
    const float* __restrict__ gvec,
    float* __restrict__ bwin)
{
  const int t = threadIdx.x;
  const int row0 = blockIdx.x * 32;

  __shared__ float xsT[256*36];   // [k][r] padded
  __shared__ float ghT[128*36];   // [h][r] padded
  __shared__ float w1s[16*128];   // [kk][h]
  __shared__ float w2s[16*256];   // [hh][c]

  // --- LN into xsT ---
  {
    int rl = t >> 3, g = t & 7;
    const float* xr = xin + (size_t)(row0+rl)*256 + g*32;
    float xv[32]; float s=0.f, s2=0.f;
#pragma unroll
    for (int i=0;i<32;i+=4){
      float4 v = *reinterpret_cast<const float4*>(xr+i);
      xv[i]=v.x; xv[i+1]=v.y; xv[i+2]=v.z; xv[i+3]=v.w;
      s  += v.x+v.y+v.z+v.w;
      s2 += v.x*v.x+v.y*v.y+v.z*v.z+v.w*v.w;
    }
#pragma unroll
    for (int m=1;m<8;m<<=1){ s += __shfl_xor(s,m); s2 += __shfl_xor(s2,m); }
    float mu = s*(1.f/256.f);
    float var = s2*(1.f/256.f) - mu*mu;
    float rstd = rsqrtf(var + 1e-6f);
#pragma unroll
    for (int i=0;i<32;++i){
      int c = g*32+i;
      xsT[c*36 + rl] = (xv[i]-mu)*rstd*lnw[c] + lnb[c];
    }
  }

  float acc2[4][8];
#pragma unroll
  for (int i=0;i<4;++i)
#pragma unroll
    for (int j=0;j<8;++j) acc2[i][j]=0.f;

  const int rg = t & 7;      // r0 = rg*4
  const int cg = t >> 3;     // c0 = cg*8   (GEMM2)
  const int hg = t >> 3;     // h0 = hg*4   (GEMM1)

  for (int hc=0; hc<8; ++hc) {
    const int hb = hc*128;
    float acc1[4][4];
#pragma unroll
    for (int i=0;i<4;++i)
#pragma unroll
      for (int j=0;j<4;++j) acc1[i][j]=0.f;

    for (int kc=0; kc<16; ++kc) {
      __syncthreads();
      for (int i=t; i<2048; i+=256) {
        int h = i >> 4, kk = i & 15;
        w1s[kk*128 + h] = W1[(size_t)(hb+h)*256 + kc*16 + kk];
      }
      __syncthreads();
#pragma unroll
      for (int kk=0; kk<16; ++kk) {
        int k = kc*16 + kk;
        float4 x4 = *reinterpret_cast<const float4*>(&xsT[k*36 + rg*4]);
        float4 w4 = *reinterpret_cast<const float4*>(&w1s[kk*128 + hg*4]);
        acc1[0][0]=fmaf(w4.x,x4.x,acc1[0][0]); acc1[0][1]=fmaf(w4.x,x4.y,acc1[0][1]);
        acc1[0][2]=fmaf(w4.x,x4.z,acc1[0][2]); acc1[0][3]=fmaf(w4.x,x4.w,acc1[0][3]);
        acc1[1][0]=fmaf(w4.y,x4.x,acc1[1][0]); acc1[1][1]=fmaf(w4.y,x4.y,acc1[1][1]);
        acc1[1][2]=fmaf(w4.y,x4.z,acc1[1][2]); acc1[1][3]=fmaf(w4.y,x4.w,acc1[1][3]);
        acc1[2][0]=fmaf(w4.z,x4.x,acc1[2][0]); acc1[2][1]=fmaf(w4.z,x4.y,acc1[2][1]);
        acc1[2][2]=fmaf(w4.z,x4.z,acc1[2][2]); acc1[2][3]=fmaf(w4.z,x4.w,acc1[2][3]);
        acc1[3][0]=fmaf(w4.w,x4.x,acc1[3][0]); acc1[3][1]=fmaf(w4.w,x4.y,acc1[3][1]);
        acc1[3][2]=fmaf(w4.w,x4.z,acc1[3][2]); acc1[3][3]=fmaf(w4.w,x4.w,acc1[3][3]);
      }
    }
    // gelu + bias -> ghT
#pragma unroll
    for (int hi=0; hi<4; ++hi) {
      float bv = B1[hb + hg*4 + hi];
      float4 gv;
      gv.x = gelu_f(acc1[hi][0]+bv);
      gv.y = gelu_f(acc1[hi][1]+bv);
      gv.z = gelu_f(acc1[hi][2]+bv);
      gv.w = gelu_f(acc1[hi][3]+bv);
      *reinterpret_cast<float4*>(&ghT[(hg*4+hi)*36 + rg*4]) = gv;
    }
    __syncthreads();

    for (int hcc=0; hcc<8; ++hcc) {
      if (hcc > 0) __syncthreads();
      for (int i=t; i<4096; i+=256) {
        int c = i >> 4, hh = i & 15;
        w2s[hh*256 + c] = W2[(size_t)c*1024 + hb + hcc*16 + hh];
      }
      __syncthreads();
#pragma unroll
      for (int hh=0; hh<16; ++hh) {
        float4 g4 = *reinterpret_cast<const float4*>(&ghT[(hcc*16+hh)*36 + rg*4]);
        float4 wa = *reinterpret_cast<const float4*>(&w2s[hh*256 + cg*8]);
        float4 wb = *reinterpret_cast<const float4*>(&w2s[hh*256 + cg*8 + 4]);
        acc2[0][0]=fmaf(g4.x,wa.x,acc2[0][0]); acc2[0][1]=fmaf(g4.x,wa.y,acc2[0][1]);
        acc2[0][2]=fmaf(g4.x,wa.z,acc2[0][2]); acc2[0][3]=fmaf(g4.x,wa.w,acc2[0][3]);
        acc2[0][4]=fmaf(g4.x,wb.x,acc2[0][4]); acc2[0][5]=fmaf(g4.x,wb.y,acc2[0][5]);
        acc2[0][6]=fmaf(g4.x,wb.z,acc2[0][6]); acc2[0][7]=fmaf(g4.x,wb.w,acc2[0][7]);
        acc2[1][0]=fmaf(g4.y,wa.x,acc2[1][0]); acc2[1][1]=fmaf(g4.y,wa.y,acc2[1][1]);
        acc2[1][2]=fmaf(g4.y,wa.z,acc2[1][2]); acc2[1][3]=fmaf(g4.y,wa.w,acc2[1][3]);
        acc2[1][4]=fmaf(g4.y,wb.x,acc2[1][4]); acc2[1][5]=fmaf(g4.y,wb.y,acc2[1][5]);
        acc2[1][6]=fmaf(g4.y,wb.z,acc2[1][6]); acc2[1][7]=fmaf(g4.y,wb.w,acc2[1][7]);
        acc2[2][0]=fmaf(g4.z,wa.x,acc2[2][0]); acc2[2][1]=fmaf(g4.z,wa.y,acc2[2][1]);
        acc2[2][2]=fmaf(g4.z,wa.z,acc2[2][2]); acc2[2][3]=fmaf(g4.z,wa.w,acc2[2][3]);
        acc2[2][4]=fmaf(g4.z,wb.x,acc2[2][4]); acc2[2][5]=fmaf(g4.z,wb.y,acc2[2][5]);
        acc2[2][6]=fmaf(g4.z,wb.z,acc2[2][6]); acc2[2][7]=fmaf(g4.z,wb.w,acc2[2][7]);
        acc2[3][0]=fmaf(g4.w,wa.x,acc2[3][0]); acc2[3][1]=fmaf(g4.w,wa.y,acc2[3][1]);
        acc2[3][2]=fmaf(g4.w,wa.z,acc2[3][2]); acc2[3][3]=fmaf(g4.w,wa.w,acc2[3][3]);
        acc2[3][4]=fmaf(g4.w,wb.x,acc2[3][4]); acc2[3][5]=fmaf(g4.w,wb.y,acc2[3][5]);
        acc2[3][6]=fmaf(g4.w,wb.z,acc2[3][6]); acc2[3][7]=fmaf(g4.w,wb.w,acc2[3][7]);
      }
    }
    // guard ghT/w1s/w2s reuse in next hc (kc-loop top sync handles w1s; need one for ghT)
  }

  // epilogue: out = (acc2 + B2)*gamma + bwin (in place residual)
#pragma unroll
  for (int ri=0; ri<4; ++ri) {
    int lrow = row0 + rg*4 + ri;
    int nl = lrow / 121, p = lrow % 121;
#pragma unroll
    for (int ci=0; ci<8; ++ci) {
      int c = cg*8 + ci;
      float v = (acc2[ri][ci] + B2[c]) * gvec[c];
      size_t idx = ((size_t)nl*256 + c)*121 + p;
      bwin[idx] += v;
    }
  }
}

// ---------------------------------------------------------------------------
// bnp 1x1 conv + gelu + gaussian-weighted spatial sum -> bn_vec[n][64]
// ---------------------------------------------------------------------------
__global__ __launch_bounds__(256) void bnvec_k(
    const float* __restrict__ bwin, const float* __restrict__ w,
    const float* __restrict__ bias, float* __restrict__ bn_vec)
{
  int n = blockIdx.x, t = threadIdx.x;
  int oc = t & 63, pg = t >> 6;

  float gsum = 0.f;
  for (int p=0;p<121;++p){
    int py=p/11, px=p%11;
    float ly=-1.f+0.2f*py, lx=-1.f+0.2f*px;
    gsum += expf(-(lx*lx+ly*ly)/0.32f);
  }

  float acc = 0.f;
  const float* wr = w + oc*256;
  float bv = bias[oc];
  for (int p = pg; p < 121; p += 4) {
    int py=p/11, px=p%11;
    float ly=-1.f+0.2f*py, lx=-1.f+0.2f*px;
    float g = expf(-(lx*lx+ly*ly)/0.32f);
    const float* bp = bwin + (size_t)n*256*121 + p;
    float s0=0,s1=0,s2=0,s3=0;
    for (int c=0;c<256;c+=4){
      float4 w4 = *reinterpret_cast<const float4*>(wr+c);
      s0 = fmaf(bp[(c+0)*121], w4.x, s0);
      s1 = fmaf(bp[(c+1)*121], w4.y, s1);
      s2 = fmaf(bp[(c+2)*121], w4.z, s2);
      s3 = fmaf(bp[(c+3)*121], w4.w, s3);
    }
    acc += gelu_f(bv+s0+s1+s2+s3) * g;
  }
  __shared__ float red[256];
  red[t] = acc; __syncthreads();
  if (t < 64) {
    float tot = red[t] + red[t+64] + red[t+128] + red[t+192];
    bn_vec[n*64 + oc] = tot / gsum;
  }
}

// ---------------------------------------------------------------------------
// FiLM: cond(84) @ film_w.T + film_b -> film[n][b][64]
// ---------------------------------------------------------------------------
__global__ __launch_bounds__(256) void film_k(
    const float* __restrict__ bn_vec, const float* __restrict__ ppb,
    const float* __restrict__ bemb, const float* __restrict__ fw,
    const float* __restrict__ fb, float* __restrict__ film)
{
  int n = blockIdx.x, t = threadIdx.x;
  __shared__ float cond[4][84];
  for (int i=t; i<4*84; i+=256) {
    int b = i/84, j = i%84;
    float v;
    if (j < 16) v = bemb[b*16 + j];
    else if (j == 16) { float p = ppb[((size_t)n*4+b)*2+0]; v = fminf(fmaxf(p*(1.f/1023.f),0.f),1.f); }
    else if (j == 17) { float p = ppb[((size_t)n*4+b)*2+1]; v = fminf(fmaxf(p*(1.f/1023.f),0.f),1.f); }
    else if (j == 18) { float p = ppb[((size_t)n*4+b)*2+0]; v = p - rintf(p); }
    else if (j == 19) { float p = ppb[((size_t)n*4+b)*2+1]; v = p - rintf(p); }
    else v = bn_vec[n*64 + (j-20)];
    cond[b][j] = v;
  }
  __syncthreads();
  int b = t >> 6, oc = t & 63;
  float s = fb[oc];
  for (int j=0;j<84;++j) s = fmaf(cond[b][j], fw[oc*84+j], s);
  film[((size_t)n*4+b)*64 + oc] = s;
}

// ---------------------------------------------------------------------------
// mod = gelu(intrinsic * (1+film[:32]) + film[32:])  (chunk of 256 nb-items)
// ---------------------------------------------------------------------------
__global__ void modgen_k(const float* __restrict__ intc, const float* __restrict__ film,
                         float* __restrict__ mod, int nbLocal0, int total)
{
  for (int idx = blockIdx.x*blockDim.x + threadIdx.x; idx < total; idx += gridDim.x*blockDim.x) {
    int il = idx / 30752;          // 32*961
    int rem = idx % 30752;
    int c = rem / 961;
    int p = rem % 961;
    int nl = (nbLocal0 + il) >> 2;
    float g  = 1.f + film[(size_t)il*64 + c];
    float be = film[(size_t)il*64 + 32 + c];
    float v = intc[((size_t)nl*32 + c)*961 + p];
    mod[idx] = gelu_f(fmaf(v, g, be));
  }
}

// ---------------------------------------------------------------------------
// dec3 1x1 conv + softplus + per-map sum-normalize -> out
// ---------------------------------------------------------------------------
__global__ __launch_bounds__(256) void dec3_k(
    const float* __restrict__ o2, const float* __restrict__ w3,
    const float* __restrict__ b3, float* __restrict__ outb)
{
  int il = blockIdx.x, t = threadIdx.x;
  float v[4];
#pragma unroll
  for (int j=0;j<4;++j) {
    int p = t + 256*j;
    float r = 0.f;
    if (p < 961) {
      float s = b3[0];
      for (int c=0;c<32;++c) s = fmaf(o2[((size_t)il*32+c)*961 + p], w3[c], s);
      r = softplus_f(s);
    }
    v[j] = r;
  }
  __shared__ float red[256];
  red[t] = v[0]+v[1]+v[2]+v[3];
  __syncthreads();
  for (int off=128; off>0; off>>=1) {
    if (t < off) red[t] += red[t+off];
    __syncthreads();
  }
  float inv = 1.f / fmaxf(red[0], 1e-8f);
#pragma unroll
  for (int j=0;j<4;++j) {
    int p = t + 256*j;
    if (p < 961) outb[(size_t)il*961 + p] = v[j]*inv;
  }
}

// ---------------------------------------------------------------------------
extern "C" void kernel_launch(void* const* d_in, const int* in_sizes, int n_in,
                              void* d_out, int out_size, void* d_ws, size_t ws_size,
                              hipStream_t stream)
{
  const float* bott = (const float*)d_in[0];
  const float* vis  = (const float*)d_in[1];
  const float* spv  = (const float*)d_in[2];
  const float* ppb  = (const float*)d_in[3];
  const float* ic1w = (const float*)d_in[4];  const float* ic1b = (const float*)d_in[5];
  const float* ic2w = (const float*)d_in[6];  const float* ic2b = (const float*)d_in[7];
  const float* ic3w = (const float*)d_in[8];  const float* ic3b = (const float*)d_in[9];
  const float* dww  = (const float*)d_in[10]; const float* dwb  = (const float*)d_in[11];
  const float* lnw  = (const float*)d_in[12]; const float* lnb  = (const float*)d_in[13];
  const float* pw1w = (const float*)d_in[14]; const float* pw1b = (const float*)d_in[15];
  const float* pw2w = (const float*)d_in[16]; const float* pw2b = (const float*)d_in[17];
  const float* cgam = (const float*)d_in[18];
  const float* bnpw = (const float*)d_in[19]; const float* bnpb = (const float*)d_in[20];
  const float* bemb = (const float*)d_in[21];
  const float* fw   = (const float*)d_in[22]; const float* fb   = (const float*)d_in[23];
  const float* d1w  = (const float*)d_in[24]; const float* d1b  = (const float*)d_in[25];
  const float* d2w  = (const float*)d_in[26]; const float* d2b  = (const float*)d_in[27];
  const float* d3w  = (const float*)d_in[28]; const float* d3b  = (const float*)d_in[29];
  float* out = (float*)d_out;

  char* ws = (char*)d_ws;
  float* regA = (float*)(ws);                 // 31,719,424 B
  float* regB = (float*)(ws + 31719424);      // 31,719,424 B
  float* regC = (float*)(ws + 63438848);      // 15,753,216 B (intrinsic chunk)
  float* bnv  = (float*)(ws + 79192064);      // 131,072 B
  float* film = (float*)(ws + 79323136);      // 524,288 B

  // ---- Phase 2: bottleneck/ConvNeXt path -> bn_vec (chunks of 256 n) ----
  for (int n0 = 0; n0 < 512; n0 += 256) {
    extbwin_k<<<4096,256,0,stream>>>(bott, spv + n0*2, regA, 256*256*121);
    dw7x7_k<<<dim3(256,11),256,0,stream>>>(regA, dww, dwb, regB);
    cnx_mlp_k<<<968,256,0,stream>>>(regB, lnw,lnb, pw1w,pw1b, pw2w,pw2b, cgam, regA);
    bnvec_k<<<256,256,0,stream>>>(regA, bnpw, bnpb, bnv + n0*64);
  }
  film_k<<<512,256,0,stream>>>(bnv, ppb, bemb, fw, fb, film);

  // ---- Phase 1+3: intrinsic chain + decoder (chunks of 128 n) ----
  for (int n0 = 0; n0 < 512; n0 += 128) {
    conv3x3_k<64,16,1,true ><<<dim3(128,4),256,0,stream>>>(vis,  spv + n0*2, ic1w, ic1b, regA);
    conv3x3_k<64,16,0,true ><<<dim3(128,4),256,0,stream>>>(regA, nullptr,    ic2w, ic2b, regB);
    conv3x3_k<64,16,0,false><<<dim3(128,2),256,0,stream>>>(regB, nullptr,    ic3w, ic3b, regC);
    for (int s = 0; s < 2; ++s) {
      int nb0 = n0*4 + s*256;
      modgen_k<<<4096,256,0,stream>>>(regC, film + (size_t)nb0*64, regA, s*256, 256*32*961);
      conv3x3_k<32,16,0,true><<<dim3(256,2),256,0,stream>>>(regA, nullptr, d1w, d1b, regB);
      conv3x3_k<32,16,0,true><<<dim3(256,2),256,0,stream>>>(regB, nullptr, d2w, d2b, regA);
      dec3_k<<<256,256,0,stream>>>(regA, d3w, d3b, out + (size_t)nb0*961);
    }
  }
}

// Round 2
// 5837.555 us; speedup vs baseline: 1.3645x; 1.3645x over previous
//
#include <hip/hip_runtime.h>
#include <cstdint>
#include <cstddef>

#define DEV __device__ __forceinline__

typedef __attribute__((ext_vector_type(8))) short bf16x8;
typedef __attribute__((ext_vector_type(4))) float f32x4;

DEV float gelu_f(float x){ return 0.5f*x*(1.0f + erff(x*0.7071067811865476f)); }
DEV float softplus_f(float x){ return fmaxf(x,0.f) + log1pf(expf(-fabsf(x))); }
DEV unsigned short f2bf(float x){
  unsigned u = __float_as_uint(x);
  unsigned r = (u + 0x7fffu + ((u>>16)&1u)) >> 16;
  return (unsigned short)r;
}

// ---------------------------------------------------------------------------
// Generic 3x3 conv, pad=1, 31x31 spatial. MODE 0: src is [item][CIN][31][31].
// MODE 1: src is vis_stem [64][1024][1024], window gathered around pos[item].
// ---------------------------------------------------------------------------
template<int CIN, int OCT, int MODE, bool FGELU>
__global__ __launch_bounds__(256,2) void conv3x3_k(
    const float* __restrict__ src, const float* __restrict__ pos,
    const float* __restrict__ W, const float* __restrict__ Bv,
    float* __restrict__ out)
{
  const int item = blockIdx.x;
  const int oc0  = blockIdx.y * OCT;
  const int COUT = gridDim.y * OCT;
  const int t = threadIdx.x;

  __shared__ float tile[33*33];
  __shared__ float wl[CIN*9*OCT];

  for (int i = t; i < CIN*9*OCT; i += 256) {
    int oc = i / (CIN*9);
    int rk = i % (CIN*9);
    wl[rk*OCT + oc] = W[(size_t)(oc0+oc)*CIN*9 + rk];
  }

  int pp[4], py[4], px[4];
#pragma unroll
  for (int j=0;j<4;++j){ pp[j]=t+256*j; int pc=min(pp[j],960); py[j]=pc/31; px[j]=pc%31; }

  float acc[OCT][4];
#pragma unroll
  for (int o=0;o<OCT;++o)
#pragma unroll
    for (int j=0;j<4;++j) acc[o][j]=0.f;

  int cx=0, cy=0;
  if (MODE==1){ cx=(int)rintf(pos[item*2+0]); cy=(int)rintf(pos[item*2+1]); }
  const float* sb = (MODE==1) ? src : src + (size_t)item*CIN*961;

  for (int ic=0; ic<CIN; ++ic) {
    __syncthreads();
    for (int i=t; i<1089; i+=256) {
      int yy = i/33 - 1, xx = i%33 - 1;
      float v = 0.f;
      if ((unsigned)yy < 31u && (unsigned)xx < 31u) {
        if (MODE==1) {
          int gy = min(max(cy-15+yy,0),1023);
          int gx = min(max(cx-15+xx,0),1023);
          v = src[((size_t)ic<<20) + (gy<<10) + gx];
        } else {
          v = sb[ic*961 + yy*31 + xx];
        }
      }
      tile[i] = v;
    }
    __syncthreads();

    float tv[4][9];
#pragma unroll
    for (int j=0;j<4;++j)
#pragma unroll
      for (int dy=0;dy<3;++dy)
#pragma unroll
        for (int dx=0;dx<3;++dx)
          tv[j][dy*3+dx] = tile[(py[j]+dy)*33 + px[j]+dx];

    const float* wic = &wl[ic*9*OCT];
#pragma unroll
    for (int k=0;k<9;++k) {
#pragma unroll
      for (int og=0; og<OCT/4; ++og) {
        const float4 w4 = *reinterpret_cast<const float4*>(&wic[k*OCT + og*4]);
#pragma unroll
        for (int j=0;j<4;++j) {
          acc[og*4+0][j] = fmaf(tv[j][k], w4.x, acc[og*4+0][j]);
          acc[og*4+1][j] = fmaf(tv[j][k], w4.y, acc[og*4+1][j]);
          acc[og*4+2][j] = fmaf(tv[j][k], w4.z, acc[og*4+2][j]);
          acc[og*4+3][j] = fmaf(tv[j][k], w4.w, acc[og*4+3][j]);
        }
      }
    }
  }

#pragma unroll
  for (int o=0;o<OCT;++o) {
    float bv = Bv[oc0+o];
#pragma unroll
    for (int j=0;j<4;++j) {
      if (pp[j] < 961) {
        float v = acc[o][j] + bv;
        if (FGELU) v = gelu_f(v);
        out[((size_t)item*COUT + oc0+o)*961 + pp[j]] = v;
      }
    }
  }
}

// ---------------------------------------------------------------------------
// bottleneck window extraction, NHWC: bwinT[il][p][c]
// ---------------------------------------------------------------------------
__global__ void extbwin2_k(const float* __restrict__ bott, const float* __restrict__ spv,
                           float* __restrict__ bwinT, int total)
{
  for (int idx = blockIdx.x*blockDim.x + threadIdx.x; idx < total; idx += gridDim.x*blockDim.x) {
    int c = idx & 255;
    int rest = idx >> 8;
    int p = rest % 121;
    int il = rest / 121;
    int y = p/11, x = p%11;
    float pxf = fminf(fmaxf(spv[il*2+0]*0.25f, 0.f), 255.f);
    float pyf = fminf(fmaxf(spv[il*2+1]*0.25f, 0.f), 255.f);
    int cx = (int)rintf(pxf), cy = (int)rintf(pyf);
    int gy = min(max(cy + y - 5, 0), 255);
    int gx = min(max(cx + x - 5, 0), 255);
    bwinT[idx] = bott[((size_t)c<<16) + (gy<<8) + gx];
  }
}

// ---------------------------------------------------------------------------
// depthwise 7x7, pad=3, NHWC in/out. thread = channel.
// ---------------------------------------------------------------------------
__global__ __launch_bounds__(256) void dw7x7_k2(
    const float* __restrict__ src, const float* __restrict__ w,
    const float* __restrict__ b, float* __restrict__ dst)
{
  int n = blockIdx.x, y = blockIdx.y, c = threadIdx.x;
  const float* base = src + (size_t)n*121*256 + c;
  const float* wc = w + c*49;
  float bias = b[c];
  for (int x=0; x<11; ++x) {
    float a = bias;
#pragma unroll
    for (int dy=0; dy<7; ++dy) {
      int yy = y + dy - 3;
      if (yy < 0 || yy >= 11) continue;
#pragma unroll
      for (int dx=0; dx<7; ++dx) {
        int xx = x + dx - 3;
        if (xx < 0 || xx >= 11) continue;
        a = fmaf(base[(yy*11+xx)*256], wc[dy*7+dx], a);
      }
    }
    dst[((size_t)n*121 + y*11 + x)*256 + c] = a;
  }
}

// ---------------------------------------------------------------------------
// Pack f32 [Cout][K] weights into bf16 MFMA fragment order:
// frag f = nt*ntk + kt; dst[(f*64+lane)*8 + j] = W[nt*16 + (lane&15)][kt*32 + (lane>>4)*8 + j]
// ---------------------------------------------------------------------------
__global__ __launch_bounds__(256) void packw_k(const float* __restrict__ W,
                                               unsigned short* __restrict__ dst,
                                               int ntn, int ntk, int K)
{
  int tid = blockIdx.x*256 + threadIdx.x;
  int total = ntn*ntk*64;
  if (tid >= total) return;
  int lane = tid & 63;
  int f = tid >> 6;
  int kt = f % ntk, nt = f / ntk;
  int row = nt*16 + (lane & 15);
  int k0 = kt*32 + (lane >> 4)*8;
  const float* src = W + (size_t)row*K + k0;
  unsigned short h[8];
#pragma unroll
  for (int j=0;j<8;++j) h[j] = f2bf(src[j]);
  uint4 pk;
  pk.x = (unsigned)h[0] | ((unsigned)h[1]<<16);
  pk.y = (unsigned)h[2] | ((unsigned)h[3]<<16);
  pk.z = (unsigned)h[4] | ((unsigned)h[5]<<16);
  pk.w = (unsigned)h[6] | ((unsigned)h[7]<<16);
  *reinterpret_cast<uint4*>(dst + (size_t)tid*8) = pk;
}

// ---------------------------------------------------------------------------
// Fused ConvNeXt MLP, bf16 MFMA: LN -> pw1 -> gelu -> pw2 -> *gamma -> +bwinT
// Block: 64 rows, 256 threads (4 waves). 16x16x32 bf16 MFMA, f32 accum.
// ---------------------------------------------------------------------------
__global__ __launch_bounds__(256) void cnx_mfma_k(
    const float* __restrict__ xin,          // [rows][256] NHWC dw output
    const float* __restrict__ lnw, const float* __restrict__ lnb,
    const unsigned short* __restrict__ W1p, const float* __restrict__ B1,
    const unsigned short* __restrict__ W2p, const float* __restrict__ B2,
    const float* __restrict__ gvec,
    float* __restrict__ bwinT)              // [rows][256] in-place residual
{
  const int t = threadIdx.x;
  const int w = t >> 6;
  const int l = t & 63;
  const int g = l >> 4;
  const int l15 = l & 15;
  const int row0 = blockIdx.x * 64;

  __shared__ unsigned short xs[64*264];   // LN'd X bf16, stride 264
  __shared__ unsigned short hs[64*136];   // H chunk bf16, stride 136

  // ---- LN -> xs ----
  {
    const int rl = t >> 2, q = t & 3;
    const float* xr = xin + (size_t)(row0+rl)*256 + q*64;
    float xv[64]; float s = 0.f, s2 = 0.f;
#pragma unroll
    for (int i=0;i<64;i+=4){
      float4 v = *reinterpret_cast<const float4*>(xr+i);
      xv[i]=v.x; xv[i+1]=v.y; xv[i+2]=v.z; xv[i+3]=v.w;
      s  += v.x+v.y+v.z+v.w;
      s2 += v.x*v.x+v.y*v.y+v.z*v.z+v.w*v.w;
    }
    s += __shfl_xor(s,1); s2 += __shfl_xor(s2,1);
    s += __shfl_xor(s,2); s2 += __shfl_xor(s2,2);
    float mu = s*(1.f/256.f);
    float rstd = rsqrtf(s2*(1.f/256.f) - mu*mu + 1e-6f);
#pragma unroll
    for (int i=0;i<64;i+=8){
      int c = q*64 + i;
      float4 w0 = *reinterpret_cast<const float4*>(lnw+c);
      float4 w1 = *reinterpret_cast<const float4*>(lnw+c+4);
      float4 b0 = *reinterpret_cast<const float4*>(lnb+c);
      float4 b1 = *reinterpret_cast<const float4*>(lnb+c+4);
      unsigned short h[8];
      h[0]=f2bf(fmaf((xv[i+0]-mu)*rstd, w0.x, b0.x));
      h[1]=f2bf(fmaf((xv[i+1]-mu)*rstd, w0.y, b0.y));
      h[2]=f2bf(fmaf((xv[i+2]-mu)*rstd, w0.z, b0.z));
      h[3]=f2bf(fmaf((xv[i+3]-mu)*rstd, w0.w, b0.w));
      h[4]=f2bf(fmaf((xv[i+4]-mu)*rstd, w1.x, b1.x));
      h[5]=f2bf(fmaf((xv[i+5]-mu)*rstd, w1.y, b1.y));
      h[6]=f2bf(fmaf((xv[i+6]-mu)*rstd, w1.z, b1.z));
      h[7]=f2bf(fmaf((xv[i+7]-mu)*rstd, w1.w, b1.w));
      uint4 pk;
      pk.x = (unsigned)h[0] | ((unsigned)h[1]<<16);
      pk.y = (unsigned)h[2] | ((unsigned)h[3]<<16);
      pk.z = (unsigned)h[4] | ((unsigned)h[5]<<16);
      pk.w = (unsigned)h[6] | ((unsigned)h[7]<<16);
      *reinterpret_cast<uint4*>(&xs[rl*264 + c]) = pk;
    }
  }
  __syncthreads();

  f32x4 acc2[16];
#pragma unroll
  for (int i=0;i<16;++i) acc2[i] = (f32x4){0.f,0.f,0.f,0.f};

  for (int hc=0; hc<8; ++hc) {
    // --- GEMM1: D1 = W1_tile x X^T ; wave w handles h-tiles nf = 2w, 2w+1 ---
    f32x4 acc1[8];
#pragma unroll
    for (int i=0;i<8;++i) acc1[i] = (f32x4){0.f,0.f,0.f,0.f};

#pragma unroll
    for (int kt=0; kt<8; ++kt) {
      bf16x8 xf[4];
#pragma unroll
      for (int rt=0; rt<4; ++rt)
        xf[rt] = *reinterpret_cast<const bf16x8*>(&xs[(rt*16+l15)*264 + kt*32 + g*8]);
#pragma unroll
      for (int i=0;i<2;++i) {
        const int ht = hc*8 + 2*w + i;
        bf16x8 wf = *reinterpret_cast<const bf16x8*>(W1p + ((size_t)(ht*8+kt)*64 + l)*8);
#pragma unroll
        for (int rt=0; rt<4; ++rt)
          acc1[i*4+rt] = __builtin_amdgcn_mfma_f32_16x16x32_bf16(wf, xf[rt], acc1[i*4+rt], 0,0,0);
      }
    }
    // bias + gelu + pack -> hs[r][h'], lane holds 4 consecutive h' per frag
#pragma unroll
    for (int i=0;i<2;++i) {
      const int hb = hc*128 + (2*w+i)*16 + 4*g;
      float4 b1v = *reinterpret_cast<const float4*>(B1 + hb);
#pragma unroll
      for (int rt=0; rt<4; ++rt) {
        unsigned short h0 = f2bf(gelu_f(acc1[i*4+rt][0] + b1v.x));
        unsigned short h1 = f2bf(gelu_f(acc1[i*4+rt][1] + b1v.y));
        unsigned short h2 = f2bf(gelu_f(acc1[i*4+rt][2] + b1v.z));
        unsigned short h3 = f2bf(gelu_f(acc1[i*4+rt][3] + b1v.w));
        uint2 pk;
        pk.x = (unsigned)h0 | ((unsigned)h1<<16);
        pk.y = (unsigned)h2 | ((unsigned)h3<<16);
        *reinterpret_cast<uint2*>(&hs[(rt*16+l15)*136 + (2*w+i)*16 + 4*g]) = pk;
      }
    }
    __syncthreads();
    // --- GEMM2: acc2 += H_chunk x W2_chunk^T ; wave w handles c-tiles w*4.. ---
#pragma unroll
    for (int kt=0; kt<4; ++kt) {
      bf16x8 hf[4];
#pragma unroll
      for (int rt=0; rt<4; ++rt)
        hf[rt] = *reinterpret_cast<const bf16x8*>(&hs[(rt*16+l15)*136 + kt*32 + g*8]);
#pragma unroll
      for (int cj=0; cj<4; ++cj) {
        const int ct = w*4 + cj;
        bf16x8 wf = *reinterpret_cast<const bf16x8*>(W2p + ((size_t)(ct*32 + hc*4 + kt)*64 + l)*8);
#pragma unroll
        for (int rt=0; rt<4; ++rt)
          acc2[rt*4+cj] = __builtin_amdgcn_mfma_f32_16x16x32_bf16(hf[rt], wf, acc2[rt*4+cj], 0,0,0);
      }
    }
    __syncthreads();
  }

  // ---- epilogue: bwinT += (acc2 + B2)*gamma ----
#pragma unroll
  for (int cj=0; cj<4; ++cj) {
    const int c = w*64 + cj*16 + l15;
    const float b2 = B2[c], gm = gvec[c];
#pragma unroll
    for (int rt=0; rt<4; ++rt) {
#pragma unroll
      for (int reg=0; reg<4; ++reg) {
        size_t idx = (size_t)(row0 + rt*16 + 4*g + reg)*256 + c;
        bwinT[idx] += (acc2[rt*4+cj][reg] + b2)*gm;
      }
    }
  }
}

// ---------------------------------------------------------------------------
// bnp 1x1 conv + gelu + gaussian-weighted spatial sum (NHWC input)
// ---------------------------------------------------------------------------
__global__ __launch_bounds__(256) void bnvec2_k(
    const float* __restrict__ bwinT, const float* __restrict__ w,
    const float* __restrict__ bias, float* __restrict__ bn_vec)
{
  int n = blockIdx.x, t = threadIdx.x;
  int oc = t & 63, pg = t >> 6;

  float gsum = 0.f;
  for (int p=0;p<121;++p){
    int py=p/11, px=p%11;
    float ly=-1.f+0.2f*py, lx=-1.f+0.2f*px;
    gsum += expf(-(lx*lx+ly*ly)/0.32f);
  }

  float acc = 0.f;
  const float* wr = w + oc*256;
  float bv = bias[oc];
  for (int p = pg; p < 121; p += 4) {
    int py=p/11, px=p%11;
    float ly=-1.f+0.2f*py, lx=-1.f+0.2f*px;
    float gw = expf(-(lx*lx+ly*ly)/0.32f);
    const float* bp = bwinT + ((size_t)n*121 + p)*256;
    float s0=0,s1=0,s2=0,s3=0;
    for (int c=0;c<256;c+=4){
      float4 x4 = *reinterpret_cast<const float4*>(bp+c);
      float4 w4 = *reinterpret_cast<const float4*>(wr+c);
      s0 = fmaf(x4.x, w4.x, s0);
      s1 = fmaf(x4.y, w4.y, s1);
      s2 = fmaf(x4.z, w4.z, s2);
      s3 = fmaf(x4.w, w4.w, s3);
    }
    acc += gelu_f(bv+s0+s1+s2+s3) * gw;
  }
  __shared__ float red[256];
  red[t] = acc; __syncthreads();
  if (t < 64) {
    float tot = red[t] + red[t+64] + red[t+128] + red[t+192];
    bn_vec[n*64 + oc] = tot / gsum;
  }
}

// ---------------------------------------------------------------------------
// FiLM: cond(84) @ film_w.T + film_b -> film[n][b][64]
// ---------------------------------------------------------------------------
__global__ __launch_bounds__(256) void film_k(
    const float* __restrict__ bn_vec, const float* __restrict__ ppb,
    const float* __restrict__ bemb, const float* __restrict__ fw,
    const float* __restrict__ fb, float* __restrict__ film)
{
  int n = blockIdx.x, t = threadIdx.x;
  __shared__ float cond[4][84];
  for (int i=t; i<4*84; i+=256) {
    int b = i/84, j = i%84;
    float v;
    if (j < 16) v = bemb[b*16 + j];
    else if (j == 16) { float p = ppb[((size_t)n*4+b)*2+0]; v = fminf(fmaxf(p*(1.f/1023.f),0.f),1.f); }
    else if (j == 17) { float p = ppb[((size_t)n*4+b)*2+1]; v = fminf(fmaxf(p*(1.f/1023.f),0.f),1.f); }
    else if (j == 18) { float p = ppb[((size_t)n*4+b)*2+0]; v = p - rintf(p); }
    else if (j == 19) { float p = ppb[((size_t)n*4+b)*2+1]; v = p - rintf(p); }
    else v = bn_vec[n*64 + (j-20)];
    cond[b][j] = v;
  }
  __syncthreads();
  int b = t >> 6, oc = t & 63;
  float s = fb[oc];
  for (int j=0;j<84;++j) s = fmaf(cond[b][j], fw[oc*84+j], s);
  film[((size_t)n*4+b)*64 + oc] = s;
}

// ---------------------------------------------------------------------------
// mod = gelu(intrinsic * (1+film[:32]) + film[32:])  (chunk of 256 nb-items)
// ---------------------------------------------------------------------------
__global__ void modgen_k(const float* __restrict__ intc, const float* __restrict__ film,
                         float* __restrict__ mod, int nbLocal0, int total)
{
  for (int idx = blockIdx.x*blockDim.x + threadIdx.x; idx < total; idx += gridDim.x*blockDim.x) {
    int il = idx / 30752;          // 32*961
    int rem = idx % 30752;
    int c = rem / 961;
    int p = rem % 961;
    int nl = (nbLocal0 + il) >> 2;
    float g  = 1.f + film[(size_t)il*64 + c];
    float be = film[(size_t)il*64 + 32 + c];
    float v = intc[((size_t)nl*32 + c)*961 + p];
    mod[idx] = gelu_f(fmaf(v, g, be));
  }
}

// ---------------------------------------------------------------------------
// dec3 1x1 conv + softplus + per-map sum-normalize -> out
// ---------------------------------------------------------------------------
__global__ __launch_bounds__(256) void dec3_k(
    const float* __restrict__ o2, const float* __restrict__ w3,
    const float* __restrict__ b3, float* __restrict__ outb)
{
  int il = blockIdx.x, t = threadIdx.x;
  float v[4];
#pragma unroll
  for (int j=0;j<4;++j) {
    int p = t + 256*j;
    float r = 0.f;
    if (p < 961) {
      float s = b3[0];
      for (int c=0;c<32;++c) s = fmaf(o2[((size_t)il*32+c)*961 + p], w3[c], s);
      r = softplus_f(s);
    }
    v[j] = r;
  }
  __shared__ float red[256];
  red[t] = v[0]+v[1]+v[2]+v[3];
  __syncthreads();
  for (int off=128; off>0; off>>=1) {
    if (t < off) red[t] += red[t+off];
    __syncthreads();
  }
  float inv = 1.f / fmaxf(red[0], 1e-8f);
#pragma unroll
  for (int j=0;j<4;++j) {
    int p = t + 256*j;
    if (p < 961) outb[(size_t)il*961 + p] = v[j]*inv;
  }
}

// ---------------------------------------------------------------------------
extern "C" void kernel_launch(void* const* d_in, const int* in_sizes, int n_in,
                              void* d_out, int out_size, void* d_ws, size_t ws_size,
                              hipStream_t stream)
{
  const float* bott = (const float*)d_in[0];
  const float* vis  = (const float*)d_in[1];
  const float* spv  = (const float*)d_in[2];
  const float* ppb  = (const float*)d_in[3];
  const float* ic1w = (const float*)d_in[4];  const float* ic1b = (const float*)d_in[5];
  const float* ic2w = (const float*)d_in[6];  const float* ic2b = (const float*)d_in[7];
  const float* ic3w = (const float*)d_in[8];  const float* ic3b = (const float*)d_in[9];
  const float* dww  = (const float*)d_in[10]; const float* dwb  = (const float*)d_in[11];
  const float* lnw  = (const float*)d_in[12]; const float* lnb  = (const float*)d_in[13];
  const float* pw1w = (const float*)d_in[14]; const float* pw1b = (const float*)d_in[15];
  const float* pw2w = (const float*)d_in[16]; const float* pw2b = (const float*)d_in[17];
  const float* cgam = (const float*)d_in[18];
  const float* bnpw = (const float*)d_in[19]; const float* bnpb = (const float*)d_in[20];
  const float* bemb = (const float*)d_in[21];
  const float* fw   = (const float*)d_in[22]; const float* fb   = (const float*)d_in[23];
  const float* d1w  = (const float*)d_in[24]; const float* d1b  = (const float*)d_in[25];
  const float* d2w  = (const float*)d_in[26]; const float* d2b  = (const float*)d_in[27];
  const float* d3w  = (const float*)d_in[28]; const float* d3b  = (const float*)d_in[29];
  float* out = (float*)d_out;

  char* ws = (char*)d_ws;
  float* regA = (float*)(ws);                              // 31,719,424 B
  float* regB = (float*)(ws + 31719424);                   // 31,719,424 B
  float* regC = (float*)(ws + 63438848);                   // 15,753,216 B
  float* bnv  = (float*)(ws + 79192064);                   // 131,072 B
  float* film = (float*)(ws + 79323136);                   // 524,288 B
  unsigned short* W1p = (unsigned short*)(ws + 79847424);  // 524,288 B
  unsigned short* W2p = (unsigned short*)(ws + 80371712);  // 524,288 B

  // ---- pack pw weights into MFMA fragment order (once per launch) ----
  packw_k<<<128,256,0,stream>>>(pw1w, W1p, 64, 8, 256);
  packw_k<<<128,256,0,stream>>>(pw2w, W2p, 16, 32, 1024);

  // ---- Phase 2: bottleneck/ConvNeXt path -> bn_vec (chunks of 256 n) ----
  for (int n0 = 0; n0 < 512; n0 += 256) {
    extbwin2_k<<<4096,256,0,stream>>>(bott, spv + n0*2, regA, 256*121*256);
    dw7x7_k2<<<dim3(256,11),256,0,stream>>>(regA, dww, dwb, regB);
    cnx_mfma_k<<<484,256,0,stream>>>(regB, lnw,lnb, W1p,pw1b, W2p,pw2b, cgam, regA);
    bnvec2_k<<<256,256,0,stream>>>(regA, bnpw, bnpb, bnv + n0*64);
  }
  film_k<<<512,256,0,stream>>>(bnv, ppb, bemb, fw, fb, film);

  // ---- Phase 1+3: intrinsic chain + decoder (chunks of 128 n) ----
  for (int n0 = 0; n0 < 512; n0 += 128) {
    conv3x3_k<64,16,1,true ><<<dim3(128,4),256,0,stream>>>(vis,  spv + n0*2, ic1w, ic1b, regA);
    conv3x3_k<64,16,0,true ><<<dim3(128,4),256,0,stream>>>(regA, nullptr,    ic2w, ic2b, regB);
    conv3x3_k<64,16,0,false><<<dim3(128,2),256,0,stream>>>(regB, nullptr,    ic3w, ic3b, regC);
    for (int s = 0; s < 2; ++s) {
      int nb0 = n0*4 + s*256;
      modgen_k<<<4096,256,0,stream>>>(regC, film + (size_t)nb0*64, regA, s*256, 256*32*961);
      conv3x3_k<32,16,0,true><<<dim3(256,2),256,0,stream>>>(regA, nullptr, d1w, d1b, regB);
      conv3x3_k<32,16,0,true><<<dim3(256,2),256,0,stream>>>(regB, nullptr, d2w, d2b, regA);
      dec3_k<<<256,256,0,stream>>>(regA, d3w, d3b, out + (size_t)nb0*961);
    }
  }
}

// Round 3
// 1654.076 us; speedup vs baseline: 4.8157x; 3.5292x over previous
//
#include <hip/hip_runtime.h>
#include <cstdint>
#include <cstddef>

#define DEV __device__ __forceinline__

typedef __attribute__((ext_vector_type(8))) short bf16x8;
typedef __attribute__((ext_vector_type(4))) float f32x4;

DEV float gelu_f(float x){ return 0.5f*x*(1.0f + erff(x*0.7071067811865476f)); }
DEV float softplus_f(float x){ return fmaxf(x,0.f) + log1pf(expf(-fabsf(x))); }
DEV unsigned short f2bf(float x){
  unsigned u = __float_as_uint(x);
  unsigned r = (u + 0x7fffu + ((u>>16)&1u)) >> 16;
  return (unsigned short)r;
}
DEV float bf2f(unsigned short h){
  unsigned u = ((unsigned)h) << 16;
  return __uint_as_float(u);
}

// ---------------------------------------------------------------------------
// Pack f32 [Cout][K] weights into bf16 MFMA fragment order.
// frag f = nt*ntk + kt; dst[(f*64+l)*8+j] = W[nt*16+(l&15)][kt*32+(l>>4)*8+j]
// ---------------------------------------------------------------------------
__global__ __launch_bounds__(256) void packw_k(const float* __restrict__ W,
                                               unsigned short* __restrict__ dst,
                                               int ntn, int ntk, int K)
{
  int tid = blockIdx.x*256 + threadIdx.x;
  int total = ntn*ntk*64;
  if (tid >= total) return;
  int lane = tid & 63;
  int f = tid >> 6;
  int kt = f % ntk, nt = f / ntk;
  int row = nt*16 + (lane & 15);
  int k0 = kt*32 + (lane >> 4)*8;
  const float* src = W + (size_t)row*K + k0;
  unsigned short h[8];
#pragma unroll
  for (int j=0;j<8;++j) h[j] = f2bf(src[j]);
  uint4 pk;
  pk.x = (unsigned)h[0] | ((unsigned)h[1]<<16);
  pk.y = (unsigned)h[2] | ((unsigned)h[3]<<16);
  pk.z = (unsigned)h[4] | ((unsigned)h[5]<<16);
  pk.w = (unsigned)h[6] | ((unsigned)h[7]<<16);
  *reinterpret_cast<uint4*>(dst + (size_t)tid*8) = pk;
}

// ---------------------------------------------------------------------------
// Pack conv weights [Cout][Cin][3][3] into fragment order with K = s*Cin+ic
// (s = dy*3+dx). Same fragment layout as packw_k.
// ---------------------------------------------------------------------------
__global__ __launch_bounds__(256) void pack_convw_k(const float* __restrict__ W,
                                                    unsigned short* __restrict__ dst,
                                                    int ntn, int ntk, int Cin)
{
  int tid = blockIdx.x*256 + threadIdx.x;
  int total = ntn*ntk*64;
  if (tid >= total) return;
  int lane = tid & 63;
  int f = tid >> 6;
  int kt = f % ntk, nt = f / ntk;
  int row = nt*16 + (lane & 15);
  int k0 = kt*32 + (lane >> 4)*8;
  unsigned short h[8];
#pragma unroll
  for (int j=0;j<8;++j) {
    int k = k0 + j;
    int s = k / Cin;
    int ic = k - s*Cin;
    h[j] = f2bf(W[((size_t)row*Cin + ic)*9 + s]);
  }
  uint4 pk;
  pk.x = (unsigned)h[0] | ((unsigned)h[1]<<16);
  pk.y = (unsigned)h[2] | ((unsigned)h[3]<<16);
  pk.z = (unsigned)h[4] | ((unsigned)h[5]<<16);
  pk.w = (unsigned)h[6] | ((unsigned)h[7]<<16);
  *reinterpret_cast<uint4*>(dst + (size_t)tid*8) = pk;
}

// ---------------------------------------------------------------------------
// Extract clamped 33x33 vis windows (incl. conv zero ring) -> bf16 NHWC
// vwin[il][wy*33+wx][64]
// ---------------------------------------------------------------------------
__global__ __launch_bounds__(256) void extvwin_k(const float* __restrict__ vis,
                                                 const float* __restrict__ spv,
                                                 unsigned short* __restrict__ vwin)
{
  int il = blockIdx.x;
  int p = blockIdx.y*256 + threadIdx.x;
  if (p >= 1089) return;
  int wy = p/33, wx = p%33;
  unsigned short* dst = vwin + ((size_t)il*1089 + p)*64;
  if (wy==0 || wy==32 || wx==0 || wx==32) {
    uint4 z = {0,0,0,0};
#pragma unroll
    for (int q=0;q<8;++q) *reinterpret_cast<uint4*>(dst + q*8) = z;
    return;
  }
  int cx = (int)rintf(spv[il*2+0]);
  int cy = (int)rintf(spv[il*2+1]);
  int gy = min(max(cy + wy - 16, 0), 1023);
  int gx = min(max(cx + wx - 16, 0), 1023);
  const float* sp = vis + (size_t)gy*1024 + gx;
  unsigned short h[64];
#pragma unroll
  for (int c=0;c<64;++c) h[c] = f2bf(sp[(size_t)c<<20]);
#pragma unroll
  for (int q=0;q<8;++q) {
    uint4 pk;
    pk.x = (unsigned)h[q*8+0] | ((unsigned)h[q*8+1]<<16);
    pk.y = (unsigned)h[q*8+2] | ((unsigned)h[q*8+3]<<16);
    pk.z = (unsigned)h[q*8+4] | ((unsigned)h[q*8+5]<<16);
    pk.w = (unsigned)h[q*8+6] | ((unsigned)h[q*8+7]<<16);
    *reinterpret_cast<uint4*>(dst + q*8) = pk;
  }
}

// ---------------------------------------------------------------------------
// MFMA implicit-GEMM 3x3 conv. Block = (item, 8-row strip), 256 threads.
// MODEW=1: src = 33x33 window buffer (halo baked in). MODEW=0: src = NHWC
// activations [item][961][CIN], zero pad. out: bf16 NHWC [item][961][COUT].
// LDS tile 10x33 rows x CIN, XOR-swizzled 16B slots.
// ---------------------------------------------------------------------------
template<int CIN, int COUT, int NKT, int MODEW, bool FGELU>
__global__ __launch_bounds__(256,2) void convmf_k(
    const unsigned short* __restrict__ src,
    const unsigned short* __restrict__ Wp,
    const float* __restrict__ Bv,
    unsigned short* __restrict__ out)
{
  constexpr int NOCT = COUT/16;
  constexpr int NSLOT = CIN/8;         // 16B slots per lds row
  constexpr int SWM = NSLOT-1;
  const int item = blockIdx.x;
  const int y0 = blockIdx.y*8;
  const int t = threadIdx.x;
  const int w = t>>6, l = t&63, g = l>>4, l15 = l&15;

  __shared__ __align__(16) unsigned short lds[330*CIN];

  // ---- stage ----
  for (int u = t; u < 330*NSLOT; u += 256) {
    int slot = u & SWM;
    int rowi = u / NSLOT;            // r*33+col
    int r = rowi / 33, col = rowi - r*33;
    uint4 val = {0,0,0,0};
    if (MODEW==1) {
      int gr = y0 + r;
      if (gr < 33)
        val = *reinterpret_cast<const uint4*>(src + ((size_t)item*1089 + gr*33 + col)*CIN + slot*8);
    } else {
      int y = y0 + r - 1, x = col - 1;
      if ((unsigned)y < 31u && (unsigned)x < 31u)
        val = *reinterpret_cast<const uint4*>(src + ((size_t)item*961 + y*31 + x)*CIN + slot*8);
    }
    int ds = slot ^ (rowi & SWM);
    *reinterpret_cast<uint4*>(&lds[rowi*CIN + ds*8]) = val;
  }
  __syncthreads();

  // per-lane positions: wave w owns pos-tiles w*4 .. w*4+3
  int pbase[4], gpos[4]; bool pvalid[4];
#pragma unroll
  for (int pt=0; pt<4; ++pt) {
    int p = (w*4+pt)*16 + l15;
    int pc = min(p, 247);
    int py = pc/31, px = pc - py*31;
    pbase[pt] = py*33 + px;
    gpos[pt] = y0*31 + p;
    pvalid[pt] = (p < 248) && (gpos[pt] < 961);
  }

  f32x4 acc[NOCT][4];
#pragma unroll
  for (int o=0;o<NOCT;++o)
#pragma unroll
    for (int pt=0;pt<4;++pt) acc[o][pt] = (f32x4){0.f,0.f,0.f,0.f};

  for (int kt=0; kt<NKT; ++kt) {
    int k0 = kt*32 + g*8;
    int s = k0 / CIN;
    int icg = (k0 - s*CIN) >> 3;
    int roff = (s/3)*33 + (s - (s/3)*3);
    bf16x8 bf[4];
#pragma unroll
    for (int pt=0; pt<4; ++pt) {
      int rowi = pbase[pt] + roff;
      int ds = icg ^ (rowi & SWM);
      bf[pt] = *reinterpret_cast<const bf16x8*>(&lds[rowi*CIN + ds*8]);
    }
#pragma unroll
    for (int o=0; o<NOCT; ++o) {
      bf16x8 af = *reinterpret_cast<const bf16x8*>(Wp + ((size_t)(o*NKT+kt)*64 + l)*8);
#pragma unroll
      for (int pt=0; pt<4; ++pt)
        acc[o][pt] = __builtin_amdgcn_mfma_f32_16x16x32_bf16(af, bf[pt], acc[o][pt], 0,0,0);
    }
  }

  // ---- epilogue: bias (+gelu) -> bf16 NHWC, 4 consecutive oc per lane ----
#pragma unroll
  for (int o=0; o<NOCT; ++o) {
    float4 bv4 = *reinterpret_cast<const float4*>(Bv + o*16 + g*4);
#pragma unroll
    for (int pt=0; pt<4; ++pt) {
      if (!pvalid[pt]) continue;
      float v0 = acc[o][pt][0] + bv4.x;
      float v1 = acc[o][pt][1] + bv4.y;
      float v2 = acc[o][pt][2] + bv4.z;
      float v3 = acc[o][pt][3] + bv4.w;
      if (FGELU) { v0=gelu_f(v0); v1=gelu_f(v1); v2=gelu_f(v2); v3=gelu_f(v3); }
      uint2 pk;
      pk.x = (unsigned)f2bf(v0) | ((unsigned)f2bf(v1)<<16);
      pk.y = (unsigned)f2bf(v2) | ((unsigned)f2bf(v3)<<16);
      *reinterpret_cast<uint2*>(out + ((size_t)item*961 + gpos[pt])*COUT + o*16 + g*4) = pk;
    }
  }
}

// ---------------------------------------------------------------------------
// bottleneck window extraction, NHWC: bwinT[il][p][c]
// ---------------------------------------------------------------------------
__global__ void extbwin2_k(const float* __restrict__ bott, const float* __restrict__ spv,
                           float* __restrict__ bwinT, int total)
{
  for (int idx = blockIdx.x*blockDim.x + threadIdx.x; idx < total; idx += gridDim.x*blockDim.x) {
    int c = idx & 255;
    int rest = idx >> 8;
    int p = rest % 121;
    int il = rest / 121;
    int y = p/11, x = p%11;
    float pxf = fminf(fmaxf(spv[il*2+0]*0.25f, 0.f), 255.f);
    float pyf = fminf(fmaxf(spv[il*2+1]*0.25f, 0.f), 255.f);
    int cx = (int)rintf(pxf), cy = (int)rintf(pyf);
    int gy = min(max(cy + y - 5, 0), 255);
    int gx = min(max(cx + x - 5, 0), 255);
    bwinT[idx] = bott[((size_t)c<<16) + (gy<<8) + gx];
  }
}

// ---------------------------------------------------------------------------
// depthwise 7x7, pad=3, NHWC in/out. thread = channel.
// ---------------------------------------------------------------------------
__global__ __launch_bounds__(256) void dw7x7_k2(
    const float* __restrict__ src, const float* __restrict__ w,
    const float* __restrict__ b, float* __restrict__ dst)
{
  int n = blockIdx.x, y = blockIdx.y, c = threadIdx.x;
  const float* base = src + (size_t)n*121*256 + c;
  const float* wc = w + c*49;
  float bias = b[c];
  for (int x=0; x<11; ++x) {
    float a = bias;
#pragma unroll
    for (int dy=0; dy<7; ++dy) {
      int yy = y + dy - 3;
      if (yy < 0 || yy >= 11) continue;
#pragma unroll
      for (int dx=0; dx<7; ++dx) {
        int xx = x + dx - 3;
        if (xx < 0 || xx >= 11) continue;
        a = fmaf(base[(yy*11+xx)*256], wc[dy*7+dx], a);
      }
    }
    dst[((size_t)n*121 + y*11 + x)*256 + c] = a;
  }
}

// ---------------------------------------------------------------------------
// Fused ConvNeXt MLP + bnp head, bf16 MFMA.
// LN -> pw1 -> gelu -> pw2 -> *gamma -> (+bwinT residual in regs) ->
// bnp 1x1 GEMM -> gelu -> gaussian-weighted row reduce -> atomicAdd bn_vec.
// Block: 64 rows, 256 threads (4 waves).
// ---------------------------------------------------------------------------
__global__ __launch_bounds__(256) void cnx_mfma2_k(
    const float* __restrict__ xin,          // [rows][256] dw output (LN input)
    const float* __restrict__ lnw, const float* __restrict__ lnb,
    const unsigned short* __restrict__ W1p, const float* __restrict__ B1,
    const unsigned short* __restrict__ W2p, const float* __restrict__ B2,
    const float* __restrict__ gvec,
    const float* __restrict__ bwinT,        // [rows][256] residual base
    const unsigned short* __restrict__ Wbp, const float* __restrict__ bnpb,
    float* __restrict__ bnv)                // [256 n][64] accumulated
{
  const int t = threadIdx.x;
  const int w = t >> 6;
  const int l = t & 63;
  const int g = l >> 4;
  const int l15 = l & 15;
  const int row0 = blockIdx.x * 64;

  __shared__ __align__(16) unsigned short xs[64*264];
  __shared__ __align__(16) unsigned short hs[64*136];

  // ---- LN -> xs ----
  {
    const int rl = t >> 2, q = t & 3;
    const float* xr = xin + (size_t)(row0+rl)*256 + q*64;
    float xv[64]; float s = 0.f, s2 = 0.f;
#pragma unroll
    for (int i=0;i<64;i+=4){
      float4 v = *reinterpret_cast<const float4*>(xr+i);
      xv[i]=v.x; xv[i+1]=v.y; xv[i+2]=v.z; xv[i+3]=v.w;
      s  += v.x+v.y+v.z+v.w;
      s2 += v.x*v.x+v.y*v.y+v.z*v.z+v.w*v.w;
    }
    s += __shfl_xor(s,1); s2 += __shfl_xor(s2,1);
    s += __shfl_xor(s,2); s2 += __shfl_xor(s2,2);
    float mu = s*(1.f/256.f);
    float rstd = rsqrtf(s2*(1.f/256.f) - mu*mu + 1e-6f);
#pragma unroll
    for (int i=0;i<64;i+=8){
      int c = q*64 + i;
      float4 w0 = *reinterpret_cast<const float4*>(lnw+c);
      float4 w1 = *reinterpret_cast<const float4*>(lnw+c+4);
      float4 b0 = *reinterpret_cast<const float4*>(lnb+c);
      float4 b1 = *reinterpret_cast<const float4*>(lnb+c+4);
      unsigned short h[8];
      h[0]=f2bf(fmaf((xv[i+0]-mu)*rstd, w0.x, b0.x));
      h[1]=f2bf(fmaf((xv[i+1]-mu)*rstd, w0.y, b0.y));
      h[2]=f2bf(fmaf((xv[i+2]-mu)*rstd, w0.z, b0.z));
      h[3]=f2bf(fmaf((xv[i+3]-mu)*rstd, w0.w, b0.w));
      h[4]=f2bf(fmaf((xv[i+4]-mu)*rstd, w1.x, b1.x));
      h[5]=f2bf(fmaf((xv[i+5]-mu)*rstd, w1.y, b1.y));
      h[6]=f2bf(fmaf((xv[i+6]-mu)*rstd, w1.z, b1.z));
      h[7]=f2bf(fmaf((xv[i+7]-mu)*rstd, w1.w, b1.w));
      uint4 pk;
      pk.x = (unsigned)h[0] | ((unsigned)h[1]<<16);
      pk.y = (unsigned)h[2] | ((unsigned)h[3]<<16);
      pk.z = (unsigned)h[4] | ((unsigned)h[5]<<16);
      pk.w = (unsigned)h[6] | ((unsigned)h[7]<<16);
      *reinterpret_cast<uint4*>(&xs[rl*264 + c]) = pk;
    }
  }
  __syncthreads();

  f32x4 acc2[16];
#pragma unroll
  for (int i=0;i<16;++i) acc2[i] = (f32x4){0.f,0.f,0.f,0.f};

  for (int hc=0; hc<8; ++hc) {
    f32x4 acc1[8];
#pragma unroll
    for (int i=0;i<8;++i) acc1[i] = (f32x4){0.f,0.f,0.f,0.f};

#pragma unroll
    for (int kt=0; kt<8; ++kt) {
      bf16x8 xf[4];
#pragma unroll
      for (int rt=0; rt<4; ++rt)
        xf[rt] = *reinterpret_cast<const bf16x8*>(&xs[(rt*16+l15)*264 + kt*32 + g*8]);
#pragma unroll
      for (int i=0;i<2;++i) {
        const int ht = hc*8 + 2*w + i;
        bf16x8 wf = *reinterpret_cast<const bf16x8*>(W1p + ((size_t)(ht*8+kt)*64 + l)*8);
#pragma unroll
        for (int rt=0; rt<4; ++rt)
          acc1[i*4+rt] = __builtin_amdgcn_mfma_f32_16x16x32_bf16(wf, xf[rt], acc1[i*4+rt], 0,0,0);
      }
    }
#pragma unroll
    for (int i=0;i<2;++i) {
      const int hb = hc*128 + (2*w+i)*16 + 4*g;
      float4 b1v = *reinterpret_cast<const float4*>(B1 + hb);
#pragma unroll
      for (int rt=0; rt<4; ++rt) {
        unsigned short h0 = f2bf(gelu_f(acc1[i*4+rt][0] + b1v.x));
        unsigned short h1 = f2bf(gelu_f(acc1[i*4+rt][1] + b1v.y));
        unsigned short h2 = f2bf(gelu_f(acc1[i*4+rt][2] + b1v.z));
        unsigned short h3 = f2bf(gelu_f(acc1[i*4+rt][3] + b1v.w));
        uint2 pk;
        pk.x = (unsigned)h0 | ((unsigned)h1<<16);
        pk.y = (unsigned)h2 | ((unsigned)h3<<16);
        *reinterpret_cast<uint2*>(&hs[(rt*16+l15)*136 + (2*w+i)*16 + 4*g]) = pk;
      }
    }
    __syncthreads();
#pragma unroll
    for (int kt=0; kt<4; ++kt) {
      bf16x8 hf[4];
#pragma unroll
      for (int rt=0; rt<4; ++rt)
        hf[rt] = *reinterpret_cast<const bf16x8*>(&hs[(rt*16+l15)*136 + kt*32 + g*8]);
#pragma unroll
      for (int cj=0; cj<4; ++cj) {
        const int ct = w*4 + cj;
        bf16x8 wf = *reinterpret_cast<const bf16x8*>(W2p + ((size_t)(ct*32 + hc*4 + kt)*64 + l)*8);
#pragma unroll
        for (int rt=0; rt<4; ++rt)
          acc2[rt*4+cj] = __builtin_amdgcn_mfma_f32_16x16x32_bf16(hf[rt], wf, acc2[rt*4+cj], 0,0,0);
      }
    }
    __syncthreads();
  }

  // ---- residual in regs -> xs as bf16 ----
#pragma unroll
  for (int cj=0; cj<4; ++cj) {
    const int c = w*64 + cj*16 + l15;
    const float b2 = B2[c], gm = gvec[c];
#pragma unroll
    for (int rt=0; rt<4; ++rt) {
#pragma unroll
      for (int reg=0; reg<4; ++reg) {
        int row = rt*16 + 4*g + reg;
        float res = bwinT[(size_t)(row0+row)*256 + c] + (acc2[rt*4+cj][reg] + b2)*gm;
        xs[row*264 + c] = f2bf(res);
      }
    }
  }
  __syncthreads();

  // ---- bnp GEMM: P[r][oc] = res[r][:] @ Wbp^T, wave w -> rows w*16.. ----
  f32x4 abn[4];
#pragma unroll
  for (int i=0;i<4;++i) abn[i] = (f32x4){0.f,0.f,0.f,0.f};
#pragma unroll
  for (int kt=0; kt<8; ++kt) {
    bf16x8 af = *reinterpret_cast<const bf16x8*>(&xs[(w*16+l15)*264 + kt*32 + g*8]);
#pragma unroll
    for (int oct=0; oct<4; ++oct) {
      bf16x8 bfw = *reinterpret_cast<const bf16x8*>(Wbp + ((size_t)(oct*8+kt)*64 + l)*8);
      abn[oct] = __builtin_amdgcn_mfma_f32_16x16x32_bf16(af, bfw, abn[oct], 0,0,0);
    }
  }

  // ---- gelu + gaussian weight -> red (alias hs), then per-n reduce ----
  float* red = reinterpret_cast<float*>(hs);
  float gsum = 0.f;
  for (int p=0;p<121;++p){
    int py=p/11, px=p-py*11;
    float ly=-1.f+0.2f*py, lx=-1.f+0.2f*px;
    gsum += expf(-(lx*lx+ly*ly)/0.32f);
  }
  const float inv_gsum = 1.f/gsum;
#pragma unroll
  for (int oct=0; oct<4; ++oct) {
    float bv = bnpb[oct*16 + l15];
#pragma unroll
    for (int reg=0; reg<4; ++reg) {
      int lr = w*16 + g*4 + reg;
      int p = (row0 + lr) % 121;
      int py=p/11, px=p-py*11;
      float ly=-1.f+0.2f*py, lx=-1.f+0.2f*px;
      float wg = expf(-(lx*lx+ly*ly)/0.32f) * inv_gsum;
      red[lr*64 + oct*16 + l15] = gelu_f(abn[oct][reg] + bv) * wg;
    }
  }
  __syncthreads();
  {
    int oc = t & 63, seg = t >> 6;
    float s = 0.f;
    int curn = (row0 + seg*16) / 121;
    for (int i=0;i<16;++i) {
      int row = seg*16 + i;
      int n = (row0 + row) / 121;
      if (n != curn) { atomicAdd(&bnv[curn*64 + oc], s); s = 0.f; curn = n; }
      s += red[row*64 + oc];
    }
    atomicAdd(&bnv[curn*64 + oc], s);
  }
}

// ---------------------------------------------------------------------------
// FiLM: cond(84) @ film_w.T + film_b -> film[n][b][64]
// ---------------------------------------------------------------------------
__global__ __launch_bounds__(256) void film_k(
    const float* __restrict__ bn_vec, const float* __restrict__ ppb,
    const float* __restrict__ bemb, const float* __restrict__ fw,
    const float* __restrict__ fb, float* __restrict__ film)
{
  int n = blockIdx.x, t = threadIdx.x;
  __shared__ float cond[4][84];
  for (int i=t; i<4*84; i+=256) {
    int b = i/84, j = i%84;
    float v;
    if (j < 16) v = bemb[b*16 + j];
    else if (j == 16) { float p = ppb[((size_t)n*4+b)*2+0]; v = fminf(fmaxf(p*(1.f/1023.f),0.f),1.f); }
    else if (j == 17) { float p = ppb[((size_t)n*4+b)*2+1]; v = fminf(fmaxf(p*(1.f/1023.f),0.f),1.f); }
    else if (j == 18) { float p = ppb[((size_t)n*4+b)*2+0]; v = p - rintf(p); }
    else if (j == 19) { float p = ppb[((size_t)n*4+b)*2+1]; v = p - rintf(p); }
    else v = bn_vec[n*64 + (j-20)];
    cond[b][j] = v;
  }
  __syncthreads();
  int b = t >> 6, oc = t & 63;
  float s = fb[oc];
  for (int j=0;j<84;++j) s = fmaf(cond[b][j], fw[oc*84+j], s);
  film[((size_t)n*4+b)*64 + oc] = s;
}

// ---------------------------------------------------------------------------
// mod = gelu(intrinsic*(1+film[:32]) + film[32:]), bf16 NHWC in/out
// ---------------------------------------------------------------------------
__global__ __launch_bounds__(256) void modgen2_k(
    const unsigned short* __restrict__ intc, const float* __restrict__ film,
    unsigned short* __restrict__ mod, int nbLocal0)
{
  int idx = blockIdx.x*256 + threadIdx.x;
  if (idx >= 256*961) return;
  int il = idx / 961, p = idx - il*961;
  int nl = (nbLocal0 + il) >> 2;
  const unsigned short* sp = intc + ((size_t)nl*961 + p)*32;
  const float* fg = film + (size_t)il*64;
  unsigned short* dp = mod + ((size_t)idx)*32;
#pragma unroll
  for (int q=0; q<4; ++q) {
    uint4 v = *reinterpret_cast<const uint4*>(sp + q*8);
    unsigned short x[8] = {
      (unsigned short)(v.x&0xffff),(unsigned short)(v.x>>16),
      (unsigned short)(v.y&0xffff),(unsigned short)(v.y>>16),
      (unsigned short)(v.z&0xffff),(unsigned short)(v.z>>16),
      (unsigned short)(v.w&0xffff),(unsigned short)(v.w>>16)};
    unsigned short o[8];
#pragma unroll
    for (int j=0;j<8;++j) {
      int c = q*8 + j;
      float val = gelu_f(fmaf(bf2f(x[j]), 1.f + fg[c], fg[32+c]));
      o[j] = f2bf(val);
    }
    uint4 pk;
    pk.x = (unsigned)o[0] | ((unsigned)o[1]<<16);
    pk.y = (unsigned)o[2] | ((unsigned)o[3]<<16);
    pk.z = (unsigned)o[4] | ((unsigned)o[5]<<16);
    pk.w = (unsigned)o[6] | ((unsigned)o[7]<<16);
    *reinterpret_cast<uint4*>(dp + q*8) = pk;
  }
}

// ---------------------------------------------------------------------------
// dec3 1x1 conv + softplus + per-map sum-normalize (bf16 NHWC input)
// ---------------------------------------------------------------------------
__global__ __launch_bounds__(256) void dec3b_k(
    const unsigned short* __restrict__ o2, const float* __restrict__ w3,
    const float* __restrict__ b3, float* __restrict__ outb)
{
  int il = blockIdx.x, t = threadIdx.x;
  __shared__ float ws3[32];
  if (t < 32) ws3[t] = w3[t];
  __syncthreads();
  float v[4];
#pragma unroll
  for (int j=0;j<4;++j) {
    int p = t + 256*j;
    float r = 0.f;
    if (p < 961) {
      const unsigned short* sp = o2 + ((size_t)il*961 + p)*32;
      float s = b3[0];
#pragma unroll
      for (int c=0;c<32;++c) s = fmaf(bf2f(sp[c]), ws3[c], s);
      r = softplus_f(s);
    }
    v[j] = r;
  }
  __shared__ float red[256];
  red[t] = v[0]+v[1]+v[2]+v[3];
  __syncthreads();
  for (int off=128; off>0; off>>=1) {
    if (t < off) red[t] += red[t+off];
    __syncthreads();
  }
  float inv = 1.f / fmaxf(red[0], 1e-8f);
#pragma unroll
  for (int j=0;j<4;++j) {
    int p = t + 256*j;
    if (p < 961) outb[(size_t)il*961 + p] = v[j]*inv;
  }
}

// ---------------------------------------------------------------------------
extern "C" void kernel_launch(void* const* d_in, const int* in_sizes, int n_in,
                              void* d_out, int out_size, void* d_ws, size_t ws_size,
                              hipStream_t stream)
{
  const float* bott = (const float*)d_in[0];
  const float* vis  = (const float*)d_in[1];
  const float* spv  = (const float*)d_in[2];
  const float* ppb  = (const float*)d_in[3];
  const float* ic1w = (const float*)d_in[4];  const float* ic1b = (const float*)d_in[5];
  const float* ic2w = (const float*)d_in[6];  const float* ic2b = (const float*)d_in[7];
  const float* ic3w = (const float*)d_in[8];  const float* ic3b = (const float*)d_in[9];
  const float* dww  = (const float*)d_in[10]; const float* dwb  = (const float*)d_in[11];
  const float* lnw  = (const float*)d_in[12]; const float* lnb  = (const float*)d_in[13];
  const float* pw1w = (const float*)d_in[14]; const float* pw1b = (const float*)d_in[15];
  const float* pw2w = (const float*)d_in[16]; const float* pw2b = (const float*)d_in[17];
  const float* cgam = (const float*)d_in[18];
  const float* bnpw = (const float*)d_in[19]; const float* bnpb = (const float*)d_in[20];
  const float* bemb = (const float*)d_in[21];
  const float* fw   = (const float*)d_in[22]; const float* fb   = (const float*)d_in[23];
  const float* d1w  = (const float*)d_in[24]; const float* d1b  = (const float*)d_in[25];
  const float* d2w  = (const float*)d_in[26]; const float* d2b  = (const float*)d_in[27];
  const float* d3w  = (const float*)d_in[28]; const float* d3b  = (const float*)d_in[29];
  float* out = (float*)d_out;

  char* ws = (char*)d_ws;
  // region A0 (0..32MB): P2 bwinT f32 | P1 vwin bf16 / decoder o2
  // region A1 (32..64MB): P2 dwout f32 | P1 bufA + bufB (16MB each)
  float* bwinT = (float*)(ws);
  unsigned short* vwin = (unsigned short*)(ws);
  unsigned short* bufW = (unsigned short*)(ws);
  float* dwout = (float*)(ws + 33554432);
  unsigned short* bufA = (unsigned short*)(ws + 33554432);
  unsigned short* bufB = (unsigned short*)(ws + 33554432 + 16777216);
  unsigned short* bufI = (unsigned short*)(ws + 67108864);            // intc 7.9MB
  float* bnv  = (float*)(ws + 75497472);                              // 131072
  float* film = (float*)(ws + 75628544);                              // 524288
  unsigned short* W1p = (unsigned short*)(ws + 76152832);             // 524288
  unsigned short* W2p = (unsigned short*)(ws + 76677120);             // 524288
  unsigned short* Wbp = (unsigned short*)(ws + 77201408);             // 32768
  unsigned short* Pc1 = (unsigned short*)(ws + 77234176);             // 73728
  unsigned short* Pc2 = (unsigned short*)(ws + 77307904);             // 73728
  unsigned short* Pc3 = (unsigned short*)(ws + 77381632);             // 36864
  unsigned short* Pd1 = (unsigned short*)(ws + 77418496);             // 18432
  unsigned short* Pd2 = (unsigned short*)(ws + 77436928);             // 18432

  // ---- weight packing ----
  packw_k<<<128,256,0,stream>>>(pw1w, W1p, 64, 8, 256);
  packw_k<<<128,256,0,stream>>>(pw2w, W2p, 16, 32, 1024);
  packw_k<<<8,  256,0,stream>>>(bnpw, Wbp, 4, 8, 256);
  pack_convw_k<<<18,256,0,stream>>>(ic1w, Pc1, 4, 18, 64);
  pack_convw_k<<<18,256,0,stream>>>(ic2w, Pc2, 4, 18, 64);
  pack_convw_k<<<9, 256,0,stream>>>(ic3w, Pc3, 2, 18, 64);
  pack_convw_k<<<5, 256,0,stream>>>(d1w,  Pd1, 2, 9, 32);
  pack_convw_k<<<5, 256,0,stream>>>(d2w,  Pd2, 2, 9, 32);

  hipMemsetAsync(bnv, 0, 131072, stream);

  // ---- Phase 2: bottleneck path -> bn_vec (chunks of 256 n) ----
  for (int n0 = 0; n0 < 512; n0 += 256) {
    extbwin2_k<<<4096,256,0,stream>>>(bott, spv + n0*2, bwinT, 256*121*256);
    dw7x7_k2<<<dim3(256,11),256,0,stream>>>(bwinT, dww, dwb, dwout);
    cnx_mfma2_k<<<484,256,0,stream>>>(dwout, lnw,lnb, W1p,pw1b, W2p,pw2b, cgam,
                                      bwinT, Wbp, bnpb, bnv + n0*64);
  }
  film_k<<<512,256,0,stream>>>(bnv, ppb, bemb, fw, fb, film);

  // ---- Phase 1+3: intrinsic chain + decoder (chunks of 128 n) ----
  for (int n0 = 0; n0 < 512; n0 += 128) {
    extvwin_k<<<dim3(128,5),256,0,stream>>>(vis, spv + n0*2, vwin);
    convmf_k<64,64,18,1,true ><<<dim3(128,4),256,0,stream>>>(vwin, Pc1, ic1b, bufA);
    convmf_k<64,64,18,0,true ><<<dim3(128,4),256,0,stream>>>(bufA, Pc2, ic2b, bufB);
    convmf_k<64,32,18,0,false><<<dim3(128,4),256,0,stream>>>(bufB, Pc3, ic3b, bufI);
    for (int s = 0; s < 2; ++s) {
      int nb0 = n0*4 + s*256;
      modgen2_k<<<961,256,0,stream>>>(bufI, film + (size_t)nb0*64, bufA, s*256);
      convmf_k<32,32,9,0,true><<<dim3(256,4),256,0,stream>>>(bufA, Pd1, d1b, bufB);
      convmf_k<32,32,9,0,true><<<dim3(256,4),256,0,stream>>>(bufB, Pd2, d2b, bufW);
      dec3b_k<<<256,256,0,stream>>>(bufW, d3w, d3b, out + (size_t)nb0*961);
    }
  }
}

// Round 4
// 1218.528 us; speedup vs baseline: 6.5371x; 1.3574x over previous
//
#include <hip/hip_runtime.h>
#include <cstdint>
#include <cstddef>
#include <cmath>

#define DEV __device__ __forceinline__

typedef __attribute__((ext_vector_type(8))) short bf16x8;
typedef __attribute__((ext_vector_type(4))) float f32x4;

DEV float gelu_f(float x){ return 0.5f*x*(1.0f + erff(x*0.7071067811865476f)); }
DEV float softplus_f(float x){ return fmaxf(x,0.f) + log1pf(expf(-fabsf(x))); }
DEV unsigned short f2bf(float x){
  unsigned u = __float_as_uint(x);
  unsigned r = (u + 0x7fffu + ((u>>16)&1u)) >> 16;
  return (unsigned short)r;
}
DEV float bf2f(unsigned short h){
  unsigned u = ((unsigned)h) << 16;
  return __uint_as_float(u);
}

// ---------------------------------------------------------------------------
// Pack f32 [Cout][K] weights into bf16 MFMA fragment order.
// ---------------------------------------------------------------------------
__global__ __launch_bounds__(256) void packw_k(const float* __restrict__ W,
                                               unsigned short* __restrict__ dst,
                                               int ntn, int ntk, int K)
{
  int tid = blockIdx.x*256 + threadIdx.x;
  int total = ntn*ntk*64;
  if (tid >= total) return;
  int lane = tid & 63;
  int f = tid >> 6;
  int kt = f % ntk, nt = f / ntk;
  int row = nt*16 + (lane & 15);
  int k0 = kt*32 + (lane >> 4)*8;
  const float* src = W + (size_t)row*K + k0;
  unsigned short h[8];
#pragma unroll
  for (int j=0;j<8;++j) h[j] = f2bf(src[j]);
  uint4 pk;
  pk.x = (unsigned)h[0] | ((unsigned)h[1]<<16);
  pk.y = (unsigned)h[2] | ((unsigned)h[3]<<16);
  pk.z = (unsigned)h[4] | ((unsigned)h[5]<<16);
  pk.w = (unsigned)h[6] | ((unsigned)h[7]<<16);
  *reinterpret_cast<uint4*>(dst + (size_t)tid*8) = pk;
}

// ---------------------------------------------------------------------------
// Pack conv weights [Cout][Cin][3][3] into fragment order with K = s*Cin+ic
// ---------------------------------------------------------------------------
__global__ __launch_bounds__(256) void pack_convw_k(const float* __restrict__ W,
                                                    unsigned short* __restrict__ dst,
                                                    int ntn, int ntk, int Cin)
{
  int tid = blockIdx.x*256 + threadIdx.x;
  int total = ntn*ntk*64;
  if (tid >= total) return;
  int lane = tid & 63;
  int f = tid >> 6;
  int kt = f % ntk, nt = f / ntk;
  int row = nt*16 + (lane & 15);
  int k0 = kt*32 + (lane >> 4)*8;
  unsigned short h[8];
#pragma unroll
  for (int j=0;j<8;++j) {
    int k = k0 + j;
    int s = k / Cin;
    int ic = k - s*Cin;
    h[j] = f2bf(W[((size_t)row*Cin + ic)*9 + s]);
  }
  uint4 pk;
  pk.x = (unsigned)h[0] | ((unsigned)h[1]<<16);
  pk.y = (unsigned)h[2] | ((unsigned)h[3]<<16);
  pk.z = (unsigned)h[4] | ((unsigned)h[5]<<16);
  pk.w = (unsigned)h[6] | ((unsigned)h[7]<<16);
  *reinterpret_cast<uint4*>(dst + (size_t)tid*8) = pk;
}

// ---------------------------------------------------------------------------
// Extract clamped 33x33 vis windows (incl. conv zero ring) -> bf16 NHWC
// ---------------------------------------------------------------------------
__global__ __launch_bounds__(256) void extvwin_k(const float* __restrict__ vis,
                                                 const float* __restrict__ spv,
                                                 unsigned short* __restrict__ vwin)
{
  int il = blockIdx.x;
  int p = blockIdx.y*256 + threadIdx.x;
  if (p >= 1089) return;
  int wy = p/33, wx = p%33;
  unsigned short* dst = vwin + ((size_t)il*1089 + p)*64;
  if (wy==0 || wy==32 || wx==0 || wx==32) {
    uint4 z = {0,0,0,0};
#pragma unroll
    for (int q=0;q<8;++q) *reinterpret_cast<uint4*>(dst + q*8) = z;
    return;
  }
  int cx = (int)rintf(spv[il*2+0]);
  int cy = (int)rintf(spv[il*2+1]);
  int gy = min(max(cy + wy - 16, 0), 1023);
  int gx = min(max(cx + wx - 16, 0), 1023);
  const float* sp = vis + (size_t)gy*1024 + gx;
  unsigned short h[64];
#pragma unroll
  for (int c=0;c<64;++c) h[c] = f2bf(sp[(size_t)c<<20]);
#pragma unroll
  for (int q=0;q<8;++q) {
    uint4 pk;
    pk.x = (unsigned)h[q*8+0] | ((unsigned)h[q*8+1]<<16);
    pk.y = (unsigned)h[q*8+2] | ((unsigned)h[q*8+3]<<16);
    pk.z = (unsigned)h[q*8+4] | ((unsigned)h[q*8+5]<<16);
    pk.w = (unsigned)h[q*8+6] | ((unsigned)h[q*8+7]<<16);
    *reinterpret_cast<uint4*>(dst + q*8) = pk;
  }
}

// ---------------------------------------------------------------------------
// MFMA implicit-GEMM 3x3 conv.
// MODE 0: src NHWC [item][961][CIN].  MODE 1: 33x33 window buffer.
// MODE 2: src NHWC [sit][961][CIN] with sit=(nbBase+item)>>2, FiLM+gelu
//         modulation applied during staging (film row = blockIdx.x*64).
// FDEC: fuse 1x1 dec3 + softplus; write f32 to outf, atomicAdd sums.
// ---------------------------------------------------------------------------
template<int CIN, int COUT, int NKT, int MODE, bool FGELU, bool FDEC>
__global__ __launch_bounds__(256,2) void convmf_k(
    const unsigned short* __restrict__ src,
    const unsigned short* __restrict__ Wp,
    const float* __restrict__ Bv,
    unsigned short* __restrict__ out,
    const float* __restrict__ film, int nbBase,
    float* __restrict__ outf, float* __restrict__ sums,
    const float* __restrict__ w3, const float* __restrict__ b3)
{
  constexpr int NOCT = COUT/16;
  constexpr int NSLOT = CIN/8;
  constexpr int SWM = NSLOT-1;
  const int item = blockIdx.x;
  const int y0 = blockIdx.y*8;
  const int t = threadIdx.x;
  const int w = t>>6, l = t&63, g = l>>4, l15 = l&15;

  __shared__ __align__(16) unsigned short lds[330*CIN];

  // ---- stage ----
  const int sit = (MODE==2) ? ((nbBase + item) >> 2) : item;
  const float* frow = (MODE==2) ? (film + (size_t)item*64) : nullptr;
  for (int u = t; u < 330*NSLOT; u += 256) {
    int slot = u & SWM;
    int rowi = u / NSLOT;            // r*33+col
    int r = rowi / 33, col = rowi - r*33;
    uint4 val = {0,0,0,0};
    if (MODE==1) {
      int gr = y0 + r;
      if (gr < 33)
        val = *reinterpret_cast<const uint4*>(src + ((size_t)item*1089 + gr*33 + col)*CIN + slot*8);
    } else {
      int y = y0 + r - 1, x = col - 1;
      if ((unsigned)y < 31u && (unsigned)x < 31u) {
        val = *reinterpret_cast<const uint4*>(src + ((size_t)sit*961 + y*31 + x)*CIN + slot*8);
        if (MODE==2) {
          int c0 = slot*8;
          float4 g0 = *reinterpret_cast<const float4*>(frow + c0);
          float4 g1 = *reinterpret_cast<const float4*>(frow + c0 + 4);
          float4 b0 = *reinterpret_cast<const float4*>(frow + 32 + c0);
          float4 b1 = *reinterpret_cast<const float4*>(frow + 32 + c0 + 4);
          unsigned short x8[8] = {
            (unsigned short)(val.x&0xffff),(unsigned short)(val.x>>16),
            (unsigned short)(val.y&0xffff),(unsigned short)(val.y>>16),
            (unsigned short)(val.z&0xffff),(unsigned short)(val.z>>16),
            (unsigned short)(val.w&0xffff),(unsigned short)(val.w>>16)};
          unsigned short o8[8];
          o8[0]=f2bf(gelu_f(fmaf(bf2f(x8[0]), 1.f+g0.x, b0.x)));
          o8[1]=f2bf(gelu_f(fmaf(bf2f(x8[1]), 1.f+g0.y, b0.y)));
          o8[2]=f2bf(gelu_f(fmaf(bf2f(x8[2]), 1.f+g0.z, b0.z)));
          o8[3]=f2bf(gelu_f(fmaf(bf2f(x8[3]), 1.f+g0.w, b0.w)));
          o8[4]=f2bf(gelu_f(fmaf(bf2f(x8[4]), 1.f+g1.x, b1.x)));
          o8[5]=f2bf(gelu_f(fmaf(bf2f(x8[5]), 1.f+g1.y, b1.y)));
          o8[6]=f2bf(gelu_f(fmaf(bf2f(x8[6]), 1.f+g1.z, b1.z)));
          o8[7]=f2bf(gelu_f(fmaf(bf2f(x8[7]), 1.f+g1.w, b1.w)));
          val.x = (unsigned)o8[0] | ((unsigned)o8[1]<<16);
          val.y = (unsigned)o8[2] | ((unsigned)o8[3]<<16);
          val.z = (unsigned)o8[4] | ((unsigned)o8[5]<<16);
          val.w = (unsigned)o8[6] | ((unsigned)o8[7]<<16);
        }
      }
    }
    int ds = slot ^ (rowi & SWM);
    *reinterpret_cast<uint4*>(&lds[rowi*CIN + ds*8]) = val;
  }
  __syncthreads();

  int pbase[4], gpos[4]; bool pvalid[4];
#pragma unroll
  for (int pt=0; pt<4; ++pt) {
    int p = (w*4+pt)*16 + l15;
    int pc = min(p, 247);
    int py = pc/31, px = pc - py*31;
    pbase[pt] = py*33 + px;
    gpos[pt] = y0*31 + p;
    pvalid[pt] = (p < 248) && (gpos[pt] < 961);
  }

  f32x4 acc[NOCT][4];
#pragma unroll
  for (int o=0;o<NOCT;++o)
#pragma unroll
    for (int pt=0;pt<4;++pt) acc[o][pt] = (f32x4){0.f,0.f,0.f,0.f};

  for (int kt=0; kt<NKT; ++kt) {
    int k0 = kt*32 + g*8;
    int s = k0 / CIN;
    int icg = (k0 - s*CIN) >> 3;
    int roff = (s/3)*33 + (s - (s/3)*3);
    bf16x8 bf[4];
#pragma unroll
    for (int pt=0; pt<4; ++pt) {
      int rowi = pbase[pt] + roff;
      int ds = icg ^ (rowi & SWM);
      bf[pt] = *reinterpret_cast<const bf16x8*>(&lds[rowi*CIN + ds*8]);
    }
#pragma unroll
    for (int o=0; o<NOCT; ++o) {
      bf16x8 af = *reinterpret_cast<const bf16x8*>(Wp + ((size_t)(o*NKT+kt)*64 + l)*8);
#pragma unroll
      for (int pt=0; pt<4; ++pt)
        acc[o][pt] = __builtin_amdgcn_mfma_f32_16x16x32_bf16(af, bf[pt], acc[o][pt], 0,0,0);
    }
  }

  if (FDEC) {
    // fused dec3 (1x1, COUT->1) + softplus; per-map sums via atomics
    float w3r[NOCT*4];
#pragma unroll
    for (int o=0;o<NOCT;++o) {
      float4 wv = *reinterpret_cast<const float4*>(w3 + o*16 + g*4);
      w3r[o*4+0]=wv.x; w3r[o*4+1]=wv.y; w3r[o*4+2]=wv.z; w3r[o*4+3]=wv.w;
    }
    float b3v = b3[0];
    float bsum = 0.f;
#pragma unroll
    for (int pt=0; pt<4; ++pt) {
      float part = 0.f;
#pragma unroll
      for (int o=0; o<NOCT; ++o) {
        float4 bv4 = *reinterpret_cast<const float4*>(Bv + o*16 + g*4);
        float v0 = acc[o][pt][0] + bv4.x;
        float v1 = acc[o][pt][1] + bv4.y;
        float v2 = acc[o][pt][2] + bv4.z;
        float v3 = acc[o][pt][3] + bv4.w;
        if (FGELU) { v0=gelu_f(v0); v1=gelu_f(v1); v2=gelu_f(v2); v3=gelu_f(v3); }
        part += v0*w3r[o*4+0] + v1*w3r[o*4+1] + v2*w3r[o*4+2] + v3*w3r[o*4+3];
      }
      part += __shfl_xor(part, 16);
      part += __shfl_xor(part, 32);
      float sp = softplus_f(part + b3v);
      if (pvalid[pt] && g==0) {
        outf[(size_t)item*961 + gpos[pt]] = sp;
        bsum += sp;
      }
    }
    __syncthreads();                 // lds no longer needed by any wave
    float* redf = reinterpret_cast<float*>(lds);
    redf[t] = bsum;
    __syncthreads();
    for (int off=128; off>0; off>>=1) {
      if (t < off) redf[t] += redf[t+off];
      __syncthreads();
    }
    if (t==0) atomicAdd(&sums[item], redf[0]);
    return;
  }

#pragma unroll
  for (int o=0; o<NOCT; ++o) {
    float4 bv4 = *reinterpret_cast<const float4*>(Bv + o*16 + g*4);
#pragma unroll
    for (int pt=0; pt<4; ++pt) {
      if (!pvalid[pt]) continue;
      float v0 = acc[o][pt][0] + bv4.x;
      float v1 = acc[o][pt][1] + bv4.y;
      float v2 = acc[o][pt][2] + bv4.z;
      float v3 = acc[o][pt][3] + bv4.w;
      if (FGELU) { v0=gelu_f(v0); v1=gelu_f(v1); v2=gelu_f(v2); v3=gelu_f(v3); }
      uint2 pk;
      pk.x = (unsigned)f2bf(v0) | ((unsigned)f2bf(v1)<<16);
      pk.y = (unsigned)f2bf(v2) | ((unsigned)f2bf(v3)<<16);
      *reinterpret_cast<uint2*>(out + ((size_t)item*961 + gpos[pt])*COUT + o*16 + g*4) = pk;
    }
  }
}

// ---------------------------------------------------------------------------
// Fused bottleneck-window gather + depthwise 7x7 (f32 throughout).
// Block per n. LDS tile [121][258] f32 (channel pairs interleaved).
// Writes bwinT f32 NHWC (residual base) and dwout f32 NHWC (LN input).
// ---------------------------------------------------------------------------
__global__ __launch_bounds__(256) void dwfused_k(
    const float* __restrict__ bott, const float* __restrict__ spv,
    const float* __restrict__ w, const float* __restrict__ b,
    float* __restrict__ bwinT, float* __restrict__ dwout)
{
  const int n = blockIdx.x, t = threadIdx.x;
  __shared__ float tile[121*258];

  float pxf = fminf(fmaxf(spv[n*2+0]*0.25f, 0.f), 255.f);
  float pyf = fminf(fmaxf(spv[n*2+1]*0.25f, 0.f), 255.f);
  int cx = (int)rintf(pxf), cy = (int)rintf(pyf);

  // ---- gather: lanes sweep positions (x-contiguous reads) ----
  for (int idx=t; idx<121*128; idx+=256) {
    int j = idx/121, p = idx - j*121;
    int y = p/11, x = p - y*11;
    int gy = min(max(cy + y - 5, 0), 255);
    int gx = min(max(cx + x - 5, 0), 255);
    const float* s0 = bott + ((size_t)(2*j)<<16) + (gy<<8) + gx;
    float v0 = s0[0], v1 = s0[65536];
    *reinterpret_cast<float2*>(&tile[p*258 + 2*j]) = (float2){v0, v1};
  }
  __syncthreads();

  // ---- write bwinT coalesced from LDS ----
  for (int idx=t; idx<121*256; idx+=256) {
    int p = idx >> 8, c = idx & 255;
    bwinT[((size_t)n*121 + p)*256 + c] = tile[p*258 + c];
  }

  // ---- dw compute: thread = 2 channels ----
  const int j2 = t & 127, h = t >> 7;
  const int c0 = 2*j2;
  float wA[49], wB[49];
#pragma unroll
  for (int k=0;k<49;++k){ wA[k]=w[(size_t)c0*49+k]; wB[k]=w[(size_t)(c0+1)*49+k]; }
  const float bA = b[c0], bB = b[c0+1];
  const int p0 = h*61, p1 = h ? 121 : 61;

  for (int p=p0; p<p1; ++p) {
    int y = p/11, x = p - y*11;
    float a0 = bA, a1 = bB;
    int dyl = max(0,3-y), dyh = min(6,13-y);
    int dxl = max(0,3-x), dxh = min(6,13-x);
#pragma unroll
    for (int dy=0; dy<7; ++dy) {
      if (dy < dyl || dy > dyh) continue;
      int yy = y + dy - 3;
#pragma unroll
      for (int dx=0; dx<7; ++dx) {
        if (dx < dxl || dx > dxh) continue;
        int xx = x + dx - 3;
        float2 v = *reinterpret_cast<const float2*>(&tile[(yy*11+xx)*258 + c0]);
        a0 = fmaf(v.x, wA[dy*7+dx], a0);
        a1 = fmaf(v.y, wB[dy*7+dx], a1);
      }
    }
    *reinterpret_cast<float2*>(&dwout[((size_t)n*121+p)*256 + c0]) = (float2){a0, a1};
  }
}

// ---------------------------------------------------------------------------
// Fused ConvNeXt MLP + bnp head, bf16 MFMA (as R3, + host inv_gsum)
// ---------------------------------------------------------------------------
__global__ __launch_bounds__(256) void cnx_mfma2_k(
    const float* __restrict__ xin,
    const float* __restrict__ lnw, const float* __restrict__ lnb,
    const unsigned short* __restrict__ W1p, const float* __restrict__ B1,
    const unsigned short* __restrict__ W2p, const float* __restrict__ B2,
    const float* __restrict__ gvec,
    const float* __restrict__ bwinT,
    const unsigned short* __restrict__ Wbp, const float* __restrict__ bnpb,
    float* __restrict__ bnv, float inv_gsum)
{
  const int t = threadIdx.x;
  const int w = t >> 6;
  const int l = t & 63;
  const int g = l >> 4;
  const int l15 = l & 15;
  const int row0 = blockIdx.x * 64;

  __shared__ __align__(16) unsigned short xs[64*264];
  __shared__ __align__(16) unsigned short hs[64*136];

  {
    const int rl = t >> 2, q = t & 3;
    const float* xr = xin + (size_t)(row0+rl)*256 + q*64;
    float xv[64]; float s = 0.f, s2 = 0.f;
#pragma unroll
    for (int i=0;i<64;i+=4){
      float4 v = *reinterpret_cast<const float4*>(xr+i);
      xv[i]=v.x; xv[i+1]=v.y; xv[i+2]=v.z; xv[i+3]=v.w;
      s  += v.x+v.y+v.z+v.w;
      s2 += v.x*v.x+v.y*v.y+v.z*v.z+v.w*v.w;
    }
    s += __shfl_xor(s,1); s2 += __shfl_xor(s2,1);
    s += __shfl_xor(s,2); s2 += __shfl_xor(s2,2);
    float mu = s*(1.f/256.f);
    float rstd = rsqrtf(s2*(1.f/256.f) - mu*mu + 1e-6f);
#pragma unroll
    for (int i=0;i<64;i+=8){
      int c = q*64 + i;
      float4 w0 = *reinterpret_cast<const float4*>(lnw+c);
      float4 w1 = *reinterpret_cast<const float4*>(lnw+c+4);
      float4 b0 = *reinterpret_cast<const float4*>(lnb+c);
      float4 b1 = *reinterpret_cast<const float4*>(lnb+c+4);
      unsigned short h[8];
      h[0]=f2bf(fmaf((xv[i+0]-mu)*rstd, w0.x, b0.x));
      h[1]=f2bf(fmaf((xv[i+1]-mu)*rstd, w0.y, b0.y));
      h[2]=f2bf(fmaf((xv[i+2]-mu)*rstd, w0.z, b0.z));
      h[3]=f2bf(fmaf((xv[i+3]-mu)*rstd, w0.w, b0.w));
      h[4]=f2bf(fmaf((xv[i+4]-mu)*rstd, w1.x, b1.x));
      h[5]=f2bf(fmaf((xv[i+5]-mu)*rstd, w1.y, b1.y));
      h[6]=f2bf(fmaf((xv[i+6]-mu)*rstd, w1.z, b1.z));
      h[7]=f2bf(fmaf((xv[i+7]-mu)*rstd, w1.w, b1.w));
      uint4 pk;
      pk.x = (unsigned)h[0] | ((unsigned)h[1]<<16);
      pk.y = (unsigned)h[2] | ((unsigned)h[3]<<16);
      pk.z = (unsigned)h[4] | ((unsigned)h[5]<<16);
      pk.w = (unsigned)h[6] | ((unsigned)h[7]<<16);
      *reinterpret_cast<uint4*>(&xs[rl*264 + c]) = pk;
    }
  }
  __syncthreads();

  f32x4 acc2[16];
#pragma unroll
  for (int i=0;i<16;++i) acc2[i] = (f32x4){0.f,0.f,0.f,0.f};

  for (int hc=0; hc<8; ++hc) {
    f32x4 acc1[8];
#pragma unroll
    for (int i=0;i<8;++i) acc1[i] = (f32x4){0.f,0.f,0.f,0.f};

#pragma unroll
    for (int kt=0; kt<8; ++kt) {
      bf16x8 xf[4];
#pragma unroll
      for (int rt=0; rt<4; ++rt)
        xf[rt] = *reinterpret_cast<const bf16x8*>(&xs[(rt*16+l15)*264 + kt*32 + g*8]);
#pragma unroll
      for (int i=0;i<2;++i) {
        const int ht = hc*8 + 2*w + i;
        bf16x8 wf = *reinterpret_cast<const bf16x8*>(W1p + ((size_t)(ht*8+kt)*64 + l)*8);
#pragma unroll
        for (int rt=0; rt<4; ++rt)
          acc1[i*4+rt] = __builtin_amdgcn_mfma_f32_16x16x32_bf16(wf, xf[rt], acc1[i*4+rt], 0,0,0);
      }
    }
#pragma unroll
    for (int i=0;i<2;++i) {
      const int hb = hc*128 + (2*w+i)*16 + 4*g;
      float4 b1v = *reinterpret_cast<const float4*>(B1 + hb);
#pragma unroll
      for (int rt=0; rt<4; ++rt) {
        unsigned short h0 = f2bf(gelu_f(acc1[i*4+rt][0] + b1v.x));
        unsigned short h1 = f2bf(gelu_f(acc1[i*4+rt][1] + b1v.y));
        unsigned short h2 = f2bf(gelu_f(acc1[i*4+rt][2] + b1v.z));
        unsigned short h3 = f2bf(gelu_f(acc1[i*4+rt][3] + b1v.w));
        uint2 pk;
        pk.x = (unsigned)h0 | ((unsigned)h1<<16);
        pk.y = (unsigned)h2 | ((unsigned)h3<<16);
        *reinterpret_cast<uint2*>(&hs[(rt*16+l15)*136 + (2*w+i)*16 + 4*g]) = pk;
      }
    }
    __syncthreads();
#pragma unroll
    for (int kt=0; kt<4; ++kt) {
      bf16x8 hf[4];
#pragma unroll
      for (int rt=0; rt<4; ++rt)
        hf[rt] = *reinterpret_cast<const bf16x8*>(&hs[(rt*16+l15)*136 + kt*32 + g*8]);
#pragma unroll
      for (int cj=0; cj<4; ++cj) {
        const int ct = w*4 + cj;
        bf16x8 wf = *reinterpret_cast<const bf16x8*>(W2p + ((size_t)(ct*32 + hc*4 + kt)*64 + l)*8);
#pragma unroll
        for (int rt=0; rt<4; ++rt)
          acc2[rt*4+cj] = __builtin_amdgcn_mfma_f32_16x16x32_bf16(hf[rt], wf, acc2[rt*4+cj], 0,0,0);
      }
    }
    __syncthreads();
  }

  // ---- residual in regs -> xs as bf16 ----
#pragma unroll
  for (int cj=0; cj<4; ++cj) {
    const int c = w*64 + cj*16 + l15;
    const float b2 = B2[c], gm = gvec[c];
#pragma unroll
    for (int rt=0; rt<4; ++rt) {
#pragma unroll
      for (int reg=0; reg<4; ++reg) {
        int row = rt*16 + 4*g + reg;
        float res = bwinT[(size_t)(row0+row)*256 + c] + (acc2[rt*4+cj][reg] + b2)*gm;
        xs[row*264 + c] = f2bf(res);
      }
    }
  }
  __syncthreads();

  // ---- bnp GEMM ----
  f32x4 abn[4];
#pragma unroll
  for (int i=0;i<4;++i) abn[i] = (f32x4){0.f,0.f,0.f,0.f};
#pragma unroll
  for (int kt=0; kt<8; ++kt) {
    bf16x8 af = *reinterpret_cast<const bf16x8*>(&xs[(w*16+l15)*264 + kt*32 + g*8]);
#pragma unroll
    for (int oct=0; oct<4; ++oct) {
      bf16x8 bfw = *reinterpret_cast<const bf16x8*>(Wbp + ((size_t)(oct*8+kt)*64 + l)*8);
      abn[oct] = __builtin_amdgcn_mfma_f32_16x16x32_bf16(af, bfw, abn[oct], 0,0,0);
    }
  }

  float* red = reinterpret_cast<float*>(hs);
#pragma unroll
  for (int oct=0; oct<4; ++oct) {
    float bv = bnpb[oct*16 + l15];
#pragma unroll
    for (int reg=0; reg<4; ++reg) {
      int lr = w*16 + g*4 + reg;
      int p = (row0 + lr) % 121;
      int py=p/11, px=p-py*11;
      float ly=-1.f+0.2f*py, lx=-1.f+0.2f*px;
      float wg = expf(-(lx*lx+ly*ly)/0.32f) * inv_gsum;
      red[lr*64 + oct*16 + l15] = gelu_f(abn[oct][reg] + bv) * wg;
    }
  }
  __syncthreads();
  {
    int oc = t & 63, seg = t >> 6;
    float s = 0.f;
    int curn = (row0 + seg*16) / 121;
    for (int i=0;i<16;++i) {
      int row = seg*16 + i;
      int n = (row0 + row) / 121;
      if (n != curn) { atomicAdd(&bnv[curn*64 + oc], s); s = 0.f; curn = n; }
      s += red[row*64 + oc];
    }
    atomicAdd(&bnv[curn*64 + oc], s);
  }
}

// ---------------------------------------------------------------------------
// FiLM
// ---------------------------------------------------------------------------
__global__ __launch_bounds__(256) void film_k(
    const float* __restrict__ bn_vec, const float* __restrict__ ppb,
    const float* __restrict__ bemb, const float* __restrict__ fw,
    const float* __restrict__ fb, float* __restrict__ film)
{
  int n = blockIdx.x, t = threadIdx.x;
  __shared__ float cond[4][84];
  for (int i=t; i<4*84; i+=256) {
    int b = i/84, j = i%84;
    float v;
    if (j < 16) v = bemb[b*16 + j];
    else if (j == 16) { float p = ppb[((size_t)n*4+b)*2+0]; v = fminf(fmaxf(p*(1.f/1023.f),0.f),1.f); }
    else if (j == 17) { float p = ppb[((size_t)n*4+b)*2+1]; v = fminf(fmaxf(p*(1.f/1023.f),0.f),1.f); }
    else if (j == 18) { float p = ppb[((size_t)n*4+b)*2+0]; v = p - rintf(p); }
    else if (j == 19) { float p = ppb[((size_t)n*4+b)*2+1]; v = p - rintf(p); }
    else v = bn_vec[n*64 + (j-20)];
    cond[b][j] = v;
  }
  __syncthreads();
  int b = t >> 6, oc = t & 63;
  float s = fb[oc];
  for (int j=0;j<84;++j) s = fmaf(cond[b][j], fw[oc*84+j], s);
  film[((size_t)n*4+b)*64 + oc] = s;
}

// ---------------------------------------------------------------------------
// final per-map normalization
// ---------------------------------------------------------------------------
__global__ __launch_bounds__(256) void norm_k(float* __restrict__ out,
                                              const float* __restrict__ sums)
{
  int il = blockIdx.x;
  int p = blockIdx.y*256 + threadIdx.x;
  if (p < 961) {
    float inv = 1.f / fmaxf(sums[il], 1e-8f);
    out[(size_t)il*961 + p] *= inv;
  }
}

// ---------------------------------------------------------------------------
extern "C" void kernel_launch(void* const* d_in, const int* in_sizes, int n_in,
                              void* d_out, int out_size, void* d_ws, size_t ws_size,
                              hipStream_t stream)
{
  const float* bott = (const float*)d_in[0];
  const float* vis  = (const float*)d_in[1];
  const float* spv  = (const float*)d_in[2];
  const float* ppb  = (const float*)d_in[3];
  const float* ic1w = (const float*)d_in[4];  const float* ic1b = (const float*)d_in[5];
  const float* ic2w = (const float*)d_in[6];  const float* ic2b = (const float*)d_in[7];
  const float* ic3w = (const float*)d_in[8];  const float* ic3b = (const float*)d_in[9];
  const float* dww  = (const float*)d_in[10]; const float* dwb  = (const float*)d_in[11];
  const float* lnw  = (const float*)d_in[12]; const float* lnb  = (const float*)d_in[13];
  const float* pw1w = (const float*)d_in[14]; const float* pw1b = (const float*)d_in[15];
  const float* pw2w = (const float*)d_in[16]; const float* pw2b = (const float*)d_in[17];
  const float* cgam = (const float*)d_in[18];
  const float* bnpw = (const float*)d_in[19]; const float* bnpb = (const float*)d_in[20];
  const float* bemb = (const float*)d_in[21];
  const float* fw   = (const float*)d_in[22]; const float* fb   = (const float*)d_in[23];
  const float* d1w  = (const float*)d_in[24]; const float* d1b  = (const float*)d_in[25];
  const float* d2w  = (const float*)d_in[26]; const float* d2b  = (const float*)d_in[27];
  const float* d3w  = (const float*)d_in[28]; const float* d3b  = (const float*)d_in[29];
  float* out = (float*)d_out;

  char* ws = (char*)d_ws;

  // ---- chunk size for phase-1 pipeline, from ws_size ----
  const int CH = (ws_size >= 116400128ull) ? 256 : 128;

  // P2 regions (overlap P1 regions; phases are stream-ordered)
  float* bwinT = (float*)(ws);                       // 31,719,424
  float* dwout = (float*)(ws + 31719424);            // 31,719,424 (end 63,438,848)
  // P1 regions
  unsigned short* vwin = (unsigned short*)(ws);
  size_t o_bufA = (size_t)CH*139392;
  size_t o_bufB = o_bufA + (size_t)CH*123008;
  size_t o_bufI = o_bufB + (size_t)CH*123008;
  size_t p1end  = o_bufI + (size_t)CH*61504;
  unsigned short* bufA = (unsigned short*)(ws + o_bufA);
  unsigned short* bufB = (unsigned short*)(ws + o_bufB);
  unsigned short* bufI = (unsigned short*)(ws + o_bufI);
  size_t tail = (p1end > 63438848ull) ? p1end : 63438848ull;

  float* bnv  = (float*)(ws + tail);                       // 131,072
  float* sums = (float*)(ws + tail + 131072);              // 8,192
  float* film = (float*)(ws + tail + 139264);              // 524,288
  unsigned short* W1p = (unsigned short*)(ws + tail + 663552);
  unsigned short* W2p = (unsigned short*)(ws + tail + 1187840);
  unsigned short* Wbp = (unsigned short*)(ws + tail + 1712128);
  unsigned short* Pc1 = (unsigned short*)(ws + tail + 1744896);
  unsigned short* Pc2 = (unsigned short*)(ws + tail + 1818624);
  unsigned short* Pc3 = (unsigned short*)(ws + tail + 1892352);
  unsigned short* Pd1 = (unsigned short*)(ws + tail + 1929216);
  unsigned short* Pd2 = (unsigned short*)(ws + tail + 1947648);

  // ---- weight packing ----
  packw_k<<<128,256,0,stream>>>(pw1w, W1p, 64, 8, 256);
  packw_k<<<128,256,0,stream>>>(pw2w, W2p, 16, 32, 1024);
  packw_k<<<8,  256,0,stream>>>(bnpw, Wbp, 4, 8, 256);
  pack_convw_k<<<18,256,0,stream>>>(ic1w, Pc1, 4, 18, 64);
  pack_convw_k<<<18,256,0,stream>>>(ic2w, Pc2, 4, 18, 64);
  pack_convw_k<<<9, 256,0,stream>>>(ic3w, Pc3, 2, 18, 64);
  pack_convw_k<<<5, 256,0,stream>>>(d1w,  Pd1, 2, 9, 32);
  pack_convw_k<<<5, 256,0,stream>>>(d2w,  Pd2, 2, 9, 32);

  hipMemsetAsync(ws + tail, 0, 139264, stream);  // bnv + sums

  // host gaussian normalizer
  float gs = 0.f;
  for (int py=0; py<11; ++py) for (int px=0; px<11; ++px) {
    float ly=-1.f+0.2f*py, lx=-1.f+0.2f*px;
    gs += expf(-(lx*lx+ly*ly)/0.32f);
  }
  const float inv_gsum = 1.f/gs;

  // ---- Phase 2: bottleneck path -> bn_vec (chunks of 256 n) ----
  for (int n0 = 0; n0 < 512; n0 += 256) {
    dwfused_k<<<256,256,0,stream>>>(bott, spv + n0*2, dww, dwb, bwinT, dwout);
    cnx_mfma2_k<<<484,256,0,stream>>>(dwout, lnw,lnb, W1p,pw1b, W2p,pw2b, cgam,
                                      bwinT, Wbp, bnpb, bnv + n0*64, inv_gsum);
  }
  film_k<<<512,256,0,stream>>>(bnv, ppb, bemb, fw, fb, film);

  // ---- Phase 1+3: intrinsic chain + decoder ----
  for (int n0 = 0; n0 < 512; n0 += CH) {
    extvwin_k<<<dim3(CH,5),256,0,stream>>>(vis, spv + n0*2, vwin);
    convmf_k<64,64,18,1,true ,false><<<dim3(CH,4),256,0,stream>>>(vwin, Pc1, ic1b, bufA, nullptr,0, nullptr,nullptr,nullptr,nullptr);
    convmf_k<64,64,18,0,true ,false><<<dim3(CH,4),256,0,stream>>>(bufA, Pc2, ic2b, bufB, nullptr,0, nullptr,nullptr,nullptr,nullptr);
    convmf_k<64,32,18,0,false,false><<<dim3(CH,4),256,0,stream>>>(bufB, Pc3, ic3b, bufI, nullptr,0, nullptr,nullptr,nullptr,nullptr);
    for (int s = 0; s < CH/64; ++s) {
      int nb0 = n0*4 + s*256;
      convmf_k<32,32,9,2,true,false><<<dim3(256,4),256,0,stream>>>(bufI, Pd1, d1b, bufB,
          film + (size_t)nb0*64, s*256, nullptr,nullptr,nullptr,nullptr);
      convmf_k<32,32,9,0,true,true ><<<dim3(256,4),256,0,stream>>>(bufB, Pd2, d2b, nullptr,
          nullptr,0, out + (size_t)nb0*961, sums + nb0, d3w, d3b);
    }
  }
  norm_k<<<dim3(2048,4),256,0,stream>>>(out, sums);
}

// Round 5
// 1072.773 us; speedup vs baseline: 7.4252x; 1.1359x over previous
//
#include <hip/hip_runtime.h>
#include <cstdint>
#include <cstddef>
#include <cmath>

#define DEV __device__ __forceinline__

typedef __attribute__((ext_vector_type(8))) short bf16x8;
typedef __attribute__((ext_vector_type(4))) float f32x4;

DEV float gelu_f(float x){ return 0.5f*x*(1.0f + erff(x*0.7071067811865476f)); }
DEV float softplus_f(float x){ return fmaxf(x,0.f) + log1pf(expf(-fabsf(x))); }
DEV unsigned short f2bf(float x){
  unsigned u = __float_as_uint(x);
  unsigned r = (u + 0x7fffu + ((u>>16)&1u)) >> 16;
  return (unsigned short)r;
}
DEV float bf2f(unsigned short h){
  unsigned u = ((unsigned)h) << 16;
  return __uint_as_float(u);
}

// ---------------------------------------------------------------------------
// Pack f32 [Cout][K] weights into bf16 MFMA fragment order.
// ---------------------------------------------------------------------------
__global__ __launch_bounds__(256) void packw_k(const float* __restrict__ W,
                                               unsigned short* __restrict__ dst,
                                               int ntn, int ntk, int K)
{
  int tid = blockIdx.x*256 + threadIdx.x;
  int total = ntn*ntk*64;
  if (tid >= total) return;
  int lane = tid & 63;
  int f = tid >> 6;
  int kt = f % ntk, nt = f / ntk;
  int row = nt*16 + (lane & 15);
  int k0 = kt*32 + (lane >> 4)*8;
  const float* src = W + (size_t)row*K + k0;
  unsigned short h[8];
#pragma unroll
  for (int j=0;j<8;++j) h[j] = f2bf(src[j]);
  uint4 pk;
  pk.x = (unsigned)h[0] | ((unsigned)h[1]<<16);
  pk.y = (unsigned)h[2] | ((unsigned)h[3]<<16);
  pk.z = (unsigned)h[4] | ((unsigned)h[5]<<16);
  pk.w = (unsigned)h[6] | ((unsigned)h[7]<<16);
  *reinterpret_cast<uint4*>(dst + (size_t)tid*8) = pk;
}

// ---------------------------------------------------------------------------
// Pack conv weights [Cout][Cin][3][3] into fragment order with K = s*Cin+ic
// ---------------------------------------------------------------------------
__global__ __launch_bounds__(256) void pack_convw_k(const float* __restrict__ W,
                                                    unsigned short* __restrict__ dst,
                                                    int ntn, int ntk, int Cin)
{
  int tid = blockIdx.x*256 + threadIdx.x;
  int total = ntn*ntk*64;
  if (tid >= total) return;
  int lane = tid & 63;
  int f = tid >> 6;
  int kt = f % ntk, nt = f / ntk;
  int row = nt*16 + (lane & 15);
  int k0 = kt*32 + (lane >> 4)*8;
  unsigned short h[8];
#pragma unroll
  for (int j=0;j<8;++j) {
    int k = k0 + j;
    int s = k / Cin;
    int ic = k - s*Cin;
    h[j] = f2bf(W[((size_t)row*Cin + ic)*9 + s]);
  }
  uint4 pk;
  pk.x = (unsigned)h[0] | ((unsigned)h[1]<<16);
  pk.y = (unsigned)h[2] | ((unsigned)h[3]<<16);
  pk.z = (unsigned)h[4] | ((unsigned)h[5]<<16);
  pk.w = (unsigned)h[6] | ((unsigned)h[7]<<16);
  *reinterpret_cast<uint4*>(dst + (size_t)tid*8) = pk;
}

// ---------------------------------------------------------------------------
// Extract clamped 33x33 vis windows (incl. conv zero ring) -> bf16 NHWC
// ---------------------------------------------------------------------------
__global__ __launch_bounds__(256) void extvwin_k(const float* __restrict__ vis,
                                                 const float* __restrict__ spv,
                                                 unsigned short* __restrict__ vwin)
{
  int il = blockIdx.x;
  int p = blockIdx.y*256 + threadIdx.x;
  if (p >= 1089) return;
  int wy = p/33, wx = p%33;
  unsigned short* dst = vwin + ((size_t)il*1089 + p)*64;
  if (wy==0 || wy==32 || wx==0 || wx==32) {
    uint4 z = {0,0,0,0};
#pragma unroll
    for (int q=0;q<8;++q) *reinterpret_cast<uint4*>(dst + q*8) = z;
    return;
  }
  int cx = (int)rintf(spv[il*2+0]);
  int cy = (int)rintf(spv[il*2+1]);
  int gy = min(max(cy + wy - 16, 0), 1023);
  int gx = min(max(cx + wx - 16, 0), 1023);
  const float* sp = vis + (size_t)gy*1024 + gx;
  unsigned short h[64];
#pragma unroll
  for (int c=0;c<64;++c) h[c] = f2bf(sp[(size_t)c<<20]);
#pragma unroll
  for (int q=0;q<8;++q) {
    uint4 pk;
    pk.x = (unsigned)h[q*8+0] | ((unsigned)h[q*8+1]<<16);
    pk.y = (unsigned)h[q*8+2] | ((unsigned)h[q*8+3]<<16);
    pk.z = (unsigned)h[q*8+4] | ((unsigned)h[q*8+5]<<16);
    pk.w = (unsigned)h[q*8+6] | ((unsigned)h[q*8+7]<<16);
    *reinterpret_cast<uint4*>(dst + q*8) = pk;
  }
}

// ---------------------------------------------------------------------------
// MFMA implicit-GEMM 3x3 conv.
// MODE 0: src NHWC [item][961][CIN].  MODE 1: 33x33 window buffer.
// MODE 2: src NHWC [sit][961][CIN] with sit=(nbBase+item)>>2, FiLM+gelu
//         modulation applied during staging.
// FDEC: fuse 1x1 dec3 + softplus; write f32 to outf, atomicAdd sums.
// ---------------------------------------------------------------------------
template<int CIN, int COUT, int NKT, int MODE, bool FGELU, bool FDEC>
__global__ __launch_bounds__(256,2) void convmf_k(
    const unsigned short* __restrict__ src,
    const unsigned short* __restrict__ Wp,
    const float* __restrict__ Bv,
    unsigned short* __restrict__ out,
    const float* __restrict__ film, int nbBase,
    float* __restrict__ outf, float* __restrict__ sums,
    const float* __restrict__ w3, const float* __restrict__ b3)
{
  constexpr int NOCT = COUT/16;
  constexpr int NSLOT = CIN/8;
  constexpr int SWM = NSLOT-1;
  const int item = blockIdx.x;
  const int y0 = blockIdx.y*8;
  const int t = threadIdx.x;
  const int w = t>>6, l = t&63, g = l>>4, l15 = l&15;

  __shared__ __align__(16) unsigned short lds[330*CIN];

  // ---- stage ----
  const int sit = (MODE==2) ? ((nbBase + item) >> 2) : item;
  const float* frow = (MODE==2) ? (film + (size_t)item*64) : nullptr;
  for (int u = t; u < 330*NSLOT; u += 256) {
    int slot = u & SWM;
    int rowi = u / NSLOT;            // r*33+col
    int r = rowi / 33, col = rowi - r*33;
    uint4 val = {0,0,0,0};
    if (MODE==1) {
      int gr = y0 + r;
      if (gr < 33)
        val = *reinterpret_cast<const uint4*>(src + ((size_t)item*1089 + gr*33 + col)*CIN + slot*8);
    } else {
      int y = y0 + r - 1, x = col - 1;
      if ((unsigned)y < 31u && (unsigned)x < 31u) {
        val = *reinterpret_cast<const uint4*>(src + ((size_t)sit*961 + y*31 + x)*CIN + slot*8);
        if (MODE==2) {
          int c0 = slot*8;
          float4 g0 = *reinterpret_cast<const float4*>(frow + c0);
          float4 g1 = *reinterpret_cast<const float4*>(frow + c0 + 4);
          float4 b0 = *reinterpret_cast<const float4*>(frow + 32 + c0);
          float4 b1 = *reinterpret_cast<const float4*>(frow + 32 + c0 + 4);
          unsigned short x8[8] = {
            (unsigned short)(val.x&0xffff),(unsigned short)(val.x>>16),
            (unsigned short)(val.y&0xffff),(unsigned short)(val.y>>16),
            (unsigned short)(val.z&0xffff),(unsigned short)(val.z>>16),
            (unsigned short)(val.w&0xffff),(unsigned short)(val.w>>16)};
          unsigned short o8[8];
          o8[0]=f2bf(gelu_f(fmaf(bf2f(x8[0]), 1.f+g0.x, b0.x)));
          o8[1]=f2bf(gelu_f(fmaf(bf2f(x8[1]), 1.f+g0.y, b0.y)));
          o8[2]=f2bf(gelu_f(fmaf(bf2f(x8[2]), 1.f+g0.z, b0.z)));
          o8[3]=f2bf(gelu_f(fmaf(bf2f(x8[3]), 1.f+g0.w, b0.w)));
          o8[4]=f2bf(gelu_f(fmaf(bf2f(x8[4]), 1.f+g1.x, b1.x)));
          o8[5]=f2bf(gelu_f(fmaf(bf2f(x8[5]), 1.f+g1.y, b1.y)));
          o8[6]=f2bf(gelu_f(fmaf(bf2f(x8[6]), 1.f+g1.z, b1.z)));
          o8[7]=f2bf(gelu_f(fmaf(bf2f(x8[7]), 1.f+g1.w, b1.w)));
          val.x = (unsigned)o8[0] | ((unsigned)o8[1]<<16);
          val.y = (unsigned)o8[2] | ((unsigned)o8[3]<<16);
          val.z = (unsigned)o8[4] | ((unsigned)o8[5]<<16);
          val.w = (unsigned)o8[6] | ((unsigned)o8[7]<<16);
        }
      }
    }
    int ds = slot ^ (rowi & SWM);
    *reinterpret_cast<uint4*>(&lds[rowi*CIN + ds*8]) = val;
  }
  __syncthreads();

  int pbase[4], gpos[4]; bool pvalid[4];
#pragma unroll
  for (int pt=0; pt<4; ++pt) {
    int p = (w*4+pt)*16 + l15;
    int pc = min(p, 247);
    int py = pc/31, px = pc - py*31;
    pbase[pt] = py*33 + px;
    gpos[pt] = y0*31 + p;
    pvalid[pt] = (p < 248) && (gpos[pt] < 961);
  }

  f32x4 acc[NOCT][4];
#pragma unroll
  for (int o=0;o<NOCT;++o)
#pragma unroll
    for (int pt=0;pt<4;++pt) acc[o][pt] = (f32x4){0.f,0.f,0.f,0.f};

  for (int kt=0; kt<NKT; ++kt) {
    int k0 = kt*32 + g*8;
    int s = k0 / CIN;
    int icg = (k0 - s*CIN) >> 3;
    int roff = (s/3)*33 + (s - (s/3)*3);
    bf16x8 bf[4];
#pragma unroll
    for (int pt=0; pt<4; ++pt) {
      int rowi = pbase[pt] + roff;
      int ds = icg ^ (rowi & SWM);
      bf[pt] = *reinterpret_cast<const bf16x8*>(&lds[rowi*CIN + ds*8]);
    }
#pragma unroll
    for (int o=0; o<NOCT; ++o) {
      bf16x8 af = *reinterpret_cast<const bf16x8*>(Wp + ((size_t)(o*NKT+kt)*64 + l)*8);
#pragma unroll
      for (int pt=0; pt<4; ++pt)
        acc[o][pt] = __builtin_amdgcn_mfma_f32_16x16x32_bf16(af, bf[pt], acc[o][pt], 0,0,0);
    }
  }

  if (FDEC) {
    float w3r[NOCT*4];
#pragma unroll
    for (int o=0;o<NOCT;++o) {
      float4 wv = *reinterpret_cast<const float4*>(w3 + o*16 + g*4);
      w3r[o*4+0]=wv.x; w3r[o*4+1]=wv.y; w3r[o*4+2]=wv.z; w3r[o*4+3]=wv.w;
    }
    float b3v = b3[0];
    float bsum = 0.f;
#pragma unroll
    for (int pt=0; pt<4; ++pt) {
      float part = 0.f;
#pragma unroll
      for (int o=0; o<NOCT; ++o) {
        float4 bv4 = *reinterpret_cast<const float4*>(Bv + o*16 + g*4);
        float v0 = acc[o][pt][0] + bv4.x;
        float v1 = acc[o][pt][1] + bv4.y;
        float v2 = acc[o][pt][2] + bv4.z;
        float v3 = acc[o][pt][3] + bv4.w;
        if (FGELU) { v0=gelu_f(v0); v1=gelu_f(v1); v2=gelu_f(v2); v3=gelu_f(v3); }
        part += v0*w3r[o*4+0] + v1*w3r[o*4+1] + v2*w3r[o*4+2] + v3*w3r[o*4+3];
      }
      part += __shfl_xor(part, 16);
      part += __shfl_xor(part, 32);
      float sp = softplus_f(part + b3v);
      if (pvalid[pt] && g==0) {
        outf[(size_t)item*961 + gpos[pt]] = sp;
        bsum += sp;
      }
    }
    __syncthreads();
    float* redf = reinterpret_cast<float*>(lds);
    redf[t] = bsum;
    __syncthreads();
    for (int off=128; off>0; off>>=1) {
      if (t < off) redf[t] += redf[t+off];
      __syncthreads();
    }
    if (t==0) atomicAdd(&sums[item], redf[0]);
    return;
  }

#pragma unroll
  for (int o=0; o<NOCT; ++o) {
    float4 bv4 = *reinterpret_cast<const float4*>(Bv + o*16 + g*4);
#pragma unroll
    for (int pt=0; pt<4; ++pt) {
      if (!pvalid[pt]) continue;
      float v0 = acc[o][pt][0] + bv4.x;
      float v1 = acc[o][pt][1] + bv4.y;
      float v2 = acc[o][pt][2] + bv4.z;
      float v3 = acc[o][pt][3] + bv4.w;
      if (FGELU) { v0=gelu_f(v0); v1=gelu_f(v1); v2=gelu_f(v2); v3=gelu_f(v3); }
      uint2 pk;
      pk.x = (unsigned)f2bf(v0) | ((unsigned)f2bf(v1)<<16);
      pk.y = (unsigned)f2bf(v2) | ((unsigned)f2bf(v3)<<16);
      *reinterpret_cast<uint2*>(out + ((size_t)item*961 + gpos[pt])*COUT + o*16 + g*4) = pk;
    }
  }
}

// ---------------------------------------------------------------------------
// Fused bottleneck-window gather + depthwise 7x7, channel-sliced.
// Block = (n, 64-ch slice). LDS [121][66] f32 = 32 KB -> ~4-5 blocks/CU.
// Writes bwinT bf16 NHWC and dwout bf16 NHWC.
// ---------------------------------------------------------------------------
__global__ __launch_bounds__(256,4) void dwfused2_k(
    const float* __restrict__ bott, const float* __restrict__ spv,
    const float* __restrict__ w, const float* __restrict__ b,
    unsigned short* __restrict__ bwinT, unsigned short* __restrict__ dwout)
{
  const int n = blockIdx.x, cs = blockIdx.y*64, t = threadIdx.x;
  __shared__ float tile[121*66];

  float pxf = fminf(fmaxf(spv[n*2+0]*0.25f, 0.f), 255.f);
  float pyf = fminf(fmaxf(spv[n*2+1]*0.25f, 0.f), 255.f);
  int cx = (int)rintf(pxf), cy = (int)rintf(pyf);

  // ---- gather: 32 channel-pairs x 121 positions ----
  for (int idx=t; idx<121*32; idx+=256) {
    int j = idx/121, p = idx - j*121;
    int y = p/11, x = p - y*11;
    int gy = min(max(cy + y - 5, 0), 255);
    int gx = min(max(cx + x - 5, 0), 255);
    const float* s0 = bott + ((size_t)(cs+2*j)<<16) + (gy<<8) + gx;
    *reinterpret_cast<float2*>(&tile[p*66 + 2*j]) = (float2){s0[0], s0[65536]};
  }
  __syncthreads();

  // ---- write bwinT slice (bf16, coalesced) ----
  for (int idx=t; idx<121*64; idx+=256) {
    int p = idx >> 6, c = idx & 63;
    bwinT[((size_t)n*121 + p)*256 + cs + c] = f2bf(tile[p*66 + c]);
  }

  // ---- dw compute: lane = channel, wave = position phase ----
  const int c = t & 63, ph = t >> 6;
  const int ch = cs + c;
  float wr[49];
#pragma unroll
  for (int k=0;k<49;++k) wr[k] = w[(size_t)ch*49 + k];
  const float bias = b[ch];

  for (int p=ph; p<121; p+=4) {
    int y = p/11, x = p - y*11;
    float a = bias;
    int dyl = max(0,3-y), dyh = min(6,13-y);
    int dxl = max(0,3-x), dxh = min(6,13-x);
#pragma unroll
    for (int dy=0; dy<7; ++dy) {
      if (dy < dyl || dy > dyh) continue;
      int yy = y + dy - 3;
#pragma unroll
      for (int dx=0; dx<7; ++dx) {
        if (dx < dxl || dx > dxh) continue;
        int xx = x + dx - 3;
        a = fmaf(tile[(yy*11+xx)*66 + c], wr[dy*7+dx], a);
      }
    }
    dwout[((size_t)n*121 + p)*256 + ch] = f2bf(a);
  }
}

// ---------------------------------------------------------------------------
// Fused ConvNeXt MLP + bnp head, bf16 MFMA. bf16 inputs (dwout, bwinT).
// ---------------------------------------------------------------------------
__global__ __launch_bounds__(256) void cnx_mfma2_k(
    const unsigned short* __restrict__ xin,
    const float* __restrict__ lnw, const float* __restrict__ lnb,
    const unsigned short* __restrict__ W1p, const float* __restrict__ B1,
    const unsigned short* __restrict__ W2p, const float* __restrict__ B2,
    const float* __restrict__ gvec,
    const unsigned short* __restrict__ bwinT,
    const unsigned short* __restrict__ Wbp, const float* __restrict__ bnpb,
    float* __restrict__ bnv, float inv_gsum)
{
  const int t = threadIdx.x;
  const int w = t >> 6;
  const int l = t & 63;
  const int g = l >> 4;
  const int l15 = l & 15;
  const int row0 = blockIdx.x * 64;

  __shared__ __align__(16) unsigned short xs[64*264];
  __shared__ __align__(16) unsigned short hs[64*136];

  {
    const int rl = t >> 2, q = t & 3;
    const unsigned short* xr = xin + (size_t)(row0+rl)*256 + q*64;
    float xv[64]; float s = 0.f, s2 = 0.f;
#pragma unroll
    for (int i=0;i<64;i+=8){
      uint4 v = *reinterpret_cast<const uint4*>(xr+i);
      unsigned short xh[8] = {
        (unsigned short)(v.x&0xffff),(unsigned short)(v.x>>16),
        (unsigned short)(v.y&0xffff),(unsigned short)(v.y>>16),
        (unsigned short)(v.z&0xffff),(unsigned short)(v.z>>16),
        (unsigned short)(v.w&0xffff),(unsigned short)(v.w>>16)};
#pragma unroll
      for (int j=0;j<8;++j){
        float f = bf2f(xh[j]);
        xv[i+j] = f; s += f; s2 += f*f;
      }
    }
    s += __shfl_xor(s,1); s2 += __shfl_xor(s2,1);
    s += __shfl_xor(s,2); s2 += __shfl_xor(s2,2);
    float mu = s*(1.f/256.f);
    float rstd = rsqrtf(s2*(1.f/256.f) - mu*mu + 1e-6f);
#pragma unroll
    for (int i=0;i<64;i+=8){
      int c = q*64 + i;
      float4 w0 = *reinterpret_cast<const float4*>(lnw+c);
      float4 w1 = *reinterpret_cast<const float4*>(lnw+c+4);
      float4 b0 = *reinterpret_cast<const float4*>(lnb+c);
      float4 b1 = *reinterpret_cast<const float4*>(lnb+c+4);
      unsigned short h[8];
      h[0]=f2bf(fmaf((xv[i+0]-mu)*rstd, w0.x, b0.x));
      h[1]=f2bf(fmaf((xv[i+1]-mu)*rstd, w0.y, b0.y));
      h[2]=f2bf(fmaf((xv[i+2]-mu)*rstd, w0.z, b0.z));
      h[3]=f2bf(fmaf((xv[i+3]-mu)*rstd, w0.w, b0.w));
      h[4]=f2bf(fmaf((xv[i+4]-mu)*rstd, w1.x, b1.x));
      h[5]=f2bf(fmaf((xv[i+5]-mu)*rstd, w1.y, b1.y));
      h[6]=f2bf(fmaf((xv[i+6]-mu)*rstd, w1.z, b1.z));
      h[7]=f2bf(fmaf((xv[i+7]-mu)*rstd, w1.w, b1.w));
      uint4 pk;
      pk.x = (unsigned)h[0] | ((unsigned)h[1]<<16);
      pk.y = (unsigned)h[2] | ((unsigned)h[3]<<16);
      pk.z = (unsigned)h[4] | ((unsigned)h[5]<<16);
      pk.w = (unsigned)h[6] | ((unsigned)h[7]<<16);
      *reinterpret_cast<uint4*>(&xs[rl*264 + c]) = pk;
    }
  }
  __syncthreads();

  f32x4 acc2[16];
#pragma unroll
  for (int i=0;i<16;++i) acc2[i] = (f32x4){0.f,0.f,0.f,0.f};

  for (int hc=0; hc<8; ++hc) {
    f32x4 acc1[8];
#pragma unroll
    for (int i=0;i<8;++i) acc1[i] = (f32x4){0.f,0.f,0.f,0.f};

#pragma unroll
    for (int kt=0; kt<8; ++kt) {
      bf16x8 xf[4];
#pragma unroll
      for (int rt=0; rt<4; ++rt)
        xf[rt] = *reinterpret_cast<const bf16x8*>(&xs[(rt*16+l15)*264 + kt*32 + g*8]);
#pragma unroll
      for (int i=0;i<2;++i) {
        const int ht = hc*8 + 2*w + i;
        bf16x8 wf = *reinterpret_cast<const bf16x8*>(W1p + ((size_t)(ht*8+kt)*64 + l)*8);
#pragma unroll
        for (int rt=0; rt<4; ++rt)
          acc1[i*4+rt] = __builtin_amdgcn_mfma_f32_16x16x32_bf16(wf, xf[rt], acc1[i*4+rt], 0,0,0);
      }
    }
#pragma unroll
    for (int i=0;i<2;++i) {
      const int hb = hc*128 + (2*w+i)*16 + 4*g;
      float4 b1v = *reinterpret_cast<const float4*>(B1 + hb);
#pragma unroll
      for (int rt=0; rt<4; ++rt) {
        unsigned short h0 = f2bf(gelu_f(acc1[i*4+rt][0] + b1v.x));
        unsigned short h1 = f2bf(gelu_f(acc1[i*4+rt][1] + b1v.y));
        unsigned short h2 = f2bf(gelu_f(acc1[i*4+rt][2] + b1v.z));
        unsigned short h3 = f2bf(gelu_f(acc1[i*4+rt][3] + b1v.w));
        uint2 pk;
        pk.x = (unsigned)h0 | ((unsigned)h1<<16);
        pk.y = (unsigned)h2 | ((unsigned)h3<<16);
        *reinterpret_cast<uint2*>(&hs[(rt*16+l15)*136 + (2*w+i)*16 + 4*g]) = pk;
      }
    }
    __syncthreads();
#pragma unroll
    for (int kt=0; kt<4; ++kt) {
      bf16x8 hf[4];
#pragma unroll
      for (int rt=0; rt<4; ++rt)
        hf[rt] = *reinterpret_cast<const bf16x8*>(&hs[(rt*16+l15)*136 + kt*32 + g*8]);
#pragma unroll
      for (int cj=0; cj<4; ++cj) {
        const int ct = w*4 + cj;
        bf16x8 wf = *reinterpret_cast<const bf16x8*>(W2p + ((size_t)(ct*32 + hc*4 + kt)*64 + l)*8);
#pragma unroll
        for (int rt=0; rt<4; ++rt)
          acc2[rt*4+cj] = __builtin_amdgcn_mfma_f32_16x16x32_bf16(hf[rt], wf, acc2[rt*4+cj], 0,0,0);
      }
    }
    __syncthreads();
  }

  // ---- residual in regs -> xs as bf16 ----
#pragma unroll
  for (int cj=0; cj<4; ++cj) {
    const int c = w*64 + cj*16 + l15;
    const float b2 = B2[c], gm = gvec[c];
#pragma unroll
    for (int rt=0; rt<4; ++rt) {
#pragma unroll
      for (int reg=0; reg<4; ++reg) {
        int row = rt*16 + 4*g + reg;
        float res = bf2f(bwinT[(size_t)(row0+row)*256 + c]) + (acc2[rt*4+cj][reg] + b2)*gm;
        xs[row*264 + c] = f2bf(res);
      }
    }
  }
  __syncthreads();

  // ---- bnp GEMM ----
  f32x4 abn[4];
#pragma unroll
  for (int i=0;i<4;++i) abn[i] = (f32x4){0.f,0.f,0.f,0.f};
#pragma unroll
  for (int kt=0; kt<8; ++kt) {
    bf16x8 af = *reinterpret_cast<const bf16x8*>(&xs[(w*16+l15)*264 + kt*32 + g*8]);
#pragma unroll
    for (int oct=0; oct<4; ++oct) {
      bf16x8 bfw = *reinterpret_cast<const bf16x8*>(Wbp + ((size_t)(oct*8+kt)*64 + l)*8);
      abn[oct] = __builtin_amdgcn_mfma_f32_16x16x32_bf16(af, bfw, abn[oct], 0,0,0);
    }
  }

  float* red = reinterpret_cast<float*>(hs);
#pragma unroll
  for (int oct=0; oct<4; ++oct) {
    float bv = bnpb[oct*16 + l15];
#pragma unroll
    for (int reg=0; reg<4; ++reg) {
      int lr = w*16 + g*4 + reg;
      int p = (row0 + lr) % 121;
      int py=p/11, px=p-py*11;
      float ly=-1.f+0.2f*py, lx=-1.f+0.2f*px;
      float wg = expf(-(lx*lx+ly*ly)/0.32f) * inv_gsum;
      red[lr*64 + oct*16 + l15] = gelu_f(abn[oct][reg] + bv) * wg;
    }
  }
  __syncthreads();
  {
    int oc = t & 63, seg = t >> 6;
    float s = 0.f;
    int curn = (row0 + seg*16) / 121;
    for (int i=0;i<16;++i) {
      int row = seg*16 + i;
      int n = (row0 + row) / 121;
      if (n != curn) { atomicAdd(&bnv[curn*64 + oc], s); s = 0.f; curn = n; }
      s += red[row*64 + oc];
    }
    atomicAdd(&bnv[curn*64 + oc], s);
  }
}

// ---------------------------------------------------------------------------
// FiLM
// ---------------------------------------------------------------------------
__global__ __launch_bounds__(256) void film_k(
    const float* __restrict__ bn_vec, const float* __restrict__ ppb,
    const float* __restrict__ bemb, const float* __restrict__ fw,
    const float* __restrict__ fb, float* __restrict__ film)
{
  int n = blockIdx.x, t = threadIdx.x;
  __shared__ float cond[4][84];
  for (int i=t; i<4*84; i+=256) {
    int b = i/84, j = i%84;
    float v;
    if (j < 16) v = bemb[b*16 + j];
    else if (j == 16) { float p = ppb[((size_t)n*4+b)*2+0]; v = fminf(fmaxf(p*(1.f/1023.f),0.f),1.f); }
    else if (j == 17) { float p = ppb[((size_t)n*4+b)*2+1]; v = fminf(fmaxf(p*(1.f/1023.f),0.f),1.f); }
    else if (j == 18) { float p = ppb[((size_t)n*4+b)*2+0]; v = p - rintf(p); }
    else if (j == 19) { float p = ppb[((size_t)n*4+b)*2+1]; v = p - rintf(p); }
    else v = bn_vec[n*64 + (j-20)];
    cond[b][j] = v;
  }
  __syncthreads();
  int b = t >> 6, oc = t & 63;
  float s = fb[oc];
  for (int j=0;j<84;++j) s = fmaf(cond[b][j], fw[oc*84+j], s);
  film[((size_t)n*4+b)*64 + oc] = s;
}

// ---------------------------------------------------------------------------
// final per-map normalization
// ---------------------------------------------------------------------------
__global__ __launch_bounds__(256) void norm_k(float* __restrict__ out,
                                              const float* __restrict__ sums)
{
  int il = blockIdx.x;
  int p = blockIdx.y*256 + threadIdx.x;
  if (p < 961) {
    float inv = 1.f / fmaxf(sums[il], 1e-8f);
    out[(size_t)il*961 + p] *= inv;
  }
}

// ---------------------------------------------------------------------------
extern "C" void kernel_launch(void* const* d_in, const int* in_sizes, int n_in,
                              void* d_out, int out_size, void* d_ws, size_t ws_size,
                              hipStream_t stream)
{
  const float* bott = (const float*)d_in[0];
  const float* vis  = (const float*)d_in[1];
  const float* spv  = (const float*)d_in[2];
  const float* ppb  = (const float*)d_in[3];
  const float* ic1w = (const float*)d_in[4];  const float* ic1b = (const float*)d_in[5];
  const float* ic2w = (const float*)d_in[6];  const float* ic2b = (const float*)d_in[7];
  const float* ic3w = (const float*)d_in[8];  const float* ic3b = (const float*)d_in[9];
  const float* dww  = (const float*)d_in[10]; const float* dwb  = (const float*)d_in[11];
  const float* lnw  = (const float*)d_in[12]; const float* lnb  = (const float*)d_in[13];
  const float* pw1w = (const float*)d_in[14]; const float* pw1b = (const float*)d_in[15];
  const float* pw2w = (const float*)d_in[16]; const float* pw2b = (const float*)d_in[17];
  const float* cgam = (const float*)d_in[18];
  const float* bnpw = (const float*)d_in[19]; const float* bnpb = (const float*)d_in[20];
  const float* bemb = (const float*)d_in[21];
  const float* fw   = (const float*)d_in[22]; const float* fb   = (const float*)d_in[23];
  const float* d1w  = (const float*)d_in[24]; const float* d1b  = (const float*)d_in[25];
  const float* d2w  = (const float*)d_in[26]; const float* d2b  = (const float*)d_in[27];
  const float* d3w  = (const float*)d_in[28]; const float* d3b  = (const float*)d_in[29];
  float* out = (float*)d_out;

  char* ws = (char*)d_ws;

  const int CH = (ws_size >= 116400128ull) ? 256 : 128;

  // P2 regions (bf16 now; overlap P1 regions, stream-ordered)
  unsigned short* bwinT = (unsigned short*)(ws);           // 512*121*256*2 = 31,719,424
  unsigned short* dwout = (unsigned short*)(ws + 31719424);// 31,719,424 (end 63,438,848)
  // P1 regions
  unsigned short* vwin = (unsigned short*)(ws);
  size_t o_bufA = (size_t)CH*139392;
  size_t o_bufB = o_bufA + (size_t)CH*123008;
  size_t o_bufI = o_bufB + (size_t)CH*123008;
  size_t p1end  = o_bufI + (size_t)CH*61504;
  unsigned short* bufA = (unsigned short*)(ws + o_bufA);
  unsigned short* bufB = (unsigned short*)(ws + o_bufB);
  unsigned short* bufI = (unsigned short*)(ws + o_bufI);
  size_t tail = (p1end > 63438848ull) ? p1end : 63438848ull;

  float* bnv  = (float*)(ws + tail);                       // 131,072
  float* sums = (float*)(ws + tail + 131072);              // 8,192
  float* film = (float*)(ws + tail + 139264);              // 524,288
  unsigned short* W1p = (unsigned short*)(ws + tail + 663552);
  unsigned short* W2p = (unsigned short*)(ws + tail + 1187840);
  unsigned short* Wbp = (unsigned short*)(ws + tail + 1712128);
  unsigned short* Pc1 = (unsigned short*)(ws + tail + 1744896);
  unsigned short* Pc2 = (unsigned short*)(ws + tail + 1818624);
  unsigned short* Pc3 = (unsigned short*)(ws + tail + 1892352);
  unsigned short* Pd1 = (unsigned short*)(ws + tail + 1929216);
  unsigned short* Pd2 = (unsigned short*)(ws + tail + 1947648);

  // ---- weight packing ----
  packw_k<<<128,256,0,stream>>>(pw1w, W1p, 64, 8, 256);
  packw_k<<<128,256,0,stream>>>(pw2w, W2p, 16, 32, 1024);
  packw_k<<<8,  256,0,stream>>>(bnpw, Wbp, 4, 8, 256);
  pack_convw_k<<<18,256,0,stream>>>(ic1w, Pc1, 4, 18, 64);
  pack_convw_k<<<18,256,0,stream>>>(ic2w, Pc2, 4, 18, 64);
  pack_convw_k<<<9, 256,0,stream>>>(ic3w, Pc3, 2, 18, 64);
  pack_convw_k<<<5, 256,0,stream>>>(d1w,  Pd1, 2, 9, 32);
  pack_convw_k<<<5, 256,0,stream>>>(d2w,  Pd2, 2, 9, 32);

  hipMemsetAsync(ws + tail, 0, 139264, stream);  // bnv + sums

  float gs = 0.f;
  for (int py=0; py<11; ++py) for (int px=0; px<11; ++px) {
    float ly=-1.f+0.2f*py, lx=-1.f+0.2f*px;
    gs += expf(-(lx*lx+ly*ly)/0.32f);
  }
  const float inv_gsum = 1.f/gs;

  // ---- Phase 2: bottleneck path -> bn_vec (single 512-n pass) ----
  dwfused2_k<<<dim3(512,4),256,0,stream>>>(bott, spv, dww, dwb, bwinT, dwout);
  cnx_mfma2_k<<<968,256,0,stream>>>(dwout, lnw,lnb, W1p,pw1b, W2p,pw2b, cgam,
                                    bwinT, Wbp, bnpb, bnv, inv_gsum);
  film_k<<<512,256,0,stream>>>(bnv, ppb, bemb, fw, fb, film);

  // ---- Phase 1+3: intrinsic chain + decoder ----
  for (int n0 = 0; n0 < 512; n0 += CH) {
    extvwin_k<<<dim3(CH,5),256,0,stream>>>(vis, spv + n0*2, vwin);
    convmf_k<64,64,18,1,true ,false><<<dim3(CH,4),256,0,stream>>>(vwin, Pc1, ic1b, bufA, nullptr,0, nullptr,nullptr,nullptr,nullptr);
    convmf_k<64,64,18,0,true ,false><<<dim3(CH,4),256,0,stream>>>(bufA, Pc2, ic2b, bufB, nullptr,0, nullptr,nullptr,nullptr,nullptr);
    convmf_k<64,32,18,0,false,false><<<dim3(CH,4),256,0,stream>>>(bufB, Pc3, ic3b, bufI, nullptr,0, nullptr,nullptr,nullptr,nullptr);
    for (int s = 0; s < CH/64; ++s) {
      int nb0 = n0*4 + s*256;
      convmf_k<32,32,9,2,true,false><<<dim3(256,4),256,0,stream>>>(bufI, Pd1, d1b, bufB,
          film + (size_t)nb0*64, s*256, nullptr,nullptr,nullptr,nullptr);
      convmf_k<32,32,9,0,true,true ><<<dim3(256,4),256,0,stream>>>(bufB, Pd2, d2b, nullptr,
          nullptr,0, out + (size_t)nb0*961, sums + nb0, d3w, d3b);
    }
  }
  norm_k<<<dim3(2048,4),256,0,stream>>>(out, sums);
}

// Round 6
// 965.073 us; speedup vs baseline: 8.2539x; 1.1116x over previous
//
#include <hip/hip_runtime.h>
#include <cstdint>
#include <cstddef>
#include <cmath>

#define DEV __device__ __forceinline__

typedef __attribute__((ext_vector_type(8))) short bf16x8;
typedef __attribute__((ext_vector_type(4))) float f32x4;

DEV float gelu_f(float x){ return 0.5f*x*(1.0f + erff(x*0.7071067811865476f)); }
DEV float softplus_f(float x){ return fmaxf(x,0.f) + log1pf(expf(-fabsf(x))); }
DEV unsigned short f2bf(float x){
  unsigned u = __float_as_uint(x);
  unsigned r = (u + 0x7fffu + ((u>>16)&1u)) >> 16;
  return (unsigned short)r;
}
DEV float bf2f(unsigned short h){
  unsigned u = ((unsigned)h) << 16;
  return __uint_as_float(u);
}

// ---------------------------------------------------------------------------
// Pack f32 [Cout][K] weights into bf16 MFMA fragment order.
// ---------------------------------------------------------------------------
__global__ __launch_bounds__(256) void packw_k(const float* __restrict__ W,
                                               unsigned short* __restrict__ dst,
                                               int ntn, int ntk, int K)
{
  int tid = blockIdx.x*256 + threadIdx.x;
  int total = ntn*ntk*64;
  if (tid >= total) return;
  int lane = tid & 63;
  int f = tid >> 6;
  int kt = f % ntk, nt = f / ntk;
  int row = nt*16 + (lane & 15);
  int k0 = kt*32 + (lane >> 4)*8;
  const float* src = W + (size_t)row*K + k0;
  unsigned short h[8];
#pragma unroll
  for (int j=0;j<8;++j) h[j] = f2bf(src[j]);
  uint4 pk;
  pk.x = (unsigned)h[0] | ((unsigned)h[1]<<16);
  pk.y = (unsigned)h[2] | ((unsigned)h[3]<<16);
  pk.z = (unsigned)h[4] | ((unsigned)h[5]<<16);
  pk.w = (unsigned)h[6] | ((unsigned)h[7]<<16);
  *reinterpret_cast<uint4*>(dst + (size_t)tid*8) = pk;
}

// ---------------------------------------------------------------------------
// Pack conv weights [Cout][Cin][3][3] into fragment order with K = s*Cin+ic
// ---------------------------------------------------------------------------
__global__ __launch_bounds__(256) void pack_convw_k(const float* __restrict__ W,
                                                    unsigned short* __restrict__ dst,
                                                    int ntn, int ntk, int Cin)
{
  int tid = blockIdx.x*256 + threadIdx.x;
  int total = ntn*ntk*64;
  if (tid >= total) return;
  int lane = tid & 63;
  int f = tid >> 6;
  int kt = f % ntk, nt = f / ntk;
  int row = nt*16 + (lane & 15);
  int k0 = kt*32 + (lane >> 4)*8;
  unsigned short h[8];
#pragma unroll
  for (int j=0;j<8;++j) {
    int k = k0 + j;
    int s = k / Cin;
    int ic = k - s*Cin;
    h[j] = f2bf(W[((size_t)row*Cin + ic)*9 + s]);
  }
  uint4 pk;
  pk.x = (unsigned)h[0] | ((unsigned)h[1]<<16);
  pk.y = (unsigned)h[2] | ((unsigned)h[3]<<16);
  pk.z = (unsigned)h[4] | ((unsigned)h[5]<<16);
  pk.w = (unsigned)h[6] | ((unsigned)h[7]<<16);
  *reinterpret_cast<uint4*>(dst + (size_t)tid*8) = pk;
}

// ---------------------------------------------------------------------------
// Extract clamped 33x33 vis windows (incl. conv zero ring) -> bf16 NHWC
// ---------------------------------------------------------------------------
__global__ __launch_bounds__(256) void extvwin_k(const float* __restrict__ vis,
                                                 const float* __restrict__ spv,
                                                 unsigned short* __restrict__ vwin)
{
  int il = blockIdx.x;
  int p = blockIdx.y*256 + threadIdx.x;
  if (p >= 1089) return;
  int wy = p/33, wx = p%33;
  unsigned short* dst = vwin + ((size_t)il*1089 + p)*64;
  if (wy==0 || wy==32 || wx==0 || wx==32) {
    uint4 z = {0,0,0,0};
#pragma unroll
    for (int q=0;q<8;++q) *reinterpret_cast<uint4*>(dst + q*8) = z;
    return;
  }
  int cx = (int)rintf(spv[il*2+0]);
  int cy = (int)rintf(spv[il*2+1]);
  int gy = min(max(cy + wy - 16, 0), 1023);
  int gx = min(max(cx + wx - 16, 0), 1023);
  const float* sp = vis + (size_t)gy*1024 + gx;
  unsigned short h[64];
#pragma unroll
  for (int c=0;c<64;++c) h[c] = f2bf(sp[(size_t)c<<20]);
#pragma unroll
  for (int q=0;q<8;++q) {
    uint4 pk;
    pk.x = (unsigned)h[q*8+0] | ((unsigned)h[q*8+1]<<16);
    pk.y = (unsigned)h[q*8+2] | ((unsigned)h[q*8+3]<<16);
    pk.z = (unsigned)h[q*8+4] | ((unsigned)h[q*8+5]<<16);
    pk.w = (unsigned)h[q*8+6] | ((unsigned)h[q*8+7]<<16);
    *reinterpret_cast<uint4*>(dst + q*8) = pk;
  }
}

// ---------------------------------------------------------------------------
// MFMA implicit-GEMM 3x3 conv, with next-kt weight prefetch.
// MODE 0: src NHWC [item][961][CIN].  MODE 1: 33x33 window buffer.
// MODE 2: src NHWC [sit][961][CIN], FiLM+gelu modulation during staging.
// FDEC: fuse 1x1 dec3 + softplus; write f32 to outf, atomicAdd sums.
// ---------------------------------------------------------------------------
template<int CIN, int COUT, int NKT, int MODE, bool FGELU, bool FDEC>
__global__ __launch_bounds__(256, (CIN==64?3:4)) void convmf_k(
    const unsigned short* __restrict__ src,
    const unsigned short* __restrict__ Wp,
    const float* __restrict__ Bv,
    unsigned short* __restrict__ out,
    const float* __restrict__ film, int nbBase,
    float* __restrict__ outf, float* __restrict__ sums,
    const float* __restrict__ w3, const float* __restrict__ b3)
{
  constexpr int NOCT = COUT/16;
  constexpr int NSLOT = CIN/8;
  constexpr int SWM = NSLOT-1;
  const int item = blockIdx.x;
  const int y0 = blockIdx.y*8;
  const int t = threadIdx.x;
  const int w = t>>6, l = t&63, g = l>>4, l15 = l&15;

  __shared__ __align__(16) unsigned short lds[330*CIN];

  // ---- stage ----
  const int sit = (MODE==2) ? ((nbBase + item) >> 2) : item;
  const float* frow = (MODE==2) ? (film + (size_t)item*64) : nullptr;
  for (int u = t; u < 330*NSLOT; u += 256) {
    int slot = u & SWM;
    int rowi = u / NSLOT;            // r*33+col
    int r = rowi / 33, col = rowi - r*33;
    uint4 val = {0,0,0,0};
    if (MODE==1) {
      int gr = y0 + r;
      if (gr < 33)
        val = *reinterpret_cast<const uint4*>(src + ((size_t)item*1089 + gr*33 + col)*CIN + slot*8);
    } else {
      int y = y0 + r - 1, x = col - 1;
      if ((unsigned)y < 31u && (unsigned)x < 31u) {
        val = *reinterpret_cast<const uint4*>(src + ((size_t)sit*961 + y*31 + x)*CIN + slot*8);
        if (MODE==2) {
          int c0 = slot*8;
          float4 g0 = *reinterpret_cast<const float4*>(frow + c0);
          float4 g1 = *reinterpret_cast<const float4*>(frow + c0 + 4);
          float4 b0 = *reinterpret_cast<const float4*>(frow + 32 + c0);
          float4 b1 = *reinterpret_cast<const float4*>(frow + 32 + c0 + 4);
          unsigned short x8[8] = {
            (unsigned short)(val.x&0xffff),(unsigned short)(val.x>>16),
            (unsigned short)(val.y&0xffff),(unsigned short)(val.y>>16),
            (unsigned short)(val.z&0xffff),(unsigned short)(val.z>>16),
            (unsigned short)(val.w&0xffff),(unsigned short)(val.w>>16)};
          unsigned short o8[8];
          o8[0]=f2bf(gelu_f(fmaf(bf2f(x8[0]), 1.f+g0.x, b0.x)));
          o8[1]=f2bf(gelu_f(fmaf(bf2f(x8[1]), 1.f+g0.y, b0.y)));
          o8[2]=f2bf(gelu_f(fmaf(bf2f(x8[2]), 1.f+g0.z, b0.z)));
          o8[3]=f2bf(gelu_f(fmaf(bf2f(x8[3]), 1.f+g0.w, b0.w)));
          o8[4]=f2bf(gelu_f(fmaf(bf2f(x8[4]), 1.f+g1.x, b1.x)));
          o8[5]=f2bf(gelu_f(fmaf(bf2f(x8[5]), 1.f+g1.y, b1.y)));
          o8[6]=f2bf(gelu_f(fmaf(bf2f(x8[6]), 1.f+g1.z, b1.z)));
          o8[7]=f2bf(gelu_f(fmaf(bf2f(x8[7]), 1.f+g1.w, b1.w)));
          val.x = (unsigned)o8[0] | ((unsigned)o8[1]<<16);
          val.y = (unsigned)o8[2] | ((unsigned)o8[3]<<16);
          val.z = (unsigned)o8[4] | ((unsigned)o8[5]<<16);
          val.w = (unsigned)o8[6] | ((unsigned)o8[7]<<16);
        }
      }
    }
    int ds = slot ^ (rowi & SWM);
    *reinterpret_cast<uint4*>(&lds[rowi*CIN + ds*8]) = val;
  }
  __syncthreads();

  int pbase[4], gpos[4]; bool pvalid[4];
#pragma unroll
  for (int pt=0; pt<4; ++pt) {
    int p = (w*4+pt)*16 + l15;
    int pc = min(p, 247);
    int py = pc/31, px = pc - py*31;
    pbase[pt] = py*33 + px;
    gpos[pt] = y0*31 + p;
    pvalid[pt] = (p < 248) && (gpos[pt] < 961);
  }

  f32x4 acc[NOCT][4];
#pragma unroll
  for (int o=0;o<NOCT;++o)
#pragma unroll
    for (int pt=0;pt<4;++pt) acc[o][pt] = (f32x4){0.f,0.f,0.f,0.f};

  // weight prefetch pipeline
  bf16x8 wcur[NOCT];
#pragma unroll
  for (int o=0;o<NOCT;++o)
    wcur[o] = *reinterpret_cast<const bf16x8*>(Wp + ((size_t)(o*NKT)*64 + l)*8);

  for (int kt=0; kt<NKT; ++kt) {
    bf16x8 wnxt[NOCT];
    if (kt+1 < NKT) {
#pragma unroll
      for (int o=0;o<NOCT;++o)
        wnxt[o] = *reinterpret_cast<const bf16x8*>(Wp + ((size_t)(o*NKT+kt+1)*64 + l)*8);
    }
    int k0 = kt*32 + g*8;
    int s = k0 / CIN;
    int icg = (k0 - s*CIN) >> 3;
    int roff = (s/3)*33 + (s - (s/3)*3);
    bf16x8 bf[4];
#pragma unroll
    for (int pt=0; pt<4; ++pt) {
      int rowi = pbase[pt] + roff;
      int ds = icg ^ (rowi & SWM);
      bf[pt] = *reinterpret_cast<const bf16x8*>(&lds[rowi*CIN + ds*8]);
    }
#pragma unroll
    for (int o=0; o<NOCT; ++o) {
#pragma unroll
      for (int pt=0; pt<4; ++pt)
        acc[o][pt] = __builtin_amdgcn_mfma_f32_16x16x32_bf16(wcur[o], bf[pt], acc[o][pt], 0,0,0);
    }
    if (kt+1 < NKT) {
#pragma unroll
      for (int o=0;o<NOCT;++o) wcur[o] = wnxt[o];
    }
  }

  if (FDEC) {
    float w3r[NOCT*4];
#pragma unroll
    for (int o=0;o<NOCT;++o) {
      float4 wv = *reinterpret_cast<const float4*>(w3 + o*16 + g*4);
      w3r[o*4+0]=wv.x; w3r[o*4+1]=wv.y; w3r[o*4+2]=wv.z; w3r[o*4+3]=wv.w;
    }
    float b3v = b3[0];
    float bsum = 0.f;
#pragma unroll
    for (int pt=0; pt<4; ++pt) {
      float part = 0.f;
#pragma unroll
      for (int o=0; o<NOCT; ++o) {
        float4 bv4 = *reinterpret_cast<const float4*>(Bv + o*16 + g*4);
        float v0 = acc[o][pt][0] + bv4.x;
        float v1 = acc[o][pt][1] + bv4.y;
        float v2 = acc[o][pt][2] + bv4.z;
        float v3 = acc[o][pt][3] + bv4.w;
        if (FGELU) { v0=gelu_f(v0); v1=gelu_f(v1); v2=gelu_f(v2); v3=gelu_f(v3); }
        part += v0*w3r[o*4+0] + v1*w3r[o*4+1] + v2*w3r[o*4+2] + v3*w3r[o*4+3];
      }
      part += __shfl_xor(part, 16);
      part += __shfl_xor(part, 32);
      float sp = softplus_f(part + b3v);
      if (pvalid[pt] && g==0) {
        outf[(size_t)item*961 + gpos[pt]] = sp;
        bsum += sp;
      }
    }
    __syncthreads();
    float* redf = reinterpret_cast<float*>(lds);
    redf[t] = bsum;
    __syncthreads();
    for (int off=128; off>0; off>>=1) {
      if (t < off) redf[t] += redf[t+off];
      __syncthreads();
    }
    if (t==0) atomicAdd(&sums[item], redf[0]);
    return;
  }

#pragma unroll
  for (int o=0; o<NOCT; ++o) {
    float4 bv4 = *reinterpret_cast<const float4*>(Bv + o*16 + g*4);
#pragma unroll
    for (int pt=0; pt<4; ++pt) {
      if (!pvalid[pt]) continue;
      float v0 = acc[o][pt][0] + bv4.x;
      float v1 = acc[o][pt][1] + bv4.y;
      float v2 = acc[o][pt][2] + bv4.z;
      float v3 = acc[o][pt][3] + bv4.w;
      if (FGELU) { v0=gelu_f(v0); v1=gelu_f(v1); v2=gelu_f(v2); v3=gelu_f(v3); }
      uint2 pk;
      pk.x = (unsigned)f2bf(v0) | ((unsigned)f2bf(v1)<<16);
      pk.y = (unsigned)f2bf(v2) | ((unsigned)f2bf(v3)<<16);
      *reinterpret_cast<uint2*>(out + ((size_t)item*961 + gpos[pt])*COUT + o*16 + g*4) = pk;
    }
  }
}

// ---------------------------------------------------------------------------
// Fused bottleneck-window gather + depthwise 7x7, channel-sliced.
// ---------------------------------------------------------------------------
__global__ __launch_bounds__(256,4) void dwfused2_k(
    const float* __restrict__ bott, const float* __restrict__ spv,
    const float* __restrict__ w, const float* __restrict__ b,
    unsigned short* __restrict__ bwinT, unsigned short* __restrict__ dwout)
{
  const int n = blockIdx.x, cs = blockIdx.y*64, t = threadIdx.x;
  __shared__ float tile[121*66];

  float pxf = fminf(fmaxf(spv[n*2+0]*0.25f, 0.f), 255.f);
  float pyf = fminf(fmaxf(spv[n*2+1]*0.25f, 0.f), 255.f);
  int cx = (int)rintf(pxf), cy = (int)rintf(pyf);

  for (int idx=t; idx<121*32; idx+=256) {
    int j = idx/121, p = idx - j*121;
    int y = p/11, x = p - y*11;
    int gy = min(max(cy + y - 5, 0), 255);
    int gx = min(max(cx + x - 5, 0), 255);
    const float* s0 = bott + ((size_t)(cs+2*j)<<16) + (gy<<8) + gx;
    *reinterpret_cast<float2*>(&tile[p*66 + 2*j]) = (float2){s0[0], s0[65536]};
  }
  __syncthreads();

  for (int idx=t; idx<121*64; idx+=256) {
    int p = idx >> 6, c = idx & 63;
    bwinT[((size_t)n*121 + p)*256 + cs + c] = f2bf(tile[p*66 + c]);
  }

  const int c = t & 63, ph = t >> 6;
  const int ch = cs + c;
  float wr[49];
#pragma unroll
  for (int k=0;k<49;++k) wr[k] = w[(size_t)ch*49 + k];
  const float bias = b[ch];

  for (int p=ph; p<121; p+=4) {
    int y = p/11, x = p - y*11;
    float a = bias;
    int dyl = max(0,3-y), dyh = min(6,13-y);
    int dxl = max(0,3-x), dxh = min(6,13-x);
#pragma unroll
    for (int dy=0; dy<7; ++dy) {
      if (dy < dyl || dy > dyh) continue;
      int yy = y + dy - 3;
#pragma unroll
      for (int dx=0; dx<7; ++dx) {
        if (dx < dxl || dx > dxh) continue;
        int xx = x + dx - 3;
        a = fmaf(tile[(yy*11+xx)*66 + c], wr[dy*7+dx], a);
      }
    }
    dwout[((size_t)n*121 + p)*256 + ch] = f2bf(a);
  }
}

// ---------------------------------------------------------------------------
// Fused ConvNeXt MLP + bnp head, bf16 MFMA. 512 threads / 8 waves, 64 rows.
// ---------------------------------------------------------------------------
__global__ __launch_bounds__(512,4) void cnx_mfma3_k(
    const unsigned short* __restrict__ xin,
    const float* __restrict__ lnw, const float* __restrict__ lnb,
    const unsigned short* __restrict__ W1p, const float* __restrict__ B1,
    const unsigned short* __restrict__ W2p, const float* __restrict__ B2,
    const float* __restrict__ gvec,
    const unsigned short* __restrict__ bwinT,
    const unsigned short* __restrict__ Wbp, const float* __restrict__ bnpb,
    float* __restrict__ bnv, float inv_gsum)
{
  const int t = threadIdx.x;
  const int w = t >> 6;          // 0..7
  const int l = t & 63;
  const int g = l >> 4;
  const int l15 = l & 15;
  const int row0 = blockIdx.x * 64;

  __shared__ __align__(16) unsigned short xs[64*264];
  __shared__ __align__(16) unsigned short hs[64*136];

  // ---- LN -> xs (8 threads per row, 32 ch each) ----
  {
    const int rl = t >> 3, q = t & 7;
    const unsigned short* xr = xin + (size_t)(row0+rl)*256 + q*32;
    float xv[32]; float s = 0.f, s2 = 0.f;
#pragma unroll
    for (int i=0;i<32;i+=8){
      uint4 v = *reinterpret_cast<const uint4*>(xr+i);
      unsigned short xh[8] = {
        (unsigned short)(v.x&0xffff),(unsigned short)(v.x>>16),
        (unsigned short)(v.y&0xffff),(unsigned short)(v.y>>16),
        (unsigned short)(v.z&0xffff),(unsigned short)(v.z>>16),
        (unsigned short)(v.w&0xffff),(unsigned short)(v.w>>16)};
#pragma unroll
      for (int j=0;j<8;++j){
        float f = bf2f(xh[j]);
        xv[i+j] = f; s += f; s2 += f*f;
      }
    }
    s += __shfl_xor(s,1); s2 += __shfl_xor(s2,1);
    s += __shfl_xor(s,2); s2 += __shfl_xor(s2,2);
    s += __shfl_xor(s,4); s2 += __shfl_xor(s2,4);
    float mu = s*(1.f/256.f);
    float rstd = rsqrtf(s2*(1.f/256.f) - mu*mu + 1e-6f);
#pragma unroll
    for (int i=0;i<32;i+=8){
      int c = q*32 + i;
      float4 w0 = *reinterpret_cast<const float4*>(lnw+c);
      float4 w1 = *reinterpret_cast<const float4*>(lnw+c+4);
      float4 b0 = *reinterpret_cast<const float4*>(lnb+c);
      float4 b1 = *reinterpret_cast<const float4*>(lnb+c+4);
      unsigned short h[8];
      h[0]=f2bf(fmaf((xv[i+0]-mu)*rstd, w0.x, b0.x));
      h[1]=f2bf(fmaf((xv[i+1]-mu)*rstd, w0.y, b0.y));
      h[2]=f2bf(fmaf((xv[i+2]-mu)*rstd, w0.z, b0.z));
      h[3]=f2bf(fmaf((xv[i+3]-mu)*rstd, w0.w, b0.w));
      h[4]=f2bf(fmaf((xv[i+4]-mu)*rstd, w1.x, b1.x));
      h[5]=f2bf(fmaf((xv[i+5]-mu)*rstd, w1.y, b1.y));
      h[6]=f2bf(fmaf((xv[i+6]-mu)*rstd, w1.z, b1.z));
      h[7]=f2bf(fmaf((xv[i+7]-mu)*rstd, w1.w, b1.w));
      uint4 pk;
      pk.x = (unsigned)h[0] | ((unsigned)h[1]<<16);
      pk.y = (unsigned)h[2] | ((unsigned)h[3]<<16);
      pk.z = (unsigned)h[4] | ((unsigned)h[5]<<16);
      pk.w = (unsigned)h[6] | ((unsigned)h[7]<<16);
      *reinterpret_cast<uint4*>(&xs[rl*264 + c]) = pk;
    }
  }
  __syncthreads();

  f32x4 acc2[8];                 // 2 c-tiles x 4 row-tiles
#pragma unroll
  for (int i=0;i<8;++i) acc2[i] = (f32x4){0.f,0.f,0.f,0.f};

  for (int hc=0; hc<8; ++hc) {
    // --- GEMM1: wave w owns h-tile ht = hc*8+w ---
    const int ht = hc*8 + w;
    f32x4 acc1[4];
#pragma unroll
    for (int i=0;i<4;++i) acc1[i] = (f32x4){0.f,0.f,0.f,0.f};

#pragma unroll
    for (int kt=0; kt<8; ++kt) {
      bf16x8 xf[4];
#pragma unroll
      for (int rt=0; rt<4; ++rt)
        xf[rt] = *reinterpret_cast<const bf16x8*>(&xs[(rt*16+l15)*264 + kt*32 + g*8]);
      bf16x8 wf = *reinterpret_cast<const bf16x8*>(W1p + ((size_t)(ht*8+kt)*64 + l)*8);
#pragma unroll
      for (int rt=0; rt<4; ++rt)
        acc1[rt] = __builtin_amdgcn_mfma_f32_16x16x32_bf16(wf, xf[rt], acc1[rt], 0,0,0);
    }
    // bias + gelu + pack -> hs
    {
      const int hb = hc*128 + w*16 + 4*g;
      float4 b1v = *reinterpret_cast<const float4*>(B1 + hb);
#pragma unroll
      for (int rt=0; rt<4; ++rt) {
        unsigned short h0 = f2bf(gelu_f(acc1[rt][0] + b1v.x));
        unsigned short h1 = f2bf(gelu_f(acc1[rt][1] + b1v.y));
        unsigned short h2 = f2bf(gelu_f(acc1[rt][2] + b1v.z));
        unsigned short h3 = f2bf(gelu_f(acc1[rt][3] + b1v.w));
        uint2 pk;
        pk.x = (unsigned)h0 | ((unsigned)h1<<16);
        pk.y = (unsigned)h2 | ((unsigned)h3<<16);
        *reinterpret_cast<uint2*>(&hs[(rt*16+l15)*136 + w*16 + 4*g]) = pk;
      }
    }
    __syncthreads();
    // --- GEMM2: wave w owns c-tiles 2w, 2w+1 ---
#pragma unroll
    for (int kt=0; kt<4; ++kt) {
      bf16x8 hf[4];
#pragma unroll
      for (int rt=0; rt<4; ++rt)
        hf[rt] = *reinterpret_cast<const bf16x8*>(&hs[(rt*16+l15)*136 + kt*32 + g*8]);
#pragma unroll
      for (int cj=0; cj<2; ++cj) {
        const int ct = 2*w + cj;
        bf16x8 wf = *reinterpret_cast<const bf16x8*>(W2p + ((size_t)(ct*32 + hc*4 + kt)*64 + l)*8);
#pragma unroll
        for (int rt=0; rt<4; ++rt)
          acc2[cj*4+rt] = __builtin_amdgcn_mfma_f32_16x16x32_bf16(hf[rt], wf, acc2[cj*4+rt], 0,0,0);
      }
    }
    __syncthreads();
  }

  // ---- residual in regs -> xs as bf16 ----
#pragma unroll
  for (int cj=0; cj<2; ++cj) {
    const int c = (2*w+cj)*16 + l15;
    const float b2 = B2[c], gm = gvec[c];
#pragma unroll
    for (int rt=0; rt<4; ++rt) {
#pragma unroll
      for (int reg=0; reg<4; ++reg) {
        int row = rt*16 + 4*g + reg;
        float res = bf2f(bwinT[(size_t)(row0+row)*256 + c]) + (acc2[cj*4+rt][reg] + b2)*gm;
        xs[row*264 + c] = f2bf(res);
      }
    }
  }
  __syncthreads();

  // ---- bnp GEMM: wave w -> oct = w&3, row-tiles {w>>2, 2+(w>>2)} ----
  {
    const int oct = w & 3;
    f32x4 abn[2];
#pragma unroll
    for (int i=0;i<2;++i) abn[i] = (f32x4){0.f,0.f,0.f,0.f};
#pragma unroll
    for (int kt=0; kt<8; ++kt) {
      bf16x8 bfw = *reinterpret_cast<const bf16x8*>(Wbp + ((size_t)(oct*8+kt)*64 + l)*8);
#pragma unroll
      for (int i=0;i<2;++i) {
        const int rt = (w>>2) + 2*i;
        bf16x8 af = *reinterpret_cast<const bf16x8*>(&xs[(rt*16+l15)*264 + kt*32 + g*8]);
        abn[i] = __builtin_amdgcn_mfma_f32_16x16x32_bf16(af, bfw, abn[i], 0,0,0);
      }
    }

    float* red = reinterpret_cast<float*>(hs);
#pragma unroll
    for (int i=0;i<2;++i) {
      const int rt = (w>>2) + 2*i;
      float bv = bnpb[oct*16 + l15];
#pragma unroll
      for (int reg=0; reg<4; ++reg) {
        int lr = rt*16 + g*4 + reg;
        int p = (row0 + lr) % 121;
        int py=p/11, px=p-py*11;
        float ly=-1.f+0.2f*py, lx=-1.f+0.2f*px;
        float wg = expf(-(lx*lx+ly*ly)/0.32f) * inv_gsum;
        red[lr*64 + oct*16 + l15] = gelu_f(abn[i][reg] + bv) * wg;
      }
    }
  }
  __syncthreads();
  {
    float* red = reinterpret_cast<float*>(hs);
    int oc = t & 63, seg = t >> 6;
    float s = 0.f;
    int curn = (row0 + seg*8) / 121;
    for (int i=0;i<8;++i) {
      int row = seg*8 + i;
      int n = (row0 + row) / 121;
      if (n != curn) { atomicAdd(&bnv[curn*64 + oc], s); s = 0.f; curn = n; }
      s += red[row*64 + oc];
    }
    atomicAdd(&bnv[curn*64 + oc], s);
  }
}

// ---------------------------------------------------------------------------
// FiLM
// ---------------------------------------------------------------------------
__global__ __launch_bounds__(256) void film_k(
    const float* __restrict__ bn_vec, const float* __restrict__ ppb,
    const float* __restrict__ bemb, const float* __restrict__ fw,
    const float* __restrict__ fb, float* __restrict__ film)
{
  int n = blockIdx.x, t = threadIdx.x;
  __shared__ float cond[4][84];
  for (int i=t; i<4*84; i+=256) {
    int b = i/84, j = i%84;
    float v;
    if (j < 16) v = bemb[b*16 + j];
    else if (j == 16) { float p = ppb[((size_t)n*4+b)*2+0]; v = fminf(fmaxf(p*(1.f/1023.f),0.f),1.f); }
    else if (j == 17) { float p = ppb[((size_t)n*4+b)*2+1]; v = fminf(fmaxf(p*(1.f/1023.f),0.f),1.f); }
    else if (j == 18) { float p = ppb[((size_t)n*4+b)*2+0]; v = p - rintf(p); }
    else if (j == 19) { float p = ppb[((size_t)n*4+b)*2+1]; v = p - rintf(p); }
    else v = bn_vec[n*64 + (j-20)];
    cond[b][j] = v;
  }
  __syncthreads();
  int b = t >> 6, oc = t & 63;
  float s = fb[oc];
  for (int j=0;j<84;++j) s = fmaf(cond[b][j], fw[oc*84+j], s);
  film[((size_t)n*4+b)*64 + oc] = s;
}

// ---------------------------------------------------------------------------
// final per-map normalization
// ---------------------------------------------------------------------------
__global__ __launch_bounds__(256) void norm_k(float* __restrict__ out,
                                              const float* __restrict__ sums)
{
  int il = blockIdx.x;
  int p = blockIdx.y*256 + threadIdx.x;
  if (p < 961) {
    float inv = 1.f / fmaxf(sums[il], 1e-8f);
    out[(size_t)il*961 + p] *= inv;
  }
}

// ---------------------------------------------------------------------------
extern "C" void kernel_launch(void* const* d_in, const int* in_sizes, int n_in,
                              void* d_out, int out_size, void* d_ws, size_t ws_size,
                              hipStream_t stream)
{
  const float* bott = (const float*)d_in[0];
  const float* vis  = (const float*)d_in[1];
  const float* spv  = (const float*)d_in[2];
  const float* ppb  = (const float*)d_in[3];
  const float* ic1w = (const float*)d_in[4];  const float* ic1b = (const float*)d_in[5];
  const float* ic2w = (const float*)d_in[6];  const float* ic2b = (const float*)d_in[7];
  const float* ic3w = (const float*)d_in[8];  const float* ic3b = (const float*)d_in[9];
  const float* dww  = (const float*)d_in[10]; const float* dwb  = (const float*)d_in[11];
  const float* lnw  = (const float*)d_in[12]; const float* lnb  = (const float*)d_in[13];
  const float* pw1w = (const float*)d_in[14]; const float* pw1b = (const float*)d_in[15];
  const float* pw2w = (const float*)d_in[16]; const float* pw2b = (const float*)d_in[17];
  const float* cgam = (const float*)d_in[18];
  const float* bnpw = (const float*)d_in[19]; const float* bnpb = (const float*)d_in[20];
  const float* bemb = (const float*)d_in[21];
  const float* fw   = (const float*)d_in[22]; const float* fb   = (const float*)d_in[23];
  const float* d1w  = (const float*)d_in[24]; const float* d1b  = (const float*)d_in[25];
  const float* d2w  = (const float*)d_in[26]; const float* d2b  = (const float*)d_in[27];
  const float* d3w  = (const float*)d_in[28]; const float* d3b  = (const float*)d_in[29];
  float* out = (float*)d_out;

  char* ws = (char*)d_ws;

  const int CH = (ws_size >= 116400128ull) ? 256 : 128;

  // P2 regions (bf16; overlap P1 regions, stream-ordered)
  unsigned short* bwinT = (unsigned short*)(ws);
  unsigned short* dwout = (unsigned short*)(ws + 31719424);
  // P1 regions
  unsigned short* vwin = (unsigned short*)(ws);
  size_t o_bufA = (size_t)CH*139392;
  size_t o_bufB = o_bufA + (size_t)CH*123008;
  size_t o_bufI = o_bufB + (size_t)CH*123008;
  size_t p1end  = o_bufI + (size_t)CH*61504;
  unsigned short* bufA = (unsigned short*)(ws + o_bufA);
  unsigned short* bufB = (unsigned short*)(ws + o_bufB);
  unsigned short* bufI = (unsigned short*)(ws + o_bufI);
  size_t tail = (p1end > 63438848ull) ? p1end : 63438848ull;

  float* bnv  = (float*)(ws + tail);
  float* sums = (float*)(ws + tail + 131072);
  float* film = (float*)(ws + tail + 139264);
  unsigned short* W1p = (unsigned short*)(ws + tail + 663552);
  unsigned short* W2p = (unsigned short*)(ws + tail + 1187840);
  unsigned short* Wbp = (unsigned short*)(ws + tail + 1712128);
  unsigned short* Pc1 = (unsigned short*)(ws + tail + 1744896);
  unsigned short* Pc2 = (unsigned short*)(ws + tail + 1818624);
  unsigned short* Pc3 = (unsigned short*)(ws + tail + 1892352);
  unsigned short* Pd1 = (unsigned short*)(ws + tail + 1929216);
  unsigned short* Pd2 = (unsigned short*)(ws + tail + 1947648);

  // ---- weight packing ----
  packw_k<<<128,256,0,stream>>>(pw1w, W1p, 64, 8, 256);
  packw_k<<<128,256,0,stream>>>(pw2w, W2p, 16, 32, 1024);
  packw_k<<<8,  256,0,stream>>>(bnpw, Wbp, 4, 8, 256);
  pack_convw_k<<<18,256,0,stream>>>(ic1w, Pc1, 4, 18, 64);
  pack_convw_k<<<18,256,0,stream>>>(ic2w, Pc2, 4, 18, 64);
  pack_convw_k<<<9, 256,0,stream>>>(ic3w, Pc3, 2, 18, 64);
  pack_convw_k<<<5, 256,0,stream>>>(d1w,  Pd1, 2, 9, 32);
  pack_convw_k<<<5, 256,0,stream>>>(d2w,  Pd2, 2, 9, 32);

  hipMemsetAsync(ws + tail, 0, 139264, stream);  // bnv + sums

  float gs = 0.f;
  for (int py=0; py<11; ++py) for (int px=0; px<11; ++px) {
    float ly=-1.f+0.2f*py, lx=-1.f+0.2f*px;
    gs += expf(-(lx*lx+ly*ly)/0.32f);
  }
  const float inv_gsum = 1.f/gs;

  // ---- Phase 2: bottleneck path -> bn_vec ----
  dwfused2_k<<<dim3(512,4),256,0,stream>>>(bott, spv, dww, dwb, bwinT, dwout);
  cnx_mfma3_k<<<968,512,0,stream>>>(dwout, lnw,lnb, W1p,pw1b, W2p,pw2b, cgam,
                                    bwinT, Wbp, bnpb, bnv, inv_gsum);
  film_k<<<512,256,0,stream>>>(bnv, ppb, bemb, fw, fb, film);

  // ---- Phase 1+3: intrinsic chain + decoder ----
  for (int n0 = 0; n0 < 512; n0 += CH) {
    extvwin_k<<<dim3(CH,5),256,0,stream>>>(vis, spv + n0*2, vwin);
    convmf_k<64,64,18,1,true ,false><<<dim3(CH,4),256,0,stream>>>(vwin, Pc1, ic1b, bufA, nullptr,0, nullptr,nullptr,nullptr,nullptr);
    convmf_k<64,64,18,0,true ,false><<<dim3(CH,4),256,0,stream>>>(bufA, Pc2, ic2b, bufB, nullptr,0, nullptr,nullptr,nullptr,nullptr);
    convmf_k<64,32,18,0,false,false><<<dim3(CH,4),256,0,stream>>>(bufB, Pc3, ic3b, bufI, nullptr,0, nullptr,nullptr,nullptr,nullptr);
    for (int s = 0; s < CH/64; ++s) {
      int nb0 = n0*4 + s*256;
      convmf_k<32,32,9,2,true,false><<<dim3(256,4),256,0,stream>>>(bufI, Pd1, d1b, bufB,
          film + (size_t)nb0*64, s*256, nullptr,nullptr,nullptr,nullptr);
      convmf_k<32,32,9,0,true,true ><<<dim3(256,4),256,0,stream>>>(bufB, Pd2, d2b, nullptr,
          nullptr,0, out + (size_t)nb0*961, sums + nb0, d3w, d3b);
    }
  }
  norm_k<<<dim3(2048,4),256,0,stream>>>(out, sums);
}

// Round 7
// 954.069 us; speedup vs baseline: 8.3491x; 1.0115x over previous
//
#include <hip/hip_runtime.h>
#include <cstdint>
#include <cstddef>
#include <cmath>

#define DEV __device__ __forceinline__

typedef __attribute__((ext_vector_type(8))) short bf16x8;
typedef __attribute__((ext_vector_type(4))) float f32x4;

DEV float gelu_f(float x){ return 0.5f*x*(1.0f + erff(x*0.7071067811865476f)); }
DEV float softplus_f(float x){ return fmaxf(x,0.f) + log1pf(expf(-fabsf(x))); }
DEV unsigned short f2bf(float x){
  unsigned u = __float_as_uint(x);
  unsigned r = (u + 0x7fffu + ((u>>16)&1u)) >> 16;
  return (unsigned short)r;
}
DEV float bf2f(unsigned short h){
  unsigned u = ((unsigned)h) << 16;
  return __uint_as_float(u);
}

// ---------------------------------------------------------------------------
// Combined weight packing: 8 jobs in one launch.
// Non-conv: dst[(f*64+l)*8+j] = W[nt*16+(l&15)][kt*32+(l>>4)*8+j]  (K = row len)
// Conv:     K field = Cin; k index maps to (s,ic), src[(row*Cin+ic)*9+s]
// ---------------------------------------------------------------------------
struct PackJobs {
  const float* src[8];
  unsigned short* dst[8];
  int ntn[8], ntk[8], K[8], conv[8], base[8];
};

__global__ __launch_bounds__(256) void packall_k(PackJobs J)
{
  int blk = blockIdx.x;
  int j = 0;
#pragma unroll
  for (int i=1;i<8;++i) if (blk >= J.base[i]) j = i;
  int tid = (blk - J.base[j])*256 + threadIdx.x;
  const int ntk = J.ntk[j], K = J.K[j];
  int total = J.ntn[j]*ntk*64;
  if (tid >= total) return;
  int lane = tid & 63;
  int f = tid >> 6;
  int kt = f % ntk, nt = f / ntk;
  int row = nt*16 + (lane & 15);
  int k0 = kt*32 + (lane >> 4)*8;
  const float* src = J.src[j];
  unsigned short h[8];
  if (J.conv[j]) {
    const int Cin = K;
#pragma unroll
    for (int q=0;q<8;++q) {
      int k = k0 + q;
      int s = k / Cin;
      int ic = k - s*Cin;
      h[q] = f2bf(src[((size_t)row*Cin + ic)*9 + s]);
    }
  } else {
#pragma unroll
    for (int q=0;q<8;++q) h[q] = f2bf(src[(size_t)row*K + k0 + q]);
  }
  uint4 pk;
  pk.x = (unsigned)h[0] | ((unsigned)h[1]<<16);
  pk.y = (unsigned)h[2] | ((unsigned)h[3]<<16);
  pk.z = (unsigned)h[4] | ((unsigned)h[5]<<16);
  pk.w = (unsigned)h[6] | ((unsigned)h[7]<<16);
  *reinterpret_cast<uint4*>(J.dst[j] + (size_t)tid*8) = pk;
}

// ---------------------------------------------------------------------------
// Extract clamped 33x33 vis windows (incl. conv zero ring) -> bf16 NHWC
// ---------------------------------------------------------------------------
__global__ __launch_bounds__(256) void extvwin_k(const float* __restrict__ vis,
                                                 const float* __restrict__ spv,
                                                 unsigned short* __restrict__ vwin)
{
  int il = blockIdx.x;
  int p = blockIdx.y*256 + threadIdx.x;
  if (p >= 1089) return;
  int wy = p/33, wx = p%33;
  unsigned short* dst = vwin + ((size_t)il*1089 + p)*64;
  if (wy==0 || wy==32 || wx==0 || wx==32) {
    uint4 z = {0,0,0,0};
#pragma unroll
    for (int q=0;q<8;++q) *reinterpret_cast<uint4*>(dst + q*8) = z;
    return;
  }
  int cx = (int)rintf(spv[il*2+0]);
  int cy = (int)rintf(spv[il*2+1]);
  int gy = min(max(cy + wy - 16, 0), 1023);
  int gx = min(max(cx + wx - 16, 0), 1023);
  const float* sp = vis + (size_t)gy*1024 + gx;
  unsigned short h[64];
#pragma unroll
  for (int c=0;c<64;++c) h[c] = f2bf(sp[(size_t)c<<20]);
#pragma unroll
  for (int q=0;q<8;++q) {
    uint4 pk;
    pk.x = (unsigned)h[q*8+0] | ((unsigned)h[q*8+1]<<16);
    pk.y = (unsigned)h[q*8+2] | ((unsigned)h[q*8+3]<<16);
    pk.z = (unsigned)h[q*8+4] | ((unsigned)h[q*8+5]<<16);
    pk.w = (unsigned)h[q*8+6] | ((unsigned)h[q*8+7]<<16);
    *reinterpret_cast<uint4*>(dst + q*8) = pk;
  }
}

// ---------------------------------------------------------------------------
// MFMA implicit-GEMM 3x3 conv, with next-kt weight prefetch.
// MODE 0: src NHWC [item][961][CIN].  MODE 1: 33x33 window buffer.
// MODE 2: src NHWC [sit][961][CIN], FiLM+gelu modulation during staging.
// FDEC: fuse 1x1 dec3 + softplus; write f32 to outf, atomicAdd sums.
// ---------------------------------------------------------------------------
template<int CIN, int COUT, int NKT, int MODE, bool FGELU, bool FDEC>
__global__ __launch_bounds__(256, (CIN==64?3:4)) void convmf_k(
    const unsigned short* __restrict__ src,
    const unsigned short* __restrict__ Wp,
    const float* __restrict__ Bv,
    unsigned short* __restrict__ out,
    const float* __restrict__ film, int nbBase,
    float* __restrict__ outf, float* __restrict__ sums,
    const float* __restrict__ w3, const float* __restrict__ b3)
{
  constexpr int NOCT = COUT/16;
  constexpr int NSLOT = CIN/8;
  constexpr int SWM = NSLOT-1;
  const int item = blockIdx.x;
  const int y0 = blockIdx.y*8;
  const int t = threadIdx.x;
  const int w = t>>6, l = t&63, g = l>>4, l15 = l&15;

  __shared__ __align__(16) unsigned short lds[330*CIN];

  // ---- stage ----
  const int sit = (MODE==2) ? ((nbBase + item) >> 2) : item;
  const float* frow = (MODE==2) ? (film + (size_t)item*64) : nullptr;
  for (int u = t; u < 330*NSLOT; u += 256) {
    int slot = u & SWM;
    int rowi = u / NSLOT;            // r*33+col
    int r = rowi / 33, col = rowi - r*33;
    uint4 val = {0,0,0,0};
    if (MODE==1) {
      int gr = y0 + r;
      if (gr < 33)
        val = *reinterpret_cast<const uint4*>(src + ((size_t)item*1089 + gr*33 + col)*CIN + slot*8);
    } else {
      int y = y0 + r - 1, x = col - 1;
      if ((unsigned)y < 31u && (unsigned)x < 31u) {
        val = *reinterpret_cast<const uint4*>(src + ((size_t)sit*961 + y*31 + x)*CIN + slot*8);
        if (MODE==2) {
          int c0 = slot*8;
          float4 g0 = *reinterpret_cast<const float4*>(frow + c0);
          float4 g1 = *reinterpret_cast<const float4*>(frow + c0 + 4);
          float4 b0 = *reinterpret_cast<const float4*>(frow + 32 + c0);
          float4 b1 = *reinterpret_cast<const float4*>(frow + 32 + c0 + 4);
          unsigned short x8[8] = {
            (unsigned short)(val.x&0xffff),(unsigned short)(val.x>>16),
            (unsigned short)(val.y&0xffff),(unsigned short)(val.y>>16),
            (unsigned short)(val.z&0xffff),(unsigned short)(val.z>>16),
            (unsigned short)(val.w&0xffff),(unsigned short)(val.w>>16)};
          unsigned short o8[8];
          o8[0]=f2bf(gelu_f(fmaf(bf2f(x8[0]), 1.f+g0.x, b0.x)));
          o8[1]=f2bf(gelu_f(fmaf(bf2f(x8[1]), 1.f+g0.y, b0.y)));
          o8[2]=f2bf(gelu_f(fmaf(bf2f(x8[2]), 1.f+g0.z, b0.z)));
          o8[3]=f2bf(gelu_f(fmaf(bf2f(x8[3]), 1.f+g0.w, b0.w)));
          o8[4]=f2bf(gelu_f(fmaf(bf2f(x8[4]), 1.f+g1.x, b1.x)));
          o8[5]=f2bf(gelu_f(fmaf(bf2f(x8[5]), 1.f+g1.y, b1.y)));
          o8[6]=f2bf(gelu_f(fmaf(bf2f(x8[6]), 1.f+g1.z, b1.z)));
          o8[7]=f2bf(gelu_f(fmaf(bf2f(x8[7]), 1.f+g1.w, b1.w)));
          val.x = (unsigned)o8[0] | ((unsigned)o8[1]<<16);
          val.y = (unsigned)o8[2] | ((unsigned)o8[3]<<16);
          val.z = (unsigned)o8[4] | ((unsigned)o8[5]<<16);
          val.w = (unsigned)o8[6] | ((unsigned)o8[7]<<16);
        }
      }
    }
    int ds = slot ^ (rowi & SWM);
    *reinterpret_cast<uint4*>(&lds[rowi*CIN + ds*8]) = val;
  }
  __syncthreads();

  int pbase[4], gpos[4]; bool pvalid[4];
#pragma unroll
  for (int pt=0; pt<4; ++pt) {
    int p = (w*4+pt)*16 + l15;
    int pc = min(p, 247);
    int py = pc/31, px = pc - py*31;
    pbase[pt] = py*33 + px;
    gpos[pt] = y0*31 + p;
    pvalid[pt] = (p < 248) && (gpos[pt] < 961);
  }

  f32x4 acc[NOCT][4];
#pragma unroll
  for (int o=0;o<NOCT;++o)
#pragma unroll
    for (int pt=0;pt<4;++pt) acc[o][pt] = (f32x4){0.f,0.f,0.f,0.f};

  // weight prefetch pipeline
  bf16x8 wcur[NOCT];
#pragma unroll
  for (int o=0;o<NOCT;++o)
    wcur[o] = *reinterpret_cast<const bf16x8*>(Wp + ((size_t)(o*NKT)*64 + l)*8);

  for (int kt=0; kt<NKT; ++kt) {
    bf16x8 wnxt[NOCT];
    if (kt+1 < NKT) {
#pragma unroll
      for (int o=0;o<NOCT;++o)
        wnxt[o] = *reinterpret_cast<const bf16x8*>(Wp + ((size_t)(o*NKT+kt+1)*64 + l)*8);
    }
    int k0 = kt*32 + g*8;
    int s = k0 / CIN;
    int icg = (k0 - s*CIN) >> 3;
    int roff = (s/3)*33 + (s - (s/3)*3);
    bf16x8 bf[4];
#pragma unroll
    for (int pt=0; pt<4; ++pt) {
      int rowi = pbase[pt] + roff;
      int ds = icg ^ (rowi & SWM);
      bf[pt] = *reinterpret_cast<const bf16x8*>(&lds[rowi*CIN + ds*8]);
    }
#pragma unroll
    for (int o=0; o<NOCT; ++o) {
#pragma unroll
      for (int pt=0; pt<4; ++pt)
        acc[o][pt] = __builtin_amdgcn_mfma_f32_16x16x32_bf16(wcur[o], bf[pt], acc[o][pt], 0,0,0);
    }
    if (kt+1 < NKT) {
#pragma unroll
      for (int o=0;o<NOCT;++o) wcur[o] = wnxt[o];
    }
  }

  if (FDEC) {
    float w3r[NOCT*4];
#pragma unroll
    for (int o=0;o<NOCT;++o) {
      float4 wv = *reinterpret_cast<const float4*>(w3 + o*16 + g*4);
      w3r[o*4+0]=wv.x; w3r[o*4+1]=wv.y; w3r[o*4+2]=wv.z; w3r[o*4+3]=wv.w;
    }
    float b3v = b3[0];
    float bsum = 0.f;
#pragma unroll
    for (int pt=0; pt<4; ++pt) {
      float part = 0.f;
#pragma unroll
      for (int o=0; o<NOCT; ++o) {
        float4 bv4 = *reinterpret_cast<const float4*>(Bv + o*16 + g*4);
        float v0 = acc[o][pt][0] + bv4.x;
        float v1 = acc[o][pt][1] + bv4.y;
        float v2 = acc[o][pt][2] + bv4.z;
        float v3 = acc[o][pt][3] + bv4.w;
        if (FGELU) { v0=gelu_f(v0); v1=gelu_f(v1); v2=gelu_f(v2); v3=gelu_f(v3); }
        part += v0*w3r[o*4+0] + v1*w3r[o*4+1] + v2*w3r[o*4+2] + v3*w3r[o*4+3];
      }
      part += __shfl_xor(part, 16);
      part += __shfl_xor(part, 32);
      float sp = softplus_f(part + b3v);
      if (pvalid[pt] && g==0) {
        outf[(size_t)item*961 + gpos[pt]] = sp;
        bsum += sp;
      }
    }
    __syncthreads();
    float* redf = reinterpret_cast<float*>(lds);
    redf[t] = bsum;
    __syncthreads();
    for (int off=128; off>0; off>>=1) {
      if (t < off) redf[t] += redf[t+off];
      __syncthreads();
    }
    if (t==0) atomicAdd(&sums[item], redf[0]);
    return;
  }

#pragma unroll
  for (int o=0; o<NOCT; ++o) {
    float4 bv4 = *reinterpret_cast<const float4*>(Bv + o*16 + g*4);
#pragma unroll
    for (int pt=0; pt<4; ++pt) {
      if (!pvalid[pt]) continue;
      float v0 = acc[o][pt][0] + bv4.x;
      float v1 = acc[o][pt][1] + bv4.y;
      float v2 = acc[o][pt][2] + bv4.z;
      float v3 = acc[o][pt][3] + bv4.w;
      if (FGELU) { v0=gelu_f(v0); v1=gelu_f(v1); v2=gelu_f(v2); v3=gelu_f(v3); }
      uint2 pk;
      pk.x = (unsigned)f2bf(v0) | ((unsigned)f2bf(v1)<<16);
      pk.y = (unsigned)f2bf(v2) | ((unsigned)f2bf(v3)<<16);
      *reinterpret_cast<uint2*>(out + ((size_t)item*961 + gpos[pt])*COUT + o*16 + g*4) = pk;
    }
  }
}

// ---------------------------------------------------------------------------
// Fused bottleneck-window gather + depthwise 7x7, channel-sliced, row-reuse.
// Block = (n, 64-ch slice). LDS [121][66] f32 = 32 KB.
// dw compute: per output row, each needed input row loaded ONCE into regs
// (7 LDS reads/output instead of 49).
// ---------------------------------------------------------------------------
__global__ __launch_bounds__(256,4) void dwfused3_k(
    const float* __restrict__ bott, const float* __restrict__ spv,
    const float* __restrict__ w, const float* __restrict__ b,
    unsigned short* __restrict__ bwinT, unsigned short* __restrict__ dwout)
{
  const int n = blockIdx.x, cs = blockIdx.y*64, t = threadIdx.x;
  __shared__ float tile[121*66];

  float pxf = fminf(fmaxf(spv[n*2+0]*0.25f, 0.f), 255.f);
  float pyf = fminf(fmaxf(spv[n*2+1]*0.25f, 0.f), 255.f);
  int cx = (int)rintf(pxf), cy = (int)rintf(pyf);

  // ---- gather: 32 channel-pairs x 121 positions (x-contiguous reads) ----
  for (int idx=t; idx<121*32; idx+=256) {
    int j = idx/121, p = idx - j*121;
    int y = p/11, x = p - y*11;
    int gy = min(max(cy + y - 5, 0), 255);
    int gx = min(max(cx + x - 5, 0), 255);
    const float* s0 = bott + ((size_t)(cs+2*j)<<16) + (gy<<8) + gx;
    *reinterpret_cast<float2*>(&tile[p*66 + 2*j]) = (float2){s0[0], s0[65536]};
  }
  __syncthreads();

  // ---- write bwinT slice (bf16, coalesced) ----
  for (int idx=t; idx<121*64; idx+=256) {
    int p = idx >> 6, c = idx & 63;
    bwinT[((size_t)n*121 + p)*256 + cs + c] = f2bf(tile[p*66 + c]);
  }

  // ---- dw compute: lane = channel, wave = row phase; row-reuse ----
  const int c = t & 63, ph = t >> 6;
  const int ch = cs + c;
  float wr[49];
#pragma unroll
  for (int k=0;k<49;++k) wr[k] = w[(size_t)ch*49 + k];
  const float bias = b[ch];

  for (int y=ph; y<11; y+=4) {
    float acc[11];
#pragma unroll
    for (int x=0;x<11;++x) acc[x] = bias;
#pragma unroll
    for (int dy=0; dy<7; ++dy) {
      int yy = y + dy - 3;             // wave-uniform branch
      if ((unsigned)yy < 11u) {
        float r[11];
#pragma unroll
        for (int k=0;k<11;++k) r[k] = tile[(yy*11+k)*66 + c];
#pragma unroll
        for (int x=0;x<11;++x) {
#pragma unroll
          for (int dx=0;dx<7;++dx) {
            constexpr int dummy = 0; (void)dummy;
            int xx = x + dx - 3;
            if (xx >= 0 && xx < 11)    // compile-time after unroll
              acc[x] = fmaf(r[xx], wr[dy*7+dx], acc[x]);
          }
        }
      }
    }
#pragma unroll
    for (int x=0;x<11;++x)
      dwout[((size_t)n*121 + y*11 + x)*256 + ch] = f2bf(acc[x]);
  }
}

// ---------------------------------------------------------------------------
// Fused ConvNeXt MLP + bnp head, bf16 MFMA. 512 threads / 8 waves, 64 rows.
// ---------------------------------------------------------------------------
__global__ __launch_bounds__(512,4) void cnx_mfma3_k(
    const unsigned short* __restrict__ xin,
    const float* __restrict__ lnw, const float* __restrict__ lnb,
    const unsigned short* __restrict__ W1p, const float* __restrict__ B1,
    const unsigned short* __restrict__ W2p, const float* __restrict__ B2,
    const float* __restrict__ gvec,
    const unsigned short* __restrict__ bwinT,
    const unsigned short* __restrict__ Wbp, const float* __restrict__ bnpb,
    float* __restrict__ bnv, float inv_gsum)
{
  const int t = threadIdx.x;
  const int w = t >> 6;          // 0..7
  const int l = t & 63;
  const int g = l >> 4;
  const int l15 = l & 15;
  const int row0 = blockIdx.x * 64;

  __shared__ __align__(16) unsigned short xs[64*264];
  __shared__ __align__(16) unsigned short hs[64*136];

  // ---- LN -> xs (8 threads per row, 32 ch each) ----
  {
    const int rl = t >> 3, q = t & 7;
    const unsigned short* xr = xin + (size_t)(row0+rl)*256 + q*32;
    float xv[32]; float s = 0.f, s2 = 0.f;
#pragma unroll
    for (int i=0;i<32;i+=8){
      uint4 v = *reinterpret_cast<const uint4*>(xr+i);
      unsigned short xh[8] = {
        (unsigned short)(v.x&0xffff),(unsigned short)(v.x>>16),
        (unsigned short)(v.y&0xffff),(unsigned short)(v.y>>16),
        (unsigned short)(v.z&0xffff),(unsigned short)(v.z>>16),
        (unsigned short)(v.w&0xffff),(unsigned short)(v.w>>16)};
#pragma unroll
      for (int j=0;j<8;++j){
        float f = bf2f(xh[j]);
        xv[i+j] = f; s += f; s2 += f*f;
      }
    }
    s += __shfl_xor(s,1); s2 += __shfl_xor(s2,1);
    s += __shfl_xor(s,2); s2 += __shfl_xor(s2,2);
    s += __shfl_xor(s,4); s2 += __shfl_xor(s2,4);
    float mu = s*(1.f/256.f);
    float rstd = rsqrtf(s2*(1.f/256.f) - mu*mu + 1e-6f);
#pragma unroll
    for (int i=0;i<32;i+=8){
      int c = q*32 + i;
      float4 w0 = *reinterpret_cast<const float4*>(lnw+c);
      float4 w1 = *reinterpret_cast<const float4*>(lnw+c+4);
      float4 b0 = *reinterpret_cast<const float4*>(lnb+c);
      float4 b1 = *reinterpret_cast<const float4*>(lnb+c+4);
      unsigned short h[8];
      h[0]=f2bf(fmaf((xv[i+0]-mu)*rstd, w0.x, b0.x));
      h[1]=f2bf(fmaf((xv[i+1]-mu)*rstd, w0.y, b0.y));
      h[2]=f2bf(fmaf((xv[i+2]-mu)*rstd, w0.z, b0.z));
      h[3]=f2bf(fmaf((xv[i+3]-mu)*rstd, w0.w, b0.w));
      h[4]=f2bf(fmaf((xv[i+4]-mu)*rstd, w1.x, b1.x));
      h[5]=f2bf(fmaf((xv[i+5]-mu)*rstd, w1.y, b1.y));
      h[6]=f2bf(fmaf((xv[i+6]-mu)*rstd, w1.z, b1.z));
      h[7]=f2bf(fmaf((xv[i+7]-mu)*rstd, w1.w, b1.w));
      uint4 pk;
      pk.x = (unsigned)h[0] | ((unsigned)h[1]<<16);
      pk.y = (unsigned)h[2] | ((unsigned)h[3]<<16);
      pk.z = (unsigned)h[4] | ((unsigned)h[5]<<16);
      pk.w = (unsigned)h[6] | ((unsigned)h[7]<<16);
      *reinterpret_cast<uint4*>(&xs[rl*264 + c]) = pk;
    }
  }
  __syncthreads();

  f32x4 acc2[8];                 // 2 c-tiles x 4 row-tiles
#pragma unroll
  for (int i=0;i<8;++i) acc2[i] = (f32x4){0.f,0.f,0.f,0.f};

  for (int hc=0; hc<8; ++hc) {
    const int ht = hc*8 + w;
    f32x4 acc1[4];
#pragma unroll
    for (int i=0;i<4;++i) acc1[i] = (f32x4){0.f,0.f,0.f,0.f};

#pragma unroll
    for (int kt=0; kt<8; ++kt) {
      bf16x8 xf[4];
#pragma unroll
      for (int rt=0; rt<4; ++rt)
        xf[rt] = *reinterpret_cast<const bf16x8*>(&xs[(rt*16+l15)*264 + kt*32 + g*8]);
      bf16x8 wf = *reinterpret_cast<const bf16x8*>(W1p + ((size_t)(ht*8+kt)*64 + l)*8);
#pragma unroll
      for (int rt=0; rt<4; ++rt)
        acc1[rt] = __builtin_amdgcn_mfma_f32_16x16x32_bf16(wf, xf[rt], acc1[rt], 0,0,0);
    }
    {
      const int hb = hc*128 + w*16 + 4*g;
      float4 b1v = *reinterpret_cast<const float4*>(B1 + hb);
#pragma unroll
      for (int rt=0; rt<4; ++rt) {
        unsigned short h0 = f2bf(gelu_f(acc1[rt][0] + b1v.x));
        unsigned short h1 = f2bf(gelu_f(acc1[rt][1] + b1v.y));
        unsigned short h2 = f2bf(gelu_f(acc1[rt][2] + b1v.z));
        unsigned short h3 = f2bf(gelu_f(acc1[rt][3] + b1v.w));
        uint2 pk;
        pk.x = (unsigned)h0 | ((unsigned)h1<<16);
        pk.y = (unsigned)h2 | ((unsigned)h3<<16);
        *reinterpret_cast<uint2*>(&hs[(rt*16+l15)*136 + w*16 + 4*g]) = pk;
      }
    }
    __syncthreads();
#pragma unroll
    for (int kt=0; kt<4; ++kt) {
      bf16x8 hf[4];
#pragma unroll
      for (int rt=0; rt<4; ++rt)
        hf[rt] = *reinterpret_cast<const bf16x8*>(&hs[(rt*16+l15)*136 + kt*32 + g*8]);
#pragma unroll
      for (int cj=0; cj<2; ++cj) {
        const int ct = 2*w + cj;
        bf16x8 wf = *reinterpret_cast<const bf16x8*>(W2p + ((size_t)(ct*32 + hc*4 + kt)*64 + l)*8);
#pragma unroll
        for (int rt=0; rt<4; ++rt)
          acc2[cj*4+rt] = __builtin_amdgcn_mfma_f32_16x16x32_bf16(hf[rt], wf, acc2[cj*4+rt], 0,0,0);
      }
    }
    __syncthreads();
  }

  // ---- residual in regs -> xs as bf16 ----
#pragma unroll
  for (int cj=0; cj<2; ++cj) {
    const int c = (2*w+cj)*16 + l15;
    const float b2 = B2[c], gm = gvec[c];
#pragma unroll
    for (int rt=0; rt<4; ++rt) {
#pragma unroll
      for (int reg=0; reg<4; ++reg) {
        int row = rt*16 + 4*g + reg;
        float res = bf2f(bwinT[(size_t)(row0+row)*256 + c]) + (acc2[cj*4+rt][reg] + b2)*gm;
        xs[row*264 + c] = f2bf(res);
      }
    }
  }
  __syncthreads();

  // ---- bnp GEMM: wave w -> oct = w&3, row-tiles {w>>2, 2+(w>>2)} ----
  {
    const int oct = w & 3;
    f32x4 abn[2];
#pragma unroll
    for (int i=0;i<2;++i) abn[i] = (f32x4){0.f,0.f,0.f,0.f};
#pragma unroll
    for (int kt=0; kt<8; ++kt) {
      bf16x8 bfw = *reinterpret_cast<const bf16x8*>(Wbp + ((size_t)(oct*8+kt)*64 + l)*8);
#pragma unroll
      for (int i=0;i<2;++i) {
        const int rt = (w>>2) + 2*i;
        bf16x8 af = *reinterpret_cast<const bf16x8*>(&xs[(rt*16+l15)*264 + kt*32 + g*8]);
        abn[i] = __builtin_amdgcn_mfma_f32_16x16x32_bf16(af, bfw, abn[i], 0,0,0);
      }
    }

    float* red = reinterpret_cast<float*>(hs);
#pragma unroll
    for (int i=0;i<2;++i) {
      const int rt = (w>>2) + 2*i;
      float bv = bnpb[oct*16 + l15];
#pragma unroll
      for (int reg=0; reg<4; ++reg) {
        int lr = rt*16 + g*4 + reg;
        int p = (row0 + lr) % 121;
        int py=p/11, px=p-py*11;
        float ly=-1.f+0.2f*py, lx=-1.f+0.2f*px;
        float wg = expf(-(lx*lx+ly*ly)/0.32f) * inv_gsum;
        red[lr*64 + oct*16 + l15] = gelu_f(abn[i][reg] + bv) * wg;
      }
    }
  }
  __syncthreads();
  {
    float* red = reinterpret_cast<float*>(hs);
    int oc = t & 63, seg = t >> 6;
    float s = 0.f;
    int curn = (row0 + seg*8) / 121;
    for (int i=0;i<8;++i) {
      int row = seg*8 + i;
      int n = (row0 + row) / 121;
      if (n != curn) { atomicAdd(&bnv[curn*64 + oc], s); s = 0.f; curn = n; }
      s += red[row*64 + oc];
    }
    atomicAdd(&bnv[curn*64 + oc], s);
  }
}

// ---------------------------------------------------------------------------
// FiLM
// ---------------------------------------------------------------------------
__global__ __launch_bounds__(256) void film_k(
    const float* __restrict__ bn_vec, const float* __restrict__ ppb,
    const float* __restrict__ bemb, const float* __restrict__ fw,
    const float* __restrict__ fb, float* __restrict__ film)
{
  int n = blockIdx.x, t = threadIdx.x;
  __shared__ float cond[4][84];
  for (int i=t; i<4*84; i+=256) {
    int b = i/84, j = i%84;
    float v;
    if (j < 16) v = bemb[b*16 + j];
    else if (j == 16) { float p = ppb[((size_t)n*4+b)*2+0]; v = fminf(fmaxf(p*(1.f/1023.f),0.f),1.f); }
    else if (j == 17) { float p = ppb[((size_t)n*4+b)*2+1]; v = fminf(fmaxf(p*(1.f/1023.f),0.f),1.f); }
    else if (j == 18) { float p = ppb[((size_t)n*4+b)*2+0]; v = p - rintf(p); }
    else if (j == 19) { float p = ppb[((size_t)n*4+b)*2+1]; v = p - rintf(p); }
    else v = bn_vec[n*64 + (j-20)];
    cond[b][j] = v;
  }
  __syncthreads();
  int b = t >> 6, oc = t & 63;
  float s = fb[oc];
  for (int j=0;j<84;++j) s = fmaf(cond[b][j], fw[oc*84+j], s);
  film[((size_t)n*4+b)*64 + oc] = s;
}

// ---------------------------------------------------------------------------
// final per-map normalization
// ---------------------------------------------------------------------------
__global__ __launch_bounds__(256) void norm_k(float* __restrict__ out,
                                              const float* __restrict__ sums)
{
  int il = blockIdx.x;
  int p = blockIdx.y*256 + threadIdx.x;
  if (p < 961) {
    float inv = 1.f / fmaxf(sums[il], 1e-8f);
    out[(size_t)il*961 + p] *= inv;
  }
}

// ---------------------------------------------------------------------------
extern "C" void kernel_launch(void* const* d_in, const int* in_sizes, int n_in,
                              void* d_out, int out_size, void* d_ws, size_t ws_size,
                              hipStream_t stream)
{
  const float* bott = (const float*)d_in[0];
  const float* vis  = (const float*)d_in[1];
  const float* spv  = (const float*)d_in[2];
  const float* ppb  = (const float*)d_in[3];
  const float* ic1w = (const float*)d_in[4];  const float* ic1b = (const float*)d_in[5];
  const float* ic2w = (const float*)d_in[6];  const float* ic2b = (const float*)d_in[7];
  const float* ic3w = (const float*)d_in[8];  const float* ic3b = (const float*)d_in[9];
  const float* dww  = (const float*)d_in[10]; const float* dwb  = (const float*)d_in[11];
  const float* lnw  = (const float*)d_in[12]; const float* lnb  = (const float*)d_in[13];
  const float* pw1w = (const float*)d_in[14]; const float* pw1b = (const float*)d_in[15];
  const float* pw2w = (const float*)d_in[16]; const float* pw2b = (const float*)d_in[17];
  const float* cgam = (const float*)d_in[18];
  const float* bnpw = (const float*)d_in[19]; const float* bnpb = (const float*)d_in[20];
  const float* bemb = (const float*)d_in[21];
  const float* fw   = (const float*)d_in[22]; const float* fb   = (const float*)d_in[23];
  const float* d1w  = (const float*)d_in[24]; const float* d1b  = (const float*)d_in[25];
  const float* d2w  = (const float*)d_in[26]; const float* d2b  = (const float*)d_in[27];
  const float* d3w  = (const float*)d_in[28]; const float* d3b  = (const float*)d_in[29];
  float* out = (float*)d_out;

  char* ws = (char*)d_ws;

  const int CH = (ws_size >= 116400128ull) ? 256 : 128;

  // P2 regions (bf16; overlap P1 regions, stream-ordered)
  unsigned short* bwinT = (unsigned short*)(ws);
  unsigned short* dwout = (unsigned short*)(ws + 31719424);
  // P1 regions
  unsigned short* vwin = (unsigned short*)(ws);
  size_t o_bufA = (size_t)CH*139392;
  size_t o_bufB = o_bufA + (size_t)CH*123008;
  size_t o_bufI = o_bufB + (size_t)CH*123008;
  size_t p1end  = o_bufI + (size_t)CH*61504;
  unsigned short* bufA = (unsigned short*)(ws + o_bufA);
  unsigned short* bufB = (unsigned short*)(ws + o_bufB);
  unsigned short* bufI = (unsigned short*)(ws + o_bufI);
  size_t tail = (p1end > 63438848ull) ? p1end : 63438848ull;

  float* bnv  = (float*)(ws + tail);
  float* sums = (float*)(ws + tail + 131072);
  float* film = (float*)(ws + tail + 139264);
  unsigned short* W1p = (unsigned short*)(ws + tail + 663552);
  unsigned short* W2p = (unsigned short*)(ws + tail + 1187840);
  unsigned short* Wbp = (unsigned short*)(ws + tail + 1712128);
  unsigned short* Pc1 = (unsigned short*)(ws + tail + 1744896);
  unsigned short* Pc2 = (unsigned short*)(ws + tail + 1818624);
  unsigned short* Pc3 = (unsigned short*)(ws + tail + 1892352);
  unsigned short* Pd1 = (unsigned short*)(ws + tail + 1929216);
  unsigned short* Pd2 = (unsigned short*)(ws + tail + 1947648);

  // ---- combined weight packing (1 launch) ----
  {
    PackJobs J;
    const float* srcs[8] = {pw1w, pw2w, bnpw, ic1w, ic2w, ic3w, d1w, d2w};
    unsigned short* dsts[8] = {W1p, W2p, Wbp, Pc1, Pc2, Pc3, Pd1, Pd2};
    int ntns[8] = {64,16,4, 4,4,2, 2,2};
    int ntks[8] = {8,32,8, 18,18,18, 9,9};
    int Ks[8]   = {256,1024,256, 64,64,64, 32,32};
    int convs[8]= {0,0,0, 1,1,1, 1,1};
    int base = 0;
    for (int i=0;i<8;++i) {
      J.src[i]=srcs[i]; J.dst[i]=dsts[i]; J.ntn[i]=ntns[i]; J.ntk[i]=ntks[i];
      J.K[i]=Ks[i]; J.conv[i]=convs[i]; J.base[i]=base;
      base += (ntns[i]*ntks[i]*64 + 255)/256;
    }
    packall_k<<<base,256,0,stream>>>(J);
  }

  hipMemsetAsync(ws + tail, 0, 139264, stream);  // bnv + sums

  float gs = 0.f;
  for (int py=0; py<11; ++py) for (int px=0; px<11; ++px) {
    float ly=-1.f+0.2f*py, lx=-1.f+0.2f*px;
    gs += expf(-(lx*lx+ly*ly)/0.32f);
  }
  const float inv_gsum = 1.f/gs;

  // ---- Phase 2: bottleneck path -> bn_vec ----
  dwfused3_k<<<dim3(512,4),256,0,stream>>>(bott, spv, dww, dwb, bwinT, dwout);
  cnx_mfma3_k<<<968,512,0,stream>>>(dwout, lnw,lnb, W1p,pw1b, W2p,pw2b, cgam,
                                    bwinT, Wbp, bnpb, bnv, inv_gsum);
  film_k<<<512,256,0,stream>>>(bnv, ppb, bemb, fw, fb, film);

  // ---- Phase 1+3: intrinsic chain + decoder ----
  for (int n0 = 0; n0 < 512; n0 += CH) {
    extvwin_k<<<dim3(CH,5),256,0,stream>>>(vis, spv + n0*2, vwin);
    convmf_k<64,64,18,1,true ,false><<<dim3(CH,4),256,0,stream>>>(vwin, Pc1, ic1b, bufA, nullptr,0, nullptr,nullptr,nullptr,nullptr);
    convmf_k<64,64,18,0,true ,false><<<dim3(CH,4),256,0,stream>>>(bufA, Pc2, ic2b, bufB, nullptr,0, nullptr,nullptr,nullptr,nullptr);
    convmf_k<64,32,18,0,false,false><<<dim3(CH,4),256,0,stream>>>(bufB, Pc3, ic3b, bufI, nullptr,0, nullptr,nullptr,nullptr,nullptr);
    for (int s = 0; s < CH/64; ++s) {
      int nb0 = n0*4 + s*256;
      convmf_k<32,32,9,2,true,false><<<dim3(256,4),256,0,stream>>>(bufI, Pd1, d1b, bufB,
          film + (size_t)nb0*64, s*256, nullptr,nullptr,nullptr,nullptr);
      convmf_k<32,32,9,0,true,true ><<<dim3(256,4),256,0,stream>>>(bufB, Pd2, d2b, nullptr,
          nullptr,0, out + (size_t)nb0*961, sums + nb0, d3w, d3b);
    }
  }
  norm_k<<<dim3(2048,4),256,0,stream>>>(out, sums);
}

// Round 8
// 879.262 us; speedup vs baseline: 9.0594x; 1.0851x over previous
//
#include <hip/hip_runtime.h>
#include <cstdint>
#include <cstddef>
#include <cmath>

#define DEV __device__ __forceinline__

typedef __attribute__((ext_vector_type(8))) short bf16x8;
typedef __attribute__((ext_vector_type(4))) float f32x4;

DEV float gelu_f(float x){ return 0.5f*x*(1.0f + erff(x*0.7071067811865476f)); }
DEV float softplus_f(float x){ return fmaxf(x,0.f) + log1pf(expf(-fabsf(x))); }
DEV unsigned short f2bf(float x){
  unsigned u = __float_as_uint(x);
  unsigned r = (u + 0x7fffu + ((u>>16)&1u)) >> 16;
  return (unsigned short)r;
}
DEV float bf2f(unsigned short h){
  unsigned u = ((unsigned)h) << 16;
  return __uint_as_float(u);
}

// ---------------------------------------------------------------------------
// Combined weight packing: 8 jobs in one launch.
// ---------------------------------------------------------------------------
struct PackJobs {
  const float* src[8];
  unsigned short* dst[8];
  int ntn[8], ntk[8], K[8], conv[8], base[8];
};

__global__ __launch_bounds__(256) void packall_k(PackJobs J)
{
  int blk = blockIdx.x;
  int j = 0;
#pragma unroll
  for (int i=1;i<8;++i) if (blk >= J.base[i]) j = i;
  int tid = (blk - J.base[j])*256 + threadIdx.x;
  const int ntk = J.ntk[j], K = J.K[j];
  int total = J.ntn[j]*ntk*64;
  if (tid >= total) return;
  int lane = tid & 63;
  int f = tid >> 6;
  int kt = f % ntk, nt = f / ntk;
  int row = nt*16 + (lane & 15);
  int k0 = kt*32 + (lane >> 4)*8;
  const float* src = J.src[j];
  unsigned short h[8];
  if (J.conv[j]) {
    const int Cin = K;
#pragma unroll
    for (int q=0;q<8;++q) {
      int k = k0 + q;
      int s = k / Cin;
      int ic = k - s*Cin;
      h[q] = f2bf(src[((size_t)row*Cin + ic)*9 + s]);
    }
  } else {
#pragma unroll
    for (int q=0;q<8;++q) h[q] = f2bf(src[(size_t)row*K + k0 + q]);
  }
  uint4 pk;
  pk.x = (unsigned)h[0] | ((unsigned)h[1]<<16);
  pk.y = (unsigned)h[2] | ((unsigned)h[3]<<16);
  pk.z = (unsigned)h[4] | ((unsigned)h[5]<<16);
  pk.w = (unsigned)h[6] | ((unsigned)h[7]<<16);
  *reinterpret_cast<uint4*>(J.dst[j] + (size_t)tid*8) = pk;
}

// dw weight transpose: wT[k][ch] = w[ch][k]  (49 x 256)
__global__ __launch_bounds__(256) void dwt_k(const float* __restrict__ w,
                                             float* __restrict__ wT)
{
  int k = blockIdx.x;           // 0..48
  int ch = threadIdx.x;         // 0..255
  wT[k*256 + ch] = w[(size_t)ch*49 + k];
}

// ---------------------------------------------------------------------------
// Extract clamped 33x33 vis windows (incl. conv zero ring) -> bf16 NHWC
// ---------------------------------------------------------------------------
__global__ __launch_bounds__(256) void extvwin_k(const float* __restrict__ vis,
                                                 const float* __restrict__ spv,
                                                 unsigned short* __restrict__ vwin)
{
  int il = blockIdx.x;
  int p = blockIdx.y*256 + threadIdx.x;
  if (p >= 1089) return;
  int wy = p/33, wx = p%33;
  unsigned short* dst = vwin + ((size_t)il*1089 + p)*64;
  if (wy==0 || wy==32 || wx==0 || wx==32) {
    uint4 z = {0,0,0,0};
#pragma unroll
    for (int q=0;q<8;++q) *reinterpret_cast<uint4*>(dst + q*8) = z;
    return;
  }
  int cx = (int)rintf(spv[il*2+0]);
  int cy = (int)rintf(spv[il*2+1]);
  int gy = min(max(cy + wy - 16, 0), 1023);
  int gx = min(max(cx + wx - 16, 0), 1023);
  const float* sp = vis + (size_t)gy*1024 + gx;
  unsigned short h[64];
#pragma unroll
  for (int c=0;c<64;++c) h[c] = f2bf(sp[(size_t)c<<20]);
#pragma unroll
  for (int q=0;q<8;++q) {
    uint4 pk;
    pk.x = (unsigned)h[q*8+0] | ((unsigned)h[q*8+1]<<16);
    pk.y = (unsigned)h[q*8+2] | ((unsigned)h[q*8+3]<<16);
    pk.z = (unsigned)h[q*8+4] | ((unsigned)h[q*8+5]<<16);
    pk.w = (unsigned)h[q*8+6] | ((unsigned)h[q*8+7]<<16);
    *reinterpret_cast<uint4*>(dst + q*8) = pk;
  }
}

// ---------------------------------------------------------------------------
// MFMA implicit-GEMM 3x3 conv, with next-kt weight prefetch.
// ---------------------------------------------------------------------------
template<int CIN, int COUT, int NKT, int MODE, bool FGELU, bool FDEC>
__global__ __launch_bounds__(256, (CIN==64?3:4)) void convmf_k(
    const unsigned short* __restrict__ src,
    const unsigned short* __restrict__ Wp,
    const float* __restrict__ Bv,
    unsigned short* __restrict__ out,
    const float* __restrict__ film, int nbBase,
    float* __restrict__ outf, float* __restrict__ sums,
    const float* __restrict__ w3, const float* __restrict__ b3)
{
  constexpr int NOCT = COUT/16;
  constexpr int NSLOT = CIN/8;
  constexpr int SWM = NSLOT-1;
  const int item = blockIdx.x;
  const int y0 = blockIdx.y*8;
  const int t = threadIdx.x;
  const int w = t>>6, l = t&63, g = l>>4, l15 = l&15;

  __shared__ __align__(16) unsigned short lds[330*CIN];

  // ---- stage ----
  const int sit = (MODE==2) ? ((nbBase + item) >> 2) : item;
  const float* frow = (MODE==2) ? (film + (size_t)item*64) : nullptr;
  for (int u = t; u < 330*NSLOT; u += 256) {
    int slot = u & SWM;
    int rowi = u / NSLOT;            // r*33+col
    int r = rowi / 33, col = rowi - r*33;
    uint4 val = {0,0,0,0};
    if (MODE==1) {
      int gr = y0 + r;
      if (gr < 33)
        val = *reinterpret_cast<const uint4*>(src + ((size_t)item*1089 + gr*33 + col)*CIN + slot*8);
    } else {
      int y = y0 + r - 1, x = col - 1;
      if ((unsigned)y < 31u && (unsigned)x < 31u) {
        val = *reinterpret_cast<const uint4*>(src + ((size_t)sit*961 + y*31 + x)*CIN + slot*8);
        if (MODE==2) {
          int c0 = slot*8;
          float4 g0 = *reinterpret_cast<const float4*>(frow + c0);
          float4 g1 = *reinterpret_cast<const float4*>(frow + c0 + 4);
          float4 b0 = *reinterpret_cast<const float4*>(frow + 32 + c0);
          float4 b1 = *reinterpret_cast<const float4*>(frow + 32 + c0 + 4);
          unsigned short x8[8] = {
            (unsigned short)(val.x&0xffff),(unsigned short)(val.x>>16),
            (unsigned short)(val.y&0xffff),(unsigned short)(val.y>>16),
            (unsigned short)(val.z&0xffff),(unsigned short)(val.z>>16),
            (unsigned short)(val.w&0xffff),(unsigned short)(val.w>>16)};
          unsigned short o8[8];
          o8[0]=f2bf(gelu_f(fmaf(bf2f(x8[0]), 1.f+g0.x, b0.x)));
          o8[1]=f2bf(gelu_f(fmaf(bf2f(x8[1]), 1.f+g0.y, b0.y)));
          o8[2]=f2bf(gelu_f(fmaf(bf2f(x8[2]), 1.f+g0.z, b0.z)));
          o8[3]=f2bf(gelu_f(fmaf(bf2f(x8[3]), 1.f+g0.w, b0.w)));
          o8[4]=f2bf(gelu_f(fmaf(bf2f(x8[4]), 1.f+g1.x, b1.x)));
          o8[5]=f2bf(gelu_f(fmaf(bf2f(x8[5]), 1.f+g1.y, b1.y)));
          o8[6]=f2bf(gelu_f(fmaf(bf2f(x8[6]), 1.f+g1.z, b1.z)));
          o8[7]=f2bf(gelu_f(fmaf(bf2f(x8[7]), 1.f+g1.w, b1.w)));
          val.x = (unsigned)o8[0] | ((unsigned)o8[1]<<16);
          val.y = (unsigned)o8[2] | ((unsigned)o8[3]<<16);
          val.z = (unsigned)o8[4] | ((unsigned)o8[5]<<16);
          val.w = (unsigned)o8[6] | ((unsigned)o8[7]<<16);
        }
      }
    }
    int ds = slot ^ (rowi & SWM);
    *reinterpret_cast<uint4*>(&lds[rowi*CIN + ds*8]) = val;
  }
  __syncthreads();

  int pbase[4], gpos[4]; bool pvalid[4];
#pragma unroll
  for (int pt=0; pt<4; ++pt) {
    int p = (w*4+pt)*16 + l15;
    int pc = min(p, 247);
    int py = pc/31, px = pc - py*31;
    pbase[pt] = py*33 + px;
    gpos[pt] = y0*31 + p;
    pvalid[pt] = (p < 248) && (gpos[pt] < 961);
  }

  f32x4 acc[NOCT][4];
#pragma unroll
  for (int o=0;o<NOCT;++o)
#pragma unroll
    for (int pt=0;pt<4;++pt) acc[o][pt] = (f32x4){0.f,0.f,0.f,0.f};

  // weight prefetch pipeline
  bf16x8 wcur[NOCT];
#pragma unroll
  for (int o=0;o<NOCT;++o)
    wcur[o] = *reinterpret_cast<const bf16x8*>(Wp + ((size_t)(o*NKT)*64 + l)*8);

  for (int kt=0; kt<NKT; ++kt) {
    bf16x8 wnxt[NOCT];
    if (kt+1 < NKT) {
#pragma unroll
      for (int o=0;o<NOCT;++o)
        wnxt[o] = *reinterpret_cast<const bf16x8*>(Wp + ((size_t)(o*NKT+kt+1)*64 + l)*8);
    }
    int k0 = kt*32 + g*8;
    int s = k0 / CIN;
    int icg = (k0 - s*CIN) >> 3;
    int roff = (s/3)*33 + (s - (s/3)*3);
    bf16x8 bf[4];
#pragma unroll
    for (int pt=0; pt<4; ++pt) {
      int rowi = pbase[pt] + roff;
      int ds = icg ^ (rowi & SWM);
      bf[pt] = *reinterpret_cast<const bf16x8*>(&lds[rowi*CIN + ds*8]);
    }
#pragma unroll
    for (int o=0; o<NOCT; ++o) {
#pragma unroll
      for (int pt=0; pt<4; ++pt)
        acc[o][pt] = __builtin_amdgcn_mfma_f32_16x16x32_bf16(wcur[o], bf[pt], acc[o][pt], 0,0,0);
    }
    if (kt+1 < NKT) {
#pragma unroll
      for (int o=0;o<NOCT;++o) wcur[o] = wnxt[o];
    }
  }

  if (FDEC) {
    float w3r[NOCT*4];
#pragma unroll
    for (int o=0;o<NOCT;++o) {
      float4 wv = *reinterpret_cast<const float4*>(w3 + o*16 + g*4);
      w3r[o*4+0]=wv.x; w3r[o*4+1]=wv.y; w3r[o*4+2]=wv.z; w3r[o*4+3]=wv.w;
    }
    float b3v = b3[0];
    float bsum = 0.f;
#pragma unroll
    for (int pt=0; pt<4; ++pt) {
      float part = 0.f;
#pragma unroll
      for (int o=0; o<NOCT; ++o) {
        float4 bv4 = *reinterpret_cast<const float4*>(Bv + o*16 + g*4);
        float v0 = acc[o][pt][0] + bv4.x;
        float v1 = acc[o][pt][1] + bv4.y;
        float v2 = acc[o][pt][2] + bv4.z;
        float v3 = acc[o][pt][3] + bv4.w;
        if (FGELU) { v0=gelu_f(v0); v1=gelu_f(v1); v2=gelu_f(v2); v3=gelu_f(v3); }
        part += v0*w3r[o*4+0] + v1*w3r[o*4+1] + v2*w3r[o*4+2] + v3*w3r[o*4+3];
      }
      part += __shfl_xor(part, 16);
      part += __shfl_xor(part, 32);
      float sp = softplus_f(part + b3v);
      if (pvalid[pt] && g==0) {
        outf[(size_t)item*961 + gpos[pt]] = sp;
        bsum += sp;
      }
    }
    __syncthreads();
    float* redf = reinterpret_cast<float*>(lds);
    redf[t] = bsum;
    __syncthreads();
    for (int off=128; off>0; off>>=1) {
      if (t < off) redf[t] += redf[t+off];
      __syncthreads();
    }
    if (t==0) atomicAdd(&sums[item], redf[0]);
    return;
  }

#pragma unroll
  for (int o=0; o<NOCT; ++o) {
    float4 bv4 = *reinterpret_cast<const float4*>(Bv + o*16 + g*4);
#pragma unroll
    for (int pt=0; pt<4; ++pt) {
      if (!pvalid[pt]) continue;
      float v0 = acc[o][pt][0] + bv4.x;
      float v1 = acc[o][pt][1] + bv4.y;
      float v2 = acc[o][pt][2] + bv4.z;
      float v3 = acc[o][pt][3] + bv4.w;
      if (FGELU) { v0=gelu_f(v0); v1=gelu_f(v1); v2=gelu_f(v2); v3=gelu_f(v3); }
      uint2 pk;
      pk.x = (unsigned)f2bf(v0) | ((unsigned)f2bf(v1)<<16);
      pk.y = (unsigned)f2bf(v2) | ((unsigned)f2bf(v3)<<16);
      *reinterpret_cast<uint2*>(out + ((size_t)item*961 + gpos[pt])*COUT + o*16 + g*4) = pk;
    }
  }
}

// ---------------------------------------------------------------------------
// Fused bottleneck-window gather + depthwise 7x7, channel-sliced, row-reuse,
// low register pressure: weights loaded 7-at-a-time from transposed wT[49][256].
// ---------------------------------------------------------------------------
__global__ __launch_bounds__(256,4) void dwfused4_k(
    const float* __restrict__ bott, const float* __restrict__ spv,
    const float* __restrict__ wT, const float* __restrict__ b,
    unsigned short* __restrict__ bwinT, unsigned short* __restrict__ dwout)
{
  const int n = blockIdx.x, cs = blockIdx.y*64, t = threadIdx.x;
  __shared__ float tile[121*66];

  float pxf = fminf(fmaxf(spv[n*2+0]*0.25f, 0.f), 255.f);
  float pyf = fminf(fmaxf(spv[n*2+1]*0.25f, 0.f), 255.f);
  int cx = (int)rintf(pxf), cy = (int)rintf(pyf);

  // ---- gather: 32 channel-pairs x 121 positions (x-contiguous reads) ----
  for (int idx=t; idx<121*32; idx+=256) {
    int j = idx/121, p = idx - j*121;
    int y = p/11, x = p - y*11;
    int gy = min(max(cy + y - 5, 0), 255);
    int gx = min(max(cx + x - 5, 0), 255);
    const float* s0 = bott + ((size_t)(cs+2*j)<<16) + (gy<<8) + gx;
    *reinterpret_cast<float2*>(&tile[p*66 + 2*j]) = (float2){s0[0], s0[65536]};
  }
  __syncthreads();

  // ---- write bwinT slice (bf16, coalesced) ----
  for (int idx=t; idx<121*64; idx+=256) {
    int p = idx >> 6, c = idx & 63;
    bwinT[((size_t)n*121 + p)*256 + cs + c] = f2bf(tile[p*66 + c]);
  }

  // ---- dw compute: lane = channel, wave = row phase; row-reuse ----
  const int c = t & 63, ph = t >> 6;
  const int ch = cs + c;
  const float bias = b[ch];

  for (int y=ph; y<11; y+=4) {
    float acc[11];
#pragma unroll
    for (int x=0;x<11;++x) acc[x] = bias;
#pragma unroll
    for (int dy=0; dy<7; ++dy) {
      int yy = y + dy - 3;             // wave-uniform branch
      if ((unsigned)yy < 11u) {
        float r[11];
#pragma unroll
        for (int k=0;k<11;++k) r[k] = tile[(yy*11+k)*66 + c];
        float w7[7];
#pragma unroll
        for (int j=0;j<7;++j) w7[j] = wT[(dy*7+j)*256 + ch];
#pragma unroll
        for (int x=0;x<11;++x) {
#pragma unroll
          for (int dx=0;dx<7;++dx) {
            int xx = x + dx - 3;
            if (xx >= 0 && xx < 11)    // compile-time after unroll
              acc[x] = fmaf(r[xx], w7[dx], acc[x]);
          }
        }
      }
    }
#pragma unroll
    for (int x=0;x<11;++x)
      dwout[((size_t)n*121 + y*11 + x)*256 + ch] = f2bf(acc[x]);
  }
}

// ---------------------------------------------------------------------------
// Fused ConvNeXt MLP + bnp head, bf16 MFMA. 512 threads / 8 waves, 64 rows.
// ---------------------------------------------------------------------------
__global__ __launch_bounds__(512,4) void cnx_mfma3_k(
    const unsigned short* __restrict__ xin,
    const float* __restrict__ lnw, const float* __restrict__ lnb,
    const unsigned short* __restrict__ W1p, const float* __restrict__ B1,
    const unsigned short* __restrict__ W2p, const float* __restrict__ B2,
    const float* __restrict__ gvec,
    const unsigned short* __restrict__ bwinT,
    const unsigned short* __restrict__ Wbp, const float* __restrict__ bnpb,
    float* __restrict__ bnv, float inv_gsum)
{
  const int t = threadIdx.x;
  const int w = t >> 6;          // 0..7
  const int l = t & 63;
  const int g = l >> 4;
  const int l15 = l & 15;
  const int row0 = blockIdx.x * 64;

  __shared__ __align__(16) unsigned short xs[64*264];
  __shared__ __align__(16) unsigned short hs[64*136];

  // ---- LN -> xs (8 threads per row, 32 ch each) ----
  {
    const int rl = t >> 3, q = t & 7;
    const unsigned short* xr = xin + (size_t)(row0+rl)*256 + q*32;
    float xv[32]; float s = 0.f, s2 = 0.f;
#pragma unroll
    for (int i=0;i<32;i+=8){
      uint4 v = *reinterpret_cast<const uint4*>(xr+i);
      unsigned short xh[8] = {
        (unsigned short)(v.x&0xffff),(unsigned short)(v.x>>16),
        (unsigned short)(v.y&0xffff),(unsigned short)(v.y>>16),
        (unsigned short)(v.z&0xffff),(unsigned short)(v.z>>16),
        (unsigned short)(v.w&0xffff),(unsigned short)(v.w>>16)};
#pragma unroll
      for (int j=0;j<8;++j){
        float f = bf2f(xh[j]);
        xv[i+j] = f; s += f; s2 += f*f;
      }
    }
    s += __shfl_xor(s,1); s2 += __shfl_xor(s2,1);
    s += __shfl_xor(s,2); s2 += __shfl_xor(s2,2);
    s += __shfl_xor(s,4); s2 += __shfl_xor(s2,4);
    float mu = s*(1.f/256.f);
    float rstd = rsqrtf(s2*(1.f/256.f) - mu*mu + 1e-6f);
#pragma unroll
    for (int i=0;i<32;i+=8){
      int c = q*32 + i;
      float4 w0 = *reinterpret_cast<const float4*>(lnw+c);
      float4 w1 = *reinterpret_cast<const float4*>(lnw+c+4);
      float4 b0 = *reinterpret_cast<const float4*>(lnb+c);
      float4 b1 = *reinterpret_cast<const float4*>(lnb+c+4);
      unsigned short h[8];
      h[0]=f2bf(fmaf((xv[i+0]-mu)*rstd, w0.x, b0.x));
      h[1]=f2bf(fmaf((xv[i+1]-mu)*rstd, w0.y, b0.y));
      h[2]=f2bf(fmaf((xv[i+2]-mu)*rstd, w0.z, b0.z));
      h[3]=f2bf(fmaf((xv[i+3]-mu)*rstd, w0.w, b0.w));
      h[4]=f2bf(fmaf((xv[i+4]-mu)*rstd, w1.x, b1.x));
      h[5]=f2bf(fmaf((xv[i+5]-mu)*rstd, w1.y, b1.y));
      h[6]=f2bf(fmaf((xv[i+6]-mu)*rstd, w1.z, b1.z));
      h[7]=f2bf(fmaf((xv[i+7]-mu)*rstd, w1.w, b1.w));
      uint4 pk;
      pk.x = (unsigned)h[0] | ((unsigned)h[1]<<16);
      pk.y = (unsigned)h[2] | ((unsigned)h[3]<<16);
      pk.z = (unsigned)h[4] | ((unsigned)h[5]<<16);
      pk.w = (unsigned)h[6] | ((unsigned)h[7]<<16);
      *reinterpret_cast<uint4*>(&xs[rl*264 + c]) = pk;
    }
  }
  __syncthreads();

  f32x4 acc2[8];                 // 2 c-tiles x 4 row-tiles
#pragma unroll
  for (int i=0;i<8;++i) acc2[i] = (f32x4){0.f,0.f,0.f,0.f};

  for (int hc=0; hc<8; ++hc) {
    const int ht = hc*8 + w;
    f32x4 acc1[4];
#pragma unroll
    for (int i=0;i<4;++i) acc1[i] = (f32x4){0.f,0.f,0.f,0.f};

#pragma unroll
    for (int kt=0; kt<8; ++kt) {
      bf16x8 xf[4];
#pragma unroll
      for (int rt=0; rt<4; ++rt)
        xf[rt] = *reinterpret_cast<const bf16x8*>(&xs[(rt*16+l15)*264 + kt*32 + g*8]);
      bf16x8 wf = *reinterpret_cast<const bf16x8*>(W1p + ((size_t)(ht*8+kt)*64 + l)*8);
#pragma unroll
      for (int rt=0; rt<4; ++rt)
        acc1[rt] = __builtin_amdgcn_mfma_f32_16x16x32_bf16(wf, xf[rt], acc1[rt], 0,0,0);
    }
    {
      const int hb = hc*128 + w*16 + 4*g;
      float4 b1v = *reinterpret_cast<const float4*>(B1 + hb);
#pragma unroll
      for (int rt=0; rt<4; ++rt) {
        unsigned short h0 = f2bf(gelu_f(acc1[rt][0] + b1v.x));
        unsigned short h1 = f2bf(gelu_f(acc1[rt][1] + b1v.y));
        unsigned short h2 = f2bf(gelu_f(acc1[rt][2] + b1v.z));
        unsigned short h3 = f2bf(gelu_f(acc1[rt][3] + b1v.w));
        uint2 pk;
        pk.x = (unsigned)h0 | ((unsigned)h1<<16);
        pk.y = (unsigned)h2 | ((unsigned)h3<<16);
        *reinterpret_cast<uint2*>(&hs[(rt*16+l15)*136 + w*16 + 4*g]) = pk;
      }
    }
    __syncthreads();
#pragma unroll
    for (int kt=0; kt<4; ++kt) {
      bf16x8 hf[4];
#pragma unroll
      for (int rt=0; rt<4; ++rt)
        hf[rt] = *reinterpret_cast<const bf16x8*>(&hs[(rt*16+l15)*136 + kt*32 + g*8]);
#pragma unroll
      for (int cj=0; cj<2; ++cj) {
        const int ct = 2*w + cj;
        bf16x8 wf = *reinterpret_cast<const bf16x8*>(W2p + ((size_t)(ct*32 + hc*4 + kt)*64 + l)*8);
#pragma unroll
        for (int rt=0; rt<4; ++rt)
          acc2[cj*4+rt] = __builtin_amdgcn_mfma_f32_16x16x32_bf16(hf[rt], wf, acc2[cj*4+rt], 0,0,0);
      }
    }
    __syncthreads();
  }

  // ---- residual in regs -> xs as bf16 ----
#pragma unroll
  for (int cj=0; cj<2; ++cj) {
    const int c = (2*w+cj)*16 + l15;
    const float b2 = B2[c], gm = gvec[c];
#pragma unroll
    for (int rt=0; rt<4; ++rt) {
#pragma unroll
      for (int reg=0; reg<4; ++reg) {
        int row = rt*16 + 4*g + reg;
        float res = bf2f(bwinT[(size_t)(row0+row)*256 + c]) + (acc2[cj*4+rt][reg] + b2)*gm;
        xs[row*264 + c] = f2bf(res);
      }
    }
  }
  __syncthreads();

  // ---- bnp GEMM: wave w -> oct = w&3, row-tiles {w>>2, 2+(w>>2)} ----
  {
    const int oct = w & 3;
    f32x4 abn[2];
#pragma unroll
    for (int i=0;i<2;++i) abn[i] = (f32x4){0.f,0.f,0.f,0.f};
#pragma unroll
    for (int kt=0; kt<8; ++kt) {
      bf16x8 bfw = *reinterpret_cast<const bf16x8*>(Wbp + ((size_t)(oct*8+kt)*64 + l)*8);
#pragma unroll
      for (int i=0;i<2;++i) {
        const int rt = (w>>2) + 2*i;
        bf16x8 af = *reinterpret_cast<const bf16x8*>(&xs[(rt*16+l15)*264 + kt*32 + g*8]);
        abn[i] = __builtin_amdgcn_mfma_f32_16x16x32_bf16(af, bfw, abn[i], 0,0,0);
      }
    }

    float* red = reinterpret_cast<float*>(hs);
#pragma unroll
    for (int i=0;i<2;++i) {
      const int rt = (w>>2) + 2*i;
      float bv = bnpb[oct*16 + l15];
#pragma unroll
      for (int reg=0; reg<4; ++reg) {
        int lr = rt*16 + g*4 + reg;
        int p = (row0 + lr) % 121;
        int py=p/11, px=p-py*11;
        float ly=-1.f+0.2f*py, lx=-1.f+0.2f*px;
        float wg = expf(-(lx*lx+ly*ly)/0.32f) * inv_gsum;
        red[lr*64 + oct*16 + l15] = gelu_f(abn[i][reg] + bv) * wg;
      }
    }
  }
  __syncthreads();
  {
    float* red = reinterpret_cast<float*>(hs);
    int oc = t & 63, seg = t >> 6;
    float s = 0.f;
    int curn = (row0 + seg*8) / 121;
    for (int i=0;i<8;++i) {
      int row = seg*8 + i;
      int n = (row0 + row) / 121;
      if (n != curn) { atomicAdd(&bnv[curn*64 + oc], s); s = 0.f; curn = n; }
      s += red[row*64 + oc];
    }
    atomicAdd(&bnv[curn*64 + oc], s);
  }
}

// ---------------------------------------------------------------------------
// FiLM
// ---------------------------------------------------------------------------
__global__ __launch_bounds__(256) void film_k(
    const float* __restrict__ bn_vec, const float* __restrict__ ppb,
    const float* __restrict__ bemb, const float* __restrict__ fw,
    const float* __restrict__ fb, float* __restrict__ film)
{
  int n = blockIdx.x, t = threadIdx.x;
  __shared__ float cond[4][84];
  for (int i=t; i<4*84; i+=256) {
    int b = i/84, j = i%84;
    float v;
    if (j < 16) v = bemb[b*16 + j];
    else if (j == 16) { float p = ppb[((size_t)n*4+b)*2+0]; v = fminf(fmaxf(p*(1.f/1023.f),0.f),1.f); }
    else if (j == 17) { float p = ppb[((size_t)n*4+b)*2+1]; v = fminf(fmaxf(p*(1.f/1023.f),0.f),1.f); }
    else if (j == 18) { float p = ppb[((size_t)n*4+b)*2+0]; v = p - rintf(p); }
    else if (j == 19) { float p = ppb[((size_t)n*4+b)*2+1]; v = p - rintf(p); }
    else v = bn_vec[n*64 + (j-20)];
    cond[b][j] = v;
  }
  __syncthreads();
  int b = t >> 6, oc = t & 63;
  float s = fb[oc];
  for (int j=0;j<84;++j) s = fmaf(cond[b][j], fw[oc*84+j], s);
  film[((size_t)n*4+b)*64 + oc] = s;
}

// ---------------------------------------------------------------------------
// final per-map normalization
// ---------------------------------------------------------------------------
__global__ __launch_bounds__(256) void norm_k(float* __restrict__ out,
                                              const float* __restrict__ sums)
{
  int il = blockIdx.x;
  int p = blockIdx.y*256 + threadIdx.x;
  if (p < 961) {
    float inv = 1.f / fmaxf(sums[il], 1e-8f);
    out[(size_t)il*961 + p] *= inv;
  }
}

// ---------------------------------------------------------------------------
extern "C" void kernel_launch(void* const* d_in, const int* in_sizes, int n_in,
                              void* d_out, int out_size, void* d_ws, size_t ws_size,
                              hipStream_t stream)
{
  const float* bott = (const float*)d_in[0];
  const float* vis  = (const float*)d_in[1];
  const float* spv  = (const float*)d_in[2];
  const float* ppb  = (const float*)d_in[3];
  const float* ic1w = (const float*)d_in[4];  const float* ic1b = (const float*)d_in[5];
  const float* ic2w = (const float*)d_in[6];  const float* ic2b = (const float*)d_in[7];
  const float* ic3w = (const float*)d_in[8];  const float* ic3b = (const float*)d_in[9];
  const float* dww  = (const float*)d_in[10]; const float* dwb  = (const float*)d_in[11];
  const float* lnw  = (const float*)d_in[12]; const float* lnb  = (const float*)d_in[13];
  const float* pw1w = (const float*)d_in[14]; const float* pw1b = (const float*)d_in[15];
  const float* pw2w = (const float*)d_in[16]; const float* pw2b = (const float*)d_in[17];
  const float* cgam = (const float*)d_in[18];
  const float* bnpw = (const float*)d_in[19]; const float* bnpb = (const float*)d_in[20];
  const float* bemb = (const float*)d_in[21];
  const float* fw   = (const float*)d_in[22]; const float* fb   = (const float*)d_in[23];
  const float* d1w  = (const float*)d_in[24]; const float* d1b  = (const float*)d_in[25];
  const float* d2w  = (const float*)d_in[26]; const float* d2b  = (const float*)d_in[27];
  const float* d3w  = (const float*)d_in[28]; const float* d3b  = (const float*)d_in[29];
  float* out = (float*)d_out;

  char* ws = (char*)d_ws;

  const int CH = (ws_size >= 116500000ull) ? 256 : 128;

  // P2 regions (bf16; overlap P1 regions, stream-ordered)
  unsigned short* bwinT = (unsigned short*)(ws);
  unsigned short* dwout = (unsigned short*)(ws + 31719424);
  // P1 regions
  unsigned short* vwin = (unsigned short*)(ws);
  size_t o_bufA = (size_t)CH*139392;
  size_t o_bufB = o_bufA + (size_t)CH*123008;
  size_t o_bufI = o_bufB + (size_t)CH*123008;
  size_t p1end  = o_bufI + (size_t)CH*61504;
  unsigned short* bufA = (unsigned short*)(ws + o_bufA);
  unsigned short* bufB = (unsigned short*)(ws + o_bufB);
  unsigned short* bufI = (unsigned short*)(ws + o_bufI);
  size_t tail = (p1end > 63438848ull) ? p1end : 63438848ull;

  float* bnv  = (float*)(ws + tail);
  float* sums = (float*)(ws + tail + 131072);
  float* film = (float*)(ws + tail + 139264);
  unsigned short* W1p = (unsigned short*)(ws + tail + 663552);
  unsigned short* W2p = (unsigned short*)(ws + tail + 1187840);
  unsigned short* Wbp = (unsigned short*)(ws + tail + 1712128);
  unsigned short* Pc1 = (unsigned short*)(ws + tail + 1744896);
  unsigned short* Pc2 = (unsigned short*)(ws + tail + 1818624);
  unsigned short* Pc3 = (unsigned short*)(ws + tail + 1892352);
  unsigned short* Pd1 = (unsigned short*)(ws + tail + 1929216);
  unsigned short* Pd2 = (unsigned short*)(ws + tail + 1947648);
  float* dwwT = (float*)(ws + tail + 1966080);             // 50,176 B

  // ---- combined weight packing (1 launch) + dw transpose ----
  {
    PackJobs J;
    const float* srcs[8] = {pw1w, pw2w, bnpw, ic1w, ic2w, ic3w, d1w, d2w};
    unsigned short* dsts[8] = {W1p, W2p, Wbp, Pc1, Pc2, Pc3, Pd1, Pd2};
    int ntns[8] = {64,16,4, 4,4,2, 2,2};
    int ntks[8] = {8,32,8, 18,18,18, 9,9};
    int Ks[8]   = {256,1024,256, 64,64,64, 32,32};
    int convs[8]= {0,0,0, 1,1,1, 1,1};
    int base = 0;
    for (int i=0;i<8;++i) {
      J.src[i]=srcs[i]; J.dst[i]=dsts[i]; J.ntn[i]=ntns[i]; J.ntk[i]=ntks[i];
      J.K[i]=Ks[i]; J.conv[i]=convs[i]; J.base[i]=base;
      base += (ntns[i]*ntks[i]*64 + 255)/256;
    }
    packall_k<<<base,256,0,stream>>>(J);
  }
  dwt_k<<<49,256,0,stream>>>(dww, dwwT);

  hipMemsetAsync(ws + tail, 0, 139264, stream);  // bnv + sums

  float gs = 0.f;
  for (int py=0; py<11; ++py) for (int px=0; px<11; ++px) {
    float ly=-1.f+0.2f*py, lx=-1.f+0.2f*px;
    gs += expf(-(lx*lx+ly*ly)/0.32f);
  }
  const float inv_gsum = 1.f/gs;

  // ---- Phase 2: bottleneck path -> bn_vec ----
  dwfused4_k<<<dim3(512,4),256,0,stream>>>(bott, spv, dwwT, dwb, bwinT, dwout);
  cnx_mfma3_k<<<968,512,0,stream>>>(dwout, lnw,lnb, W1p,pw1b, W2p,pw2b, cgam,
                                    bwinT, Wbp, bnpb, bnv, inv_gsum);
  film_k<<<512,256,0,stream>>>(bnv, ppb, bemb, fw, fb, film);

  // ---- Phase 1+3: intrinsic chain + decoder ----
  for (int n0 = 0; n0 < 512; n0 += CH) {
    extvwin_k<<<dim3(CH,5),256,0,stream>>>(vis, spv + n0*2, vwin);
    convmf_k<64,64,18,1,true ,false><<<dim3(CH,4),256,0,stream>>>(vwin, Pc1, ic1b, bufA, nullptr,0, nullptr,nullptr,nullptr,nullptr);
    convmf_k<64,64,18,0,true ,false><<<dim3(CH,4),256,0,stream>>>(bufA, Pc2, ic2b, bufB, nullptr,0, nullptr,nullptr,nullptr,nullptr);
    convmf_k<64,32,18,0,false,false><<<dim3(CH,4),256,0,stream>>>(bufB, Pc3, ic3b, bufI, nullptr,0, nullptr,nullptr,nullptr,nullptr);
    for (int s = 0; s < CH/64; ++s) {
      int nb0 = n0*4 + s*256;
      convmf_k<32,32,9,2,true,false><<<dim3(256,4),256,0,stream>>>(bufI, Pd1, d1b, bufB,
          film + (size_t)nb0*64, s*256, nullptr,nullptr,nullptr,nullptr);
      convmf_k<32,32,9,0,true,true ><<<dim3(256,4),256,0,stream>>>(bufB, Pd2, d2b, nullptr,
          nullptr,0, out + (size_t)nb0*961, sums + nb0, d3w, d3b);
    }
  }
  norm_k<<<dim3(2048,4),256,0,stream>>>(out, sums);
}

// Round 9
// 774.240 us; speedup vs baseline: 10.2883x; 1.1356x over previous
//
#include <hip/hip_runtime.h>
#include <cstdint>
#include <cstddef>
#include <cmath>

#define DEV __device__ __forceinline__

typedef __attribute__((ext_vector_type(8))) short bf16x8;
typedef __attribute__((ext_vector_type(4))) float f32x4;

// Abramowitz-Stegun 7.1.26 erf approx, |abs err| <= 1.5e-7
DEV float erf_fast(float x){
  float ax = fabsf(x);
  float t = __builtin_amdgcn_rcpf(fmaf(0.3275911f, ax, 1.f));
  float p = t*fmaf(t, fmaf(t, fmaf(t, fmaf(t, 1.061405429f, -1.453152027f),
             1.421413741f), -0.284496736f), 0.254829592f);
  float e = __expf(-ax*ax);
  float r = fmaf(-p, e, 1.f);
  return x >= 0.f ? r : -r;
}
DEV float gelu_f(float x){ return 0.5f*x*(1.0f + erf_fast(x*0.7071067811865476f)); }
DEV float softplus_f(float x){ return fmaxf(x,0.f) + log1pf(expf(-fabsf(x))); }
DEV unsigned short f2bf(float x){
  unsigned u = __float_as_uint(x);
  unsigned r = (u + 0x7fffu + ((u>>16)&1u)) >> 16;
  return (unsigned short)r;
}
DEV float bf2f(unsigned short h){
  unsigned u = ((unsigned)h) << 16;
  return __uint_as_float(u);
}

// ---------------------------------------------------------------------------
// Combined weight packing: 8 jobs in one launch.
// ---------------------------------------------------------------------------
struct PackJobs {
  const float* src[8];
  unsigned short* dst[8];
  int ntn[8], ntk[8], K[8], conv[8], base[8];
};

__global__ __launch_bounds__(256) void packall_k(PackJobs J)
{
  int blk = blockIdx.x;
  int j = 0;
#pragma unroll
  for (int i=1;i<8;++i) if (blk >= J.base[i]) j = i;
  int tid = (blk - J.base[j])*256 + threadIdx.x;
  const int ntk = J.ntk[j], K = J.K[j];
  int total = J.ntn[j]*ntk*64;
  if (tid >= total) return;
  int lane = tid & 63;
  int f = tid >> 6;
  int kt = f % ntk, nt = f / ntk;
  int row = nt*16 + (lane & 15);
  int k0 = kt*32 + (lane >> 4)*8;
  const float* src = J.src[j];
  unsigned short h[8];
  if (J.conv[j]) {
    const int Cin = K;
#pragma unroll
    for (int q=0;q<8;++q) {
      int k = k0 + q;
      int s = k / Cin;
      int ic = k - s*Cin;
      h[q] = f2bf(src[((size_t)row*Cin + ic)*9 + s]);
    }
  } else {
#pragma unroll
    for (int q=0;q<8;++q) h[q] = f2bf(src[(size_t)row*K + k0 + q]);
  }
  uint4 pk;
  pk.x = (unsigned)h[0] | ((unsigned)h[1]<<16);
  pk.y = (unsigned)h[2] | ((unsigned)h[3]<<16);
  pk.z = (unsigned)h[4] | ((unsigned)h[5]<<16);
  pk.w = (unsigned)h[6] | ((unsigned)h[7]<<16);
  *reinterpret_cast<uint4*>(J.dst[j] + (size_t)tid*8) = pk;
}

// dw weight transpose: wT[k][ch] = w[ch][k]  (49 x 256)
__global__ __launch_bounds__(256) void dwt_k(const float* __restrict__ w,
                                             float* __restrict__ wT)
{
  int k = blockIdx.x;
  int ch = threadIdx.x;
  wT[k*256 + ch] = w[(size_t)ch*49 + k];
}

// ---------------------------------------------------------------------------
// Extract clamped 33x33 vis windows (incl. conv zero ring) -> bf16 NHWC
// ---------------------------------------------------------------------------
__global__ __launch_bounds__(256) void extvwin_k(const float* __restrict__ vis,
                                                 const float* __restrict__ spv,
                                                 unsigned short* __restrict__ vwin)
{
  int il = blockIdx.x;
  int p = blockIdx.y*256 + threadIdx.x;
  if (p >= 1089) return;
  int wy = p/33, wx = p%33;
  unsigned short* dst = vwin + ((size_t)il*1089 + p)*64;
  if (wy==0 || wy==32 || wx==0 || wx==32) {
    uint4 z = {0,0,0,0};
#pragma unroll
    for (int q=0;q<8;++q) *reinterpret_cast<uint4*>(dst + q*8) = z;
    return;
  }
  int cx = (int)rintf(spv[il*2+0]);
  int cy = (int)rintf(spv[il*2+1]);
  int gy = min(max(cy + wy - 16, 0), 1023);
  int gx = min(max(cx + wx - 16, 0), 1023);
  const float* sp = vis + (size_t)gy*1024 + gx;
  unsigned short h[64];
#pragma unroll
  for (int c=0;c<64;++c) h[c] = f2bf(sp[(size_t)c<<20]);
#pragma unroll
  for (int q=0;q<8;++q) {
    uint4 pk;
    pk.x = (unsigned)h[q*8+0] | ((unsigned)h[q*8+1]<<16);
    pk.y = (unsigned)h[q*8+2] | ((unsigned)h[q*8+3]<<16);
    pk.z = (unsigned)h[q*8+4] | ((unsigned)h[q*8+5]<<16);
    pk.w = (unsigned)h[q*8+6] | ((unsigned)h[q*8+7]<<16);
    *reinterpret_cast<uint4*>(dst + q*8) = pk;
  }
}

// ---------------------------------------------------------------------------
// MFMA implicit-GEMM 3x3 conv (intrinsic chain only now).
// MODE 0: src NHWC [item][961][CIN].  MODE 1: 33x33 window buffer.
// ---------------------------------------------------------------------------
template<int CIN, int COUT, int NKT, int MODE, bool FGELU>
__global__ __launch_bounds__(256,3) void convmf_k(
    const unsigned short* __restrict__ src,
    const unsigned short* __restrict__ Wp,
    const float* __restrict__ Bv,
    unsigned short* __restrict__ out)
{
  constexpr int NOCT = COUT/16;
  constexpr int NSLOT = CIN/8;
  constexpr int SWM = NSLOT-1;
  const int item = blockIdx.x;
  const int y0 = blockIdx.y*8;
  const int t = threadIdx.x;
  const int w = t>>6, l = t&63, g = l>>4, l15 = l&15;

  __shared__ __align__(16) unsigned short lds[330*CIN];

  for (int u = t; u < 330*NSLOT; u += 256) {
    int slot = u & SWM;
    int rowi = u / NSLOT;
    int r = rowi / 33, col = rowi - r*33;
    uint4 val = {0,0,0,0};
    if (MODE==1) {
      int gr = y0 + r;
      if (gr < 33)
        val = *reinterpret_cast<const uint4*>(src + ((size_t)item*1089 + gr*33 + col)*CIN + slot*8);
    } else {
      int y = y0 + r - 1, x = col - 1;
      if ((unsigned)y < 31u && (unsigned)x < 31u)
        val = *reinterpret_cast<const uint4*>(src + ((size_t)item*961 + y*31 + x)*CIN + slot*8);
    }
    int ds = slot ^ (rowi & SWM);
    *reinterpret_cast<uint4*>(&lds[rowi*CIN + ds*8]) = val;
  }
  __syncthreads();

  int pbase[4], gpos[4]; bool pvalid[4];
#pragma unroll
  for (int pt=0; pt<4; ++pt) {
    int p = (w*4+pt)*16 + l15;
    int pc = min(p, 247);
    int py = pc/31, px = pc - py*31;
    pbase[pt] = py*33 + px;
    gpos[pt] = y0*31 + p;
    pvalid[pt] = (p < 248) && (gpos[pt] < 961);
  }

  f32x4 acc[NOCT][4];
#pragma unroll
  for (int o=0;o<NOCT;++o)
#pragma unroll
    for (int pt=0;pt<4;++pt) acc[o][pt] = (f32x4){0.f,0.f,0.f,0.f};

  bf16x8 wcur[NOCT];
#pragma unroll
  for (int o=0;o<NOCT;++o)
    wcur[o] = *reinterpret_cast<const bf16x8*>(Wp + ((size_t)(o*NKT)*64 + l)*8);

  for (int kt=0; kt<NKT; ++kt) {
    bf16x8 wnxt[NOCT];
    if (kt+1 < NKT) {
#pragma unroll
      for (int o=0;o<NOCT;++o)
        wnxt[o] = *reinterpret_cast<const bf16x8*>(Wp + ((size_t)(o*NKT+kt+1)*64 + l)*8);
    }
    int k0 = kt*32 + g*8;
    int s = k0 / CIN;
    int icg = (k0 - s*CIN) >> 3;
    int roff = (s/3)*33 + (s - (s/3)*3);
    bf16x8 bf[4];
#pragma unroll
    for (int pt=0; pt<4; ++pt) {
      int rowi = pbase[pt] + roff;
      int ds = icg ^ (rowi & SWM);
      bf[pt] = *reinterpret_cast<const bf16x8*>(&lds[rowi*CIN + ds*8]);
    }
#pragma unroll
    for (int o=0; o<NOCT; ++o) {
#pragma unroll
      for (int pt=0; pt<4; ++pt)
        acc[o][pt] = __builtin_amdgcn_mfma_f32_16x16x32_bf16(wcur[o], bf[pt], acc[o][pt], 0,0,0);
    }
    if (kt+1 < NKT) {
#pragma unroll
      for (int o=0;o<NOCT;++o) wcur[o] = wnxt[o];
    }
  }

#pragma unroll
  for (int o=0; o<NOCT; ++o) {
    float4 bv4 = *reinterpret_cast<const float4*>(Bv + o*16 + g*4);
#pragma unroll
    for (int pt=0; pt<4; ++pt) {
      if (!pvalid[pt]) continue;
      float v0 = acc[o][pt][0] + bv4.x;
      float v1 = acc[o][pt][1] + bv4.y;
      float v2 = acc[o][pt][2] + bv4.z;
      float v3 = acc[o][pt][3] + bv4.w;
      if (FGELU) { v0=gelu_f(v0); v1=gelu_f(v1); v2=gelu_f(v2); v3=gelu_f(v3); }
      uint2 pk;
      pk.x = (unsigned)f2bf(v0) | ((unsigned)f2bf(v1)<<16);
      pk.y = (unsigned)f2bf(v2) | ((unsigned)f2bf(v3)<<16);
      *reinterpret_cast<uint2*>(out + ((size_t)item*961 + gpos[pt])*COUT + o*16 + g*4) = pk;
    }
  }
}

// ---------------------------------------------------------------------------
// Fused decoder: FiLM+gelu staging -> dec1(3x3)+gelu -> dec2(3x3)+gelu ->
// dec3(1x1)+softplus+sum, all in LDS. Block = (nb item, 8-row strip).
// LDS A: 12x33x32 modulated input; LDS B: 10x33x32 dec1 output (halo rows).
// ---------------------------------------------------------------------------
__global__ __launch_bounds__(256,3) void decfused_k(
    const unsigned short* __restrict__ intc,
    const unsigned short* __restrict__ Wp1, const float* __restrict__ B1,
    const unsigned short* __restrict__ Wp2, const float* __restrict__ B2,
    const float* __restrict__ film,
    const float* __restrict__ w3, const float* __restrict__ b3,
    float* __restrict__ outf, float* __restrict__ sums)
{
  const int item = blockIdx.x;
  const int y0 = blockIdx.y*8;
  const int t = threadIdx.x;
  const int w = t>>6, l = t&63, g = l>>4, l15 = l&15;

  __shared__ __align__(16) unsigned short ldsA[12*33*32];
  __shared__ __align__(16) unsigned short ldsB[10*33*32];

  const int sit = item >> 2;
  const float* frow = film + (size_t)item*64;

  // zero B (halo rows / pad cols stay zero)
  for (int u=t; u<1320; u+=256)
    *reinterpret_cast<uint4*>(ldsB + u*8) = (uint4){0,0,0,0};

  // stage A with FiLM + gelu
  for (int u=t; u<1584; u+=256) {
    int slot = u & 3;
    int rowi = u >> 2;            // r*33+col, r in 0..11
    int r = rowi/33, col = rowi - r*33;
    int y = y0 + r - 2, x = col - 1;
    uint4 val = {0,0,0,0};
    if ((unsigned)y < 31u && (unsigned)x < 31u) {
      val = *reinterpret_cast<const uint4*>(intc + ((size_t)sit*961 + y*31 + x)*32 + slot*8);
      int c0 = slot*8;
      float4 g0 = *reinterpret_cast<const float4*>(frow + c0);
      float4 g1 = *reinterpret_cast<const float4*>(frow + c0 + 4);
      float4 b0 = *reinterpret_cast<const float4*>(frow + 32 + c0);
      float4 b1 = *reinterpret_cast<const float4*>(frow + 32 + c0 + 4);
      unsigned short x8[8] = {
        (unsigned short)(val.x&0xffff),(unsigned short)(val.x>>16),
        (unsigned short)(val.y&0xffff),(unsigned short)(val.y>>16),
        (unsigned short)(val.z&0xffff),(unsigned short)(val.z>>16),
        (unsigned short)(val.w&0xffff),(unsigned short)(val.w>>16)};
      unsigned short o8[8];
      o8[0]=f2bf(gelu_f(fmaf(bf2f(x8[0]), 1.f+g0.x, b0.x)));
      o8[1]=f2bf(gelu_f(fmaf(bf2f(x8[1]), 1.f+g0.y, b0.y)));
      o8[2]=f2bf(gelu_f(fmaf(bf2f(x8[2]), 1.f+g0.z, b0.z)));
      o8[3]=f2bf(gelu_f(fmaf(bf2f(x8[3]), 1.f+g0.w, b0.w)));
      o8[4]=f2bf(gelu_f(fmaf(bf2f(x8[4]), 1.f+g1.x, b1.x)));
      o8[5]=f2bf(gelu_f(fmaf(bf2f(x8[5]), 1.f+g1.y, b1.y)));
      o8[6]=f2bf(gelu_f(fmaf(bf2f(x8[6]), 1.f+g1.z, b1.z)));
      o8[7]=f2bf(gelu_f(fmaf(bf2f(x8[7]), 1.f+g1.w, b1.w)));
      val.x = (unsigned)o8[0] | ((unsigned)o8[1]<<16);
      val.y = (unsigned)o8[2] | ((unsigned)o8[3]<<16);
      val.z = (unsigned)o8[4] | ((unsigned)o8[5]<<16);
      val.w = (unsigned)o8[6] | ((unsigned)o8[7]<<16);
    }
    int ds = slot ^ (rowi & 3);
    *reinterpret_cast<uint4*>(&ldsA[rowi*32 + ds*8]) = val;
  }
  __syncthreads();

  // ---- dec1: 10 rows x 31 cols (rows y0-1..y0+8), gelu, -> ldsB ----
  {
    int pbase[5], rowB[5]; bool pv[5];
#pragma unroll
    for (int pt=0; pt<5; ++pt) {
      int pd = (w*5+pt)*16 + l15;
      int pc = min(pd, 309);
      int ry = pc/31, rx = pc - ry*31;
      pbase[pt] = ry*33 + rx;
      rowB[pt] = ry*33 + rx + 1;
      int gy = y0 - 1 + ry;
      pv[pt] = (pd < 310) && ((unsigned)gy < 31u);
    }
    f32x4 a1[2][5];
#pragma unroll
    for (int o=0;o<2;++o)
#pragma unroll
      for (int pt=0;pt<5;++pt) a1[o][pt] = (f32x4){0.f,0.f,0.f,0.f};

    for (int kt=0; kt<9; ++kt) {
      int roff = (kt/3)*33 + (kt - (kt/3)*3);
      bf16x8 bf[5];
#pragma unroll
      for (int pt=0; pt<5; ++pt) {
        int rowi = pbase[pt] + roff;
        int ds = g ^ (rowi & 3);
        bf[pt] = *reinterpret_cast<const bf16x8*>(&ldsA[rowi*32 + ds*8]);
      }
#pragma unroll
      for (int o=0; o<2; ++o) {
        bf16x8 af = *reinterpret_cast<const bf16x8*>(Wp1 + ((size_t)(o*9+kt)*64 + l)*8);
#pragma unroll
        for (int pt=0; pt<5; ++pt)
          a1[o][pt] = __builtin_amdgcn_mfma_f32_16x16x32_bf16(af, bf[pt], a1[o][pt], 0,0,0);
      }
    }
#pragma unroll
    for (int o=0; o<2; ++o) {
      float4 bv4 = *reinterpret_cast<const float4*>(B1 + o*16 + g*4);
      int sl = o*2 + (g>>1);
#pragma unroll
      for (int pt=0; pt<5; ++pt) {
        if (!pv[pt]) continue;
        float v0 = gelu_f(a1[o][pt][0] + bv4.x);
        float v1 = gelu_f(a1[o][pt][1] + bv4.y);
        float v2 = gelu_f(a1[o][pt][2] + bv4.z);
        float v3 = gelu_f(a1[o][pt][3] + bv4.w);
        uint2 pk;
        pk.x = (unsigned)f2bf(v0) | ((unsigned)f2bf(v1)<<16);
        pk.y = (unsigned)f2bf(v2) | ((unsigned)f2bf(v3)<<16);
        int phys = sl ^ (rowB[pt] & 3);
        *reinterpret_cast<uint2*>(&ldsB[rowB[pt]*32 + phys*8 + (g&1)*4]) = pk;
      }
    }
  }
  __syncthreads();

  // ---- dec2 + gelu + dec3(1x1) + softplus + per-map sum ----
  float bsum = 0.f;
  {
    int pbase[4], gpos[4]; bool pv[4];
#pragma unroll
    for (int pt=0; pt<4; ++pt) {
      int pd = (w*4+pt)*16 + l15;
      int pc = min(pd, 247);
      int py = pc/31, px = pc - py*31;
      pbase[pt] = py*33 + px;
      gpos[pt] = y0*31 + pd;
      pv[pt] = (pd < 248) && (gpos[pt] < 961);
    }
    f32x4 a2[2][4];
#pragma unroll
    for (int o=0;o<2;++o)
#pragma unroll
      for (int pt=0;pt<4;++pt) a2[o][pt] = (f32x4){0.f,0.f,0.f,0.f};

    for (int kt=0; kt<9; ++kt) {
      int roff = (kt/3)*33 + (kt - (kt/3)*3);
      bf16x8 bf[4];
#pragma unroll
      for (int pt=0; pt<4; ++pt) {
        int rowi = pbase[pt] + roff;
        int ds = g ^ (rowi & 3);
        bf[pt] = *reinterpret_cast<const bf16x8*>(&ldsB[rowi*32 + ds*8]);
      }
#pragma unroll
      for (int o=0; o<2; ++o) {
        bf16x8 af = *reinterpret_cast<const bf16x8*>(Wp2 + ((size_t)(o*9+kt)*64 + l)*8);
#pragma unroll
        for (int pt=0; pt<4; ++pt)
          a2[o][pt] = __builtin_amdgcn_mfma_f32_16x16x32_bf16(af, bf[pt], a2[o][pt], 0,0,0);
      }
    }

    float w3r[8];
#pragma unroll
    for (int o=0;o<2;++o) {
      float4 wv = *reinterpret_cast<const float4*>(w3 + o*16 + g*4);
      w3r[o*4+0]=wv.x; w3r[o*4+1]=wv.y; w3r[o*4+2]=wv.z; w3r[o*4+3]=wv.w;
    }
    float b3v = b3[0];
#pragma unroll
    for (int pt=0; pt<4; ++pt) {
      float part = 0.f;
#pragma unroll
      for (int o=0; o<2; ++o) {
        float4 bv4 = *reinterpret_cast<const float4*>(B2 + o*16 + g*4);
        float v0 = gelu_f(a2[o][pt][0] + bv4.x);
        float v1 = gelu_f(a2[o][pt][1] + bv4.y);
        float v2 = gelu_f(a2[o][pt][2] + bv4.z);
        float v3 = gelu_f(a2[o][pt][3] + bv4.w);
        part += v0*w3r[o*4+0] + v1*w3r[o*4+1] + v2*w3r[o*4+2] + v3*w3r[o*4+3];
      }
      part += __shfl_xor(part, 16);
      part += __shfl_xor(part, 32);
      float sp = softplus_f(part + b3v);
      if (pv[pt] && g==0) {
        outf[(size_t)item*961 + gpos[pt]] = sp;
        bsum += sp;
      }
    }
  }
  // block reduce into sums[item]
  {
    float* redf = reinterpret_cast<float*>(ldsA);
    redf[t] = bsum;
    __syncthreads();
    for (int off=128; off>0; off>>=1) {
      if (t < off) redf[t] += redf[t+off];
      __syncthreads();
    }
    if (t==0) atomicAdd(&sums[item], redf[0]);
  }
}

// ---------------------------------------------------------------------------
// Fused bottleneck-window gather + depthwise 7x7, channel-sliced, row-reuse.
// ---------------------------------------------------------------------------
__global__ __launch_bounds__(256,4) void dwfused4_k(
    const float* __restrict__ bott, const float* __restrict__ spv,
    const float* __restrict__ wT, const float* __restrict__ b,
    unsigned short* __restrict__ bwinT, unsigned short* __restrict__ dwout)
{
  const int n = blockIdx.x, cs = blockIdx.y*64, t = threadIdx.x;
  __shared__ float tile[121*66];

  float pxf = fminf(fmaxf(spv[n*2+0]*0.25f, 0.f), 255.f);
  float pyf = fminf(fmaxf(spv[n*2+1]*0.25f, 0.f), 255.f);
  int cx = (int)rintf(pxf), cy = (int)rintf(pyf);

  for (int idx=t; idx<121*32; idx+=256) {
    int j = idx/121, p = idx - j*121;
    int y = p/11, x = p - y*11;
    int gy = min(max(cy + y - 5, 0), 255);
    int gx = min(max(cx + x - 5, 0), 255);
    const float* s0 = bott + ((size_t)(cs+2*j)<<16) + (gy<<8) + gx;
    *reinterpret_cast<float2*>(&tile[p*66 + 2*j]) = (float2){s0[0], s0[65536]};
  }
  __syncthreads();

  for (int idx=t; idx<121*64; idx+=256) {
    int p = idx >> 6, c = idx & 63;
    bwinT[((size_t)n*121 + p)*256 + cs + c] = f2bf(tile[p*66 + c]);
  }

  const int c = t & 63, ph = t >> 6;
  const int ch = cs + c;
  const float bias = b[ch];

  for (int y=ph; y<11; y+=4) {
    float acc[11];
#pragma unroll
    for (int x=0;x<11;++x) acc[x] = bias;
#pragma unroll
    for (int dy=0; dy<7; ++dy) {
      int yy = y + dy - 3;
      if ((unsigned)yy < 11u) {
        float r[11];
#pragma unroll
        for (int k=0;k<11;++k) r[k] = tile[(yy*11+k)*66 + c];
        float w7[7];
#pragma unroll
        for (int j=0;j<7;++j) w7[j] = wT[(dy*7+j)*256 + ch];
#pragma unroll
        for (int x=0;x<11;++x) {
#pragma unroll
          for (int dx=0;dx<7;++dx) {
            int xx = x + dx - 3;
            if (xx >= 0 && xx < 11)
              acc[x] = fmaf(r[xx], w7[dx], acc[x]);
          }
        }
      }
    }
#pragma unroll
    for (int x=0;x<11;++x)
      dwout[((size_t)n*121 + y*11 + x)*256 + ch] = f2bf(acc[x]);
  }
}

// ---------------------------------------------------------------------------
// Fused ConvNeXt MLP + bnp head, bf16 MFMA. 512 threads / 8 waves, 64 rows.
// ---------------------------------------------------------------------------
__global__ __launch_bounds__(512,4) void cnx_mfma3_k(
    const unsigned short* __restrict__ xin,
    const float* __restrict__ lnw, const float* __restrict__ lnb,
    const unsigned short* __restrict__ W1p, const float* __restrict__ B1,
    const unsigned short* __restrict__ W2p, const float* __restrict__ B2,
    const float* __restrict__ gvec,
    const unsigned short* __restrict__ bwinT,
    const unsigned short* __restrict__ Wbp, const float* __restrict__ bnpb,
    float* __restrict__ bnv, float inv_gsum)
{
  const int t = threadIdx.x;
  const int w = t >> 6;
  const int l = t & 63;
  const int g = l >> 4;
  const int l15 = l & 15;
  const int row0 = blockIdx.x * 64;

  __shared__ __align__(16) unsigned short xs[64*264];
  __shared__ __align__(16) unsigned short hs[64*136];

  {
    const int rl = t >> 3, q = t & 7;
    const unsigned short* xr = xin + (size_t)(row0+rl)*256 + q*32;
    float xv[32]; float s = 0.f, s2 = 0.f;
#pragma unroll
    for (int i=0;i<32;i+=8){
      uint4 v = *reinterpret_cast<const uint4*>(xr+i);
      unsigned short xh[8] = {
        (unsigned short)(v.x&0xffff),(unsigned short)(v.x>>16),
        (unsigned short)(v.y&0xffff),(unsigned short)(v.y>>16),
        (unsigned short)(v.z&0xffff),(unsigned short)(v.z>>16),
        (unsigned short)(v.w&0xffff),(unsigned short)(v.w>>16)};
#pragma unroll
      for (int j=0;j<8;++j){
        float f = bf2f(xh[j]);
        xv[i+j] = f; s += f; s2 += f*f;
      }
    }
    s += __shfl_xor(s,1); s2 += __shfl_xor(s2,1);
    s += __shfl_xor(s,2); s2 += __shfl_xor(s2,2);
    s += __shfl_xor(s,4); s2 += __shfl_xor(s2,4);
    float mu = s*(1.f/256.f);
    float rstd = rsqrtf(s2*(1.f/256.f) - mu*mu + 1e-6f);
#pragma unroll
    for (int i=0;i<32;i+=8){
      int c = q*32 + i;
      float4 w0 = *reinterpret_cast<const float4*>(lnw+c);
      float4 w1 = *reinterpret_cast<const float4*>(lnw+c+4);
      float4 b0 = *reinterpret_cast<const float4*>(lnb+c);
      float4 b1 = *reinterpret_cast<const float4*>(lnb+c+4);
      unsigned short h[8];
      h[0]=f2bf(fmaf((xv[i+0]-mu)*rstd, w0.x, b0.x));
      h[1]=f2bf(fmaf((xv[i+1]-mu)*rstd, w0.y, b0.y));
      h[2]=f2bf(fmaf((xv[i+2]-mu)*rstd, w0.z, b0.z));
      h[3]=f2bf(fmaf((xv[i+3]-mu)*rstd, w0.w, b0.w));
      h[4]=f2bf(fmaf((xv[i+4]-mu)*rstd, w1.x, b1.x));
      h[5]=f2bf(fmaf((xv[i+5]-mu)*rstd, w1.y, b1.y));
      h[6]=f2bf(fmaf((xv[i+6]-mu)*rstd, w1.z, b1.z));
      h[7]=f2bf(fmaf((xv[i+7]-mu)*rstd, w1.w, b1.w));
      uint4 pk;
      pk.x = (unsigned)h[0] | ((unsigned)h[1]<<16);
      pk.y = (unsigned)h[2] | ((unsigned)h[3]<<16);
      pk.z = (unsigned)h[4] | ((unsigned)h[5]<<16);
      pk.w = (unsigned)h[6] | ((unsigned)h[7]<<16);
      *reinterpret_cast<uint4*>(&xs[rl*264 + c]) = pk;
    }
  }
  __syncthreads();

  f32x4 acc2[8];
#pragma unroll
  for (int i=0;i<8;++i) acc2[i] = (f32x4){0.f,0.f,0.f,0.f};

  for (int hc=0; hc<8; ++hc) {
    const int ht = hc*8 + w;
    f32x4 acc1[4];
#pragma unroll
    for (int i=0;i<4;++i) acc1[i] = (f32x4){0.f,0.f,0.f,0.f};

#pragma unroll
    for (int kt=0; kt<8; ++kt) {
      bf16x8 xf[4];
#pragma unroll
      for (int rt=0; rt<4; ++rt)
        xf[rt] = *reinterpret_cast<const bf16x8*>(&xs[(rt*16+l15)*264 + kt*32 + g*8]);
      bf16x8 wf = *reinterpret_cast<const bf16x8*>(W1p + ((size_t)(ht*8+kt)*64 + l)*8);
#pragma unroll
      for (int rt=0; rt<4; ++rt)
        acc1[rt] = __builtin_amdgcn_mfma_f32_16x16x32_bf16(wf, xf[rt], acc1[rt], 0,0,0);
    }
    {
      const int hb = hc*128 + w*16 + 4*g;
      float4 b1v = *reinterpret_cast<const float4*>(B1 + hb);
#pragma unroll
      for (int rt=0; rt<4; ++rt) {
        unsigned short h0 = f2bf(gelu_f(acc1[rt][0] + b1v.x));
        unsigned short h1 = f2bf(gelu_f(acc1[rt][1] + b1v.y));
        unsigned short h2 = f2bf(gelu_f(acc1[rt][2] + b1v.z));
        unsigned short h3 = f2bf(gelu_f(acc1[rt][3] + b1v.w));
        uint2 pk;
        pk.x = (unsigned)h0 | ((unsigned)h1<<16);
        pk.y = (unsigned)h2 | ((unsigned)h3<<16);
        *reinterpret_cast<uint2*>(&hs[(rt*16+l15)*136 + w*16 + 4*g]) = pk;
      }
    }
    __syncthreads();
#pragma unroll
    for (int kt=0; kt<4; ++kt) {
      bf16x8 hf[4];
#pragma unroll
      for (int rt=0; rt<4; ++rt)
        hf[rt] = *reinterpret_cast<const bf16x8*>(&hs[(rt*16+l15)*136 + kt*32 + g*8]);
#pragma unroll
      for (int cj=0; cj<2; ++cj) {
        const int ct = 2*w + cj;
        bf16x8 wf = *reinterpret_cast<const bf16x8*>(W2p + ((size_t)(ct*32 + hc*4 + kt)*64 + l)*8);
#pragma unroll
        for (int rt=0; rt<4; ++rt)
          acc2[cj*4+rt] = __builtin_amdgcn_mfma_f32_16x16x32_bf16(hf[rt], wf, acc2[cj*4+rt], 0,0,0);
      }
    }
    __syncthreads();
  }

#pragma unroll
  for (int cj=0; cj<2; ++cj) {
    const int c = (2*w+cj)*16 + l15;
    const float b2 = B2[c], gm = gvec[c];
#pragma unroll
    for (int rt=0; rt<4; ++rt) {
#pragma unroll
      for (int reg=0; reg<4; ++reg) {
        int row = rt*16 + 4*g + reg;
        float res = bf2f(bwinT[(size_t)(row0+row)*256 + c]) + (acc2[cj*4+rt][reg] + b2)*gm;
        xs[row*264 + c] = f2bf(res);
      }
    }
  }
  __syncthreads();

  {
    const int oct = w & 3;
    f32x4 abn[2];
#pragma unroll
    for (int i=0;i<2;++i) abn[i] = (f32x4){0.f,0.f,0.f,0.f};
#pragma unroll
    for (int kt=0; kt<8; ++kt) {
      bf16x8 bfw = *reinterpret_cast<const bf16x8*>(Wbp + ((size_t)(oct*8+kt)*64 + l)*8);
#pragma unroll
      for (int i=0;i<2;++i) {
        const int rt = (w>>2) + 2*i;
        bf16x8 af = *reinterpret_cast<const bf16x8*>(&xs[(rt*16+l15)*264 + kt*32 + g*8]);
        abn[i] = __builtin_amdgcn_mfma_f32_16x16x32_bf16(af, bfw, abn[i], 0,0,0);
      }
    }

    float* red = reinterpret_cast<float*>(hs);
#pragma unroll
    for (int i=0;i<2;++i) {
      const int rt = (w>>2) + 2*i;
      float bv = bnpb[oct*16 + l15];
#pragma unroll
      for (int reg=0; reg<4; ++reg) {
        int lr = rt*16 + g*4 + reg;
        int p = (row0 + lr) % 121;
        int py=p/11, px=p-py*11;
        float ly=-1.f+0.2f*py, lx=-1.f+0.2f*px;
        float wg = __expf(-(lx*lx+ly*ly)/0.32f) * inv_gsum;
        red[lr*64 + oct*16 + l15] = gelu_f(abn[i][reg] + bv) * wg;
      }
    }
  }
  __syncthreads();
  {
    float* red = reinterpret_cast<float*>(hs);
    int oc = t & 63, seg = t >> 6;
    float s = 0.f;
    int curn = (row0 + seg*8) / 121;
    for (int i=0;i<8;++i) {
      int row = seg*8 + i;
      int n = (row0 + row) / 121;
      if (n != curn) { atomicAdd(&bnv[curn*64 + oc], s); s = 0.f; curn = n; }
      s += red[row*64 + oc];
    }
    atomicAdd(&bnv[curn*64 + oc], s);
  }
}

// ---------------------------------------------------------------------------
// FiLM
// ---------------------------------------------------------------------------
__global__ __launch_bounds__(256) void film_k(
    const float* __restrict__ bn_vec, const float* __restrict__ ppb,
    const float* __restrict__ bemb, const float* __restrict__ fw,
    const float* __restrict__ fb, float* __restrict__ film)
{
  int n = blockIdx.x, t = threadIdx.x;
  __shared__ float cond[4][84];
  for (int i=t; i<4*84; i+=256) {
    int b = i/84, j = i%84;
    float v;
    if (j < 16) v = bemb[b*16 + j];
    else if (j == 16) { float p = ppb[((size_t)n*4+b)*2+0]; v = fminf(fmaxf(p*(1.f/1023.f),0.f),1.f); }
    else if (j == 17) { float p = ppb[((size_t)n*4+b)*2+1]; v = fminf(fmaxf(p*(1.f/1023.f),0.f),1.f); }
    else if (j == 18) { float p = ppb[((size_t)n*4+b)*2+0]; v = p - rintf(p); }
    else if (j == 19) { float p = ppb[((size_t)n*4+b)*2+1]; v = p - rintf(p); }
    else v = bn_vec[n*64 + (j-20)];
    cond[b][j] = v;
  }
  __syncthreads();
  int b = t >> 6, oc = t & 63;
  float s = fb[oc];
  for (int j=0;j<84;++j) s = fmaf(cond[b][j], fw[oc*84+j], s);
  film[((size_t)n*4+b)*64 + oc] = s;
}

// ---------------------------------------------------------------------------
// final per-map normalization
// ---------------------------------------------------------------------------
__global__ __launch_bounds__(256) void norm_k(float* __restrict__ out,
                                              const float* __restrict__ sums)
{
  int il = blockIdx.x;
  int p = blockIdx.y*256 + threadIdx.x;
  if (p < 961) {
    float inv = 1.f / fmaxf(sums[il], 1e-8f);
    out[(size_t)il*961 + p] *= inv;
  }
}

// ---------------------------------------------------------------------------
extern "C" void kernel_launch(void* const* d_in, const int* in_sizes, int n_in,
                              void* d_out, int out_size, void* d_ws, size_t ws_size,
                              hipStream_t stream)
{
  const float* bott = (const float*)d_in[0];
  const float* vis  = (const float*)d_in[1];
  const float* spv  = (const float*)d_in[2];
  const float* ppb  = (const float*)d_in[3];
  const float* ic1w = (const float*)d_in[4];  const float* ic1b = (const float*)d_in[5];
  const float* ic2w = (const float*)d_in[6];  const float* ic2b = (const float*)d_in[7];
  const float* ic3w = (const float*)d_in[8];  const float* ic3b = (const float*)d_in[9];
  const float* dww  = (const float*)d_in[10]; const float* dwb  = (const float*)d_in[11];
  const float* lnw  = (const float*)d_in[12]; const float* lnb  = (const float*)d_in[13];
  const float* pw1w = (const float*)d_in[14]; const float* pw1b = (const float*)d_in[15];
  const float* pw2w = (const float*)d_in[16]; const float* pw2b = (const float*)d_in[17];
  const float* cgam = (const float*)d_in[18];
  const float* bnpw = (const float*)d_in[19]; const float* bnpb = (const float*)d_in[20];
  const float* bemb = (const float*)d_in[21];
  const float* fw   = (const float*)d_in[22]; const float* fb   = (const float*)d_in[23];
  const float* d1w  = (const float*)d_in[24]; const float* d1b  = (const float*)d_in[25];
  const float* d2w  = (const float*)d_in[26]; const float* d2b  = (const float*)d_in[27];
  const float* d3w  = (const float*)d_in[28]; const float* d3b  = (const float*)d_in[29];
  float* out = (float*)d_out;

  char* ws = (char*)d_ws;

  const int CH = (ws_size >= 116500000ull) ? 256 : 128;

  // P2 regions (bf16; overlap P1 regions, stream-ordered)
  unsigned short* bwinT = (unsigned short*)(ws);
  unsigned short* dwout = (unsigned short*)(ws + 31719424);
  // P1 regions
  unsigned short* vwin = (unsigned short*)(ws);
  size_t o_bufA = (size_t)CH*139392;
  size_t o_bufB = o_bufA + (size_t)CH*123008;
  size_t o_bufI = o_bufB + (size_t)CH*123008;
  size_t p1end  = o_bufI + (size_t)CH*61504;
  unsigned short* bufA = (unsigned short*)(ws + o_bufA);
  unsigned short* bufB = (unsigned short*)(ws + o_bufB);
  unsigned short* bufI = (unsigned short*)(ws + o_bufI);
  size_t tail = (p1end > 63438848ull) ? p1end : 63438848ull;

  float* bnv  = (float*)(ws + tail);
  float* sums = (float*)(ws + tail + 131072);
  float* film = (float*)(ws + tail + 139264);
  unsigned short* W1p = (unsigned short*)(ws + tail + 663552);
  unsigned short* W2p = (unsigned short*)(ws + tail + 1187840);
  unsigned short* Wbp = (unsigned short*)(ws + tail + 1712128);
  unsigned short* Pc1 = (unsigned short*)(ws + tail + 1744896);
  unsigned short* Pc2 = (unsigned short*)(ws + tail + 1818624);
  unsigned short* Pc3 = (unsigned short*)(ws + tail + 1892352);
  unsigned short* Pd1 = (unsigned short*)(ws + tail + 1929216);
  unsigned short* Pd2 = (unsigned short*)(ws + tail + 1947648);
  float* dwwT = (float*)(ws + tail + 1966080);

  // ---- combined weight packing (1 launch) + dw transpose ----
  {
    PackJobs J;
    const float* srcs[8] = {pw1w, pw2w, bnpw, ic1w, ic2w, ic3w, d1w, d2w};
    unsigned short* dsts[8] = {W1p, W2p, Wbp, Pc1, Pc2, Pc3, Pd1, Pd2};
    int ntns[8] = {64,16,4, 4,4,2, 2,2};
    int ntks[8] = {8,32,8, 18,18,18, 9,9};
    int Ks[8]   = {256,1024,256, 64,64,64, 32,32};
    int convs[8]= {0,0,0, 1,1,1, 1,1};
    int base = 0;
    for (int i=0;i<8;++i) {
      J.src[i]=srcs[i]; J.dst[i]=dsts[i]; J.ntn[i]=ntns[i]; J.ntk[i]=ntks[i];
      J.K[i]=Ks[i]; J.conv[i]=convs[i]; J.base[i]=base;
      base += (ntns[i]*ntks[i]*64 + 255)/256;
    }
    packall_k<<<base,256,0,stream>>>(J);
  }
  dwt_k<<<49,256,0,stream>>>(dww, dwwT);

  hipMemsetAsync(ws + tail, 0, 139264, stream);  // bnv + sums

  float gs = 0.f;
  for (int py=0; py<11; ++py) for (int px=0; px<11; ++px) {
    float ly=-1.f+0.2f*py, lx=-1.f+0.2f*px;
    gs += expf(-(lx*lx+ly*ly)/0.32f);
  }
  const float inv_gsum = 1.f/gs;

  // ---- Phase 2: bottleneck path -> bn_vec ----
  dwfused4_k<<<dim3(512,4),256,0,stream>>>(bott, spv, dwwT, dwb, bwinT, dwout);
  cnx_mfma3_k<<<968,512,0,stream>>>(dwout, lnw,lnb, W1p,pw1b, W2p,pw2b, cgam,
                                    bwinT, Wbp, bnpb, bnv, inv_gsum);
  film_k<<<512,256,0,stream>>>(bnv, ppb, bemb, fw, fb, film);

  // ---- Phase 1+3: intrinsic chain + fused decoder ----
  for (int n0 = 0; n0 < 512; n0 += CH) {
    extvwin_k<<<dim3(CH,5),256,0,stream>>>(vis, spv + n0*2, vwin);
    convmf_k<64,64,18,1,true ><<<dim3(CH,4),256,0,stream>>>(vwin, Pc1, ic1b, bufA);
    convmf_k<64,64,18,0,true ><<<dim3(CH,4),256,0,stream>>>(bufA, Pc2, ic2b, bufB);
    convmf_k<64,32,18,0,false><<<dim3(CH,4),256,0,stream>>>(bufB, Pc3, ic3b, bufI);
    decfused_k<<<dim3(CH*4,4),256,0,stream>>>(bufI, Pd1, d1b, Pd2, d2b,
        film + (size_t)n0*4*64, d3w, d3b,
        out + (size_t)n0*4*961, sums + n0*4);
  }
  norm_k<<<dim3(2048,4),256,0,stream>>>(out, sums);
}

// Round 10
// 752.154 us; speedup vs baseline: 10.5904x; 1.0294x over previous
//
#include <hip/hip_runtime.h>
#include <cstdint>
#include <cstddef>
#include <cmath>

#define DEV __device__ __forceinline__

typedef __attribute__((ext_vector_type(8))) short bf16x8;
typedef __attribute__((ext_vector_type(4))) float f32x4;

// Abramowitz-Stegun 7.1.26 erf approx, |abs err| <= 1.5e-7
DEV float erf_fast(float x){
  float ax = fabsf(x);
  float t = __builtin_amdgcn_rcpf(fmaf(0.3275911f, ax, 1.f));
  float p = t*fmaf(t, fmaf(t, fmaf(t, fmaf(t, 1.061405429f, -1.453152027f),
             1.421413741f), -0.284496736f), 0.254829592f);
  float e = __expf(-ax*ax);
  float r = fmaf(-p, e, 1.f);
  return x >= 0.f ? r : -r;
}
DEV float gelu_f(float x){ return 0.5f*x*(1.0f + erf_fast(x*0.7071067811865476f)); }
DEV float softplus_f(float x){ return fmaxf(x,0.f) + log1pf(expf(-fabsf(x))); }
DEV unsigned short f2bf(float x){
  unsigned u = __float_as_uint(x);
  unsigned r = (u + 0x7fffu + ((u>>16)&1u)) >> 16;
  return (unsigned short)r;
}
DEV float bf2f(unsigned short h){
  unsigned u = ((unsigned)h) << 16;
  return __uint_as_float(u);
}

// ---------------------------------------------------------------------------
// Combined weight packing: 8 jobs in one launch.
// ---------------------------------------------------------------------------
struct PackJobs {
  const float* src[8];
  unsigned short* dst[8];
  int ntn[8], ntk[8], K[8], conv[8], base[8];
};

__global__ __launch_bounds__(256) void packall_k(PackJobs J)
{
  int blk = blockIdx.x;
  int j = 0;
#pragma unroll
  for (int i=1;i<8;++i) if (blk >= J.base[i]) j = i;
  int tid = (blk - J.base[j])*256 + threadIdx.x;
  const int ntk = J.ntk[j], K = J.K[j];
  int total = J.ntn[j]*ntk*64;
  if (tid >= total) return;
  int lane = tid & 63;
  int f = tid >> 6;
  int kt = f % ntk, nt = f / ntk;
  int row = nt*16 + (lane & 15);
  int k0 = kt*32 + (lane >> 4)*8;
  const float* src = J.src[j];
  unsigned short h[8];
  if (J.conv[j]) {
    const int Cin = K;
#pragma unroll
    for (int q=0;q<8;++q) {
      int k = k0 + q;
      int s = k / Cin;
      int ic = k - s*Cin;
      h[q] = f2bf(src[((size_t)row*Cin + ic)*9 + s]);
    }
  } else {
#pragma unroll
    for (int q=0;q<8;++q) h[q] = f2bf(src[(size_t)row*K + k0 + q]);
  }
  uint4 pk;
  pk.x = (unsigned)h[0] | ((unsigned)h[1]<<16);
  pk.y = (unsigned)h[2] | ((unsigned)h[3]<<16);
  pk.z = (unsigned)h[4] | ((unsigned)h[5]<<16);
  pk.w = (unsigned)h[6] | ((unsigned)h[7]<<16);
  *reinterpret_cast<uint4*>(J.dst[j] + (size_t)tid*8) = pk;
}

// dw weight transpose: wT[k][ch] = w[ch][k]  (49 x 256)
__global__ __launch_bounds__(256) void dwt_k(const float* __restrict__ w,
                                             float* __restrict__ wT)
{
  int k = blockIdx.x;
  int ch = threadIdx.x;
  wT[k*256 + ch] = w[(size_t)ch*49 + k];
}

// ---------------------------------------------------------------------------
// Extract clamped 33x33 vis windows (incl. conv zero ring) -> bf16 NHWC
// ---------------------------------------------------------------------------
__global__ __launch_bounds__(256) void extvwin_k(const float* __restrict__ vis,
                                                 const float* __restrict__ spv,
                                                 unsigned short* __restrict__ vwin)
{
  int il = blockIdx.x;
  int p = blockIdx.y*256 + threadIdx.x;
  if (p >= 1089) return;
  int wy = p/33, wx = p%33;
  unsigned short* dst = vwin + ((size_t)il*1089 + p)*64;
  if (wy==0 || wy==32 || wx==0 || wx==32) {
    uint4 z = {0,0,0,0};
#pragma unroll
    for (int q=0;q<8;++q) *reinterpret_cast<uint4*>(dst + q*8) = z;
    return;
  }
  int cx = (int)rintf(spv[il*2+0]);
  int cy = (int)rintf(spv[il*2+1]);
  int gy = min(max(cy + wy - 16, 0), 1023);
  int gx = min(max(cx + wx - 16, 0), 1023);
  const float* sp = vis + (size_t)gy*1024 + gx;
  unsigned short h[64];
#pragma unroll
  for (int c=0;c<64;++c) h[c] = f2bf(sp[(size_t)c<<20]);
#pragma unroll
  for (int q=0;q<8;++q) {
    uint4 pk;
    pk.x = (unsigned)h[q*8+0] | ((unsigned)h[q*8+1]<<16);
    pk.y = (unsigned)h[q*8+2] | ((unsigned)h[q*8+3]<<16);
    pk.z = (unsigned)h[q*8+4] | ((unsigned)h[q*8+5]<<16);
    pk.w = (unsigned)h[q*8+6] | ((unsigned)h[q*8+7]<<16);
    *reinterpret_cast<uint4*>(dst + q*8) = pk;
  }
}

// ---------------------------------------------------------------------------
// Fused intrinsic conv chain: c1(64->64,gelu) -> c2(64->64,gelu) ->
// c3(64->32, linear), all in LDS with halo recompute.
// Block = (item, 8-out-row strip), 512 threads / 8 waves.
// bufIn: 14x33 rows x 64ch (window rows y0-2..y0+11); bufC1: 12x33 rows.
// bufC2 aliases bufIn (10x33 rows).
// ---------------------------------------------------------------------------
__global__ __launch_bounds__(512,2) void convchain_k(
    const unsigned short* __restrict__ vwin,
    const unsigned short* __restrict__ Wp1, const float* __restrict__ B1,
    const unsigned short* __restrict__ Wp2, const float* __restrict__ B2,
    const unsigned short* __restrict__ Wp3, const float* __restrict__ B3,
    unsigned short* __restrict__ outI)
{
  const int item = blockIdx.x;
  const int y0 = blockIdx.y*8;
  const int t = threadIdx.x;
  const int w = t>>6, l = t&63, g = l>>4, l15 = l&15;

  __shared__ __align__(16) unsigned short bufIn[462*64];   // 59,136 B
  __shared__ __align__(16) unsigned short bufC1[396*64];   // 50,688 B
  unsigned short* bufC2 = bufIn;                           // 330*64 needed

  const uint4 z4 = {0,0,0,0};

  // ---- zero bufC1 + stage bufIn ----
  for (int u=t; u<396*8; u+=512)
    *reinterpret_cast<uint4*>(bufC1 + u*8) = z4;
  for (int u=t; u<462*8; u+=512) {
    int slot = u & 7;
    int rowi = u >> 3;              // r*33+col, r in 0..13
    int r = rowi/33;
    int wy = y0 - 2 + r;
    uint4 val = z4;
    if ((unsigned)wy < 33u)
      val = *reinterpret_cast<const uint4*>(
          vwin + ((size_t)item*1089 + wy*33 + (rowi - r*33))*64 + slot*8);
    int ds = slot ^ (rowi & 7);
    *reinterpret_cast<uint4*>(&bufIn[rowi*64 + ds*8]) = val;
  }
  __syncthreads();

  // ---- c1: 12 rows x 31 cols (372 pos, 24 tiles, 3/wave), gelu -> bufC1 ----
  {
    int pbase[3], rowB[3]; bool pv[3];
#pragma unroll
    for (int pt=0; pt<3; ++pt) {
      int pd = (w*3+pt)*16 + l15;
      int pc = min(pd, 371);
      int ry = pc/31, rx = pc - ry*31;
      pbase[pt] = ry*33 + rx;
      rowB[pt] = ry*33 + rx + 1;
      int yab = y0 - 2 + ry;
      pv[pt] = (pd < 372) && ((unsigned)yab < 31u);
    }
    f32x4 a1[4][3];
#pragma unroll
    for (int o=0;o<4;++o)
#pragma unroll
      for (int pt=0;pt<3;++pt) a1[o][pt] = (f32x4){0.f,0.f,0.f,0.f};

    for (int kt=0; kt<18; ++kt) {
      int k0 = kt*32 + g*8;
      int s = k0 >> 6;
      int icg = (k0 - (s<<6)) >> 3;
      int roff = (s/3)*33 + (s - (s/3)*3);
      bf16x8 bf[3];
#pragma unroll
      for (int pt=0; pt<3; ++pt) {
        int rowi = pbase[pt] + roff;
        int ds = icg ^ (rowi & 7);
        bf[pt] = *reinterpret_cast<const bf16x8*>(&bufIn[rowi*64 + ds*8]);
      }
#pragma unroll
      for (int o=0; o<4; ++o) {
        bf16x8 af = *reinterpret_cast<const bf16x8*>(Wp1 + ((size_t)(o*18+kt)*64 + l)*8);
#pragma unroll
        for (int pt=0; pt<3; ++pt)
          a1[o][pt] = __builtin_amdgcn_mfma_f32_16x16x32_bf16(af, bf[pt], a1[o][pt], 0,0,0);
      }
    }
#pragma unroll
    for (int o=0; o<4; ++o) {
      float4 bv4 = *reinterpret_cast<const float4*>(B1 + o*16 + g*4);
      int sl = o*2 + (g>>1);
#pragma unroll
      for (int pt=0; pt<3; ++pt) {
        if (!pv[pt]) continue;
        float v0 = gelu_f(a1[o][pt][0] + bv4.x);
        float v1 = gelu_f(a1[o][pt][1] + bv4.y);
        float v2 = gelu_f(a1[o][pt][2] + bv4.z);
        float v3 = gelu_f(a1[o][pt][3] + bv4.w);
        uint2 pk;
        pk.x = (unsigned)f2bf(v0) | ((unsigned)f2bf(v1)<<16);
        pk.y = (unsigned)f2bf(v2) | ((unsigned)f2bf(v3)<<16);
        int phys = sl ^ (rowB[pt] & 7);
        *reinterpret_cast<uint2*>(&bufC1[rowB[pt]*64 + phys*8 + (g&1)*4]) = pk;
      }
    }
  }
  __syncthreads();

  // ---- zero bufC2 (aliases bufIn; c1 reads done) ----
  for (int u=t; u<330*8; u+=512)
    *reinterpret_cast<uint4*>(bufC2 + u*8) = z4;
  __syncthreads();

  // ---- c2: 10 rows x 31 cols (310 pos, 24 tiles w/ mask), gelu -> bufC2 ----
  {
    int pbase[3], rowB[3]; bool pv[3];
#pragma unroll
    for (int pt=0; pt<3; ++pt) {
      int pd = (w*3+pt)*16 + l15;
      int pc = min(pd, 309);
      int ry = pc/31, rx = pc - ry*31;
      pbase[pt] = ry*33 + rx;
      rowB[pt] = ry*33 + rx + 1;
      int yab = y0 - 1 + ry;
      pv[pt] = (pd < 310) && ((unsigned)yab < 31u);
    }
    f32x4 a2[4][3];
#pragma unroll
    for (int o=0;o<4;++o)
#pragma unroll
      for (int pt=0;pt<3;++pt) a2[o][pt] = (f32x4){0.f,0.f,0.f,0.f};

    for (int kt=0; kt<18; ++kt) {
      int k0 = kt*32 + g*8;
      int s = k0 >> 6;
      int icg = (k0 - (s<<6)) >> 3;
      int roff = (s/3)*33 + (s - (s/3)*3);
      bf16x8 bf[3];
#pragma unroll
      for (int pt=0; pt<3; ++pt) {
        int rowi = pbase[pt] + roff;
        int ds = icg ^ (rowi & 7);
        bf[pt] = *reinterpret_cast<const bf16x8*>(&bufC1[rowi*64 + ds*8]);
      }
#pragma unroll
      for (int o=0; o<4; ++o) {
        bf16x8 af = *reinterpret_cast<const bf16x8*>(Wp2 + ((size_t)(o*18+kt)*64 + l)*8);
#pragma unroll
        for (int pt=0; pt<3; ++pt)
          a2[o][pt] = __builtin_amdgcn_mfma_f32_16x16x32_bf16(af, bf[pt], a2[o][pt], 0,0,0);
      }
    }
#pragma unroll
    for (int o=0; o<4; ++o) {
      float4 bv4 = *reinterpret_cast<const float4*>(B2 + o*16 + g*4);
      int sl = o*2 + (g>>1);
#pragma unroll
      for (int pt=0; pt<3; ++pt) {
        if (!pv[pt]) continue;
        float v0 = gelu_f(a2[o][pt][0] + bv4.x);
        float v1 = gelu_f(a2[o][pt][1] + bv4.y);
        float v2 = gelu_f(a2[o][pt][2] + bv4.z);
        float v3 = gelu_f(a2[o][pt][3] + bv4.w);
        uint2 pk;
        pk.x = (unsigned)f2bf(v0) | ((unsigned)f2bf(v1)<<16);
        pk.y = (unsigned)f2bf(v2) | ((unsigned)f2bf(v3)<<16);
        int phys = sl ^ (rowB[pt] & 7);
        *reinterpret_cast<uint2*>(&bufC2[rowB[pt]*64 + phys*8 + (g&1)*4]) = pk;
      }
    }
  }
  __syncthreads();

  // ---- c3: 8 rows x 31 cols (248 pos, 16 tiles, 2/wave) -> global bf16 ----
  {
    int pbase[2], gpos[2]; bool pv[2];
#pragma unroll
    for (int pt=0; pt<2; ++pt) {
      int pd = (w*2+pt)*16 + l15;
      int pc = min(pd, 247);
      int ry = pc/31, rx = pc - ry*31;
      pbase[pt] = ry*33 + rx;
      gpos[pt] = y0*31 + pd;
      pv[pt] = (pd < 248) && (gpos[pt] < 961);
    }
    f32x4 a3[2][2];
#pragma unroll
    for (int o=0;o<2;++o)
#pragma unroll
      for (int pt=0;pt<2;++pt) a3[o][pt] = (f32x4){0.f,0.f,0.f,0.f};

    for (int kt=0; kt<18; ++kt) {
      int k0 = kt*32 + g*8;
      int s = k0 >> 6;
      int icg = (k0 - (s<<6)) >> 3;
      int roff = (s/3)*33 + (s - (s/3)*3);
      bf16x8 bf[2];
#pragma unroll
      for (int pt=0; pt<2; ++pt) {
        int rowi = pbase[pt] + roff;
        int ds = icg ^ (rowi & 7);
        bf[pt] = *reinterpret_cast<const bf16x8*>(&bufC2[rowi*64 + ds*8]);
      }
#pragma unroll
      for (int o=0; o<2; ++o) {
        bf16x8 af = *reinterpret_cast<const bf16x8*>(Wp3 + ((size_t)(o*18+kt)*64 + l)*8);
#pragma unroll
        for (int pt=0; pt<2; ++pt)
          a3[o][pt] = __builtin_amdgcn_mfma_f32_16x16x32_bf16(af, bf[pt], a3[o][pt], 0,0,0);
      }
    }
#pragma unroll
    for (int o=0; o<2; ++o) {
      float4 bv4 = *reinterpret_cast<const float4*>(B3 + o*16 + g*4);
#pragma unroll
      for (int pt=0; pt<2; ++pt) {
        if (!pv[pt]) continue;
        float v0 = a3[o][pt][0] + bv4.x;
        float v1 = a3[o][pt][1] + bv4.y;
        float v2 = a3[o][pt][2] + bv4.z;
        float v3 = a3[o][pt][3] + bv4.w;
        uint2 pk;
        pk.x = (unsigned)f2bf(v0) | ((unsigned)f2bf(v1)<<16);
        pk.y = (unsigned)f2bf(v2) | ((unsigned)f2bf(v3)<<16);
        *reinterpret_cast<uint2*>(outI + ((size_t)item*961 + gpos[pt])*32 + o*16 + g*4) = pk;
      }
    }
  }
}

// ---------------------------------------------------------------------------
// Fused decoder: FiLM+gelu staging -> dec1(3x3)+gelu -> dec2(3x3)+gelu ->
// dec3(1x1)+softplus+sum, all in LDS. Block = (nb item, 8-row strip).
// ---------------------------------------------------------------------------
__global__ __launch_bounds__(256,3) void decfused_k(
    const unsigned short* __restrict__ intc,
    const unsigned short* __restrict__ Wp1, const float* __restrict__ B1,
    const unsigned short* __restrict__ Wp2, const float* __restrict__ B2,
    const float* __restrict__ film,
    const float* __restrict__ w3, const float* __restrict__ b3,
    float* __restrict__ outf, float* __restrict__ sums)
{
  const int item = blockIdx.x;
  const int y0 = blockIdx.y*8;
  const int t = threadIdx.x;
  const int w = t>>6, l = t&63, g = l>>4, l15 = l&15;

  __shared__ __align__(16) unsigned short ldsA[12*33*32];
  __shared__ __align__(16) unsigned short ldsB[10*33*32];

  const int sit = item >> 2;
  const float* frow = film + (size_t)item*64;

  for (int u=t; u<1320; u+=256)
    *reinterpret_cast<uint4*>(ldsB + u*8) = (uint4){0,0,0,0};

  for (int u=t; u<1584; u+=256) {
    int slot = u & 3;
    int rowi = u >> 2;
    int r = rowi/33, col = rowi - r*33;
    int y = y0 + r - 2, x = col - 1;
    uint4 val = {0,0,0,0};
    if ((unsigned)y < 31u && (unsigned)x < 31u) {
      val = *reinterpret_cast<const uint4*>(intc + ((size_t)sit*961 + y*31 + x)*32 + slot*8);
      int c0 = slot*8;
      float4 g0 = *reinterpret_cast<const float4*>(frow + c0);
      float4 g1 = *reinterpret_cast<const float4*>(frow + c0 + 4);
      float4 b0 = *reinterpret_cast<const float4*>(frow + 32 + c0);
      float4 b1 = *reinterpret_cast<const float4*>(frow + 32 + c0 + 4);
      unsigned short x8[8] = {
        (unsigned short)(val.x&0xffff),(unsigned short)(val.x>>16),
        (unsigned short)(val.y&0xffff),(unsigned short)(val.y>>16),
        (unsigned short)(val.z&0xffff),(unsigned short)(val.z>>16),
        (unsigned short)(val.w&0xffff),(unsigned short)(val.w>>16)};
      unsigned short o8[8];
      o8[0]=f2bf(gelu_f(fmaf(bf2f(x8[0]), 1.f+g0.x, b0.x)));
      o8[1]=f2bf(gelu_f(fmaf(bf2f(x8[1]), 1.f+g0.y, b0.y)));
      o8[2]=f2bf(gelu_f(fmaf(bf2f(x8[2]), 1.f+g0.z, b0.z)));
      o8[3]=f2bf(gelu_f(fmaf(bf2f(x8[3]), 1.f+g0.w, b0.w)));
      o8[4]=f2bf(gelu_f(fmaf(bf2f(x8[4]), 1.f+g1.x, b1.x)));
      o8[5]=f2bf(gelu_f(fmaf(bf2f(x8[5]), 1.f+g1.y, b1.y)));
      o8[6]=f2bf(gelu_f(fmaf(bf2f(x8[6]), 1.f+g1.z, b1.z)));
      o8[7]=f2bf(gelu_f(fmaf(bf2f(x8[7]), 1.f+g1.w, b1.w)));
      val.x = (unsigned)o8[0] | ((unsigned)o8[1]<<16);
      val.y = (unsigned)o8[2] | ((unsigned)o8[3]<<16);
      val.z = (unsigned)o8[4] | ((unsigned)o8[5]<<16);
      val.w = (unsigned)o8[6] | ((unsigned)o8[7]<<16);
    }
    int ds = slot ^ (rowi & 3);
    *reinterpret_cast<uint4*>(&ldsA[rowi*32 + ds*8]) = val;
  }
  __syncthreads();

  {
    int pbase[5], rowB[5]; bool pv[5];
#pragma unroll
    for (int pt=0; pt<5; ++pt) {
      int pd = (w*5+pt)*16 + l15;
      int pc = min(pd, 309);
      int ry = pc/31, rx = pc - ry*31;
      pbase[pt] = ry*33 + rx;
      rowB[pt] = ry*33 + rx + 1;
      int gy = y0 - 1 + ry;
      pv[pt] = (pd < 310) && ((unsigned)gy < 31u);
    }
    f32x4 a1[2][5];
#pragma unroll
    for (int o=0;o<2;++o)
#pragma unroll
      for (int pt=0;pt<5;++pt) a1[o][pt] = (f32x4){0.f,0.f,0.f,0.f};

    for (int kt=0; kt<9; ++kt) {
      int roff = (kt/3)*33 + (kt - (kt/3)*3);
      bf16x8 bf[5];
#pragma unroll
      for (int pt=0; pt<5; ++pt) {
        int rowi = pbase[pt] + roff;
        int ds = g ^ (rowi & 3);
        bf[pt] = *reinterpret_cast<const bf16x8*>(&ldsA[rowi*32 + ds*8]);
      }
#pragma unroll
      for (int o=0; o<2; ++o) {
        bf16x8 af = *reinterpret_cast<const bf16x8*>(Wp1 + ((size_t)(o*9+kt)*64 + l)*8);
#pragma unroll
        for (int pt=0; pt<5; ++pt)
          a1[o][pt] = __builtin_amdgcn_mfma_f32_16x16x32_bf16(af, bf[pt], a1[o][pt], 0,0,0);
      }
    }
#pragma unroll
    for (int o=0; o<2; ++o) {
      float4 bv4 = *reinterpret_cast<const float4*>(B1 + o*16 + g*4);
      int sl = o*2 + (g>>1);
#pragma unroll
      for (int pt=0; pt<5; ++pt) {
        if (!pv[pt]) continue;
        float v0 = gelu_f(a1[o][pt][0] + bv4.x);
        float v1 = gelu_f(a1[o][pt][1] + bv4.y);
        float v2 = gelu_f(a1[o][pt][2] + bv4.z);
        float v3 = gelu_f(a1[o][pt][3] + bv4.w);
        uint2 pk;
        pk.x = (unsigned)f2bf(v0) | ((unsigned)f2bf(v1)<<16);
        pk.y = (unsigned)f2bf(v2) | ((unsigned)f2bf(v3)<<16);
        int phys = sl ^ (rowB[pt] & 3);
        *reinterpret_cast<uint2*>(&ldsB[rowB[pt]*32 + phys*8 + (g&1)*4]) = pk;
      }
    }
  }
  __syncthreads();

  float bsum = 0.f;
  {
    int pbase[4], gpos[4]; bool pv[4];
#pragma unroll
    for (int pt=0; pt<4; ++pt) {
      int pd = (w*4+pt)*16 + l15;
      int pc = min(pd, 247);
      int py = pc/31, px = pc - py*31;
      pbase[pt] = py*33 + px;
      gpos[pt] = y0*31 + pd;
      pv[pt] = (pd < 248) && (gpos[pt] < 961);
    }
    f32x4 a2[2][4];
#pragma unroll
    for (int o=0;o<2;++o)
#pragma unroll
      for (int pt=0;pt<4;++pt) a2[o][pt] = (f32x4){0.f,0.f,0.f,0.f};

    for (int kt=0; kt<9; ++kt) {
      int roff = (kt/3)*33 + (kt - (kt/3)*3);
      bf16x8 bf[4];
#pragma unroll
      for (int pt=0; pt<4; ++pt) {
        int rowi = pbase[pt] + roff;
        int ds = g ^ (rowi & 3);
        bf[pt] = *reinterpret_cast<const bf16x8*>(&ldsB[rowi*32 + ds*8]);
      }
#pragma unroll
      for (int o=0; o<2; ++o) {
        bf16x8 af = *reinterpret_cast<const bf16x8*>(Wp2 + ((size_t)(o*9+kt)*64 + l)*8);
#pragma unroll
        for (int pt=0; pt<4; ++pt)
          a2[o][pt] = __builtin_amdgcn_mfma_f32_16x16x32_bf16(af, bf[pt], a2[o][pt], 0,0,0);
      }
    }

    float w3r[8];
#pragma unroll
    for (int o=0;o<2;++o) {
      float4 wv = *reinterpret_cast<const float4*>(w3 + o*16 + g*4);
      w3r[o*4+0]=wv.x; w3r[o*4+1]=wv.y; w3r[o*4+2]=wv.z; w3r[o*4+3]=wv.w;
    }
    float b3v = b3[0];
#pragma unroll
    for (int pt=0; pt<4; ++pt) {
      float part = 0.f;
#pragma unroll
      for (int o=0; o<2; ++o) {
        float4 bv4 = *reinterpret_cast<const float4*>(B2 + o*16 + g*4);
        float v0 = gelu_f(a2[o][pt][0] + bv4.x);
        float v1 = gelu_f(a2[o][pt][1] + bv4.y);
        float v2 = gelu_f(a2[o][pt][2] + bv4.z);
        float v3 = gelu_f(a2[o][pt][3] + bv4.w);
        part += v0*w3r[o*4+0] + v1*w3r[o*4+1] + v2*w3r[o*4+2] + v3*w3r[o*4+3];
      }
      part += __shfl_xor(part, 16);
      part += __shfl_xor(part, 32);
      float sp = softplus_f(part + b3v);
      if (pv[pt] && g==0) {
        outf[(size_t)item*961 + gpos[pt]] = sp;
        bsum += sp;
      }
    }
  }
  {
    float* redf = reinterpret_cast<float*>(ldsA);
    redf[t] = bsum;
    __syncthreads();
    for (int off=128; off>0; off>>=1) {
      if (t < off) redf[t] += redf[t+off];
      __syncthreads();
    }
    if (t==0) atomicAdd(&sums[item], redf[0]);
  }
}

// ---------------------------------------------------------------------------
// Fused bottleneck-window gather + depthwise 7x7, channel-sliced, row-reuse.
// ---------------------------------------------------------------------------
__global__ __launch_bounds__(256,4) void dwfused4_k(
    const float* __restrict__ bott, const float* __restrict__ spv,
    const float* __restrict__ wT, const float* __restrict__ b,
    unsigned short* __restrict__ bwinT, unsigned short* __restrict__ dwout)
{
  const int n = blockIdx.x, cs = blockIdx.y*64, t = threadIdx.x;
  __shared__ float tile[121*66];

  float pxf = fminf(fmaxf(spv[n*2+0]*0.25f, 0.f), 255.f);
  float pyf = fminf(fmaxf(spv[n*2+1]*0.25f, 0.f), 255.f);
  int cx = (int)rintf(pxf), cy = (int)rintf(pyf);

  for (int idx=t; idx<121*32; idx+=256) {
    int j = idx/121, p = idx - j*121;
    int y = p/11, x = p - y*11;
    int gy = min(max(cy + y - 5, 0), 255);
    int gx = min(max(cx + x - 5, 0), 255);
    const float* s0 = bott + ((size_t)(cs+2*j)<<16) + (gy<<8) + gx;
    *reinterpret_cast<float2*>(&tile[p*66 + 2*j]) = (float2){s0[0], s0[65536]};
  }
  __syncthreads();

  for (int idx=t; idx<121*64; idx+=256) {
    int p = idx >> 6, c = idx & 63;
    bwinT[((size_t)n*121 + p)*256 + cs + c] = f2bf(tile[p*66 + c]);
  }

  const int c = t & 63, ph = t >> 6;
  const int ch = cs + c;
  const float bias = b[ch];

  for (int y=ph; y<11; y+=4) {
    float acc[11];
#pragma unroll
    for (int x=0;x<11;++x) acc[x] = bias;
#pragma unroll
    for (int dy=0; dy<7; ++dy) {
      int yy = y + dy - 3;
      if ((unsigned)yy < 11u) {
        float r[11];
#pragma unroll
        for (int k=0;k<11;++k) r[k] = tile[(yy*11+k)*66 + c];
        float w7[7];
#pragma unroll
        for (int j=0;j<7;++j) w7[j] = wT[(dy*7+j)*256 + ch];
#pragma unroll
        for (int x=0;x<11;++x) {
#pragma unroll
          for (int dx=0;dx<7;++dx) {
            int xx = x + dx - 3;
            if (xx >= 0 && xx < 11)
              acc[x] = fmaf(r[xx], w7[dx], acc[x]);
          }
        }
      }
    }
#pragma unroll
    for (int x=0;x<11;++x)
      dwout[((size_t)n*121 + y*11 + x)*256 + ch] = f2bf(acc[x]);
  }
}

// ---------------------------------------------------------------------------
// Fused ConvNeXt MLP + bnp head, bf16 MFMA. 512 threads / 8 waves, 64 rows.
// ---------------------------------------------------------------------------
__global__ __launch_bounds__(512,4) void cnx_mfma3_k(
    const unsigned short* __restrict__ xin,
    const float* __restrict__ lnw, const float* __restrict__ lnb,
    const unsigned short* __restrict__ W1p, const float* __restrict__ B1,
    const unsigned short* __restrict__ W2p, const float* __restrict__ B2,
    const float* __restrict__ gvec,
    const unsigned short* __restrict__ bwinT,
    const unsigned short* __restrict__ Wbp, const float* __restrict__ bnpb,
    float* __restrict__ bnv, float inv_gsum)
{
  const int t = threadIdx.x;
  const int w = t >> 6;
  const int l = t & 63;
  const int g = l >> 4;
  const int l15 = l & 15;
  const int row0 = blockIdx.x * 64;

  __shared__ __align__(16) unsigned short xs[64*264];
  __shared__ __align__(16) unsigned short hs[64*136];

  {
    const int rl = t >> 3, q = t & 7;
    const unsigned short* xr = xin + (size_t)(row0+rl)*256 + q*32;
    float xv[32]; float s = 0.f, s2 = 0.f;
#pragma unroll
    for (int i=0;i<32;i+=8){
      uint4 v = *reinterpret_cast<const uint4*>(xr+i);
      unsigned short xh[8] = {
        (unsigned short)(v.x&0xffff),(unsigned short)(v.x>>16),
        (unsigned short)(v.y&0xffff),(unsigned short)(v.y>>16),
        (unsigned short)(v.z&0xffff),(unsigned short)(v.z>>16),
        (unsigned short)(v.w&0xffff),(unsigned short)(v.w>>16)};
#pragma unroll
      for (int j=0;j<8;++j){
        float f = bf2f(xh[j]);
        xv[i+j] = f; s += f; s2 += f*f;
      }
    }
    s += __shfl_xor(s,1); s2 += __shfl_xor(s2,1);
    s += __shfl_xor(s,2); s2 += __shfl_xor(s2,2);
    s += __shfl_xor(s,4); s2 += __shfl_xor(s2,4);
    float mu = s*(1.f/256.f);
    float rstd = rsqrtf(s2*(1.f/256.f) - mu*mu + 1e-6f);
#pragma unroll
    for (int i=0;i<32;i+=8){
      int c = q*32 + i;
      float4 w0 = *reinterpret_cast<const float4*>(lnw+c);
      float4 w1 = *reinterpret_cast<const float4*>(lnw+c+4);
      float4 b0 = *reinterpret_cast<const float4*>(lnb+c);
      float4 b1 = *reinterpret_cast<const float4*>(lnb+c+4);
      unsigned short h[8];
      h[0]=f2bf(fmaf((xv[i+0]-mu)*rstd, w0.x, b0.x));
      h[1]=f2bf(fmaf((xv[i+1]-mu)*rstd, w0.y, b0.y));
      h[2]=f2bf(fmaf((xv[i+2]-mu)*rstd, w0.z, b0.z));
      h[3]=f2bf(fmaf((xv[i+3]-mu)*rstd, w0.w, b0.w));
      h[4]=f2bf(fmaf((xv[i+4]-mu)*rstd, w1.x, b1.x));
      h[5]=f2bf(fmaf((xv[i+5]-mu)*rstd, w1.y, b1.y));
      h[6]=f2bf(fmaf((xv[i+6]-mu)*rstd, w1.z, b1.z));
      h[7]=f2bf(fmaf((xv[i+7]-mu)*rstd, w1.w, b1.w));
      uint4 pk;
      pk.x = (unsigned)h[0] | ((unsigned)h[1]<<16);
      pk.y = (unsigned)h[2] | ((unsigned)h[3]<<16);
      pk.z = (unsigned)h[4] | ((unsigned)h[5]<<16);
      pk.w = (unsigned)h[6] | ((unsigned)h[7]<<16);
      *reinterpret_cast<uint4*>(&xs[rl*264 + c]) = pk;
    }
  }
  __syncthreads();

  f32x4 acc2[8];
#pragma unroll
  for (int i=0;i<8;++i) acc2[i] = (f32x4){0.f,0.f,0.f,0.f};

  for (int hc=0; hc<8; ++hc) {
    const int ht = hc*8 + w;
    f32x4 acc1[4];
#pragma unroll
    for (int i=0;i<4;++i) acc1[i] = (f32x4){0.f,0.f,0.f,0.f};

#pragma unroll
    for (int kt=0; kt<8; ++kt) {
      bf16x8 xf[4];
#pragma unroll
      for (int rt=0; rt<4; ++rt)
        xf[rt] = *reinterpret_cast<const bf16x8*>(&xs[(rt*16+l15)*264 + kt*32 + g*8]);
      bf16x8 wf = *reinterpret_cast<const bf16x8*>(W1p + ((size_t)(ht*8+kt)*64 + l)*8);
#pragma unroll
      for (int rt=0; rt<4; ++rt)
        acc1[rt] = __builtin_amdgcn_mfma_f32_16x16x32_bf16(wf, xf[rt], acc1[rt], 0,0,0);
    }
    {
      const int hb = hc*128 + w*16 + 4*g;
      float4 b1v = *reinterpret_cast<const float4*>(B1 + hb);
#pragma unroll
      for (int rt=0; rt<4; ++rt) {
        unsigned short h0 = f2bf(gelu_f(acc1[rt][0] + b1v.x));
        unsigned short h1 = f2bf(gelu_f(acc1[rt][1] + b1v.y));
        unsigned short h2 = f2bf(gelu_f(acc1[rt][2] + b1v.z));
        unsigned short h3 = f2bf(gelu_f(acc1[rt][3] + b1v.w));
        uint2 pk;
        pk.x = (unsigned)h0 | ((unsigned)h1<<16);
        pk.y = (unsigned)h2 | ((unsigned)h3<<16);
        *reinterpret_cast<uint2*>(&hs[(rt*16+l15)*136 + w*16 + 4*g]) = pk;
      }
    }
    __syncthreads();
#pragma unroll
    for (int kt=0; kt<4; ++kt) {
      bf16x8 hf[4];
#pragma unroll
      for (int rt=0; rt<4; ++rt)
        hf[rt] = *reinterpret_cast<const bf16x8*>(&hs[(rt*16+l15)*136 + kt*32 + g*8]);
#pragma unroll
      for (int cj=0; cj<2; ++cj) {
        const int ct = 2*w + cj;
        bf16x8 wf = *reinterpret_cast<const bf16x8*>(W2p + ((size_t)(ct*32 + hc*4 + kt)*64 + l)*8);
#pragma unroll
        for (int rt=0; rt<4; ++rt)
          acc2[cj*4+rt] = __builtin_amdgcn_mfma_f32_16x16x32_bf16(hf[rt], wf, acc2[cj*4+rt], 0,0,0);
      }
    }
    __syncthreads();
  }

#pragma unroll
  for (int cj=0; cj<2; ++cj) {
    const int c = (2*w+cj)*16 + l15;
    const float b2 = B2[c], gm = gvec[c];
#pragma unroll
    for (int rt=0; rt<4; ++rt) {
#pragma unroll
      for (int reg=0; reg<4; ++reg) {
        int row = rt*16 + 4*g + reg;
        float res = bf2f(bwinT[(size_t)(row0+row)*256 + c]) + (acc2[cj*4+rt][reg] + b2)*gm;
        xs[row*264 + c] = f2bf(res);
      }
    }
  }
  __syncthreads();

  {
    const int oct = w & 3;
    f32x4 abn[2];
#pragma unroll
    for (int i=0;i<2;++i) abn[i] = (f32x4){0.f,0.f,0.f,0.f};
#pragma unroll
    for (int kt=0; kt<8; ++kt) {
      bf16x8 bfw = *reinterpret_cast<const bf16x8*>(Wbp + ((size_t)(oct*8+kt)*64 + l)*8);
#pragma unroll
      for (int i=0;i<2;++i) {
        const int rt = (w>>2) + 2*i;
        bf16x8 af = *reinterpret_cast<const bf16x8*>(&xs[(rt*16+l15)*264 + kt*32 + g*8]);
        abn[i] = __builtin_amdgcn_mfma_f32_16x16x32_bf16(af, bfw, abn[i], 0,0,0);
      }
    }

    float* red = reinterpret_cast<float*>(hs);
#pragma unroll
    for (int i=0;i<2;++i) {
      const int rt = (w>>2) + 2*i;
      float bv = bnpb[oct*16 + l15];
#pragma unroll
      for (int reg=0; reg<4; ++reg) {
        int lr = rt*16 + g*4 + reg;
        int p = (row0 + lr) % 121;
        int py=p/11, px=p-py*11;
        float ly=-1.f+0.2f*py, lx=-1.f+0.2f*px;
        float wg = __expf(-(lx*lx+ly*ly)/0.32f) * inv_gsum;
        red[lr*64 + oct*16 + l15] = gelu_f(abn[i][reg] + bv) * wg;
      }
    }
  }
  __syncthreads();
  {
    float* red = reinterpret_cast<float*>(hs);
    int oc = t & 63, seg = t >> 6;
    float s = 0.f;
    int curn = (row0 + seg*8) / 121;
    for (int i=0;i<8;++i) {
      int row = seg*8 + i;
      int n = (row0 + row) / 121;
      if (n != curn) { atomicAdd(&bnv[curn*64 + oc], s); s = 0.f; curn = n; }
      s += red[row*64 + oc];
    }
    atomicAdd(&bnv[curn*64 + oc], s);
  }
}

// ---------------------------------------------------------------------------
// FiLM
// ---------------------------------------------------------------------------
__global__ __launch_bounds__(256) void film_k(
    const float* __restrict__ bn_vec, const float* __restrict__ ppb,
    const float* __restrict__ bemb, const float* __restrict__ fw,
    const float* __restrict__ fb, float* __restrict__ film)
{
  int n = blockIdx.x, t = threadIdx.x;
  __shared__ float cond[4][84];
  for (int i=t; i<4*84; i+=256) {
    int b = i/84, j = i%84;
    float v;
    if (j < 16) v = bemb[b*16 + j];
    else if (j == 16) { float p = ppb[((size_t)n*4+b)*2+0]; v = fminf(fmaxf(p*(1.f/1023.f),0.f),1.f); }
    else if (j == 17) { float p = ppb[((size_t)n*4+b)*2+1]; v = fminf(fmaxf(p*(1.f/1023.f),0.f),1.f); }
    else if (j == 18) { float p = ppb[((size_t)n*4+b)*2+0]; v = p - rintf(p); }
    else if (j == 19) { float p = ppb[((size_t)n*4+b)*2+1]; v = p - rintf(p); }
    else v = bn_vec[n*64 + (j-20)];
    cond[b][j] = v;
  }
  __syncthreads();
  int b = t >> 6, oc = t & 63;
  float s = fb[oc];
  for (int j=0;j<84;++j) s = fmaf(cond[b][j], fw[oc*84+j], s);
  film[((size_t)n*4+b)*64 + oc] = s;
}

// ---------------------------------------------------------------------------
// final per-map normalization
// ---------------------------------------------------------------------------
__global__ __launch_bounds__(256) void norm_k(float* __restrict__ out,
                                              const float* __restrict__ sums)
{
  int il = blockIdx.x;
  int p = blockIdx.y*256 + threadIdx.x;
  if (p < 961) {
    float inv = 1.f / fmaxf(sums[il], 1e-8f);
    out[(size_t)il*961 + p] *= inv;
  }
}

// ---------------------------------------------------------------------------
extern "C" void kernel_launch(void* const* d_in, const int* in_sizes, int n_in,
                              void* d_out, int out_size, void* d_ws, size_t ws_size,
                              hipStream_t stream)
{
  const float* bott = (const float*)d_in[0];
  const float* vis  = (const float*)d_in[1];
  const float* spv  = (const float*)d_in[2];
  const float* ppb  = (const float*)d_in[3];
  const float* ic1w = (const float*)d_in[4];  const float* ic1b = (const float*)d_in[5];
  const float* ic2w = (const float*)d_in[6];  const float* ic2b = (const float*)d_in[7];
  const float* ic3w = (const float*)d_in[8];  const float* ic3b = (const float*)d_in[9];
  const float* dww  = (const float*)d_in[10]; const float* dwb  = (const float*)d_in[11];
  const float* lnw  = (const float*)d_in[12]; const float* lnb  = (const float*)d_in[13];
  const float* pw1w = (const float*)d_in[14]; const float* pw1b = (const float*)d_in[15];
  const float* pw2w = (const float*)d_in[16]; const float* pw2b = (const float*)d_in[17];
  const float* cgam = (const float*)d_in[18];
  const float* bnpw = (const float*)d_in[19]; const float* bnpb = (const float*)d_in[20];
  const float* bemb = (const float*)d_in[21];
  const float* fw   = (const float*)d_in[22]; const float* fb   = (const float*)d_in[23];
  const float* d1w  = (const float*)d_in[24]; const float* d1b  = (const float*)d_in[25];
  const float* d2w  = (const float*)d_in[26]; const float* d2b  = (const float*)d_in[27];
  const float* d3w  = (const float*)d_in[28]; const float* d3b  = (const float*)d_in[29];
  float* out = (float*)d_out;

  char* ws = (char*)d_ws;

  // Phase-2 buffers [0, 63.4 MB); vwin reuses [0, 71.4 MB) after phase 2.
  unsigned short* bwinT = (unsigned short*)(ws);
  unsigned short* dwout = (unsigned short*)(ws + 31719424);
  unsigned short* vwin  = (unsigned short*)(ws);            // 512*1089*64*2 = 71,368,704
  unsigned short* bufI  = (unsigned short*)(ws + 71368704); // 512*961*32*2 = 31,490,048
  size_t tail = 102858752;

  float* bnv  = (float*)(ws + tail);
  float* sums = (float*)(ws + tail + 131072);
  float* film = (float*)(ws + tail + 139264);
  unsigned short* W1p = (unsigned short*)(ws + tail + 663552);
  unsigned short* W2p = (unsigned short*)(ws + tail + 1187840);
  unsigned short* Wbp = (unsigned short*)(ws + tail + 1712128);
  unsigned short* Pc1 = (unsigned short*)(ws + tail + 1744896);
  unsigned short* Pc2 = (unsigned short*)(ws + tail + 1818624);
  unsigned short* Pc3 = (unsigned short*)(ws + tail + 1892352);
  unsigned short* Pd1 = (unsigned short*)(ws + tail + 1929216);
  unsigned short* Pd2 = (unsigned short*)(ws + tail + 1947648);
  float* dwwT = (float*)(ws + tail + 1966080);

  // ---- combined weight packing (1 launch) + dw transpose ----
  {
    PackJobs J;
    const float* srcs[8] = {pw1w, pw2w, bnpw, ic1w, ic2w, ic3w, d1w, d2w};
    unsigned short* dsts[8] = {W1p, W2p, Wbp, Pc1, Pc2, Pc3, Pd1, Pd2};
    int ntns[8] = {64,16,4, 4,4,2, 2,2};
    int ntks[8] = {8,32,8, 18,18,18, 9,9};
    int Ks[8]   = {256,1024,256, 64,64,64, 32,32};
    int convs[8]= {0,0,0, 1,1,1, 1,1};
    int base = 0;
    for (int i=0;i<8;++i) {
      J.src[i]=srcs[i]; J.dst[i]=dsts[i]; J.ntn[i]=ntns[i]; J.ntk[i]=ntks[i];
      J.K[i]=Ks[i]; J.conv[i]=convs[i]; J.base[i]=base;
      base += (ntns[i]*ntks[i]*64 + 255)/256;
    }
    packall_k<<<base,256,0,stream>>>(J);
  }
  dwt_k<<<49,256,0,stream>>>(dww, dwwT);

  hipMemsetAsync(ws + tail, 0, 139264, stream);  // bnv + sums

  float gs = 0.f;
  for (int py=0; py<11; ++py) for (int px=0; px<11; ++px) {
    float ly=-1.f+0.2f*py, lx=-1.f+0.2f*px;
    gs += expf(-(lx*lx+ly*ly)/0.32f);
  }
  const float inv_gsum = 1.f/gs;

  // ---- Phase 2: bottleneck path -> bn_vec -> film ----
  dwfused4_k<<<dim3(512,4),256,0,stream>>>(bott, spv, dwwT, dwb, bwinT, dwout);
  cnx_mfma3_k<<<968,512,0,stream>>>(dwout, lnw,lnb, W1p,pw1b, W2p,pw2b, cgam,
                                    bwinT, Wbp, bnpb, bnv, inv_gsum);
  film_k<<<512,256,0,stream>>>(bnv, ppb, bemb, fw, fb, film);

  // ---- Phase 1+3: window extract -> fused conv chain -> fused decoder ----
  extvwin_k<<<dim3(512,5),256,0,stream>>>(vis, spv, vwin);
  convchain_k<<<dim3(512,4),512,0,stream>>>(vwin, Pc1,ic1b, Pc2,ic2b, Pc3,ic3b, bufI);
  decfused_k<<<dim3(2048,4),256,0,stream>>>(bufI, Pd1,d1b, Pd2,d2b,
      film, d3w, d3b, out, sums);
  norm_k<<<dim3(2048,4),256,0,stream>>>(out, sums);
}

// Round 11
// 743.983 us; speedup vs baseline: 10.7067x; 1.0110x over previous
//
#include <hip/hip_runtime.h>
#include <cstdint>
#include <cstddef>
#include <cmath>

#define DEV __device__ __forceinline__

typedef __attribute__((ext_vector_type(8))) short bf16x8;
typedef __attribute__((ext_vector_type(4))) float f32x4;

// Abramowitz-Stegun 7.1.26 erf approx, |abs err| <= 1.5e-7
DEV float erf_fast(float x){
  float ax = fabsf(x);
  float t = __builtin_amdgcn_rcpf(fmaf(0.3275911f, ax, 1.f));
  float p = t*fmaf(t, fmaf(t, fmaf(t, fmaf(t, 1.061405429f, -1.453152027f),
             1.421413741f), -0.284496736f), 0.254829592f);
  float e = __expf(-ax*ax);
  float r = fmaf(-p, e, 1.f);
  return x >= 0.f ? r : -r;
}
DEV float gelu_f(float x){ return 0.5f*x*(1.0f + erf_fast(x*0.7071067811865476f)); }
DEV float softplus_f(float x){ return fmaxf(x,0.f) + log1pf(expf(-fabsf(x))); }
DEV unsigned short f2bf(float x){
  unsigned u = __float_as_uint(x);
  unsigned r = (u + 0x7fffu + ((u>>16)&1u)) >> 16;
  return (unsigned short)r;
}
DEV float bf2f(unsigned short h){
  unsigned u = ((unsigned)h) << 16;
  return __uint_as_float(u);
}

// ---------------------------------------------------------------------------
// Combined weight packing: 8 jobs in one launch.
// ---------------------------------------------------------------------------
struct PackJobs {
  const float* src[8];
  unsigned short* dst[8];
  int ntn[8], ntk[8], K[8], conv[8], base[8];
};

__global__ __launch_bounds__(256) void packall_k(PackJobs J)
{
  int blk = blockIdx.x;
  int j = 0;
#pragma unroll
  for (int i=1;i<8;++i) if (blk >= J.base[i]) j = i;
  int tid = (blk - J.base[j])*256 + threadIdx.x;
  const int ntk = J.ntk[j], K = J.K[j];
  int total = J.ntn[j]*ntk*64;
  if (tid >= total) return;
  int lane = tid & 63;
  int f = tid >> 6;
  int kt = f % ntk, nt = f / ntk;
  int row = nt*16 + (lane & 15);
  int k0 = kt*32 + (lane >> 4)*8;
  const float* src = J.src[j];
  unsigned short h[8];
  if (J.conv[j]) {
    const int Cin = K;
#pragma unroll
    for (int q=0;q<8;++q) {
      int k = k0 + q;
      int s = k / Cin;
      int ic = k - s*Cin;
      h[q] = f2bf(src[((size_t)row*Cin + ic)*9 + s]);
    }
  } else {
#pragma unroll
    for (int q=0;q<8;++q) h[q] = f2bf(src[(size_t)row*K + k0 + q]);
  }
  uint4 pk;
  pk.x = (unsigned)h[0] | ((unsigned)h[1]<<16);
  pk.y = (unsigned)h[2] | ((unsigned)h[3]<<16);
  pk.z = (unsigned)h[4] | ((unsigned)h[5]<<16);
  pk.w = (unsigned)h[6] | ((unsigned)h[7]<<16);
  *reinterpret_cast<uint4*>(J.dst[j] + (size_t)tid*8) = pk;
}

// dw weight transpose: wT[k][ch] = w[ch][k]  (49 x 256)
__global__ __launch_bounds__(256) void dwt_k(const float* __restrict__ w,
                                             float* __restrict__ wT)
{
  int k = blockIdx.x;
  int ch = threadIdx.x;
  wT[k*256 + ch] = w[(size_t)ch*49 + k];
}

// ---------------------------------------------------------------------------
// Extract clamped 33x33 vis windows (incl. conv zero ring) -> bf16 NHWC
// ---------------------------------------------------------------------------
__global__ __launch_bounds__(256) void extvwin_k(const float* __restrict__ vis,
                                                 const float* __restrict__ spv,
                                                 unsigned short* __restrict__ vwin)
{
  int il = blockIdx.x;
  int p = blockIdx.y*256 + threadIdx.x;
  if (p >= 1089) return;
  int wy = p/33, wx = p%33;
  unsigned short* dst = vwin + ((size_t)il*1089 + p)*64;
  if (wy==0 || wy==32 || wx==0 || wx==32) {
    uint4 z = {0,0,0,0};
#pragma unroll
    for (int q=0;q<8;++q) *reinterpret_cast<uint4*>(dst + q*8) = z;
    return;
  }
  int cx = (int)rintf(spv[il*2+0]);
  int cy = (int)rintf(spv[il*2+1]);
  int gy = min(max(cy + wy - 16, 0), 1023);
  int gx = min(max(cx + wx - 16, 0), 1023);
  const float* sp = vis + (size_t)gy*1024 + gx;
  unsigned short h[64];
#pragma unroll
  for (int c=0;c<64;++c) h[c] = f2bf(sp[(size_t)c<<20]);
#pragma unroll
  for (int q=0;q<8;++q) {
    uint4 pk;
    pk.x = (unsigned)h[q*8+0] | ((unsigned)h[q*8+1]<<16);
    pk.y = (unsigned)h[q*8+2] | ((unsigned)h[q*8+3]<<16);
    pk.z = (unsigned)h[q*8+4] | ((unsigned)h[q*8+5]<<16);
    pk.w = (unsigned)h[q*8+6] | ((unsigned)h[q*8+7]<<16);
    *reinterpret_cast<uint4*>(dst + q*8) = pk;
  }
}

// ---------------------------------------------------------------------------
// Fused intrinsic conv chain: c1(64->64,gelu) -> c2(64->64,gelu) ->
// c3(64->32, linear), all in LDS with halo recompute.
// ---------------------------------------------------------------------------
__global__ __launch_bounds__(512,2) void convchain_k(
    const unsigned short* __restrict__ vwin,
    const unsigned short* __restrict__ Wp1, const float* __restrict__ B1,
    const unsigned short* __restrict__ Wp2, const float* __restrict__ B2,
    const unsigned short* __restrict__ Wp3, const float* __restrict__ B3,
    unsigned short* __restrict__ outI)
{
  const int item = blockIdx.x;
  const int y0 = blockIdx.y*8;
  const int t = threadIdx.x;
  const int w = t>>6, l = t&63, g = l>>4, l15 = l&15;

  __shared__ __align__(16) unsigned short bufIn[462*64];
  __shared__ __align__(16) unsigned short bufC1[396*64];
  unsigned short* bufC2 = bufIn;

  const uint4 z4 = {0,0,0,0};

  for (int u=t; u<396*8; u+=512)
    *reinterpret_cast<uint4*>(bufC1 + u*8) = z4;
  for (int u=t; u<462*8; u+=512) {
    int slot = u & 7;
    int rowi = u >> 3;
    int r = rowi/33;
    int wy = y0 - 2 + r;
    uint4 val = z4;
    if ((unsigned)wy < 33u)
      val = *reinterpret_cast<const uint4*>(
          vwin + ((size_t)item*1089 + wy*33 + (rowi - r*33))*64 + slot*8);
    int ds = slot ^ (rowi & 7);
    *reinterpret_cast<uint4*>(&bufIn[rowi*64 + ds*8]) = val;
  }
  __syncthreads();

  // ---- c1 ----
  {
    int pbase[3], rowB[3]; bool pv[3];
#pragma unroll
    for (int pt=0; pt<3; ++pt) {
      int pd = (w*3+pt)*16 + l15;
      int pc = min(pd, 371);
      int ry = pc/31, rx = pc - ry*31;
      pbase[pt] = ry*33 + rx;
      rowB[pt] = ry*33 + rx + 1;
      int yab = y0 - 2 + ry;
      pv[pt] = (pd < 372) && ((unsigned)yab < 31u);
    }
    f32x4 a1[4][3];
#pragma unroll
    for (int o=0;o<4;++o)
#pragma unroll
      for (int pt=0;pt<3;++pt) a1[o][pt] = (f32x4){0.f,0.f,0.f,0.f};

    for (int kt=0; kt<18; ++kt) {
      int k0 = kt*32 + g*8;
      int s = k0 >> 6;
      int icg = (k0 - (s<<6)) >> 3;
      int roff = (s/3)*33 + (s - (s/3)*3);
      bf16x8 bf[3];
#pragma unroll
      for (int pt=0; pt<3; ++pt) {
        int rowi = pbase[pt] + roff;
        int ds = icg ^ (rowi & 7);
        bf[pt] = *reinterpret_cast<const bf16x8*>(&bufIn[rowi*64 + ds*8]);
      }
#pragma unroll
      for (int o=0; o<4; ++o) {
        bf16x8 af = *reinterpret_cast<const bf16x8*>(Wp1 + ((size_t)(o*18+kt)*64 + l)*8);
#pragma unroll
        for (int pt=0; pt<3; ++pt)
          a1[o][pt] = __builtin_amdgcn_mfma_f32_16x16x32_bf16(af, bf[pt], a1[o][pt], 0,0,0);
      }
    }
#pragma unroll
    for (int o=0; o<4; ++o) {
      float4 bv4 = *reinterpret_cast<const float4*>(B1 + o*16 + g*4);
      int sl = o*2 + (g>>1);
#pragma unroll
      for (int pt=0; pt<3; ++pt) {
        if (!pv[pt]) continue;
        float v0 = gelu_f(a1[o][pt][0] + bv4.x);
        float v1 = gelu_f(a1[o][pt][1] + bv4.y);
        float v2 = gelu_f(a1[o][pt][2] + bv4.z);
        float v3 = gelu_f(a1[o][pt][3] + bv4.w);
        uint2 pk;
        pk.x = (unsigned)f2bf(v0) | ((unsigned)f2bf(v1)<<16);
        pk.y = (unsigned)f2bf(v2) | ((unsigned)f2bf(v3)<<16);
        int phys = sl ^ (rowB[pt] & 7);
        *reinterpret_cast<uint2*>(&bufC1[rowB[pt]*64 + phys*8 + (g&1)*4]) = pk;
      }
    }
  }
  __syncthreads();

  for (int u=t; u<330*8; u+=512)
    *reinterpret_cast<uint4*>(bufC2 + u*8) = z4;
  __syncthreads();

  // ---- c2 ----
  {
    int pbase[3], rowB[3]; bool pv[3];
#pragma unroll
    for (int pt=0; pt<3; ++pt) {
      int pd = (w*3+pt)*16 + l15;
      int pc = min(pd, 309);
      int ry = pc/31, rx = pc - ry*31;
      pbase[pt] = ry*33 + rx;
      rowB[pt] = ry*33 + rx + 1;
      int yab = y0 - 1 + ry;
      pv[pt] = (pd < 310) && ((unsigned)yab < 31u);
    }
    f32x4 a2[4][3];
#pragma unroll
    for (int o=0;o<4;++o)
#pragma unroll
      for (int pt=0;pt<3;++pt) a2[o][pt] = (f32x4){0.f,0.f,0.f,0.f};

    for (int kt=0; kt<18; ++kt) {
      int k0 = kt*32 + g*8;
      int s = k0 >> 6;
      int icg = (k0 - (s<<6)) >> 3;
      int roff = (s/3)*33 + (s - (s/3)*3);
      bf16x8 bf[3];
#pragma unroll
      for (int pt=0; pt<3; ++pt) {
        int rowi = pbase[pt] + roff;
        int ds = icg ^ (rowi & 7);
        bf[pt] = *reinterpret_cast<const bf16x8*>(&bufC1[rowi*64 + ds*8]);
      }
#pragma unroll
      for (int o=0; o<4; ++o) {
        bf16x8 af = *reinterpret_cast<const bf16x8*>(Wp2 + ((size_t)(o*18+kt)*64 + l)*8);
#pragma unroll
        for (int pt=0; pt<3; ++pt)
          a2[o][pt] = __builtin_amdgcn_mfma_f32_16x16x32_bf16(af, bf[pt], a2[o][pt], 0,0,0);
      }
    }
#pragma unroll
    for (int o=0; o<4; ++o) {
      float4 bv4 = *reinterpret_cast<const float4*>(B2 + o*16 + g*4);
      int sl = o*2 + (g>>1);
#pragma unroll
      for (int pt=0; pt<3; ++pt) {
        if (!pv[pt]) continue;
        float v0 = gelu_f(a2[o][pt][0] + bv4.x);
        float v1 = gelu_f(a2[o][pt][1] + bv4.y);
        float v2 = gelu_f(a2[o][pt][2] + bv4.z);
        float v3 = gelu_f(a2[o][pt][3] + bv4.w);
        uint2 pk;
        pk.x = (unsigned)f2bf(v0) | ((unsigned)f2bf(v1)<<16);
        pk.y = (unsigned)f2bf(v2) | ((unsigned)f2bf(v3)<<16);
        int phys = sl ^ (rowB[pt] & 7);
        *reinterpret_cast<uint2*>(&bufC2[rowB[pt]*64 + phys*8 + (g&1)*4]) = pk;
      }
    }
  }
  __syncthreads();

  // ---- c3 ----
  {
    int pbase[2], gpos[2]; bool pv[2];
#pragma unroll
    for (int pt=0; pt<2; ++pt) {
      int pd = (w*2+pt)*16 + l15;
      int pc = min(pd, 247);
      int ry = pc/31, rx = pc - ry*31;
      pbase[pt] = ry*33 + rx;
      gpos[pt] = y0*31 + pd;
      pv[pt] = (pd < 248) && (gpos[pt] < 961);
    }
    f32x4 a3[2][2];
#pragma unroll
    for (int o=0;o<2;++o)
#pragma unroll
      for (int pt=0;pt<2;++pt) a3[o][pt] = (f32x4){0.f,0.f,0.f,0.f};

    for (int kt=0; kt<18; ++kt) {
      int k0 = kt*32 + g*8;
      int s = k0 >> 6;
      int icg = (k0 - (s<<6)) >> 3;
      int roff = (s/3)*33 + (s - (s/3)*3);
      bf16x8 bf[2];
#pragma unroll
      for (int pt=0; pt<2; ++pt) {
        int rowi = pbase[pt] + roff;
        int ds = icg ^ (rowi & 7);
        bf[pt] = *reinterpret_cast<const bf16x8*>(&bufC2[rowi*64 + ds*8]);
      }
#pragma unroll
      for (int o=0; o<2; ++o) {
        bf16x8 af = *reinterpret_cast<const bf16x8*>(Wp3 + ((size_t)(o*18+kt)*64 + l)*8);
#pragma unroll
        for (int pt=0; pt<2; ++pt)
          a3[o][pt] = __builtin_amdgcn_mfma_f32_16x16x32_bf16(af, bf[pt], a3[o][pt], 0,0,0);
      }
    }
#pragma unroll
    for (int o=0; o<2; ++o) {
      float4 bv4 = *reinterpret_cast<const float4*>(B3 + o*16 + g*4);
#pragma unroll
      for (int pt=0; pt<2; ++pt) {
        if (!pv[pt]) continue;
        float v0 = a3[o][pt][0] + bv4.x;
        float v1 = a3[o][pt][1] + bv4.y;
        float v2 = a3[o][pt][2] + bv4.z;
        float v3 = a3[o][pt][3] + bv4.w;
        uint2 pk;
        pk.x = (unsigned)f2bf(v0) | ((unsigned)f2bf(v1)<<16);
        pk.y = (unsigned)f2bf(v2) | ((unsigned)f2bf(v3)<<16);
        *reinterpret_cast<uint2*>(outI + ((size_t)item*961 + gpos[pt])*32 + o*16 + g*4) = pk;
      }
    }
  }
}

// ---------------------------------------------------------------------------
// Fused decoder v2: 16-row strips, 512 threads / 8 waves, 2 strips per item.
// FiLM+gelu staging -> dec1(3x3)+gelu -> dec2(3x3)+gelu -> dec3+softplus+sum.
// LDS A: 20x33x32 (rows y0-2..y0+17); LDS B: 18x33x32 (rows y0-1..y0+16).
// ---------------------------------------------------------------------------
__global__ __launch_bounds__(512,4) void decfused2_k(
    const unsigned short* __restrict__ intc,
    const unsigned short* __restrict__ Wp1, const float* __restrict__ B1,
    const unsigned short* __restrict__ Wp2, const float* __restrict__ B2,
    const float* __restrict__ film,
    const float* __restrict__ w3, const float* __restrict__ b3,
    float* __restrict__ outf, float* __restrict__ sums)
{
  const int item = blockIdx.x;
  const int y0 = blockIdx.y*16;
  const int t = threadIdx.x;
  const int w = t>>6, l = t&63, g = l>>4, l15 = l&15;

  __shared__ __align__(16) unsigned short ldsA[20*33*32];  // 42,240 B
  __shared__ __align__(16) unsigned short ldsB[18*33*32];  // 38,016 B

  const int sit = item >> 2;
  const float* frow = film + (size_t)item*64;

  // zero B
  for (int u=t; u<18*33*4; u+=512)
    *reinterpret_cast<uint4*>(ldsB + u*8) = (uint4){0,0,0,0};

  // stage A with FiLM + gelu (rows y0-2..y0+17)
  for (int u=t; u<20*33*4; u+=512) {
    int slot = u & 3;
    int rowi = u >> 2;
    int r = rowi/33, col = rowi - r*33;
    int y = y0 + r - 2, x = col - 1;
    uint4 val = {0,0,0,0};
    if ((unsigned)y < 31u && (unsigned)x < 31u) {
      val = *reinterpret_cast<const uint4*>(intc + ((size_t)sit*961 + y*31 + x)*32 + slot*8);
      int c0 = slot*8;
      float4 g0 = *reinterpret_cast<const float4*>(frow + c0);
      float4 g1 = *reinterpret_cast<const float4*>(frow + c0 + 4);
      float4 b0 = *reinterpret_cast<const float4*>(frow + 32 + c0);
      float4 b1 = *reinterpret_cast<const float4*>(frow + 32 + c0 + 4);
      unsigned short x8[8] = {
        (unsigned short)(val.x&0xffff),(unsigned short)(val.x>>16),
        (unsigned short)(val.y&0xffff),(unsigned short)(val.y>>16),
        (unsigned short)(val.z&0xffff),(unsigned short)(val.z>>16),
        (unsigned short)(val.w&0xffff),(unsigned short)(val.w>>16)};
      unsigned short o8[8];
      o8[0]=f2bf(gelu_f(fmaf(bf2f(x8[0]), 1.f+g0.x, b0.x)));
      o8[1]=f2bf(gelu_f(fmaf(bf2f(x8[1]), 1.f+g0.y, b0.y)));
      o8[2]=f2bf(gelu_f(fmaf(bf2f(x8[2]), 1.f+g0.z, b0.z)));
      o8[3]=f2bf(gelu_f(fmaf(bf2f(x8[3]), 1.f+g0.w, b0.w)));
      o8[4]=f2bf(gelu_f(fmaf(bf2f(x8[4]), 1.f+g1.x, b1.x)));
      o8[5]=f2bf(gelu_f(fmaf(bf2f(x8[5]), 1.f+g1.y, b1.y)));
      o8[6]=f2bf(gelu_f(fmaf(bf2f(x8[6]), 1.f+g1.z, b1.z)));
      o8[7]=f2bf(gelu_f(fmaf(bf2f(x8[7]), 1.f+g1.w, b1.w)));
      val.x = (unsigned)o8[0] | ((unsigned)o8[1]<<16);
      val.y = (unsigned)o8[2] | ((unsigned)o8[3]<<16);
      val.z = (unsigned)o8[4] | ((unsigned)o8[5]<<16);
      val.w = (unsigned)o8[6] | ((unsigned)o8[7]<<16);
    }
    int ds = slot ^ (rowi & 3);
    *reinterpret_cast<uint4*>(&ldsA[rowi*32 + ds*8]) = val;
  }
  __syncthreads();

  // ---- dec1: 18 rows x 31 cols (558 pos, 40 tiles, 5/wave), gelu -> ldsB ----
  {
    int pbase[5], rowB[5]; bool pv[5];
#pragma unroll
    for (int pt=0; pt<5; ++pt) {
      int pd = (w*5+pt)*16 + l15;
      int pc = min(pd, 557);
      int ry = pc/31, rx = pc - ry*31;
      pbase[pt] = ry*33 + rx;
      rowB[pt] = ry*33 + rx + 1;
      int gy = y0 - 1 + ry;
      pv[pt] = (pd < 558) && ((unsigned)gy < 31u);
    }
    f32x4 a1[2][5];
#pragma unroll
    for (int o=0;o<2;++o)
#pragma unroll
      for (int pt=0;pt<5;++pt) a1[o][pt] = (f32x4){0.f,0.f,0.f,0.f};

    for (int kt=0; kt<9; ++kt) {
      int roff = (kt/3)*33 + (kt - (kt/3)*3);
      bf16x8 bf[5];
#pragma unroll
      for (int pt=0; pt<5; ++pt) {
        int rowi = pbase[pt] + roff;
        int ds = g ^ (rowi & 3);
        bf[pt] = *reinterpret_cast<const bf16x8*>(&ldsA[rowi*32 + ds*8]);
      }
#pragma unroll
      for (int o=0; o<2; ++o) {
        bf16x8 af = *reinterpret_cast<const bf16x8*>(Wp1 + ((size_t)(o*9+kt)*64 + l)*8);
#pragma unroll
        for (int pt=0; pt<5; ++pt)
          a1[o][pt] = __builtin_amdgcn_mfma_f32_16x16x32_bf16(af, bf[pt], a1[o][pt], 0,0,0);
      }
    }
#pragma unroll
    for (int o=0; o<2; ++o) {
      float4 bv4 = *reinterpret_cast<const float4*>(B1 + o*16 + g*4);
      int sl = o*2 + (g>>1);
#pragma unroll
      for (int pt=0; pt<5; ++pt) {
        if (!pv[pt]) continue;
        float v0 = gelu_f(a1[o][pt][0] + bv4.x);
        float v1 = gelu_f(a1[o][pt][1] + bv4.y);
        float v2 = gelu_f(a1[o][pt][2] + bv4.z);
        float v3 = gelu_f(a1[o][pt][3] + bv4.w);
        uint2 pk;
        pk.x = (unsigned)f2bf(v0) | ((unsigned)f2bf(v1)<<16);
        pk.y = (unsigned)f2bf(v2) | ((unsigned)f2bf(v3)<<16);
        int phys = sl ^ (rowB[pt] & 3);
        *reinterpret_cast<uint2*>(&ldsB[rowB[pt]*32 + phys*8 + (g&1)*4]) = pk;
      }
    }
  }
  __syncthreads();

  // ---- dec2 + gelu + dec3(1x1) + softplus + per-map sum ----
  float bsum = 0.f;
  {
    int pbase[4], gpos[4]; bool pv[4];
#pragma unroll
    for (int pt=0; pt<4; ++pt) {
      int pd = (w*4+pt)*16 + l15;
      int pc = min(pd, 495);
      int py = pc/31, px = pc - py*31;
      pbase[pt] = py*33 + px;
      gpos[pt] = y0*31 + pd;
      pv[pt] = (pd < 496) && (gpos[pt] < 961);
    }
    f32x4 a2[2][4];
#pragma unroll
    for (int o=0;o<2;++o)
#pragma unroll
      for (int pt=0;pt<4;++pt) a2[o][pt] = (f32x4){0.f,0.f,0.f,0.f};

    for (int kt=0; kt<9; ++kt) {
      int roff = (kt/3)*33 + (kt - (kt/3)*3);
      bf16x8 bf[4];
#pragma unroll
      for (int pt=0; pt<4; ++pt) {
        int rowi = pbase[pt] + roff;
        int ds = g ^ (rowi & 3);
        bf[pt] = *reinterpret_cast<const bf16x8*>(&ldsB[rowi*32 + ds*8]);
      }
#pragma unroll
      for (int o=0; o<2; ++o) {
        bf16x8 af = *reinterpret_cast<const bf16x8*>(Wp2 + ((size_t)(o*9+kt)*64 + l)*8);
#pragma unroll
        for (int pt=0; pt<4; ++pt)
          a2[o][pt] = __builtin_amdgcn_mfma_f32_16x16x32_bf16(af, bf[pt], a2[o][pt], 0,0,0);
      }
    }

    float w3r[8];
#pragma unroll
    for (int o=0;o<2;++o) {
      float4 wv = *reinterpret_cast<const float4*>(w3 + o*16 + g*4);
      w3r[o*4+0]=wv.x; w3r[o*4+1]=wv.y; w3r[o*4+2]=wv.z; w3r[o*4+3]=wv.w;
    }
    float b3v = b3[0];
#pragma unroll
    for (int pt=0; pt<4; ++pt) {
      float part = 0.f;
#pragma unroll
      for (int o=0; o<2; ++o) {
        float4 bv4 = *reinterpret_cast<const float4*>(B2 + o*16 + g*4);
        float v0 = gelu_f(a2[o][pt][0] + bv4.x);
        float v1 = gelu_f(a2[o][pt][1] + bv4.y);
        float v2 = gelu_f(a2[o][pt][2] + bv4.z);
        float v3 = gelu_f(a2[o][pt][3] + bv4.w);
        part += v0*w3r[o*4+0] + v1*w3r[o*4+1] + v2*w3r[o*4+2] + v3*w3r[o*4+3];
      }
      part += __shfl_xor(part, 16);
      part += __shfl_xor(part, 32);
      float sp = softplus_f(part + b3v);
      if (pv[pt] && g==0) {
        outf[(size_t)item*961 + gpos[pt]] = sp;
        bsum += sp;
      }
    }
  }
  // block reduce into sums[item]
  {
    float* redf = reinterpret_cast<float*>(ldsA);
    redf[t] = bsum;
    __syncthreads();
    for (int off=256; off>0; off>>=1) {
      if (t < off) redf[t] += redf[t+off];
      __syncthreads();
    }
    if (t==0) atomicAdd(&sums[item], redf[0]);
  }
}

// ---------------------------------------------------------------------------
// Fused bottleneck-window gather + depthwise 7x7, channel-sliced, row-reuse.
// ---------------------------------------------------------------------------
__global__ __launch_bounds__(256,4) void dwfused4_k(
    const float* __restrict__ bott, const float* __restrict__ spv,
    const float* __restrict__ wT, const float* __restrict__ b,
    unsigned short* __restrict__ bwinT, unsigned short* __restrict__ dwout)
{
  const int n = blockIdx.x, cs = blockIdx.y*64, t = threadIdx.x;
  __shared__ float tile[121*66];

  float pxf = fminf(fmaxf(spv[n*2+0]*0.25f, 0.f), 255.f);
  float pyf = fminf(fmaxf(spv[n*2+1]*0.25f, 0.f), 255.f);
  int cx = (int)rintf(pxf), cy = (int)rintf(pyf);

  for (int idx=t; idx<121*32; idx+=256) {
    int j = idx/121, p = idx - j*121;
    int y = p/11, x = p - y*11;
    int gy = min(max(cy + y - 5, 0), 255);
    int gx = min(max(cx + x - 5, 0), 255);
    const float* s0 = bott + ((size_t)(cs+2*j)<<16) + (gy<<8) + gx;
    *reinterpret_cast<float2*>(&tile[p*66 + 2*j]) = (float2){s0[0], s0[65536]};
  }
  __syncthreads();

  for (int idx=t; idx<121*64; idx+=256) {
    int p = idx >> 6, c = idx & 63;
    bwinT[((size_t)n*121 + p)*256 + cs + c] = f2bf(tile[p*66 + c]);
  }

  const int c = t & 63, ph = t >> 6;
  const int ch = cs + c;
  const float bias = b[ch];

  for (int y=ph; y<11; y+=4) {
    float acc[11];
#pragma unroll
    for (int x=0;x<11;++x) acc[x] = bias;
#pragma unroll
    for (int dy=0; dy<7; ++dy) {
      int yy = y + dy - 3;
      if ((unsigned)yy < 11u) {
        float r[11];
#pragma unroll
        for (int k=0;k<11;++k) r[k] = tile[(yy*11+k)*66 + c];
        float w7[7];
#pragma unroll
        for (int j=0;j<7;++j) w7[j] = wT[(dy*7+j)*256 + ch];
#pragma unroll
        for (int x=0;x<11;++x) {
#pragma unroll
          for (int dx=0;dx<7;++dx) {
            int xx = x + dx - 3;
            if (xx >= 0 && xx < 11)
              acc[x] = fmaf(r[xx], w7[dx], acc[x]);
          }
        }
      }
    }
#pragma unroll
    for (int x=0;x<11;++x)
      dwout[((size_t)n*121 + y*11 + x)*256 + ch] = f2bf(acc[x]);
  }
}

// ---------------------------------------------------------------------------
// Fused ConvNeXt MLP + bnp head, bf16 MFMA. 512 threads / 8 waves, 64 rows.
// ---------------------------------------------------------------------------
__global__ __launch_bounds__(512,4) void cnx_mfma3_k(
    const unsigned short* __restrict__ xin,
    const float* __restrict__ lnw, const float* __restrict__ lnb,
    const unsigned short* __restrict__ W1p, const float* __restrict__ B1,
    const unsigned short* __restrict__ W2p, const float* __restrict__ B2,
    const float* __restrict__ gvec,
    const unsigned short* __restrict__ bwinT,
    const unsigned short* __restrict__ Wbp, const float* __restrict__ bnpb,
    float* __restrict__ bnv, float inv_gsum)
{
  const int t = threadIdx.x;
  const int w = t >> 6;
  const int l = t & 63;
  const int g = l >> 4;
  const int l15 = l & 15;
  const int row0 = blockIdx.x * 64;

  __shared__ __align__(16) unsigned short xs[64*264];
  __shared__ __align__(16) unsigned short hs[64*136];

  {
    const int rl = t >> 3, q = t & 7;
    const unsigned short* xr = xin + (size_t)(row0+rl)*256 + q*32;
    float xv[32]; float s = 0.f, s2 = 0.f;
#pragma unroll
    for (int i=0;i<32;i+=8){
      uint4 v = *reinterpret_cast<const uint4*>(xr+i);
      unsigned short xh[8] = {
        (unsigned short)(v.x&0xffff),(unsigned short)(v.x>>16),
        (unsigned short)(v.y&0xffff),(unsigned short)(v.y>>16),
        (unsigned short)(v.z&0xffff),(unsigned short)(v.z>>16),
        (unsigned short)(v.w&0xffff),(unsigned short)(v.w>>16)};
#pragma unroll
      for (int j=0;j<8;++j){
        float f = bf2f(xh[j]);
        xv[i+j] = f; s += f; s2 += f*f;
      }
    }
    s += __shfl_xor(s,1); s2 += __shfl_xor(s2,1);
    s += __shfl_xor(s,2); s2 += __shfl_xor(s2,2);
    s += __shfl_xor(s,4); s2 += __shfl_xor(s2,4);
    float mu = s*(1.f/256.f);
    float rstd = rsqrtf(s2*(1.f/256.f) - mu*mu + 1e-6f);
#pragma unroll
    for (int i=0;i<32;i+=8){
      int c = q*32 + i;
      float4 w0 = *reinterpret_cast<const float4*>(lnw+c);
      float4 w1 = *reinterpret_cast<const float4*>(lnw+c+4);
      float4 b0 = *reinterpret_cast<const float4*>(lnb+c);
      float4 b1 = *reinterpret_cast<const float4*>(lnb+c+4);
      unsigned short h[8];
      h[0]=f2bf(fmaf((xv[i+0]-mu)*rstd, w0.x, b0.x));
      h[1]=f2bf(fmaf((xv[i+1]-mu)*rstd, w0.y, b0.y));
      h[2]=f2bf(fmaf((xv[i+2]-mu)*rstd, w0.z, b0.z));
      h[3]=f2bf(fmaf((xv[i+3]-mu)*rstd, w0.w, b0.w));
      h[4]=f2bf(fmaf((xv[i+4]-mu)*rstd, w1.x, b1.x));
      h[5]=f2bf(fmaf((xv[i+5]-mu)*rstd, w1.y, b1.y));
      h[6]=f2bf(fmaf((xv[i+6]-mu)*rstd, w1.z, b1.z));
      h[7]=f2bf(fmaf((xv[i+7]-mu)*rstd, w1.w, b1.w));
      uint4 pk;
      pk.x = (unsigned)h[0] | ((unsigned)h[1]<<16);
      pk.y = (unsigned)h[2] | ((unsigned)h[3]<<16);
      pk.z = (unsigned)h[4] | ((unsigned)h[5]<<16);
      pk.w = (unsigned)h[6] | ((unsigned)h[7]<<16);
      *reinterpret_cast<uint4*>(&xs[rl*264 + c]) = pk;
    }
  }
  __syncthreads();

  f32x4 acc2[8];
#pragma unroll
  for (int i=0;i<8;++i) acc2[i] = (f32x4){0.f,0.f,0.f,0.f};

  for (int hc=0; hc<8; ++hc) {
    const int ht = hc*8 + w;
    f32x4 acc1[4];
#pragma unroll
    for (int i=0;i<4;++i) acc1[i] = (f32x4){0.f,0.f,0.f,0.f};

#pragma unroll
    for (int kt=0; kt<8; ++kt) {
      bf16x8 xf[4];
#pragma unroll
      for (int rt=0; rt<4; ++rt)
        xf[rt] = *reinterpret_cast<const bf16x8*>(&xs[(rt*16+l15)*264 + kt*32 + g*8]);
      bf16x8 wf = *reinterpret_cast<const bf16x8*>(W1p + ((size_t)(ht*8+kt)*64 + l)*8);
#pragma unroll
      for (int rt=0; rt<4; ++rt)
        acc1[rt] = __builtin_amdgcn_mfma_f32_16x16x32_bf16(wf, xf[rt], acc1[rt], 0,0,0);
    }
    {
      const int hb = hc*128 + w*16 + 4*g;
      float4 b1v = *reinterpret_cast<const float4*>(B1 + hb);
#pragma unroll
      for (int rt=0; rt<4; ++rt) {
        unsigned short h0 = f2bf(gelu_f(acc1[rt][0] + b1v.x));
        unsigned short h1 = f2bf(gelu_f(acc1[rt][1] + b1v.y));
        unsigned short h2 = f2bf(gelu_f(acc1[rt][2] + b1v.z));
        unsigned short h3 = f2bf(gelu_f(acc1[rt][3] + b1v.w));
        uint2 pk;
        pk.x = (unsigned)h0 | ((unsigned)h1<<16);
        pk.y = (unsigned)h2 | ((unsigned)h3<<16);
        *reinterpret_cast<uint2*>(&hs[(rt*16+l15)*136 + w*16 + 4*g]) = pk;
      }
    }
    __syncthreads();
#pragma unroll
    for (int kt=0; kt<4; ++kt) {
      bf16x8 hf[4];
#pragma unroll
      for (int rt=0; rt<4; ++rt)
        hf[rt] = *reinterpret_cast<const bf16x8*>(&hs[(rt*16+l15)*136 + kt*32 + g*8]);
#pragma unroll
      for (int cj=0; cj<2; ++cj) {
        const int ct = 2*w + cj;
        bf16x8 wf = *reinterpret_cast<const bf16x8*>(W2p + ((size_t)(ct*32 + hc*4 + kt)*64 + l)*8);
#pragma unroll
        for (int rt=0; rt<4; ++rt)
          acc2[cj*4+rt] = __builtin_amdgcn_mfma_f32_16x16x32_bf16(hf[rt], wf, acc2[cj*4+rt], 0,0,0);
      }
    }
    __syncthreads();
  }

#pragma unroll
  for (int cj=0; cj<2; ++cj) {
    const int c = (2*w+cj)*16 + l15;
    const float b2 = B2[c], gm = gvec[c];
#pragma unroll
    for (int rt=0; rt<4; ++rt) {
#pragma unroll
      for (int reg=0; reg<4; ++reg) {
        int row = rt*16 + 4*g + reg;
        float res = bf2f(bwinT[(size_t)(row0+row)*256 + c]) + (acc2[cj*4+rt][reg] + b2)*gm;
        xs[row*264 + c] = f2bf(res);
      }
    }
  }
  __syncthreads();

  {
    const int oct = w & 3;
    f32x4 abn[2];
#pragma unroll
    for (int i=0;i<2;++i) abn[i] = (f32x4){0.f,0.f,0.f,0.f};
#pragma unroll
    for (int kt=0; kt<8; ++kt) {
      bf16x8 bfw = *reinterpret_cast<const bf16x8*>(Wbp + ((size_t)(oct*8+kt)*64 + l)*8);
#pragma unroll
      for (int i=0;i<2;++i) {
        const int rt = (w>>2) + 2*i;
        bf16x8 af = *reinterpret_cast<const bf16x8*>(&xs[(rt*16+l15)*264 + kt*32 + g*8]);
        abn[i] = __builtin_amdgcn_mfma_f32_16x16x32_bf16(af, bfw, abn[i], 0,0,0);
      }
    }

    float* red = reinterpret_cast<float*>(hs);
#pragma unroll
    for (int i=0;i<2;++i) {
      const int rt = (w>>2) + 2*i;
      float bv = bnpb[oct*16 + l15];
#pragma unroll
      for (int reg=0; reg<4; ++reg) {
        int lr = rt*16 + g*4 + reg;
        int p = (row0 + lr) % 121;
        int py=p/11, px=p-py*11;
        float ly=-1.f+0.2f*py, lx=-1.f+0.2f*px;
        float wg = __expf(-(lx*lx+ly*ly)/0.32f) * inv_gsum;
        red[lr*64 + oct*16 + l15] = gelu_f(abn[i][reg] + bv) * wg;
      }
    }
  }
  __syncthreads();
  {
    float* red = reinterpret_cast<float*>(hs);
    int oc = t & 63, seg = t >> 6;
    float s = 0.f;
    int curn = (row0 + seg*8) / 121;
    for (int i=0;i<8;++i) {
      int row = seg*8 + i;
      int n = (row0 + row) / 121;
      if (n != curn) { atomicAdd(&bnv[curn*64 + oc], s); s = 0.f; curn = n; }
      s += red[row*64 + oc];
    }
    atomicAdd(&bnv[curn*64 + oc], s);
  }
}

// ---------------------------------------------------------------------------
// FiLM
// ---------------------------------------------------------------------------
__global__ __launch_bounds__(256) void film_k(
    const float* __restrict__ bn_vec, const float* __restrict__ ppb,
    const float* __restrict__ bemb, const float* __restrict__ fw,
    const float* __restrict__ fb, float* __restrict__ film)
{
  int n = blockIdx.x, t = threadIdx.x;
  __shared__ float cond[4][84];
  for (int i=t; i<4*84; i+=256) {
    int b = i/84, j = i%84;
    float v;
    if (j < 16) v = bemb[b*16 + j];
    else if (j == 16) { float p = ppb[((size_t)n*4+b)*2+0]; v = fminf(fmaxf(p*(1.f/1023.f),0.f),1.f); }
    else if (j == 17) { float p = ppb[((size_t)n*4+b)*2+1]; v = fminf(fmaxf(p*(1.f/1023.f),0.f),1.f); }
    else if (j == 18) { float p = ppb[((size_t)n*4+b)*2+0]; v = p - rintf(p); }
    else if (j == 19) { float p = ppb[((size_t)n*4+b)*2+1]; v = p - rintf(p); }
    else v = bn_vec[n*64 + (j-20)];
    cond[b][j] = v;
  }
  __syncthreads();
  int b = t >> 6, oc = t & 63;
  float s = fb[oc];
  for (int j=0;j<84;++j) s = fmaf(cond[b][j], fw[oc*84+j], s);
  film[((size_t)n*4+b)*64 + oc] = s;
}

// ---------------------------------------------------------------------------
// final per-map normalization
// ---------------------------------------------------------------------------
__global__ __launch_bounds__(256) void norm_k(float* __restrict__ out,
                                              const float* __restrict__ sums)
{
  int il = blockIdx.x;
  int p = blockIdx.y*256 + threadIdx.x;
  if (p < 961) {
    float inv = 1.f / fmaxf(sums[il], 1e-8f);
    out[(size_t)il*961 + p] *= inv;
  }
}

// ---------------------------------------------------------------------------
extern "C" void kernel_launch(void* const* d_in, const int* in_sizes, int n_in,
                              void* d_out, int out_size, void* d_ws, size_t ws_size,
                              hipStream_t stream)
{
  const float* bott = (const float*)d_in[0];
  const float* vis  = (const float*)d_in[1];
  const float* spv  = (const float*)d_in[2];
  const float* ppb  = (const float*)d_in[3];
  const float* ic1w = (const float*)d_in[4];  const float* ic1b = (const float*)d_in[5];
  const float* ic2w = (const float*)d_in[6];  const float* ic2b = (const float*)d_in[7];
  const float* ic3w = (const float*)d_in[8];  const float* ic3b = (const float*)d_in[9];
  const float* dww  = (const float*)d_in[10]; const float* dwb  = (const float*)d_in[11];
  const float* lnw  = (const float*)d_in[12]; const float* lnb  = (const float*)d_in[13];
  const float* pw1w = (const float*)d_in[14]; const float* pw1b = (const float*)d_in[15];
  const float* pw2w = (const float*)d_in[16]; const float* pw2b = (const float*)d_in[17];
  const float* cgam = (const float*)d_in[18];
  const float* bnpw = (const float*)d_in[19]; const float* bnpb = (const float*)d_in[20];
  const float* bemb = (const float*)d_in[21];
  const float* fw   = (const float*)d_in[22]; const float* fb   = (const float*)d_in[23];
  const float* d1w  = (const float*)d_in[24]; const float* d1b  = (const float*)d_in[25];
  const float* d2w  = (const float*)d_in[26]; const float* d2b  = (const float*)d_in[27];
  const float* d3w  = (const float*)d_in[28]; const float* d3b  = (const float*)d_in[29];
  float* out = (float*)d_out;

  char* ws = (char*)d_ws;

  unsigned short* bwinT = (unsigned short*)(ws);
  unsigned short* dwout = (unsigned short*)(ws + 31719424);
  unsigned short* vwin  = (unsigned short*)(ws);
  unsigned short* bufI  = (unsigned short*)(ws + 71368704);
  size_t tail = 102858752;

  float* bnv  = (float*)(ws + tail);
  float* sums = (float*)(ws + tail + 131072);
  float* film = (float*)(ws + tail + 139264);
  unsigned short* W1p = (unsigned short*)(ws + tail + 663552);
  unsigned short* W2p = (unsigned short*)(ws + tail + 1187840);
  unsigned short* Wbp = (unsigned short*)(ws + tail + 1712128);
  unsigned short* Pc1 = (unsigned short*)(ws + tail + 1744896);
  unsigned short* Pc2 = (unsigned short*)(ws + tail + 1818624);
  unsigned short* Pc3 = (unsigned short*)(ws + tail + 1892352);
  unsigned short* Pd1 = (unsigned short*)(ws + tail + 1929216);
  unsigned short* Pd2 = (unsigned short*)(ws + tail + 1947648);
  float* dwwT = (float*)(ws + tail + 1966080);

  {
    PackJobs J;
    const float* srcs[8] = {pw1w, pw2w, bnpw, ic1w, ic2w, ic3w, d1w, d2w};
    unsigned short* dsts[8] = {W1p, W2p, Wbp, Pc1, Pc2, Pc3, Pd1, Pd2};
    int ntns[8] = {64,16,4, 4,4,2, 2,2};
    int ntks[8] = {8,32,8, 18,18,18, 9,9};
    int Ks[8]   = {256,1024,256, 64,64,64, 32,32};
    int convs[8]= {0,0,0, 1,1,1, 1,1};
    int base = 0;
    for (int i=0;i<8;++i) {
      J.src[i]=srcs[i]; J.dst[i]=dsts[i]; J.ntn[i]=ntns[i]; J.ntk[i]=ntks[i];
      J.K[i]=Ks[i]; J.conv[i]=convs[i]; J.base[i]=base;
      base += (ntns[i]*ntks[i]*64 + 255)/256;
    }
    packall_k<<<base,256,0,stream>>>(J);
  }
  dwt_k<<<49,256,0,stream>>>(dww, dwwT);

  hipMemsetAsync(ws + tail, 0, 139264, stream);  // bnv + sums

  float gs = 0.f;
  for (int py=0; py<11; ++py) for (int px=0; px<11; ++px) {
    float ly=-1.f+0.2f*py, lx=-1.f+0.2f*px;
    gs += expf(-(lx*lx+ly*ly)/0.32f);
  }
  const float inv_gsum = 1.f/gs;

  // ---- Phase 2: bottleneck path -> bn_vec -> film ----
  dwfused4_k<<<dim3(512,4),256,0,stream>>>(bott, spv, dwwT, dwb, bwinT, dwout);
  cnx_mfma3_k<<<968,512,0,stream>>>(dwout, lnw,lnb, W1p,pw1b, W2p,pw2b, cgam,
                                    bwinT, Wbp, bnpb, bnv, inv_gsum);
  film_k<<<512,256,0,stream>>>(bnv, ppb, bemb, fw, fb, film);

  // ---- Phase 1+3: window extract -> fused conv chain -> fused decoder ----
  extvwin_k<<<dim3(512,5),256,0,stream>>>(vis, spv, vwin);
  convchain_k<<<dim3(512,4),512,0,stream>>>(vwin, Pc1,ic1b, Pc2,ic2b, Pc3,ic3b, bufI);
  decfused2_k<<<dim3(2048,2),512,0,stream>>>(bufI, Pd1,d1b, Pd2,d2b,
      film, d3w, d3b, out, sums);
  norm_k<<<dim3(2048,4),256,0,stream>>>(out, sums);
}

// Round 12
// 699.910 us; speedup vs baseline: 11.3809x; 1.0630x over previous
//
#include <hip/hip_runtime.h>
#include <hip/hip_bf16.h>
#include <cstdint>
#include <cstddef>
#include <cmath>

#define DEV __device__ __forceinline__

typedef __attribute__((ext_vector_type(8))) short bf16x8;
typedef __attribute__((ext_vector_type(4))) float f32x4;

// Abramowitz-Stegun 7.1.26 erf approx, |abs err| <= 1.5e-7
DEV float erf_fast(float x){
  float ax = fabsf(x);
  float t = __builtin_amdgcn_rcpf(fmaf(0.3275911f, ax, 1.f));
  float p = t*fmaf(t, fmaf(t, fmaf(t, fmaf(t, 1.061405429f, -1.453152027f),
             1.421413741f), -0.284496736f), 0.254829592f);
  float e = __expf(-ax*ax);
  float r = fmaf(-p, e, 1.f);
  return x >= 0.f ? r : -r;
}
DEV float gelu_f(float x){ return 0.5f*x*(1.0f + erf_fast(x*0.7071067811865476f)); }
DEV float softplus_f(float x){ return fmaxf(x,0.f) + log1pf(expf(-fabsf(x))); }
DEV unsigned short f2bf(float x){
  __hip_bfloat16 h = __float2bfloat16(x);          // hw v_cvt (RNE), 1 op
  return reinterpret_cast<unsigned short&>(h);
}
DEV float bf2f(unsigned short h){
  unsigned u = ((unsigned)h) << 16;
  return __uint_as_float(u);
}

// ---------------------------------------------------------------------------
// Combined weight packing: 8 jobs in one launch.
// ---------------------------------------------------------------------------
struct PackJobs {
  const float* src[8];
  unsigned short* dst[8];
  int ntn[8], ntk[8], K[8], conv[8], base[8];
};

__global__ __launch_bounds__(256) void packall_k(PackJobs J)
{
  int blk = blockIdx.x;
  int j = 0;
#pragma unroll
  for (int i=1;i<8;++i) if (blk >= J.base[i]) j = i;
  int tid = (blk - J.base[j])*256 + threadIdx.x;
  const int ntk = J.ntk[j], K = J.K[j];
  int total = J.ntn[j]*ntk*64;
  if (tid >= total) return;
  int lane = tid & 63;
  int f = tid >> 6;
  int kt = f % ntk, nt = f / ntk;
  int row = nt*16 + (lane & 15);
  int k0 = kt*32 + (lane >> 4)*8;
  const float* src = J.src[j];
  unsigned short h[8];
  if (J.conv[j]) {
    const int Cin = K;
#pragma unroll
    for (int q=0;q<8;++q) {
      int k = k0 + q;
      int s = k / Cin;
      int ic = k - s*Cin;
      h[q] = f2bf(src[((size_t)row*Cin + ic)*9 + s]);
    }
  } else {
#pragma unroll
    for (int q=0;q<8;++q) h[q] = f2bf(src[(size_t)row*K + k0 + q]);
  }
  uint4 pk;
  pk.x = (unsigned)h[0] | ((unsigned)h[1]<<16);
  pk.y = (unsigned)h[2] | ((unsigned)h[3]<<16);
  pk.z = (unsigned)h[4] | ((unsigned)h[5]<<16);
  pk.w = (unsigned)h[6] | ((unsigned)h[7]<<16);
  *reinterpret_cast<uint4*>(J.dst[j] + (size_t)tid*8) = pk;
}

// dw weight transpose: wT[k][ch] = w[ch][k]  (49 x 256)
__global__ __launch_bounds__(256) void dwt_k(const float* __restrict__ w,
                                             float* __restrict__ wT)
{
  int k = blockIdx.x;
  int ch = threadIdx.x;
  wT[k*256 + ch] = w[(size_t)ch*49 + k];
}

// ---------------------------------------------------------------------------
// Extract clamped 33x33 vis windows (incl. conv zero ring) -> bf16 NHWC
// ---------------------------------------------------------------------------
__global__ __launch_bounds__(256) void extvwin_k(const float* __restrict__ vis,
                                                 const float* __restrict__ spv,
                                                 unsigned short* __restrict__ vwin)
{
  int il = blockIdx.x;
  int p = blockIdx.y*256 + threadIdx.x;
  if (p >= 1089) return;
  int wy = p/33, wx = p%33;
  unsigned short* dst = vwin + ((size_t)il*1089 + p)*64;
  if (wy==0 || wy==32 || wx==0 || wx==32) {
    uint4 z = {0,0,0,0};
#pragma unroll
    for (int q=0;q<8;++q) *reinterpret_cast<uint4*>(dst + q*8) = z;
    return;
  }
  int cx = (int)rintf(spv[il*2+0]);
  int cy = (int)rintf(spv[il*2+1]);
  int gy = min(max(cy + wy - 16, 0), 1023);
  int gx = min(max(cx + wx - 16, 0), 1023);
  const float* sp = vis + (size_t)gy*1024 + gx;
  unsigned short h[64];
#pragma unroll
  for (int c=0;c<64;++c) h[c] = f2bf(sp[(size_t)c<<20]);
#pragma unroll
  for (int q=0;q<8;++q) {
    uint4 pk;
    pk.x = (unsigned)h[q*8+0] | ((unsigned)h[q*8+1]<<16);
    pk.y = (unsigned)h[q*8+2] | ((unsigned)h[q*8+3]<<16);
    pk.z = (unsigned)h[q*8+4] | ((unsigned)h[q*8+5]<<16);
    pk.w = (unsigned)h[q*8+6] | ((unsigned)h[q*8+7]<<16);
    *reinterpret_cast<uint4*>(dst + q*8) = pk;
  }
}

// ---------------------------------------------------------------------------
// Fused intrinsic conv chain: c1(64->64,gelu) -> c2(64->64,gelu) ->
// c3(64->32, linear), all in LDS with halo recompute.
// ---------------------------------------------------------------------------
__global__ __launch_bounds__(512,2) void convchain_k(
    const unsigned short* __restrict__ vwin,
    const unsigned short* __restrict__ Wp1, const float* __restrict__ B1,
    const unsigned short* __restrict__ Wp2, const float* __restrict__ B2,
    const unsigned short* __restrict__ Wp3, const float* __restrict__ B3,
    unsigned short* __restrict__ outI)
{
  const int item = blockIdx.x;
  const int y0 = blockIdx.y*8;
  const int t = threadIdx.x;
  const int w = t>>6, l = t&63, g = l>>4, l15 = l&15;

  __shared__ __align__(16) unsigned short bufIn[462*64];
  __shared__ __align__(16) unsigned short bufC1[396*64];
  unsigned short* bufC2 = bufIn;

  const uint4 z4 = {0,0,0,0};

  for (int u=t; u<396*8; u+=512)
    *reinterpret_cast<uint4*>(bufC1 + u*8) = z4;
  for (int u=t; u<462*8; u+=512) {
    int slot = u & 7;
    int rowi = u >> 3;
    int r = rowi/33;
    int wy = y0 - 2 + r;
    uint4 val = z4;
    if ((unsigned)wy < 33u)
      val = *reinterpret_cast<const uint4*>(
          vwin + ((size_t)item*1089 + wy*33 + (rowi - r*33))*64 + slot*8);
    int ds = slot ^ (rowi & 7);
    *reinterpret_cast<uint4*>(&bufIn[rowi*64 + ds*8]) = val;
  }
  __syncthreads();

  // ---- c1 ----
  {
    int pbase[3], rowB[3]; bool pv[3];
#pragma unroll
    for (int pt=0; pt<3; ++pt) {
      int pd = (w*3+pt)*16 + l15;
      int pc = min(pd, 371);
      int ry = pc/31, rx = pc - ry*31;
      pbase[pt] = ry*33 + rx;
      rowB[pt] = ry*33 + rx + 1;
      int yab = y0 - 2 + ry;
      pv[pt] = (pd < 372) && ((unsigned)yab < 31u);
    }
    f32x4 a1[4][3];
#pragma unroll
    for (int o=0;o<4;++o)
#pragma unroll
      for (int pt=0;pt<3;++pt) a1[o][pt] = (f32x4){0.f,0.f,0.f,0.f};

    for (int kt=0; kt<18; ++kt) {
      int k0 = kt*32 + g*8;
      int s = k0 >> 6;
      int icg = (k0 - (s<<6)) >> 3;
      int roff = (s/3)*33 + (s - (s/3)*3);
      bf16x8 bf[3];
#pragma unroll
      for (int pt=0; pt<3; ++pt) {
        int rowi = pbase[pt] + roff;
        int ds = icg ^ (rowi & 7);
        bf[pt] = *reinterpret_cast<const bf16x8*>(&bufIn[rowi*64 + ds*8]);
      }
#pragma unroll
      for (int o=0; o<4; ++o) {
        bf16x8 af = *reinterpret_cast<const bf16x8*>(Wp1 + ((size_t)(o*18+kt)*64 + l)*8);
#pragma unroll
        for (int pt=0; pt<3; ++pt)
          a1[o][pt] = __builtin_amdgcn_mfma_f32_16x16x32_bf16(af, bf[pt], a1[o][pt], 0,0,0);
      }
    }
#pragma unroll
    for (int o=0; o<4; ++o) {
      float4 bv4 = *reinterpret_cast<const float4*>(B1 + o*16 + g*4);
      int sl = o*2 + (g>>1);
#pragma unroll
      for (int pt=0; pt<3; ++pt) {
        if (!pv[pt]) continue;
        float v0 = gelu_f(a1[o][pt][0] + bv4.x);
        float v1 = gelu_f(a1[o][pt][1] + bv4.y);
        float v2 = gelu_f(a1[o][pt][2] + bv4.z);
        float v3 = gelu_f(a1[o][pt][3] + bv4.w);
        uint2 pk;
        pk.x = (unsigned)f2bf(v0) | ((unsigned)f2bf(v1)<<16);
        pk.y = (unsigned)f2bf(v2) | ((unsigned)f2bf(v3)<<16);
        int phys = sl ^ (rowB[pt] & 7);
        *reinterpret_cast<uint2*>(&bufC1[rowB[pt]*64 + phys*8 + (g&1)*4]) = pk;
      }
    }
  }
  __syncthreads();

  for (int u=t; u<330*8; u+=512)
    *reinterpret_cast<uint4*>(bufC2 + u*8) = z4;
  __syncthreads();

  // ---- c2 ----
  {
    int pbase[3], rowB[3]; bool pv[3];
#pragma unroll
    for (int pt=0; pt<3; ++pt) {
      int pd = (w*3+pt)*16 + l15;
      int pc = min(pd, 309);
      int ry = pc/31, rx = pc - ry*31;
      pbase[pt] = ry*33 + rx;
      rowB[pt] = ry*33 + rx + 1;
      int yab = y0 - 1 + ry;
      pv[pt] = (pd < 310) && ((unsigned)yab < 31u);
    }
    f32x4 a2[4][3];
#pragma unroll
    for (int o=0;o<4;++o)
#pragma unroll
      for (int pt=0;pt<3;++pt) a2[o][pt] = (f32x4){0.f,0.f,0.f,0.f};

    for (int kt=0; kt<18; ++kt) {
      int k0 = kt*32 + g*8;
      int s = k0 >> 6;
      int icg = (k0 - (s<<6)) >> 3;
      int roff = (s/3)*33 + (s - (s/3)*3);
      bf16x8 bf[3];
#pragma unroll
      for (int pt=0; pt<3; ++pt) {
        int rowi = pbase[pt] + roff;
        int ds = icg ^ (rowi & 7);
        bf[pt] = *reinterpret_cast<const bf16x8*>(&bufC1[rowi*64 + ds*8]);
      }
#pragma unroll
      for (int o=0; o<4; ++o) {
        bf16x8 af = *reinterpret_cast<const bf16x8*>(Wp2 + ((size_t)(o*18+kt)*64 + l)*8);
#pragma unroll
        for (int pt=0; pt<3; ++pt)
          a2[o][pt] = __builtin_amdgcn_mfma_f32_16x16x32_bf16(af, bf[pt], a2[o][pt], 0,0,0);
      }
    }
#pragma unroll
    for (int o=0; o<4; ++o) {
      float4 bv4 = *reinterpret_cast<const float4*>(B2 + o*16 + g*4);
      int sl = o*2 + (g>>1);
#pragma unroll
      for (int pt=0; pt<3; ++pt) {
        if (!pv[pt]) continue;
        float v0 = gelu_f(a2[o][pt][0] + bv4.x);
        float v1 = gelu_f(a2[o][pt][1] + bv4.y);
        float v2 = gelu_f(a2[o][pt][2] + bv4.z);
        float v3 = gelu_f(a2[o][pt][3] + bv4.w);
        uint2 pk;
        pk.x = (unsigned)f2bf(v0) | ((unsigned)f2bf(v1)<<16);
        pk.y = (unsigned)f2bf(v2) | ((unsigned)f2bf(v3)<<16);
        int phys = sl ^ (rowB[pt] & 7);
        *reinterpret_cast<uint2*>(&bufC2[rowB[pt]*64 + phys*8 + (g&1)*4]) = pk;
      }
    }
  }
  __syncthreads();

  // ---- c3 ----
  {
    int pbase[2], gpos[2]; bool pv[2];
#pragma unroll
    for (int pt=0; pt<2; ++pt) {
      int pd = (w*2+pt)*16 + l15;
      int pc = min(pd, 247);
      int ry = pc/31, rx = pc - ry*31;
      pbase[pt] = ry*33 + rx;
      gpos[pt] = y0*31 + pd;
      pv[pt] = (pd < 248) && (gpos[pt] < 961);
    }
    f32x4 a3[2][2];
#pragma unroll
    for (int o=0;o<2;++o)
#pragma unroll
      for (int pt=0;pt<2;++pt) a3[o][pt] = (f32x4){0.f,0.f,0.f,0.f};

    for (int kt=0; kt<18; ++kt) {
      int k0 = kt*32 + g*8;
      int s = k0 >> 6;
      int icg = (k0 - (s<<6)) >> 3;
      int roff = (s/3)*33 + (s - (s/3)*3);
      bf16x8 bf[2];
#pragma unroll
      for (int pt=0; pt<2; ++pt) {
        int rowi = pbase[pt] + roff;
        int ds = icg ^ (rowi & 7);
        bf[pt] = *reinterpret_cast<const bf16x8*>(&bufC2[rowi*64 + ds*8]);
      }
#pragma unroll
      for (int o=0; o<2; ++o) {
        bf16x8 af = *reinterpret_cast<const bf16x8*>(Wp3 + ((size_t)(o*18+kt)*64 + l)*8);
#pragma unroll
        for (int pt=0; pt<2; ++pt)
          a3[o][pt] = __builtin_amdgcn_mfma_f32_16x16x32_bf16(af, bf[pt], a3[o][pt], 0,0,0);
      }
    }
#pragma unroll
    for (int o=0; o<2; ++o) {
      float4 bv4 = *reinterpret_cast<const float4*>(B3 + o*16 + g*4);
#pragma unroll
      for (int pt=0; pt<2; ++pt) {
        if (!pv[pt]) continue;
        float v0 = a3[o][pt][0] + bv4.x;
        float v1 = a3[o][pt][1] + bv4.y;
        float v2 = a3[o][pt][2] + bv4.z;
        float v3 = a3[o][pt][3] + bv4.w;
        uint2 pk;
        pk.x = (unsigned)f2bf(v0) | ((unsigned)f2bf(v1)<<16);
        pk.y = (unsigned)f2bf(v2) | ((unsigned)f2bf(v3)<<16);
        *reinterpret_cast<uint2*>(outI + ((size_t)item*961 + gpos[pt])*32 + o*16 + g*4) = pk;
      }
    }
  }
}

// ---------------------------------------------------------------------------
// Fused decoder v3: 16-row strips, 512 threads, CHANNEL-MAJOR LDS planes
// (conflict-free fragment reads, no XOR). ldsA[4][660][8]; ldsB[4][594][8].
// ---------------------------------------------------------------------------
__global__ __launch_bounds__(512,4) void decfused3_k(
    const unsigned short* __restrict__ intc,
    const unsigned short* __restrict__ Wp1, const float* __restrict__ B1,
    const unsigned short* __restrict__ Wp2, const float* __restrict__ B2,
    const float* __restrict__ film,
    const float* __restrict__ w3, const float* __restrict__ b3,
    float* __restrict__ outf, float* __restrict__ sums)
{
  const int item = blockIdx.x;
  const int y0 = blockIdx.y*16;
  const int t = threadIdx.x;
  const int w = t>>6, l = t&63, g = l>>4, l15 = l&15;

  constexpr int PA = 660;   // 20*33 rows per plane
  constexpr int PB = 594;   // 18*33 rows per plane
  __shared__ __align__(16) unsigned short ldsA[4*PA*8];  // 42,240 B
  __shared__ __align__(16) unsigned short ldsB[4*PB*8];  // 38,016 B

  const int sit = item >> 2;
  const float* frow = film + (size_t)item*64;

  // zero B
  for (int u=t; u<4*PB; u+=512)
    *reinterpret_cast<uint4*>(ldsB + u*8) = (uint4){0,0,0,0};

  // stage A with FiLM + gelu (rows y0-2..y0+17); slot fastest for global coalesce
  for (int u=t; u<PA*4; u+=512) {
    int slot = u & 3;
    int rowi = u >> 2;
    int r = rowi/33, col = rowi - r*33;
    int y = y0 + r - 2, x = col - 1;
    uint4 val = {0,0,0,0};
    if ((unsigned)y < 31u && (unsigned)x < 31u) {
      val = *reinterpret_cast<const uint4*>(intc + ((size_t)sit*961 + y*31 + x)*32 + slot*8);
      int c0 = slot*8;
      float4 g0 = *reinterpret_cast<const float4*>(frow + c0);
      float4 g1 = *reinterpret_cast<const float4*>(frow + c0 + 4);
      float4 b0 = *reinterpret_cast<const float4*>(frow + 32 + c0);
      float4 b1 = *reinterpret_cast<const float4*>(frow + 32 + c0 + 4);
      unsigned short x8[8] = {
        (unsigned short)(val.x&0xffff),(unsigned short)(val.x>>16),
        (unsigned short)(val.y&0xffff),(unsigned short)(val.y>>16),
        (unsigned short)(val.z&0xffff),(unsigned short)(val.z>>16),
        (unsigned short)(val.w&0xffff),(unsigned short)(val.w>>16)};
      unsigned short o8[8];
      o8[0]=f2bf(gelu_f(fmaf(bf2f(x8[0]), 1.f+g0.x, b0.x)));
      o8[1]=f2bf(gelu_f(fmaf(bf2f(x8[1]), 1.f+g0.y, b0.y)));
      o8[2]=f2bf(gelu_f(fmaf(bf2f(x8[2]), 1.f+g0.z, b0.z)));
      o8[3]=f2bf(gelu_f(fmaf(bf2f(x8[3]), 1.f+g0.w, b0.w)));
      o8[4]=f2bf(gelu_f(fmaf(bf2f(x8[4]), 1.f+g1.x, b1.x)));
      o8[5]=f2bf(gelu_f(fmaf(bf2f(x8[5]), 1.f+g1.y, b1.y)));
      o8[6]=f2bf(gelu_f(fmaf(bf2f(x8[6]), 1.f+g1.z, b1.z)));
      o8[7]=f2bf(gelu_f(fmaf(bf2f(x8[7]), 1.f+g1.w, b1.w)));
      val.x = (unsigned)o8[0] | ((unsigned)o8[1]<<16);
      val.y = (unsigned)o8[2] | ((unsigned)o8[3]<<16);
      val.z = (unsigned)o8[4] | ((unsigned)o8[5]<<16);
      val.w = (unsigned)o8[6] | ((unsigned)o8[7]<<16);
    }
    *reinterpret_cast<uint4*>(&ldsA[((size_t)slot*PA + rowi)*8]) = val;
  }
  __syncthreads();

  // ---- dec1: 18 rows x 31 cols (558 pos, 40 tiles, 5/wave), gelu -> ldsB ----
  {
    int pbase[5], rowB[5]; bool pv[5];
#pragma unroll
    for (int pt=0; pt<5; ++pt) {
      int pd = (w*5+pt)*16 + l15;
      int pc = min(pd, 557);
      int ry = pc/31, rx = pc - ry*31;
      pbase[pt] = ry*33 + rx;
      rowB[pt] = ry*33 + rx + 1;
      int gy = y0 - 1 + ry;
      pv[pt] = (pd < 558) && ((unsigned)gy < 31u);
    }
    f32x4 a1[2][5];
#pragma unroll
    for (int o=0;o<2;++o)
#pragma unroll
      for (int pt=0;pt<5;++pt) a1[o][pt] = (f32x4){0.f,0.f,0.f,0.f};

    for (int kt=0; kt<9; ++kt) {
      int roff = (kt/3)*33 + (kt - (kt/3)*3);
      bf16x8 bf[5];
#pragma unroll
      for (int pt=0; pt<5; ++pt) {
        int rowi = pbase[pt] + roff;
        bf[pt] = *reinterpret_cast<const bf16x8*>(&ldsA[((size_t)g*PA + rowi)*8]);
      }
#pragma unroll
      for (int o=0; o<2; ++o) {
        bf16x8 af = *reinterpret_cast<const bf16x8*>(Wp1 + ((size_t)(o*9+kt)*64 + l)*8);
#pragma unroll
        for (int pt=0; pt<5; ++pt)
          a1[o][pt] = __builtin_amdgcn_mfma_f32_16x16x32_bf16(af, bf[pt], a1[o][pt], 0,0,0);
      }
    }
#pragma unroll
    for (int o=0; o<2; ++o) {
      float4 bv4 = *reinterpret_cast<const float4*>(B1 + o*16 + g*4);
      int sl = o*2 + (g>>1);
#pragma unroll
      for (int pt=0; pt<5; ++pt) {
        if (!pv[pt]) continue;
        float v0 = gelu_f(a1[o][pt][0] + bv4.x);
        float v1 = gelu_f(a1[o][pt][1] + bv4.y);
        float v2 = gelu_f(a1[o][pt][2] + bv4.z);
        float v3 = gelu_f(a1[o][pt][3] + bv4.w);
        uint2 pk;
        pk.x = (unsigned)f2bf(v0) | ((unsigned)f2bf(v1)<<16);
        pk.y = (unsigned)f2bf(v2) | ((unsigned)f2bf(v3)<<16);
        *reinterpret_cast<uint2*>(&ldsB[((size_t)sl*PB + rowB[pt])*8 + (g&1)*4]) = pk;
      }
    }
  }
  __syncthreads();

  // ---- dec2 + gelu + dec3(1x1) + softplus + per-map sum ----
  float bsum = 0.f;
  {
    int pbase[4], gpos[4]; bool pv[4];
#pragma unroll
    for (int pt=0; pt<4; ++pt) {
      int pd = (w*4+pt)*16 + l15;
      int pc = min(pd, 495);
      int py = pc/31, px = pc - py*31;
      pbase[pt] = py*33 + px;
      gpos[pt] = y0*31 + pd;
      pv[pt] = (pd < 496) && (gpos[pt] < 961);
    }
    f32x4 a2[2][4];
#pragma unroll
    for (int o=0;o<2;++o)
#pragma unroll
      for (int pt=0;pt<4;++pt) a2[o][pt] = (f32x4){0.f,0.f,0.f,0.f};

    for (int kt=0; kt<9; ++kt) {
      int roff = (kt/3)*33 + (kt - (kt/3)*3);
      bf16x8 bf[4];
#pragma unroll
      for (int pt=0; pt<4; ++pt) {
        int rowi = pbase[pt] + roff;
        bf[pt] = *reinterpret_cast<const bf16x8*>(&ldsB[((size_t)g*PB + rowi)*8]);
      }
#pragma unroll
      for (int o=0; o<2; ++o) {
        bf16x8 af = *reinterpret_cast<const bf16x8*>(Wp2 + ((size_t)(o*9+kt)*64 + l)*8);
#pragma unroll
        for (int pt=0; pt<4; ++pt)
          a2[o][pt] = __builtin_amdgcn_mfma_f32_16x16x32_bf16(af, bf[pt], a2[o][pt], 0,0,0);
      }
    }

    float w3r[8];
#pragma unroll
    for (int o=0;o<2;++o) {
      float4 wv = *reinterpret_cast<const float4*>(w3 + o*16 + g*4);
      w3r[o*4+0]=wv.x; w3r[o*4+1]=wv.y; w3r[o*4+2]=wv.z; w3r[o*4+3]=wv.w;
    }
    float b3v = b3[0];
#pragma unroll
    for (int pt=0; pt<4; ++pt) {
      float part = 0.f;
#pragma unroll
      for (int o=0; o<2; ++o) {
        float4 bv4 = *reinterpret_cast<const float4*>(B2 + o*16 + g*4);
        float v0 = gelu_f(a2[o][pt][0] + bv4.x);
        float v1 = gelu_f(a2[o][pt][1] + bv4.y);
        float v2 = gelu_f(a2[o][pt][2] + bv4.z);
        float v3 = gelu_f(a2[o][pt][3] + bv4.w);
        part += v0*w3r[o*4+0] + v1*w3r[o*4+1] + v2*w3r[o*4+2] + v3*w3r[o*4+3];
      }
      part += __shfl_xor(part, 16);
      part += __shfl_xor(part, 32);
      float sp = softplus_f(part + b3v);
      if (pv[pt] && g==0) {
        outf[(size_t)item*961 + gpos[pt]] = sp;
        bsum += sp;
      }
    }
  }
  // block reduce into sums[item]
  {
    float* redf = reinterpret_cast<float*>(ldsA);
    redf[t] = bsum;
    __syncthreads();
    for (int off=256; off>0; off>>=1) {
      if (t < off) redf[t] += redf[t+off];
      __syncthreads();
    }
    if (t==0) atomicAdd(&sums[item], redf[0]);
  }
}

// ---------------------------------------------------------------------------
// Fused bottleneck-window gather + depthwise 7x7, channel-sliced, row-reuse.
// ---------------------------------------------------------------------------
__global__ __launch_bounds__(256,4) void dwfused4_k(
    const float* __restrict__ bott, const float* __restrict__ spv,
    const float* __restrict__ wT, const float* __restrict__ b,
    unsigned short* __restrict__ bwinT, unsigned short* __restrict__ dwout)
{
  const int n = blockIdx.x, cs = blockIdx.y*64, t = threadIdx.x;
  __shared__ float tile[121*66];

  float pxf = fminf(fmaxf(spv[n*2+0]*0.25f, 0.f), 255.f);
  float pyf = fminf(fmaxf(spv[n*2+1]*0.25f, 0.f), 255.f);
  int cx = (int)rintf(pxf), cy = (int)rintf(pyf);

  for (int idx=t; idx<121*32; idx+=256) {
    int j = idx/121, p = idx - j*121;
    int y = p/11, x = p - y*11;
    int gy = min(max(cy + y - 5, 0), 255);
    int gx = min(max(cx + x - 5, 0), 255);
    const float* s0 = bott + ((size_t)(cs+2*j)<<16) + (gy<<8) + gx;
    *reinterpret_cast<float2*>(&tile[p*66 + 2*j]) = (float2){s0[0], s0[65536]};
  }
  __syncthreads();

  for (int idx=t; idx<121*64; idx+=256) {
    int p = idx >> 6, c = idx & 63;
    bwinT[((size_t)n*121 + p)*256 + cs + c] = f2bf(tile[p*66 + c]);
  }

  const int c = t & 63, ph = t >> 6;
  const int ch = cs + c;
  const float bias = b[ch];

  for (int y=ph; y<11; y+=4) {
    float acc[11];
#pragma unroll
    for (int x=0;x<11;++x) acc[x] = bias;
#pragma unroll
    for (int dy=0; dy<7; ++dy) {
      int yy = y + dy - 3;
      if ((unsigned)yy < 11u) {
        float r[11];
#pragma unroll
        for (int k=0;k<11;++k) r[k] = tile[(yy*11+k)*66 + c];
        float w7[7];
#pragma unroll
        for (int j=0;j<7;++j) w7[j] = wT[(dy*7+j)*256 + ch];
#pragma unroll
        for (int x=0;x<11;++x) {
#pragma unroll
          for (int dx=0;dx<7;++dx) {
            int xx = x + dx - 3;
            if (xx >= 0 && xx < 11)
              acc[x] = fmaf(r[xx], w7[dx], acc[x]);
          }
        }
      }
    }
#pragma unroll
    for (int x=0;x<11;++x)
      dwout[((size_t)n*121 + y*11 + x)*256 + ch] = f2bf(acc[x]);
  }
}

// ---------------------------------------------------------------------------
// Fused ConvNeXt MLP + bnp head, bf16 MFMA. 512 threads / 8 waves, 64 rows.
// ---------------------------------------------------------------------------
__global__ __launch_bounds__(512,4) void cnx_mfma3_k(
    const unsigned short* __restrict__ xin,
    const float* __restrict__ lnw, const float* __restrict__ lnb,
    const unsigned short* __restrict__ W1p, const float* __restrict__ B1,
    const unsigned short* __restrict__ W2p, const float* __restrict__ B2,
    const float* __restrict__ gvec,
    const unsigned short* __restrict__ bwinT,
    const unsigned short* __restrict__ Wbp, const float* __restrict__ bnpb,
    float* __restrict__ bnv, float inv_gsum)
{
  const int t = threadIdx.x;
  const int w = t >> 6;
  const int l = t & 63;
  const int g = l >> 4;
  const int l15 = l & 15;
  const int row0 = blockIdx.x * 64;

  __shared__ __align__(16) unsigned short xs[64*264];
  __shared__ __align__(16) unsigned short hs[64*136];

  {
    const int rl = t >> 3, q = t & 7;
    const unsigned short* xr = xin + (size_t)(row0+rl)*256 + q*32;
    float xv[32]; float s = 0.f, s2 = 0.f;
#pragma unroll
    for (int i=0;i<32;i+=8){
      uint4 v = *reinterpret_cast<const uint4*>(xr+i);
      unsigned short xh[8] = {
        (unsigned short)(v.x&0xffff),(unsigned short)(v.x>>16),
        (unsigned short)(v.y&0xffff),(unsigned short)(v.y>>16),
        (unsigned short)(v.z&0xffff),(unsigned short)(v.z>>16),
        (unsigned short)(v.w&0xffff),(unsigned short)(v.w>>16)};
#pragma unroll
      for (int j=0;j<8;++j){
        float f = bf2f(xh[j]);
        xv[i+j] = f; s += f; s2 += f*f;
      }
    }
    s += __shfl_xor(s,1); s2 += __shfl_xor(s2,1);
    s += __shfl_xor(s,2); s2 += __shfl_xor(s2,2);
    s += __shfl_xor(s,4); s2 += __shfl_xor(s2,4);
    float mu = s*(1.f/256.f);
    float rstd = rsqrtf(s2*(1.f/256.f) - mu*mu + 1e-6f);
#pragma unroll
    for (int i=0;i<32;i+=8){
      int c = q*32 + i;
      float4 w0 = *reinterpret_cast<const float4*>(lnw+c);
      float4 w1 = *reinterpret_cast<const float4*>(lnw+c+4);
      float4 b0 = *reinterpret_cast<const float4*>(lnb+c);
      float4 b1 = *reinterpret_cast<const float4*>(lnb+c+4);
      unsigned short h[8];
      h[0]=f2bf(fmaf((xv[i+0]-mu)*rstd, w0.x, b0.x));
      h[1]=f2bf(fmaf((xv[i+1]-mu)*rstd, w0.y, b0.y));
      h[2]=f2bf(fmaf((xv[i+2]-mu)*rstd, w0.z, b0.z));
      h[3]=f2bf(fmaf((xv[i+3]-mu)*rstd, w0.w, b0.w));
      h[4]=f2bf(fmaf((xv[i+4]-mu)*rstd, w1.x, b1.x));
      h[5]=f2bf(fmaf((xv[i+5]-mu)*rstd, w1.y, b1.y));
      h[6]=f2bf(fmaf((xv[i+6]-mu)*rstd, w1.z, b1.z));
      h[7]=f2bf(fmaf((xv[i+7]-mu)*rstd, w1.w, b1.w));
      uint4 pk;
      pk.x = (unsigned)h[0] | ((unsigned)h[1]<<16);
      pk.y = (unsigned)h[2] | ((unsigned)h[3]<<16);
      pk.z = (unsigned)h[4] | ((unsigned)h[5]<<16);
      pk.w = (unsigned)h[6] | ((unsigned)h[7]<<16);
      *reinterpret_cast<uint4*>(&xs[rl*264 + c]) = pk;
    }
  }
  __syncthreads();

  f32x4 acc2[8];
#pragma unroll
  for (int i=0;i<8;++i) acc2[i] = (f32x4){0.f,0.f,0.f,0.f};

  for (int hc=0; hc<8; ++hc) {
    const int ht = hc*8 + w;
    f32x4 acc1[4];
#pragma unroll
    for (int i=0;i<4;++i) acc1[i] = (f32x4){0.f,0.f,0.f,0.f};

#pragma unroll
    for (int kt=0; kt<8; ++kt) {
      bf16x8 xf[4];
#pragma unroll
      for (int rt=0; rt<4; ++rt)
        xf[rt] = *reinterpret_cast<const bf16x8*>(&xs[(rt*16+l15)*264 + kt*32 + g*8]);
      bf16x8 wf = *reinterpret_cast<const bf16x8*>(W1p + ((size_t)(ht*8+kt)*64 + l)*8);
#pragma unroll
      for (int rt=0; rt<4; ++rt)
        acc1[rt] = __builtin_amdgcn_mfma_f32_16x16x32_bf16(wf, xf[rt], acc1[rt], 0,0,0);
    }
    {
      const int hb = hc*128 + w*16 + 4*g;
      float4 b1v = *reinterpret_cast<const float4*>(B1 + hb);
#pragma unroll
      for (int rt=0; rt<4; ++rt) {
        unsigned short h0 = f2bf(gelu_f(acc1[rt][0] + b1v.x));
        unsigned short h1 = f2bf(gelu_f(acc1[rt][1] + b1v.y));
        unsigned short h2 = f2bf(gelu_f(acc1[rt][2] + b1v.z));
        unsigned short h3 = f2bf(gelu_f(acc1[rt][3] + b1v.w));
        uint2 pk;
        pk.x = (unsigned)h0 | ((unsigned)h1<<16);
        pk.y = (unsigned)h2 | ((unsigned)h3<<16);
        *reinterpret_cast<uint2*>(&hs[(rt*16+l15)*136 + w*16 + 4*g]) = pk;
      }
    }
    __syncthreads();
#pragma unroll
    for (int kt=0; kt<4; ++kt) {
      bf16x8 hf[4];
#pragma unroll
      for (int rt=0; rt<4; ++rt)
        hf[rt] = *reinterpret_cast<const bf16x8*>(&hs[(rt*16+l15)*136 + kt*32 + g*8]);
#pragma unroll
      for (int cj=0; cj<2; ++cj) {
        const int ct = 2*w + cj;
        bf16x8 wf = *reinterpret_cast<const bf16x8*>(W2p + ((size_t)(ct*32 + hc*4 + kt)*64 + l)*8);
#pragma unroll
        for (int rt=0; rt<4; ++rt)
          acc2[cj*4+rt] = __builtin_amdgcn_mfma_f32_16x16x32_bf16(hf[rt], wf, acc2[cj*4+rt], 0,0,0);
      }
    }
    __syncthreads();
  }

#pragma unroll
  for (int cj=0; cj<2; ++cj) {
    const int c = (2*w+cj)*16 + l15;
    const float b2 = B2[c], gm = gvec[c];
#pragma unroll
    for (int rt=0; rt<4; ++rt) {
#pragma unroll
      for (int reg=0; reg<4; ++reg) {
        int row = rt*16 + 4*g + reg;
        float res = bf2f(bwinT[(size_t)(row0+row)*256 + c]) + (acc2[cj*4+rt][reg] + b2)*gm;
        xs[row*264 + c] = f2bf(res);
      }
    }
  }
  __syncthreads();

  {
    const int oct = w & 3;
    f32x4 abn[2];
#pragma unroll
    for (int i=0;i<2;++i) abn[i] = (f32x4){0.f,0.f,0.f,0.f};
#pragma unroll
    for (int kt=0; kt<8; ++kt) {
      bf16x8 bfw = *reinterpret_cast<const bf16x8*>(Wbp + ((size_t)(oct*8+kt)*64 + l)*8);
#pragma unroll
      for (int i=0;i<2;++i) {
        const int rt = (w>>2) + 2*i;
        bf16x8 af = *reinterpret_cast<const bf16x8*>(&xs[(rt*16+l15)*264 + kt*32 + g*8]);
        abn[i] = __builtin_amdgcn_mfma_f32_16x16x32_bf16(af, bfw, abn[i], 0,0,0);
      }
    }

    float* red = reinterpret_cast<float*>(hs);
#pragma unroll
    for (int i=0;i<2;++i) {
      const int rt = (w>>2) + 2*i;
      float bv = bnpb[oct*16 + l15];
#pragma unroll
      for (int reg=0; reg<4; ++reg) {
        int lr = rt*16 + g*4 + reg;
        int p = (row0 + lr) % 121;
        int py=p/11, px=p-py*11;
        float ly=-1.f+0.2f*py, lx=-1.f+0.2f*px;
        float wg = __expf(-(lx*lx+ly*ly)/0.32f) * inv_gsum;
        red[lr*64 + oct*16 + l15] = gelu_f(abn[i][reg] + bv) * wg;
      }
    }
  }
  __syncthreads();
  {
    float* red = reinterpret_cast<float*>(hs);
    int oc = t & 63, seg = t >> 6;
    float s = 0.f;
    int curn = (row0 + seg*8) / 121;
    for (int i=0;i<8;++i) {
      int row = seg*8 + i;
      int n = (row0 + row) / 121;
      if (n != curn) { atomicAdd(&bnv[curn*64 + oc], s); s = 0.f; curn = n; }
      s += red[row*64 + oc];
    }
    atomicAdd(&bnv[curn*64 + oc], s);
  }
}

// ---------------------------------------------------------------------------
// FiLM
// ---------------------------------------------------------------------------
__global__ __launch_bounds__(256) void film_k(
    const float* __restrict__ bn_vec, const float* __restrict__ ppb,
    const float* __restrict__ bemb, const float* __restrict__ fw,
    const float* __restrict__ fb, float* __restrict__ film)
{
  int n = blockIdx.x, t = threadIdx.x;
  __shared__ float cond[4][84];
  for (int i=t; i<4*84; i+=256) {
    int b = i/84, j = i%84;
    float v;
    if (j < 16) v = bemb[b*16 + j];
    else if (j == 16) { float p = ppb[((size_t)n*4+b)*2+0]; v = fminf(fmaxf(p*(1.f/1023.f),0.f),1.f); }
    else if (j == 17) { float p = ppb[((size_t)n*4+b)*2+1]; v = fminf(fmaxf(p*(1.f/1023.f),0.f),1.f); }
    else if (j == 18) { float p = ppb[((size_t)n*4+b)*2+0]; v = p - rintf(p); }
    else if (j == 19) { float p = ppb[((size_t)n*4+b)*2+1]; v = p - rintf(p); }
    else v = bn_vec[n*64 + (j-20)];
    cond[b][j] = v;
  }
  __syncthreads();
  int b = t >> 6, oc = t & 63;
  float s = fb[oc];
  for (int j=0;j<84;++j) s = fmaf(cond[b][j], fw[oc*84+j], s);
  film[((size_t)n*4+b)*64 + oc] = s;
}

// ---------------------------------------------------------------------------
// final per-map normalization
// ---------------------------------------------------------------------------
__global__ __launch_bounds__(256) void norm_k(float* __restrict__ out,
                                              const float* __restrict__ sums)
{
  int il = blockIdx.x;
  int p = blockIdx.y*256 + threadIdx.x;
  if (p < 961) {
    float inv = 1.f / fmaxf(sums[il], 1e-8f);
    out[(size_t)il*961 + p] *= inv;
  }
}

// ---------------------------------------------------------------------------
extern "C" void kernel_launch(void* const* d_in, const int* in_sizes, int n_in,
                              void* d_out, int out_size, void* d_ws, size_t ws_size,
                              hipStream_t stream)
{
  const float* bott = (const float*)d_in[0];
  const float* vis  = (const float*)d_in[1];
  const float* spv  = (const float*)d_in[2];
  const float* ppb  = (const float*)d_in[3];
  const float* ic1w = (const float*)d_in[4];  const float* ic1b = (const float*)d_in[5];
  const float* ic2w = (const float*)d_in[6];  const float* ic2b = (const float*)d_in[7];
  const float* ic3w = (const float*)d_in[8];  const float* ic3b = (const float*)d_in[9];
  const float* dww  = (const float*)d_in[10]; const float* dwb  = (const float*)d_in[11];
  const float* lnw  = (const float*)d_in[12]; const float* lnb  = (const float*)d_in[13];
  const float* pw1w = (const float*)d_in[14]; const float* pw1b = (const float*)d_in[15];
  const float* pw2w = (const float*)d_in[16]; const float* pw2b = (const float*)d_in[17];
  const float* cgam = (const float*)d_in[18];
  const float* bnpw = (const float*)d_in[19]; const float* bnpb = (const float*)d_in[20];
  const float* bemb = (const float*)d_in[21];
  const float* fw   = (const float*)d_in[22]; const float* fb   = (const float*)d_in[23];
  const float* d1w  = (const float*)d_in[24]; const float* d1b  = (const float*)d_in[25];
  const float* d2w  = (const float*)d_in[26]; const float* d2b  = (const float*)d_in[27];
  const float* d3w  = (const float*)d_in[28]; const float* d3b  = (const float*)d_in[29];
  float* out = (float*)d_out;

  char* ws = (char*)d_ws;

  unsigned short* bwinT = (unsigned short*)(ws);
  unsigned short* dwout = (unsigned short*)(ws + 31719424);
  unsigned short* vwin  = (unsigned short*)(ws);
  unsigned short* bufI  = (unsigned short*)(ws + 71368704);
  size_t tail = 102858752;

  float* bnv  = (float*)(ws + tail);
  float* sums = (float*)(ws + tail + 131072);
  float* film = (float*)(ws + tail + 139264);
  unsigned short* W1p = (unsigned short*)(ws + tail + 663552);
  unsigned short* W2p = (unsigned short*)(ws + tail + 1187840);
  unsigned short* Wbp = (unsigned short*)(ws + tail + 1712128);
  unsigned short* Pc1 = (unsigned short*)(ws + tail + 1744896);
  unsigned short* Pc2 = (unsigned short*)(ws + tail + 1818624);
  unsigned short* Pc3 = (unsigned short*)(ws + tail + 1892352);
  unsigned short* Pd1 = (unsigned short*)(ws + tail + 1929216);
  unsigned short* Pd2 = (unsigned short*)(ws + tail + 1947648);
  float* dwwT = (float*)(ws + tail + 1966080);

  {
    PackJobs J;
    const float* srcs[8] = {pw1w, pw2w, bnpw, ic1w, ic2w, ic3w, d1w, d2w};
    unsigned short* dsts[8] = {W1p, W2p, Wbp, Pc1, Pc2, Pc3, Pd1, Pd2};
    int ntns[8] = {64,16,4, 4,4,2, 2,2};
    int ntks[8] = {8,32,8, 18,18,18, 9,9};
    int Ks[8]   = {256,1024,256, 64,64,64, 32,32};
    int convs[8]= {0,0,0, 1,1,1, 1,1};
    int base = 0;
    for (int i=0;i<8;++i) {
      J.src[i]=srcs[i]; J.dst[i]=dsts[i]; J.ntn[i]=ntns[i]; J.ntk[i]=ntks[i];
      J.K[i]=Ks[i]; J.conv[i]=convs[i]; J.base[i]=base;
      base += (ntns[i]*ntks[i]*64 + 255)/256;
    }
    packall_k<<<base,256,0,stream>>>(J);
  }
  dwt_k<<<49,256,0,stream>>>(dww, dwwT);

  hipMemsetAsync(ws + tail, 0, 139264, stream);  // bnv + sums

  float gs = 0.f;
  for (int py=0; py<11; ++py) for (int px=0; px<11; ++px) {
    float ly=-1.f+0.2f*py, lx=-1.f+0.2f*px;
    gs += expf(-(lx*lx+ly*ly)/0.32f);
  }
  const float inv_gsum = 1.f/gs;

  // ---- Phase 2: bottleneck path -> bn_vec -> film ----
  dwfused4_k<<<dim3(512,4),256,0,stream>>>(bott, spv, dwwT, dwb, bwinT, dwout);
  cnx_mfma3_k<<<968,512,0,stream>>>(dwout, lnw,lnb, W1p,pw1b, W2p,pw2b, cgam,
                                    bwinT, Wbp, bnpb, bnv, inv_gsum);
  film_k<<<512,256,0,stream>>>(bnv, ppb, bemb, fw, fb, film);

  // ---- Phase 1+3: window extract -> fused conv chain -> fused decoder ----
  extvwin_k<<<dim3(512,5),256,0,stream>>>(vis, spv, vwin);
  convchain_k<<<dim3(512,4),512,0,stream>>>(vwin, Pc1,ic1b, Pc2,ic2b, Pc3,ic3b, bufI);
  decfused3_k<<<dim3(2048,2),512,0,stream>>>(bufI, Pd1,d1b, Pd2,d2b,
      film, d3w, d3b, out, sums);
  norm_k<<<dim3(2048,4),256,0,stream>>>(out, sums);
}